// Round 1
// baseline (3219.782 us; speedup 1.0000x reference)
//
#include <hip/hip_runtime.h>
#include <hip/hip_bf16.h>

#define N_NODES 100000
#define N_EDGESC 1600000
#define BATCH_B 16
#define NMAXC 4096
#define LATC 64

// output layout offsets (flat f32)
#define OUT_NODES 0
#define OUT_EDGES 65536
#define OUT_FUEL  589824
#define OUT_ALT   917504
#define OUT_SLOPE 983040
#define OUT_MU    1048576
#define OUT_LG    1049600

__global__ void hist_kernel(const int* __restrict__ idx, int* __restrict__ cnt, int n) {
    int i = blockIdx.x * blockDim.x + threadIdx.x;
    if (i < n) atomicAdd(&cnt[idx[i]], 1);
}

// single-block exclusive scan of deg[0..n) -> offs[0..n], also copies into cursor
__global__ void scan_kernel(const int* __restrict__ deg, int* __restrict__ offs,
                            int* __restrict__ cursor, int n) {
    __shared__ int part[1024];
    int tid = threadIdx.x;
    int chunk = (n + 1023) >> 10;
    int s0 = tid * chunk;
    int s1 = min(s0 + chunk, n);
    int s = 0;
    for (int i = s0; i < s1; i++) s += deg[i];
    part[tid] = s;
    __syncthreads();
    for (int off = 1; off < 1024; off <<= 1) {
        int v = (tid >= off) ? part[tid - off] : 0;
        __syncthreads();
        part[tid] += v;
        __syncthreads();
    }
    int run = part[tid] - s;  // exclusive prefix
    for (int i = s0; i < s1; i++) {
        offs[i] = run; cursor[i] = run; run += deg[i];
    }
    if (tid == 1023) offs[n] = part[1023];
}

__global__ void fill_adj(const int* __restrict__ src, const int* __restrict__ dst,
                         int* __restrict__ cursor, int* __restrict__ adj, int n) {
    int i = blockIdx.x * blockDim.x + threadIdx.x;
    if (i < n) {
        int d = dst[i];
        int p = atomicAdd(&cursor[d], 1);
        adj[p] = src[i];
    }
}

__global__ void dinv_kernel(const int* __restrict__ deg, float* __restrict__ dinv, int n) {
    int i = blockIdx.x * blockDim.x + threadIdx.x;
    if (i < n) dinv[i] = rsqrtf((float)(deg[i] + 1));  // +1 = self loop
}

// hws[n,f] = dinv[n] * sum_k in[n,k] * W[k,f]
template <int K, int F, int RPB>
__global__ void matmul_scale(const float* __restrict__ in, const float* __restrict__ W,
                             const float* __restrict__ dinv, float* __restrict__ out, int N) {
    __shared__ float Ws[K * F];
    __shared__ float xs[RPB][K];
    int tid = threadIdx.x;
    for (int i = tid; i < K * F; i += 256) Ws[i] = W[i];
    int node0 = blockIdx.x * RPB;
    for (int i = tid; i < RPB * K; i += 256) {
        int r = i / K, k = i % K;
        int n = node0 + r;
        xs[r][k] = (n < N) ? in[(size_t)n * K + k] : 0.f;
    }
    __syncthreads();
    int r = tid / F, f = tid % F;
    int n = node0 + r;
    if (n < N) {
        float acc = 0.f;
#pragma unroll
        for (int k = 0; k < K; k++) acc += xs[r][k] * Ws[k * F + f];
        out[(size_t)n * F + f] = acc * dinv[n];
    }
}

// out[n,f] = relu(dinv[n]*(hws[n,f] + sum_{e} hws[adj[e],f]) + b[f])
template <int F>
__global__ void aggregate(const float* __restrict__ hws, const int* __restrict__ offs,
                          const int* __restrict__ adj, const float* __restrict__ dinv,
                          const float* __restrict__ bias, float* __restrict__ out, int N) {
    int n = blockIdx.x;
    int f = threadIdx.x;
    float s = hws[(size_t)n * F + f];
    int e0 = offs[n], e1 = offs[n + 1];
    for (int e = e0; e < e1; e++) {
        int sn = adj[e];
        s += hws[(size_t)sn * F + f];
    }
    out[(size_t)n * F + f] = fmaxf(dinv[n] * s + bias[f], 0.f);
}

#define POOL_CHUNK 128
__global__ void pool_kernel(const float* __restrict__ h, const int* __restrict__ batch,
                            float* __restrict__ sums, int n) {
    int f = threadIdx.x;  // 0..63
    int s0 = blockIdx.x * POOL_CHUNK;
    if (s0 >= n) return;
    int s1 = min(s0 + POOL_CHUNK, n);
    int cur = batch[s0];
    float acc = 0.f;
    for (int i = s0; i < s1; i++) {
        int b = batch[i];
        if (b != cur) { atomicAdd(&sums[cur * 64 + f], acc); acc = 0.f; cur = b; }
        acc += h[(size_t)i * 64 + f];
    }
    atomicAdd(&sums[cur * 64 + f], acc);
}

__global__ void finalize_pool(const float* __restrict__ sum_mu, const float* __restrict__ sum_lg,
                              const int* __restrict__ bcnt, float* __restrict__ out,
                              float* __restrict__ zbuf) {
    int i = threadIdx.x;  // 1024 threads
    int b = i >> 6;
    float c = fmaxf((float)bcnt[b], 1.f);
    float m = sum_mu[i] / c;
    float l = sum_lg[i] / c;
    out[OUT_MU + i] = m;
    out[OUT_LG + i] = l;
    zbuf[i] = m;
}

__global__ void decoder_kernel(const float* __restrict__ z, const float* __restrict__ pos_all,
                               const float* __restrict__ nm_wi, const float* __restrict__ nm_bi,
                               const float* __restrict__ nm_g, const float* __restrict__ nm_be,
                               const float* __restrict__ nm_wo, const float* __restrict__ nm_bo,
                               const float* __restrict__ ex_w, const float* __restrict__ ex_b,
                               const float* __restrict__ fu_w, const float* __restrict__ fu_b,
                               const float* __restrict__ al_w, const float* __restrict__ al_b,
                               const float* __restrict__ sl_w, const float* __restrict__ sl_b,
                               const float* __restrict__ em_wi, const float* __restrict__ em_bi,
                               const float* __restrict__ em_g, const float* __restrict__ em_be,
                               const float* __restrict__ em_wo, const float* __restrict__ em_bo,
                               float* __restrict__ out) {
    int row = blockIdx.x;             // 0..65535
    int b = row >> 12;                // batch
    int i = row & (NMAXC - 1);        // node idx
    int t = threadIdx.x;              // 0..127
    __shared__ float zp[66];
    __shared__ float s1[128];
    __shared__ float h2s[128];
    __shared__ float rA[128];
    __shared__ float rB[128];

    if (t < 64) zp[t] = z[b * 64 + t];
    else if (t < 66) zp[t] = pos_all[i * 2 + (t - 64)];
    __syncthreads();

    // node MLP layer 1
    float a = nm_bi[t];
#pragma unroll
    for (int k = 0; k < 66; k++) a += zp[k] * nm_wi[k * 128 + t];
    rA[t] = a; rB[t] = a * a;
    __syncthreads();
    for (int s = 64; s > 0; s >>= 1) {
        if (t < s) { rA[t] += rA[t + s]; rB[t] += rB[t + s]; }
        __syncthreads();
    }
    float mean = rA[0] * (1.f / 128.f);
    float var = rB[0] * (1.f / 128.f) - mean * mean;
    float sv = fmaxf((a - mean) * rsqrtf(var + 1e-5f) * nm_g[t] + nm_be[t], 0.f);
    __syncthreads();               // rA/rB reads done before reuse; s1 about to be written
    s1[t] = sv;
    __syncthreads();

    // node MLP layer 2
    float h2 = nm_bo[t];
#pragma unroll 8
    for (int k = 0; k < 128; k++) h2 += s1[k] * nm_wo[k * 128 + t];
    h2s[t] = h2;
    __syncthreads();

    // heads: 8 outputs x 16 lanes each
    int j = t >> 4, l16 = t & 15;
    float p = 0.f;
    for (int k = l16; k < 128; k += 16) {
        float hv = h2s[k];
        float w = (j == 0) ? ex_w[k] : (j <= 5) ? fu_w[k * 5 + (j - 1)]
                 : (j == 6) ? al_w[k] : sl_w[k];
        p += hv * w;
    }
    for (int s = 8; s > 0; s >>= 1) p += __shfl_down(p, s, 16);
    if (l16 == 0) {
        if (j == 0)       out[OUT_NODES + row] = p + ex_b[0];
        else if (j <= 5)  out[OUT_FUEL + (size_t)row * 5 + (j - 1)] = p + fu_b[j - 1];
        else if (j == 6)  out[OUT_ALT + row] = p + al_b[0];
        else              out[OUT_SLOPE + row] = p + sl_b[0];
    }

    // edge MLP layer 1
    float e = em_bi[t];
#pragma unroll
    for (int k = 0; k < 66; k++) e += zp[k] * em_wi[k * 128 + t];
    __syncthreads();               // heads done with h2s; nm layer2 done with s1
    rA[t] = e; rB[t] = e * e;
    __syncthreads();
    for (int s = 64; s > 0; s >>= 1) {
        if (t < s) { rA[t] += rA[t + s]; rB[t] += rB[t + s]; }
        __syncthreads();
    }
    float mean2 = rA[0] * (1.f / 128.f);
    float var2 = rB[0] * (1.f / 128.f) - mean2 * mean2;
    float se = fmaxf((e - mean2) * rsqrtf(var2 + 1e-5f) * em_g[t] + em_be[t], 0.f);
    __syncthreads();
    s1[t] = se;
    __syncthreads();

    float p2 = 0.f;
    for (int k = l16; k < 128; k += 16) p2 += s1[k] * em_wo[k * 8 + j];
    for (int s = 8; s > 0; s >>= 1) p2 += __shfl_down(p2, s, 16);
    if (l16 == 0) out[OUT_EDGES + (size_t)row * 8 + j] = p2 + em_bo[j];
}

extern "C" void kernel_launch(void* const* d_in, const int* in_sizes, int n_in,
                              void* d_out, int out_size, void* d_ws, size_t ws_size,
                              hipStream_t stream) {
    const float* x    = (const float*)d_in[0];
    const int* edge   = (const int*)d_in[1];
    const int* batch  = (const int*)d_in[2];
    const float* w1m = (const float*)d_in[3];  const float* b1m = (const float*)d_in[4];
    const float* w2m = (const float*)d_in[5];  const float* b2m = (const float*)d_in[6];
    const float* w3m = (const float*)d_in[7];  const float* b3m = (const float*)d_in[8];
    const float* w1l = (const float*)d_in[9];  const float* b1l = (const float*)d_in[10];
    const float* w2l = (const float*)d_in[11]; const float* b2l = (const float*)d_in[12];
    const float* w3l = (const float*)d_in[13]; const float* b3l = (const float*)d_in[14];
    const float* nm_wi = (const float*)d_in[15]; const float* nm_bi = (const float*)d_in[16];
    const float* nm_g  = (const float*)d_in[17]; const float* nm_be = (const float*)d_in[18];
    const float* nm_wo = (const float*)d_in[19]; const float* nm_bo = (const float*)d_in[20];
    const float* ex_w = (const float*)d_in[21]; const float* ex_b = (const float*)d_in[22];
    const float* fu_w = (const float*)d_in[23]; const float* fu_b = (const float*)d_in[24];
    const float* al_w = (const float*)d_in[25]; const float* al_b = (const float*)d_in[26];
    const float* sl_w = (const float*)d_in[27]; const float* sl_b = (const float*)d_in[28];
    const float* em_wi = (const float*)d_in[29]; const float* em_bi = (const float*)d_in[30];
    const float* em_g  = (const float*)d_in[31]; const float* em_be = (const float*)d_in[32];
    const float* em_wo = (const float*)d_in[33]; const float* em_bo = (const float*)d_in[34];
    const float* pos_all = (const float*)d_in[35];
    float* out = (float*)d_out;

    char* p = (char*)d_ws;
    auto alloc = [&](size_t bytes) -> void* {
        void* r = (void*)p;
        p += ((bytes + 255) / 256) * 256;
        return r;
    };
    int* deg     = (int*)alloc((size_t)N_NODES * 4);
    int* offs    = (int*)alloc((size_t)(N_NODES + 1) * 4);
    int* cursor  = (int*)alloc((size_t)N_NODES * 4);
    int* adj     = (int*)alloc((size_t)N_EDGESC * 4);
    float* dinv  = (float*)alloc((size_t)N_NODES * 4);
    int* bcnt    = (int*)alloc(BATCH_B * 4);
    float* sum_mu = (float*)alloc(BATCH_B * LATC * 4);
    float* sum_lg = (float*)alloc(BATCH_B * LATC * 4);
    float* zbuf   = (float*)alloc(BATCH_B * LATC * 4);
    float* hws  = (float*)alloc((size_t)N_NODES * 128 * 4);
    float* actA = (float*)alloc((size_t)N_NODES * 128 * 4);
    float* actB = (float*)alloc((size_t)N_NODES * 128 * 4);

    const int* srcp = edge;
    const int* dstp = edge + N_EDGESC;

    hipMemsetAsync(deg, 0, (size_t)N_NODES * 4, stream);
    hipMemsetAsync(bcnt, 0, (size_t)((char*)zbuf - (char*)bcnt), stream);  // bcnt + sums

    hist_kernel<<<(N_EDGESC + 255) / 256, 256, 0, stream>>>(dstp, deg, N_EDGESC);
    hist_kernel<<<(N_NODES + 255) / 256, 256, 0, stream>>>(batch, bcnt, N_NODES);
    scan_kernel<<<1, 1024, 0, stream>>>(deg, offs, cursor, N_NODES);
    fill_adj<<<(N_EDGESC + 255) / 256, 256, 0, stream>>>(srcp, dstp, cursor, adj, N_EDGESC);
    dinv_kernel<<<(N_NODES + 255) / 256, 256, 0, stream>>>(deg, dinv, N_NODES);

    // ---- mu branch ----
    matmul_scale<32, 64, 4><<<N_NODES / 4, 256, 0, stream>>>(x, w1m, dinv, hws, N_NODES);
    aggregate<64><<<N_NODES, 64, 0, stream>>>(hws, offs, adj, dinv, b1m, actA, N_NODES);
    matmul_scale<64, 128, 2><<<N_NODES / 2, 256, 0, stream>>>(actA, w2m, dinv, hws, N_NODES);
    aggregate<128><<<N_NODES, 128, 0, stream>>>(hws, offs, adj, dinv, b2m, actB, N_NODES);
    matmul_scale<128, 64, 4><<<N_NODES / 4, 256, 0, stream>>>(actB, w3m, dinv, hws, N_NODES);
    aggregate<64><<<N_NODES, 64, 0, stream>>>(hws, offs, adj, dinv, b3m, actA, N_NODES);
    pool_kernel<<<(N_NODES + POOL_CHUNK - 1) / POOL_CHUNK, 64, 0, stream>>>(actA, batch, sum_mu, N_NODES);

    // ---- lg branch ----
    matmul_scale<32, 64, 4><<<N_NODES / 4, 256, 0, stream>>>(x, w1l, dinv, hws, N_NODES);
    aggregate<64><<<N_NODES, 64, 0, stream>>>(hws, offs, adj, dinv, b1l, actB, N_NODES);
    matmul_scale<64, 128, 2><<<N_NODES / 2, 256, 0, stream>>>(actB, w2l, dinv, hws, N_NODES);
    aggregate<128><<<N_NODES, 128, 0, stream>>>(hws, offs, adj, dinv, b2l, actA, N_NODES);
    matmul_scale<128, 64, 4><<<N_NODES / 4, 256, 0, stream>>>(actA, w3l, dinv, hws, N_NODES);
    aggregate<64><<<N_NODES, 64, 0, stream>>>(hws, offs, adj, dinv, b3l, actB, N_NODES);
    pool_kernel<<<(N_NODES + POOL_CHUNK - 1) / POOL_CHUNK, 64, 0, stream>>>(actB, batch, sum_lg, N_NODES);

    finalize_pool<<<1, 1024, 0, stream>>>(sum_mu, sum_lg, bcnt, out, zbuf);

    decoder_kernel<<<BATCH_B * NMAXC, 128, 0, stream>>>(
        zbuf, pos_all, nm_wi, nm_bi, nm_g, nm_be, nm_wo, nm_bo,
        ex_w, ex_b, fu_w, fu_b, al_w, al_b, sl_w, sl_b,
        em_wi, em_bi, em_g, em_be, em_wo, em_bo, out);
}

// Round 2
// 1581.453 us; speedup vs baseline: 2.0360x; 2.0360x over previous
//
#include <hip/hip_runtime.h>
#include <hip/hip_bf16.h>

#define N_NODES 100000
#define N_EDGESC 1600000
#define BATCH_B 16
#define NMAXC 4096
#define LATC 64

// output layout offsets (flat f32)
#define OUT_NODES 0
#define OUT_EDGES 65536
#define OUT_FUEL  589824
#define OUT_ALT   917504
#define OUT_SLOPE 983040
#define OUT_MU    1048576
#define OUT_LG    1049600

__global__ void hist_kernel(const int* __restrict__ idx, int* __restrict__ cnt, int n) {
    int i = blockIdx.x * blockDim.x + threadIdx.x;
    if (i < n) atomicAdd(&cnt[idx[i]], 1);
}

// batch is sorted: count[b] = upper_bound(b) - lower_bound(b). 16 threads.
__global__ void batch_count(const int* __restrict__ batch, int* __restrict__ bcnt, int n) {
    int b = threadIdx.x;
    if (b >= BATCH_B) return;
    int lo = 0, hi = n;
    while (lo < hi) { int mid = (lo + hi) >> 1; if (batch[mid] < b) lo = mid + 1; else hi = mid; }
    int start = lo;
    lo = 0; hi = n;
    while (lo < hi) { int mid = (lo + hi) >> 1; if (batch[mid] <= b) lo = mid + 1; else hi = mid; }
    bcnt[b] = lo - start;
}

// single-block exclusive scan of deg[0..n) -> offs[0..n], also copies into cursor
__global__ void scan_kernel(const int* __restrict__ deg, int* __restrict__ offs,
                            int* __restrict__ cursor, int n) {
    __shared__ int part[1024];
    int tid = threadIdx.x;
    int chunk = (n + 1023) >> 10;
    int s0 = tid * chunk;
    int s1 = min(s0 + chunk, n);
    int s = 0;
    for (int i = s0; i < s1; i++) s += deg[i];
    part[tid] = s;
    __syncthreads();
    for (int off = 1; off < 1024; off <<= 1) {
        int v = (tid >= off) ? part[tid - off] : 0;
        __syncthreads();
        part[tid] += v;
        __syncthreads();
    }
    int run = part[tid] - s;  // exclusive prefix
    for (int i = s0; i < s1; i++) {
        offs[i] = run; cursor[i] = run; run += deg[i];
    }
    if (tid == 1023) offs[n] = part[1023];
}

__global__ void fill_adj(const int* __restrict__ src, const int* __restrict__ dst,
                         int* __restrict__ cursor, int* __restrict__ adj, int n) {
    int i = blockIdx.x * blockDim.x + threadIdx.x;
    if (i < n) {
        int d = dst[i];
        int p = atomicAdd(&cursor[d], 1);
        adj[p] = src[i];
    }
}

__global__ void dinv_kernel(const int* __restrict__ deg, float* __restrict__ dinv, int n) {
    int i = blockIdx.x * blockDim.x + threadIdx.x;
    if (i < n) dinv[i] = rsqrtf((float)(deg[i] + 1));  // +1 = self loop
}

// hws[n,f] = dinv[n] * sum_k in[n,k] * W[k,f]
template <int K, int F, int RPB>
__global__ void matmul_scale(const float* __restrict__ in, const float* __restrict__ W,
                             const float* __restrict__ dinv, float* __restrict__ out, int N) {
    __shared__ float Ws[K * F];
    __shared__ float xs[RPB][K];
    int tid = threadIdx.x;
    for (int i = tid; i < K * F; i += 256) Ws[i] = W[i];
    int node0 = blockIdx.x * RPB;
    for (int i = tid; i < RPB * K; i += 256) {
        int r = i / K, k = i % K;
        int n = node0 + r;
        xs[r][k] = (n < N) ? in[(size_t)n * K + k] : 0.f;
    }
    __syncthreads();
    int r = tid / F, f = tid % F;
    int n = node0 + r;
    if (n < N) {
        float acc = 0.f;
#pragma unroll
        for (int k = 0; k < K; k++) acc += xs[r][k] * Ws[k * F + f];
        out[(size_t)n * F + f] = acc * dinv[n];
    }
}

// out[n,f] = relu(dinv[n]*(hws[n,f] + sum_{e} hws[adj[e],f]) + b[f])
// 4x edge unroll -> 4 gathers in flight (latency-bound otherwise)
template <int F>
__global__ void aggregate(const float* __restrict__ hws, const int* __restrict__ offs,
                          const int* __restrict__ adj, const float* __restrict__ dinv,
                          const float* __restrict__ bias, float* __restrict__ out, int N) {
    int n = blockIdx.x;
    int f = threadIdx.x;
    float s = hws[(size_t)n * F + f];
    int e0 = offs[n], e1 = offs[n + 1];
    int e = e0;
    for (; e + 4 <= e1; e += 4) {
        int i0 = adj[e], i1 = adj[e + 1], i2 = adj[e + 2], i3 = adj[e + 3];
        float v0 = hws[(size_t)i0 * F + f];
        float v1 = hws[(size_t)i1 * F + f];
        float v2 = hws[(size_t)i2 * F + f];
        float v3 = hws[(size_t)i3 * F + f];
        s += (v0 + v1) + (v2 + v3);
    }
    for (; e < e1; e++) s += hws[(size_t)adj[e] * F + f];
    out[(size_t)n * F + f] = fmaxf(dinv[n] * s + bias[f], 0.f);
}

#define POOL_CHUNK 128
__global__ void pool_kernel(const float* __restrict__ h, const int* __restrict__ batch,
                            float* __restrict__ sums, int n) {
    int f = threadIdx.x;  // 0..63
    int s0 = blockIdx.x * POOL_CHUNK;
    if (s0 >= n) return;
    int s1 = min(s0 + POOL_CHUNK, n);
    int cur = batch[s0];
    float acc = 0.f;
    for (int i = s0; i < s1; i++) {
        int b = batch[i];
        if (b != cur) { atomicAdd(&sums[cur * 64 + f], acc); acc = 0.f; cur = b; }
        acc += h[(size_t)i * 64 + f];
    }
    atomicAdd(&sums[cur * 64 + f], acc);
}

__global__ void finalize_pool(const float* __restrict__ sum_mu, const float* __restrict__ sum_lg,
                              const int* __restrict__ bcnt, float* __restrict__ out,
                              float* __restrict__ zbuf) {
    int i = threadIdx.x;  // 1024 threads
    int b = i >> 6;
    float c = fmaxf((float)bcnt[b], 1.f);
    float m = sum_mu[i] / c;
    float l = sum_lg[i] / c;
    out[OUT_MU + i] = m;
    out[OUT_LG + i] = l;
    zbuf[i] = m;
}

// zwi[b][t] = bi[t] + sum_k z[b,k]*wi[k*128+t]  (first 64 rows of Wi folded once)
__global__ void zwi_kernel(const float* __restrict__ z,
                           const float* __restrict__ nm_wi, const float* __restrict__ nm_bi,
                           const float* __restrict__ em_wi, const float* __restrict__ em_bi,
                           float* __restrict__ zwi_nm, float* __restrict__ zwi_em) {
    int b = blockIdx.x, t = threadIdx.x;  // 16 blocks x 128 threads
    float an = nm_bi[t], ae = em_bi[t];
    for (int k = 0; k < 64; k++) {
        float zv = z[b * 64 + k];
        an += zv * nm_wi[k * 128 + t];
        ae += zv * em_wi[k * 128 + t];
    }
    zwi_nm[b * 128 + t] = an;
    zwi_em[b * 128 + t] = ae;
}

#define DEC_WAVES 4
#define DEC_RPW 8
#define DEC_ROWS (DEC_WAVES * DEC_RPW)  // 32 rows/block

__global__ __launch_bounds__(256) void decoder2(
    const float* __restrict__ zwi_nm, const float* __restrict__ zwi_em,
    const float* __restrict__ nm_wi, const float* __restrict__ em_wi,
    const float* __restrict__ nm_g, const float* __restrict__ nm_be,
    const float* __restrict__ nm_wo, const float* __restrict__ nm_bo,
    const float* __restrict__ em_g, const float* __restrict__ em_be,
    const float* __restrict__ em_wo,
    const float* __restrict__ ex_w, const float* __restrict__ ex_b,
    const float* __restrict__ fu_w, const float* __restrict__ fu_b,
    const float* __restrict__ al_w, const float* __restrict__ al_b,
    const float* __restrict__ sl_w, const float* __restrict__ sl_b,
    const float* __restrict__ em_bo,
    const float* __restrict__ pos_all,
    float* __restrict__ out) {
    __shared__ float s1[DEC_WAVES][DEC_RPW][128];
    int t = threadIdx.x;
    int lane = t & 63, wave = t >> 6;
    int rowBase = blockIdx.x * DEC_ROWS;
    int b = rowBase >> 12;                 // 32 | 4096 -> same b for whole block
    int row0 = rowBase + wave * DEC_RPW;

    int f0 = lane, f1 = lane + 64;
    // hoisted per-lane weights (read once per block from L2)
    float zn0 = zwi_nm[b * 128 + f0], zn1 = zwi_nm[b * 128 + f1];
    float ze0 = zwi_em[b * 128 + f0], ze1 = zwi_em[b * 128 + f1];
    float wn64_0 = nm_wi[64 * 128 + f0], wn64_1 = nm_wi[64 * 128 + f1];
    float wn65_0 = nm_wi[65 * 128 + f0], wn65_1 = nm_wi[65 * 128 + f1];
    float we64_0 = em_wi[64 * 128 + f0], we64_1 = em_wi[64 * 128 + f1];
    float we65_0 = em_wi[65 * 128 + f0], we65_1 = em_wi[65 * 128 + f1];
    float gn0 = nm_g[f0], gn1 = nm_g[f1], bn0 = nm_be[f0], bn1 = nm_be[f1];
    float ge0 = em_g[f0], ge1 = em_g[f1], be0 = em_be[f0], be1 = em_be[f1];
    float bo0 = nm_bo[f0], bo1 = nm_bo[f1];
    float exw0 = ex_w[f0], exw1 = ex_w[f1];
    float alw0 = al_w[f0], alw1 = al_w[f1];
    float slw0 = sl_w[f0], slw1 = sl_w[f1];
    float fuw0[5], fuw1[5];
#pragma unroll
    for (int j = 0; j < 5; j++) { fuw0[j] = fu_w[f0 * 5 + j]; fuw1[j] = fu_w[f1 * 5 + j]; }
    float ew0[8], ew1[8];
#pragma unroll
    for (int j = 0; j < 8; j++) { ew0[j] = em_wo[f0 * 8 + j]; ew1[j] = em_wo[f1 * 8 + j]; }
    float nhb = 0.f;
    if (lane == 0) nhb = ex_b[0];
    else if (lane < 6) nhb = fu_b[lane - 1];
    else if (lane == 6) nhb = al_b[0];
    else if (lane == 7) nhb = sl_b[0];
    float ehb = (lane < 8) ? em_bo[lane] : 0.f;

    float pxs[DEC_RPW], pys[DEC_RPW];

    // ---- node MLP layer1 + LN (wave-local, no barriers) ----
#pragma unroll
    for (int r = 0; r < DEC_RPW; r++) {
        int row = row0 + r, i = row & (NMAXC - 1);
        float px = pos_all[i * 2], py = pos_all[i * 2 + 1];
        pxs[r] = px; pys[r] = py;
        float a0 = zn0 + px * wn64_0 + py * wn65_0;
        float a1 = zn1 + px * wn64_1 + py * wn65_1;
        float sm = a0 + a1, sq = a0 * a0 + a1 * a1;
#pragma unroll
        for (int d = 1; d < 64; d <<= 1) { sm += __shfl_xor(sm, d); sq += __shfl_xor(sq, d); }
        float mean = sm * (1.f / 128.f);
        float var = sq * (1.f / 128.f) - mean * mean;
        float rstd = rsqrtf(var + 1e-5f);
        s1[wave][r][f0] = fmaxf((a0 - mean) * rstd * gn0 + bn0, 0.f);
        s1[wave][r][f1] = fmaxf((a1 - mean) * rstd * gn1 + bn1, 0.f);
    }

    // ---- node MLP layer2: 8-row register blocking, nm_wo fetched once per 8 rows ----
    float acc0[DEC_RPW], acc1[DEC_RPW];
#pragma unroll
    for (int r = 0; r < DEC_RPW; r++) { acc0[r] = bo0; acc1[r] = bo1; }
    for (int k4 = 0; k4 < 32; k4++) {
        float4 sv[DEC_RPW];
#pragma unroll
        for (int r = 0; r < DEC_RPW; r++)
            sv[r] = *(const float4*)&s1[wave][r][k4 * 4];
#pragma unroll
        for (int kk = 0; kk < 4; kk++) {
            int k = k4 * 4 + kk;
            float w0 = nm_wo[k * 128 + f0];
            float w1 = nm_wo[k * 128 + f1];
#pragma unroll
            for (int r = 0; r < DEC_RPW; r++) {
                float skv = (&sv[r].x)[kk];
                acc0[r] += skv * w0;
                acc1[r] += skv * w1;
            }
        }
    }

    // ---- node heads ----
#pragma unroll
    for (int r = 0; r < DEC_RPW; r++) {
        float h0 = acc0[r], h1 = acc1[r];
        float p[8];
        p[0] = h0 * exw0 + h1 * exw1;
#pragma unroll
        for (int j = 0; j < 5; j++) p[1 + j] = h0 * fuw0[j] + h1 * fuw1[j];
        p[6] = h0 * alw0 + h1 * alw1;
        p[7] = h0 * slw0 + h1 * slw1;
#pragma unroll
        for (int d = 1; d < 64; d <<= 1) {
#pragma unroll
            for (int j = 0; j < 8; j++) p[j] += __shfl_xor(p[j], d);
        }
        int row = row0 + r;
        if (lane < 8) {
            float v = 0.f;
#pragma unroll
            for (int j = 0; j < 8; j++) if (lane == j) v = p[j];
            v += nhb;
            size_t addr = (lane == 0) ? (size_t)(OUT_NODES + row)
                        : (lane < 6) ? (size_t)OUT_FUEL + (size_t)row * 5 + (lane - 1)
                        : (lane == 6) ? (size_t)(OUT_ALT + row)
                                      : (size_t)(OUT_SLOPE + row);
            out[addr] = v;
        }
    }

    // ---- edge MLP (fully in-register: out-dim 8 needs no feature mixing via LDS) ----
#pragma unroll
    for (int r = 0; r < DEC_RPW; r++) {
        float px = pxs[r], py = pys[r];
        float a0 = ze0 + px * we64_0 + py * we65_0;
        float a1 = ze1 + px * we64_1 + py * we65_1;
        float sm = a0 + a1, sq = a0 * a0 + a1 * a1;
#pragma unroll
        for (int d = 1; d < 64; d <<= 1) { sm += __shfl_xor(sm, d); sq += __shfl_xor(sq, d); }
        float mean = sm * (1.f / 128.f);
        float var = sq * (1.f / 128.f) - mean * mean;
        float rstd = rsqrtf(var + 1e-5f);
        float se0 = fmaxf((a0 - mean) * rstd * ge0 + be0, 0.f);
        float se1 = fmaxf((a1 - mean) * rstd * ge1 + be1, 0.f);
        float p[8];
#pragma unroll
        for (int j = 0; j < 8; j++) p[j] = se0 * ew0[j] + se1 * ew1[j];
#pragma unroll
        for (int d = 1; d < 64; d <<= 1) {
#pragma unroll
            for (int j = 0; j < 8; j++) p[j] += __shfl_xor(p[j], d);
        }
        if (lane < 8) {
            float v = 0.f;
#pragma unroll
            for (int j = 0; j < 8; j++) if (lane == j) v = p[j];
            out[OUT_EDGES + (size_t)(row0 + r) * 8 + lane] = v + ehb;
        }
    }
}

extern "C" void kernel_launch(void* const* d_in, const int* in_sizes, int n_in,
                              void* d_out, int out_size, void* d_ws, size_t ws_size,
                              hipStream_t stream) {
    const float* x    = (const float*)d_in[0];
    const int* edge   = (const int*)d_in[1];
    const int* batch  = (const int*)d_in[2];
    const float* w1m = (const float*)d_in[3];  const float* b1m = (const float*)d_in[4];
    const float* w2m = (const float*)d_in[5];  const float* b2m = (const float*)d_in[6];
    const float* w3m = (const float*)d_in[7];  const float* b3m = (const float*)d_in[8];
    const float* w1l = (const float*)d_in[9];  const float* b1l = (const float*)d_in[10];
    const float* w2l = (const float*)d_in[11]; const float* b2l = (const float*)d_in[12];
    const float* w3l = (const float*)d_in[13]; const float* b3l = (const float*)d_in[14];
    const float* nm_wi = (const float*)d_in[15]; const float* nm_bi = (const float*)d_in[16];
    const float* nm_g  = (const float*)d_in[17]; const float* nm_be = (const float*)d_in[18];
    const float* nm_wo = (const float*)d_in[19]; const float* nm_bo = (const float*)d_in[20];
    const float* ex_w = (const float*)d_in[21]; const float* ex_b = (const float*)d_in[22];
    const float* fu_w = (const float*)d_in[23]; const float* fu_b = (const float*)d_in[24];
    const float* al_w = (const float*)d_in[25]; const float* al_b = (const float*)d_in[26];
    const float* sl_w = (const float*)d_in[27]; const float* sl_b = (const float*)d_in[28];
    const float* em_wi = (const float*)d_in[29]; const float* em_bi = (const float*)d_in[30];
    const float* em_g  = (const float*)d_in[31]; const float* em_be = (const float*)d_in[32];
    const float* em_wo = (const float*)d_in[33]; const float* em_bo = (const float*)d_in[34];
    const float* pos_all = (const float*)d_in[35];
    float* out = (float*)d_out;

    char* p = (char*)d_ws;
    auto alloc = [&](size_t bytes) -> void* {
        void* r = (void*)p;
        p += ((bytes + 255) / 256) * 256;
        return r;
    };
    int* deg     = (int*)alloc((size_t)N_NODES * 4);
    int* offs    = (int*)alloc((size_t)(N_NODES + 1) * 4);
    int* cursor  = (int*)alloc((size_t)N_NODES * 4);
    int* adj     = (int*)alloc((size_t)N_EDGESC * 4);
    float* dinv  = (float*)alloc((size_t)N_NODES * 4);
    int* bcnt    = (int*)alloc(BATCH_B * 4);
    float* sum_mu = (float*)alloc(BATCH_B * LATC * 4);
    float* sum_lg = (float*)alloc(BATCH_B * LATC * 4);
    float* zbuf   = (float*)alloc(BATCH_B * LATC * 4);
    float* zwi_nm = (float*)alloc(BATCH_B * 128 * 4);
    float* zwi_em = (float*)alloc(BATCH_B * 128 * 4);
    float* hws  = (float*)alloc((size_t)N_NODES * 128 * 4);
    float* actA = (float*)alloc((size_t)N_NODES * 128 * 4);
    float* actB = (float*)alloc((size_t)N_NODES * 128 * 4);

    const int* srcp = edge;
    const int* dstp = edge + N_EDGESC;

    hipMemsetAsync(deg, 0, (size_t)N_NODES * 4, stream);
    hipMemsetAsync(sum_mu, 0, (size_t)2 * BATCH_B * LATC * 4, stream);

    hist_kernel<<<(N_EDGESC + 255) / 256, 256, 0, stream>>>(dstp, deg, N_EDGESC);
    batch_count<<<1, 64, 0, stream>>>(batch, bcnt, N_NODES);
    scan_kernel<<<1, 1024, 0, stream>>>(deg, offs, cursor, N_NODES);
    fill_adj<<<(N_EDGESC + 255) / 256, 256, 0, stream>>>(srcp, dstp, cursor, adj, N_EDGESC);
    dinv_kernel<<<(N_NODES + 255) / 256, 256, 0, stream>>>(deg, dinv, N_NODES);

    // ---- mu branch ----
    matmul_scale<32, 64, 4><<<N_NODES / 4, 256, 0, stream>>>(x, w1m, dinv, hws, N_NODES);
    aggregate<64><<<N_NODES, 64, 0, stream>>>(hws, offs, adj, dinv, b1m, actA, N_NODES);
    matmul_scale<64, 128, 2><<<N_NODES / 2, 256, 0, stream>>>(actA, w2m, dinv, hws, N_NODES);
    aggregate<128><<<N_NODES, 128, 0, stream>>>(hws, offs, adj, dinv, b2m, actB, N_NODES);
    matmul_scale<128, 64, 4><<<N_NODES / 4, 256, 0, stream>>>(actB, w3m, dinv, hws, N_NODES);
    aggregate<64><<<N_NODES, 64, 0, stream>>>(hws, offs, adj, dinv, b3m, actA, N_NODES);
    pool_kernel<<<(N_NODES + POOL_CHUNK - 1) / POOL_CHUNK, 64, 0, stream>>>(actA, batch, sum_mu, N_NODES);

    // ---- lg branch ----
    matmul_scale<32, 64, 4><<<N_NODES / 4, 256, 0, stream>>>(x, w1l, dinv, hws, N_NODES);
    aggregate<64><<<N_NODES, 64, 0, stream>>>(hws, offs, adj, dinv, b1l, actB, N_NODES);
    matmul_scale<64, 128, 2><<<N_NODES / 2, 256, 0, stream>>>(actB, w2l, dinv, hws, N_NODES);
    aggregate<128><<<N_NODES, 128, 0, stream>>>(hws, offs, adj, dinv, b2l, actA, N_NODES);
    matmul_scale<128, 64, 4><<<N_NODES / 4, 256, 0, stream>>>(actA, w3l, dinv, hws, N_NODES);
    aggregate<64><<<N_NODES, 64, 0, stream>>>(hws, offs, adj, dinv, b3l, actB, N_NODES);
    pool_kernel<<<(N_NODES + POOL_CHUNK - 1) / POOL_CHUNK, 64, 0, stream>>>(actB, batch, sum_lg, N_NODES);

    finalize_pool<<<1, 1024, 0, stream>>>(sum_mu, sum_lg, bcnt, out, zbuf);

    zwi_kernel<<<BATCH_B, 128, 0, stream>>>(zbuf, nm_wi, nm_bi, em_wi, em_bi, zwi_nm, zwi_em);

    decoder2<<<BATCH_B * NMAXC / DEC_ROWS, 256, 0, stream>>>(
        zwi_nm, zwi_em, nm_wi, em_wi, nm_g, nm_be, nm_wo, nm_bo,
        em_g, em_be, em_wo, ex_w, ex_b, fu_w, fu_b, al_w, al_b, sl_w, sl_b,
        em_bo, pos_all, out);
}

// Round 3
// 908.321 us; speedup vs baseline: 3.5448x; 1.7411x over previous
//
#include <hip/hip_runtime.h>
#include <hip/hip_bf16.h>

#define N_NODES 100000
#define N_EDGESC 1600000
#define BATCH_B 16
#define NMAXC 4096
#define LATC 64

// output layout offsets (flat f32)
#define OUT_NODES 0
#define OUT_EDGES 65536
#define OUT_FUEL  589824
#define OUT_ALT   917504
#define OUT_SLOPE 983040
#define OUT_MU    1048576
#define OUT_LG    1049600

__global__ void hist_kernel(const int* __restrict__ idx, int* __restrict__ cnt, int n) {
    int i = blockIdx.x * blockDim.x + threadIdx.x;
    if (i < n) atomicAdd(&cnt[idx[i]], 1);
}

// batch is sorted: count[b] = upper_bound(b) - lower_bound(b)
__global__ void batch_count(const int* __restrict__ batch, int* __restrict__ bcnt, int n) {
    int b = threadIdx.x;
    if (b >= BATCH_B) return;
    int lo = 0, hi = n;
    while (lo < hi) { int mid = (lo + hi) >> 1; if (batch[mid] < b) lo = mid + 1; else hi = mid; }
    int start = lo;
    lo = 0; hi = n;
    while (lo < hi) { int mid = (lo + hi) >> 1; if (batch[mid] <= b) lo = mid + 1; else hi = mid; }
    bcnt[b] = lo - start;
}

// ---- 3-phase multi-block exclusive scan of deg -> offs/cursor ----
__global__ void scan_p1(const int* __restrict__ deg, int* __restrict__ bsum, int n) {
    int i = blockIdx.x * 256 + threadIdx.x;
    int v = (i < n) ? deg[i] : 0;
#pragma unroll
    for (int d = 1; d < 64; d <<= 1) v += __shfl_xor(v, d);
    __shared__ int ws[4];
    if ((threadIdx.x & 63) == 0) ws[threadIdx.x >> 6] = v;
    __syncthreads();
    if (threadIdx.x == 0) bsum[blockIdx.x] = ws[0] + ws[1] + ws[2] + ws[3];
}

__global__ void scan_p2(int* __restrict__ bsum, int nb) {
    __shared__ int sh[512];
    int t = threadIdx.x;
    int v = (t < nb) ? bsum[t] : 0;
    sh[t] = v;
    __syncthreads();
    for (int off = 1; off < 512; off <<= 1) {
        int u = (t >= off) ? sh[t - off] : 0;
        __syncthreads();
        sh[t] += u;
        __syncthreads();
    }
    if (t < nb) bsum[t] = sh[t] - v;  // exclusive
}

__global__ void scan_p3(const int* __restrict__ deg, const int* __restrict__ bsum,
                        int* __restrict__ offs, int* __restrict__ cursor, int n) {
    __shared__ int sh[256];
    int t = threadIdx.x;
    int i = blockIdx.x * 256 + t;
    int v = (i < n) ? deg[i] : 0;
    sh[t] = v;
    __syncthreads();
    for (int off = 1; off < 256; off <<= 1) {
        int u = (t >= off) ? sh[t - off] : 0;
        __syncthreads();
        sh[t] += u;
        __syncthreads();
    }
    int excl = sh[t] - v + bsum[blockIdx.x];
    if (i < n) { offs[i] = excl; cursor[i] = excl; }
    if (i == n - 1) offs[n] = excl + v;
}

__global__ void fill_adj(const int* __restrict__ src, const int* __restrict__ dst,
                         int* __restrict__ cursor, int* __restrict__ adj, int n) {
    int i = blockIdx.x * blockDim.x + threadIdx.x;
    if (i < n) {
        int d = dst[i];
        int p = atomicAdd(&cursor[d], 1);
        adj[p] = src[i];
    }
}

__global__ void dinv_kernel(const int* __restrict__ deg, float* __restrict__ dinv, int n) {
    int i = blockIdx.x * blockDim.x + threadIdx.x;
    if (i < n) dinv[i] = rsqrtf((float)(deg[i] + 1));  // +1 = self loop
}

// xs = dinv (broadcast per row of 32) * x, float4
__global__ void prescale_x(const float* __restrict__ x, const float* __restrict__ dinv,
                           float* __restrict__ xs, int total4) {
    int i4 = blockIdx.x * blockDim.x + threadIdx.x;
    if (i4 < total4) {
        int i = i4 * 4;
        float4 v = *(const float4*)&x[i];
        float d = dinv[i >> 5];
        v.x *= d; v.y *= d; v.z *= d; v.w *= d;
        *(float4*)&xs[i] = v;
    }
}

// agg0 = S x : out[n,f] = dinv[n] * (xs[n,f] + sum_src xs[src,f]); 4 nodes per 128-thread block
__global__ void agg_s32(const float* __restrict__ xs, const int* __restrict__ offs,
                        const int* __restrict__ adj, const float* __restrict__ dinv,
                        float* __restrict__ out, int N) {
    int t = threadIdx.x;
    int sub = t >> 5, f = t & 31;
    int n = blockIdx.x * 4 + sub;
    if (n >= N) return;
    float s = xs[(size_t)n * 32 + f];
    int e0 = offs[n], e1 = offs[n + 1];
    int e = e0;
    for (; e + 4 <= e1; e += 4) {
        int i0 = adj[e], i1 = adj[e + 1], i2 = adj[e + 2], i3 = adj[e + 3];
        s += (xs[(size_t)i0 * 32 + f] + xs[(size_t)i1 * 32 + f])
           + (xs[(size_t)i2 * 32 + f] + xs[(size_t)i3 * 32 + f]);
    }
    for (; e < e1; e++) s += xs[(size_t)adj[e] * 32 + f];
    out[(size_t)n * 32 + f] = dinv[n] * s;
}

// 64-dim aggregation, 2 nodes per 128-thread block (one wave each)
// BIASRELU=false: out = dinv[n]*sum   (plain S apply)
// BIASRELU=true : out = relu(dinv[n]*sum + bias)
template <bool BIASRELU>
__global__ void agg64(const float* __restrict__ h, const int* __restrict__ offs,
                      const int* __restrict__ adj, const float* __restrict__ dinv,
                      const float* __restrict__ bias, float* __restrict__ out, int N) {
    int wave = threadIdx.x >> 6, f = threadIdx.x & 63;
    int n = blockIdx.x * 2 + wave;
    if (n >= N) return;
    float s = h[(size_t)n * 64 + f];
    int e0 = offs[n], e1 = offs[n + 1];
    int e = e0;
    for (; e + 4 <= e1; e += 4) {
        int i0 = adj[e], i1 = adj[e + 1], i2 = adj[e + 2], i3 = adj[e + 3];
        s += (h[(size_t)i0 * 64 + f] + h[(size_t)i1 * 64 + f])
           + (h[(size_t)i2 * 64 + f] + h[(size_t)i3 * 64 + f]);
    }
    for (; e < e1; e++) s += h[(size_t)adj[e] * 64 + f];
    float v = dinv[n] * s;
    if (BIASRELU) v = fmaxf(v + bias[f], 0.f);
    out[(size_t)n * 64 + f] = v;
}

// Register-tiled matmul: out[n,f] = epilogue(sum_k in[n,k]*W[k,f])
// TN=4 fixed; block 256 threads covers BM=TM*(256/(F/4)) rows.
// BIASRELU: v=relu(v+bias[f]); SCALE: v*=dinv[n] (applied after relu)
template <int K, int F, int TM, bool BIASRELU, bool SCALE>
__global__ __launch_bounds__(256) void matmul2(const float* __restrict__ in, const float* __restrict__ W,
                                               const float* __restrict__ bias, const float* __restrict__ dinv,
                                               float* __restrict__ out, int N) {
    constexpr int TN = 4;
    constexpr int CG = F / TN;
    constexpr int RG = 256 / CG;
    constexpr int BM = TM * RG;
    __shared__ float Ws[K * F];
    __shared__ float xs[BM][K];
    int tid = threadIdx.x;
    for (int i = tid * 4; i < K * F; i += 1024)
        *(float4*)&Ws[i] = *(const float4*)&W[i];
    int node0 = blockIdx.x * BM;
    for (int i = tid * 4; i < BM * K; i += 1024) {
        int r = i / K, k = i % K;
        int n = node0 + r;
        *(float4*)&xs[r][k] = (n < N) ? *(const float4*)&in[(size_t)n * K + k]
                                      : make_float4(0.f, 0.f, 0.f, 0.f);
    }
    __syncthreads();
    int cg = tid % CG, rg = tid / CG;
    int f0 = cg * TN;
    float acc[TM][TN];
#pragma unroll
    for (int m = 0; m < TM; m++)
#pragma unroll
        for (int j = 0; j < TN; j++) acc[m][j] = 0.f;
    for (int k4 = 0; k4 < K; k4 += 4) {
        float4 wv[4];
#pragma unroll
        for (int kk = 0; kk < 4; kk++) wv[kk] = *(const float4*)&Ws[(k4 + kk) * F + f0];
#pragma unroll
        for (int m = 0; m < TM; m++) {
            float4 xv = *(const float4*)&xs[rg * TM + m][k4];
#pragma unroll
            for (int kk = 0; kk < 4; kk++) {
                float xk = (&xv.x)[kk];
                acc[m][0] += xk * wv[kk].x;
                acc[m][1] += xk * wv[kk].y;
                acc[m][2] += xk * wv[kk].z;
                acc[m][3] += xk * wv[kk].w;
            }
        }
    }
#pragma unroll
    for (int m = 0; m < TM; m++) {
        int n = node0 + rg * TM + m;
        if (n < N) {
            float4 o;
#pragma unroll
            for (int j = 0; j < TN; j++) {
                float v = acc[m][j];
                if (BIASRELU) v = fmaxf(v + bias[f0 + j], 0.f);
                if (SCALE) v *= dinv[n];
                (&o.x)[j] = v;
            }
            *(float4*)&out[(size_t)n * F + f0] = o;
        }
    }
}

#define POOL_CHUNK 128
__global__ void pool_kernel(const float* __restrict__ h, const int* __restrict__ batch,
                            float* __restrict__ sums, int n) {
    int f = threadIdx.x;  // 0..63
    int s0 = blockIdx.x * POOL_CHUNK;
    if (s0 >= n) return;
    int s1 = min(s0 + POOL_CHUNK, n);
    int cur = batch[s0];
    float acc = 0.f;
    for (int i = s0; i < s1; i++) {
        int b = batch[i];
        if (b != cur) { atomicAdd(&sums[cur * 64 + f], acc); acc = 0.f; cur = b; }
        acc += h[(size_t)i * 64 + f];
    }
    atomicAdd(&sums[cur * 64 + f], acc);
}

__global__ void finalize_pool(const float* __restrict__ sum_mu, const float* __restrict__ sum_lg,
                              const int* __restrict__ bcnt, float* __restrict__ out,
                              float* __restrict__ zbuf) {
    int i = threadIdx.x;  // 1024 threads
    int b = i >> 6;
    float c = fmaxf((float)bcnt[b], 1.f);
    float m = sum_mu[i] / c;
    float l = sum_lg[i] / c;
    out[OUT_MU + i] = m;
    out[OUT_LG + i] = l;
    zbuf[i] = m;
}

// zwi[b][t] = bi[t] + sum_k z[b,k]*wi[k*128+t]
__global__ void zwi_kernel(const float* __restrict__ z,
                           const float* __restrict__ nm_wi, const float* __restrict__ nm_bi,
                           const float* __restrict__ em_wi, const float* __restrict__ em_bi,
                           float* __restrict__ zwi_nm, float* __restrict__ zwi_em) {
    int b = blockIdx.x, t = threadIdx.x;  // 16 blocks x 128 threads
    float an = nm_bi[t], ae = em_bi[t];
    for (int k = 0; k < 64; k++) {
        float zv = z[b * 64 + k];
        an += zv * nm_wi[k * 128 + t];
        ae += zv * em_wi[k * 128 + t];
    }
    zwi_nm[b * 128 + t] = an;
    zwi_em[b * 128 + t] = ae;
}

#define DEC_WAVES 4
#define DEC_RPW 8
#define DEC_ROWS (DEC_WAVES * DEC_RPW)  // 32 rows/block

__global__ __launch_bounds__(256) void decoder2(
    const float* __restrict__ zwi_nm, const float* __restrict__ zwi_em,
    const float* __restrict__ nm_wi, const float* __restrict__ em_wi,
    const float* __restrict__ nm_g, const float* __restrict__ nm_be,
    const float* __restrict__ nm_wo, const float* __restrict__ nm_bo,
    const float* __restrict__ em_g, const float* __restrict__ em_be,
    const float* __restrict__ em_wo,
    const float* __restrict__ ex_w, const float* __restrict__ ex_b,
    const float* __restrict__ fu_w, const float* __restrict__ fu_b,
    const float* __restrict__ al_w, const float* __restrict__ al_b,
    const float* __restrict__ sl_w, const float* __restrict__ sl_b,
    const float* __restrict__ em_bo,
    const float* __restrict__ pos_all,
    float* __restrict__ out) {
    __shared__ float s1[DEC_WAVES][DEC_RPW][128];
    int t = threadIdx.x;
    int lane = t & 63, wave = t >> 6;
    int rowBase = blockIdx.x * DEC_ROWS;
    int b = rowBase >> 12;
    int row0 = rowBase + wave * DEC_RPW;

    int f0 = lane, f1 = lane + 64;
    float zn0 = zwi_nm[b * 128 + f0], zn1 = zwi_nm[b * 128 + f1];
    float ze0 = zwi_em[b * 128 + f0], ze1 = zwi_em[b * 128 + f1];
    float wn64_0 = nm_wi[64 * 128 + f0], wn64_1 = nm_wi[64 * 128 + f1];
    float wn65_0 = nm_wi[65 * 128 + f0], wn65_1 = nm_wi[65 * 128 + f1];
    float we64_0 = em_wi[64 * 128 + f0], we64_1 = em_wi[64 * 128 + f1];
    float we65_0 = em_wi[65 * 128 + f0], we65_1 = em_wi[65 * 128 + f1];
    float gn0 = nm_g[f0], gn1 = nm_g[f1], bn0 = nm_be[f0], bn1 = nm_be[f1];
    float ge0 = em_g[f0], ge1 = em_g[f1], be0 = em_be[f0], be1 = em_be[f1];
    float bo0 = nm_bo[f0], bo1 = nm_bo[f1];
    float exw0 = ex_w[f0], exw1 = ex_w[f1];
    float alw0 = al_w[f0], alw1 = al_w[f1];
    float slw0 = sl_w[f0], slw1 = sl_w[f1];
    float fuw0[5], fuw1[5];
#pragma unroll
    for (int j = 0; j < 5; j++) { fuw0[j] = fu_w[f0 * 5 + j]; fuw1[j] = fu_w[f1 * 5 + j]; }
    float ew0[8], ew1[8];
#pragma unroll
    for (int j = 0; j < 8; j++) { ew0[j] = em_wo[f0 * 8 + j]; ew1[j] = em_wo[f1 * 8 + j]; }
    float nhb = 0.f;
    if (lane == 0) nhb = ex_b[0];
    else if (lane < 6) nhb = fu_b[lane - 1];
    else if (lane == 6) nhb = al_b[0];
    else if (lane == 7) nhb = sl_b[0];
    float ehb = (lane < 8) ? em_bo[lane] : 0.f;

    float pxs[DEC_RPW], pys[DEC_RPW];

#pragma unroll
    for (int r = 0; r < DEC_RPW; r++) {
        int row = row0 + r, i = row & (NMAXC - 1);
        float px = pos_all[i * 2], py = pos_all[i * 2 + 1];
        pxs[r] = px; pys[r] = py;
        float a0 = zn0 + px * wn64_0 + py * wn65_0;
        float a1 = zn1 + px * wn64_1 + py * wn65_1;
        float sm = a0 + a1, sq = a0 * a0 + a1 * a1;
#pragma unroll
        for (int d = 1; d < 64; d <<= 1) { sm += __shfl_xor(sm, d); sq += __shfl_xor(sq, d); }
        float mean = sm * (1.f / 128.f);
        float var = sq * (1.f / 128.f) - mean * mean;
        float rstd = rsqrtf(var + 1e-5f);
        s1[wave][r][f0] = fmaxf((a0 - mean) * rstd * gn0 + bn0, 0.f);
        s1[wave][r][f1] = fmaxf((a1 - mean) * rstd * gn1 + bn1, 0.f);
    }

    float acc0[DEC_RPW], acc1[DEC_RPW];
#pragma unroll
    for (int r = 0; r < DEC_RPW; r++) { acc0[r] = bo0; acc1[r] = bo1; }
    for (int k4 = 0; k4 < 32; k4++) {
        float4 sv[DEC_RPW];
#pragma unroll
        for (int r = 0; r < DEC_RPW; r++)
            sv[r] = *(const float4*)&s1[wave][r][k4 * 4];
#pragma unroll
        for (int kk = 0; kk < 4; kk++) {
            int k = k4 * 4 + kk;
            float w0 = nm_wo[k * 128 + f0];
            float w1 = nm_wo[k * 128 + f1];
#pragma unroll
            for (int r = 0; r < DEC_RPW; r++) {
                float skv = (&sv[r].x)[kk];
                acc0[r] += skv * w0;
                acc1[r] += skv * w1;
            }
        }
    }

#pragma unroll
    for (int r = 0; r < DEC_RPW; r++) {
        float h0 = acc0[r], h1 = acc1[r];
        float p[8];
        p[0] = h0 * exw0 + h1 * exw1;
#pragma unroll
        for (int j = 0; j < 5; j++) p[1 + j] = h0 * fuw0[j] + h1 * fuw1[j];
        p[6] = h0 * alw0 + h1 * alw1;
        p[7] = h0 * slw0 + h1 * slw1;
#pragma unroll
        for (int d = 1; d < 64; d <<= 1) {
#pragma unroll
            for (int j = 0; j < 8; j++) p[j] += __shfl_xor(p[j], d);
        }
        int row = row0 + r;
        if (lane < 8) {
            float v = 0.f;
#pragma unroll
            for (int j = 0; j < 8; j++) if (lane == j) v = p[j];
            v += nhb;
            size_t addr = (lane == 0) ? (size_t)(OUT_NODES + row)
                        : (lane < 6) ? (size_t)OUT_FUEL + (size_t)row * 5 + (lane - 1)
                        : (lane == 6) ? (size_t)(OUT_ALT + row)
                                      : (size_t)(OUT_SLOPE + row);
            out[addr] = v;
        }
    }

#pragma unroll
    for (int r = 0; r < DEC_RPW; r++) {
        float px = pxs[r], py = pys[r];
        float a0 = ze0 + px * we64_0 + py * we65_0;
        float a1 = ze1 + px * we64_1 + py * we65_1;
        float sm = a0 + a1, sq = a0 * a0 + a1 * a1;
#pragma unroll
        for (int d = 1; d < 64; d <<= 1) { sm += __shfl_xor(sm, d); sq += __shfl_xor(sq, d); }
        float mean = sm * (1.f / 128.f);
        float var = sq * (1.f / 128.f) - mean * mean;
        float rstd = rsqrtf(var + 1e-5f);
        float se0 = fmaxf((a0 - mean) * rstd * ge0 + be0, 0.f);
        float se1 = fmaxf((a1 - mean) * rstd * ge1 + be1, 0.f);
        float p[8];
#pragma unroll
        for (int j = 0; j < 8; j++) p[j] = se0 * ew0[j] + se1 * ew1[j];
#pragma unroll
        for (int d = 1; d < 64; d <<= 1) {
#pragma unroll
            for (int j = 0; j < 8; j++) p[j] += __shfl_xor(p[j], d);
        }
        if (lane < 8) {
            float v = 0.f;
#pragma unroll
            for (int j = 0; j < 8; j++) if (lane == j) v = p[j];
            out[OUT_EDGES + (size_t)(row0 + r) * 8 + lane] = v + ehb;
        }
    }
}

extern "C" void kernel_launch(void* const* d_in, const int* in_sizes, int n_in,
                              void* d_out, int out_size, void* d_ws, size_t ws_size,
                              hipStream_t stream) {
    const float* x    = (const float*)d_in[0];
    const int* edge   = (const int*)d_in[1];
    const int* batch  = (const int*)d_in[2];
    const float* w1m = (const float*)d_in[3];  const float* b1m = (const float*)d_in[4];
    const float* w2m = (const float*)d_in[5];  const float* b2m = (const float*)d_in[6];
    const float* w3m = (const float*)d_in[7];  const float* b3m = (const float*)d_in[8];
    const float* w1l = (const float*)d_in[9];  const float* b1l = (const float*)d_in[10];
    const float* w2l = (const float*)d_in[11]; const float* b2l = (const float*)d_in[12];
    const float* w3l = (const float*)d_in[13]; const float* b3l = (const float*)d_in[14];
    const float* nm_wi = (const float*)d_in[15]; const float* nm_bi = (const float*)d_in[16];
    const float* nm_g  = (const float*)d_in[17]; const float* nm_be = (const float*)d_in[18];
    const float* nm_wo = (const float*)d_in[19]; const float* nm_bo = (const float*)d_in[20];
    const float* ex_w = (const float*)d_in[21]; const float* ex_b = (const float*)d_in[22];
    const float* fu_w = (const float*)d_in[23]; const float* fu_b = (const float*)d_in[24];
    const float* al_w = (const float*)d_in[25]; const float* al_b = (const float*)d_in[26];
    const float* sl_w = (const float*)d_in[27]; const float* sl_b = (const float*)d_in[28];
    const float* em_wi = (const float*)d_in[29]; const float* em_bi = (const float*)d_in[30];
    const float* em_g  = (const float*)d_in[31]; const float* em_be = (const float*)d_in[32];
    const float* em_wo = (const float*)d_in[33]; const float* em_bo = (const float*)d_in[34];
    const float* pos_all = (const float*)d_in[35];
    float* out = (float*)d_out;

    char* p = (char*)d_ws;
    auto alloc = [&](size_t bytes) -> void* {
        void* r = (void*)p;
        p += ((bytes + 255) / 256) * 256;
        return r;
    };
    int* deg     = (int*)alloc((size_t)N_NODES * 4);
    int* offs    = (int*)alloc((size_t)(N_NODES + 1) * 4);
    int* cursor  = (int*)alloc((size_t)N_NODES * 4);
    int* adj     = (int*)alloc((size_t)N_EDGESC * 4);
    float* dinv  = (float*)alloc((size_t)N_NODES * 4);
    int* bsum    = (int*)alloc(512 * 4);
    int* bcnt    = (int*)alloc(BATCH_B * 4);
    float* sum_mu = (float*)alloc(BATCH_B * LATC * 4);
    float* sum_lg = (float*)alloc(BATCH_B * LATC * 4);
    float* zbuf   = (float*)alloc(BATCH_B * LATC * 4);
    float* zwi_nm = (float*)alloc(BATCH_B * 128 * 4);
    float* zwi_em = (float*)alloc(BATCH_B * 128 * 4);
    float* xs32   = (float*)alloc((size_t)N_NODES * 32 * 4);
    float* agg0   = (float*)alloc((size_t)N_NODES * 32 * 4);
    float* h64a   = (float*)alloc((size_t)N_NODES * 64 * 4);
    float* h64b   = (float*)alloc((size_t)N_NODES * 64 * 4);
    float* h128   = (float*)alloc((size_t)N_NODES * 128 * 4);

    const int* srcp = edge;
    const int* dstp = edge + N_EDGESC;

    hipMemsetAsync(deg, 0, (size_t)N_NODES * 4, stream);
    hipMemsetAsync(sum_mu, 0, (size_t)2 * BATCH_B * LATC * 4, stream);

    const int SCAN_NB = (N_NODES + 255) / 256;  // 391

    hist_kernel<<<(N_EDGESC + 255) / 256, 256, 0, stream>>>(dstp, deg, N_EDGESC);
    batch_count<<<1, 64, 0, stream>>>(batch, bcnt, N_NODES);
    scan_p1<<<SCAN_NB, 256, 0, stream>>>(deg, bsum, N_NODES);
    scan_p2<<<1, 512, 0, stream>>>(bsum, SCAN_NB);
    scan_p3<<<SCAN_NB, 256, 0, stream>>>(deg, bsum, offs, cursor, N_NODES);
    fill_adj<<<(N_EDGESC + 255) / 256, 256, 0, stream>>>(srcp, dstp, cursor, adj, N_EDGESC);
    dinv_kernel<<<(N_NODES + 255) / 256, 256, 0, stream>>>(deg, dinv, N_NODES);

    // shared L1 aggregation: agg0 = S x
    prescale_x<<<(N_NODES * 32 / 4 + 255) / 256, 256, 0, stream>>>(x, dinv, xs32, N_NODES * 32 / 4);
    agg_s32<<<(N_NODES + 3) / 4, 128, 0, stream>>>(xs32, offs, adj, dinv, agg0, N_NODES);

    // ---- mu branch ----
    matmul2<32, 64, 4, true, true><<<(N_NODES + 63) / 64, 256, 0, stream>>>(agg0, w1m, b1m, dinv, h64a, N_NODES);
    agg64<false><<<(N_NODES + 1) / 2, 128, 0, stream>>>(h64a, offs, adj, dinv, nullptr, h64b, N_NODES);
    matmul2<64, 128, 4, true, false><<<(N_NODES + 31) / 32, 256, 0, stream>>>(h64b, w2m, b2m, nullptr, h128, N_NODES);
    matmul2<128, 64, 3, false, true><<<(N_NODES + 47) / 48, 256, 0, stream>>>(h128, w3m, nullptr, dinv, h64a, N_NODES);
    agg64<true><<<(N_NODES + 1) / 2, 128, 0, stream>>>(h64a, offs, adj, dinv, b3m, h64b, N_NODES);
    pool_kernel<<<(N_NODES + POOL_CHUNK - 1) / POOL_CHUNK, 64, 0, stream>>>(h64b, batch, sum_mu, N_NODES);

    // ---- lg branch ----
    matmul2<32, 64, 4, true, true><<<(N_NODES + 63) / 64, 256, 0, stream>>>(agg0, w1l, b1l, dinv, h64a, N_NODES);
    agg64<false><<<(N_NODES + 1) / 2, 128, 0, stream>>>(h64a, offs, adj, dinv, nullptr, h64b, N_NODES);
    matmul2<64, 128, 4, true, false><<<(N_NODES + 31) / 32, 256, 0, stream>>>(h64b, w2l, b2l, nullptr, h128, N_NODES);
    matmul2<128, 64, 3, false, true><<<(N_NODES + 47) / 48, 256, 0, stream>>>(h128, w3l, nullptr, dinv, h64a, N_NODES);
    agg64<true><<<(N_NODES + 1) / 2, 128, 0, stream>>>(h64a, offs, adj, dinv, b3l, h64b, N_NODES);
    pool_kernel<<<(N_NODES + POOL_CHUNK - 1) / POOL_CHUNK, 64, 0, stream>>>(h64b, batch, sum_lg, N_NODES);

    finalize_pool<<<1, 1024, 0, stream>>>(sum_mu, sum_lg, bcnt, out, zbuf);

    zwi_kernel<<<BATCH_B, 128, 0, stream>>>(zbuf, nm_wi, nm_bi, em_wi, em_bi, zwi_nm, zwi_em);

    decoder2<<<BATCH_B * NMAXC / DEC_ROWS, 256, 0, stream>>>(
        zwi_nm, zwi_em, nm_wi, em_wi, nm_g, nm_be, nm_wo, nm_bo,
        em_g, em_be, em_wo, ex_w, ex_b, fu_w, fu_b, al_w, al_b, sl_w, sl_b,
        em_bo, pos_all, out);
}

// Round 4
// 660.525 us; speedup vs baseline: 4.8746x; 1.3751x over previous
//
#include <hip/hip_runtime.h>
#include <hip/hip_bf16.h>

#define N_NODES 100000
#define N_EDGESC 1600000
#define BATCH_B 16
#define NMAXC 4096
#define LATC 64
#define CAP 64  // padded CSR bucket capacity; P(deg>64 | Binom(1.6M,1e-5)) ~ 1e-15

// output layout offsets (flat f32)
#define OUT_NODES 0
#define OUT_EDGES 65536
#define OUT_FUEL  589824
#define OUT_ALT   917504
#define OUT_SLOPE 983040
#define OUT_MU    1048576
#define OUT_LG    1049600

__device__ __forceinline__ unsigned short f2bf(float f) {
    unsigned int u = __float_as_uint(f);
    return (unsigned short)((u + 0x7FFFu + ((u >> 16) & 1u)) >> 16);  // RNE
}
__device__ __forceinline__ float bf2f(unsigned short h) {
    return __uint_as_float(((unsigned int)h) << 16);
}
__device__ __forceinline__ float bfLO(unsigned int u) { return __uint_as_float(u << 16); }
__device__ __forceinline__ float bfHI(unsigned int u) { return __uint_as_float(u & 0xFFFF0000u); }

// batch is sorted: count[b] = upper_bound(b) - lower_bound(b)
__global__ void batch_count(const int* __restrict__ batch, int* __restrict__ bcnt, int n) {
    int b = threadIdx.x;
    if (b >= BATCH_B) return;
    int lo = 0, hi = n;
    while (lo < hi) { int mid = (lo + hi) >> 1; if (batch[mid] < b) lo = mid + 1; else hi = mid; }
    int start = lo;
    lo = 0; hi = n;
    while (lo < hi) { int mid = (lo + hi) >> 1; if (batch[mid] <= b) lo = mid + 1; else hi = mid; }
    bcnt[b] = lo - start;
}

// one-pass padded-CSR build: rank atomic gives slot AND final counts (deg)
__global__ void fill_pass(const int* __restrict__ src, const int* __restrict__ dst,
                          int* __restrict__ cnt, int* __restrict__ adj, int n) {
    int i = blockIdx.x * 256 + threadIdx.x;
    if (i < n) {
        int d = dst[i];
        int r = atomicAdd(&cnt[d], 1);
        if (r < CAP) __builtin_nontemporal_store(src[i], &adj[(size_t)d * CAP + r]);
    }
}

__global__ void dinv_kernel(const int* __restrict__ cnt, float* __restrict__ dinv, int n) {
    int i = blockIdx.x * blockDim.x + threadIdx.x;
    if (i < n) dinv[i] = rsqrtf((float)(cnt[i] + 1));  // +1 = self loop
}

// xs = dinv (broadcast per row of 32) * x, float4
__global__ void prescale_x(const float* __restrict__ x, const float* __restrict__ dinv,
                           float* __restrict__ xs, int total4) {
    int i4 = blockIdx.x * blockDim.x + threadIdx.x;
    if (i4 < total4) {
        int i = i4 * 4;
        float4 v = *(const float4*)&x[i];
        float d = dinv[i >> 5];
        v.x *= d; v.y *= d; v.z *= d; v.w *= d;
        *(float4*)&xs[i] = v;
    }
}

// agg0 = S x : out[n,f] = dinv[n] * (xs[n,f] + sum_src xs[src,f]); 8 nodes / 256-thr block
__global__ void agg_s32(const float* __restrict__ xs, const int* __restrict__ cnt,
                        const int* __restrict__ adj, const float* __restrict__ dinv,
                        float* __restrict__ out, int N) {
    int t = threadIdx.x;
    int sub = t >> 5, f = t & 31;
    int n = blockIdx.x * 8 + sub;
    if (n >= N) return;
    float s = xs[(size_t)n * 32 + f];
    int e1 = min(cnt[n], CAP);
    const int* ap = &adj[(size_t)n * CAP];
    int e = 0;
    for (; e + 4 <= e1; e += 4) {
        int i0 = ap[e], i1 = ap[e + 1], i2 = ap[e + 2], i3 = ap[e + 3];
        s += (xs[(size_t)i0 * 32 + f] + xs[(size_t)i1 * 32 + f])
           + (xs[(size_t)i2 * 32 + f] + xs[(size_t)i3 * 32 + f]);
    }
    for (; e < e1; e++) s += xs[(size_t)ap[e] * 32 + f];
    out[(size_t)n * 32 + f] = dinv[n] * s;
}

// 128-dim bf16-table aggregation: out[n,:] = epi(dinv[n] * (tbl[n,:] + sum_src tbl[src,:]))
// tbl viewed as uint[n][64] (2 bf16 per uint). 4 nodes per 256-thread block.
template <bool BIASRELU, bool OUT_BF16>
__global__ void agg128(const unsigned int* __restrict__ tbl, const int* __restrict__ cnt,
                       const int* __restrict__ adj, const float* __restrict__ dinv,
                       const float* __restrict__ bias, void* __restrict__ outv, int N) {
    int t = threadIdx.x;
    int sub = t >> 6, f2 = t & 63;
    int n = blockIdx.x * 4 + sub;
    if (n >= N) return;
    unsigned int su = tbl[(size_t)n * 64 + f2];
    float s0 = bfLO(su), s1 = bfHI(su);
    int e1 = min(cnt[n], CAP);
    const int* ap = &adj[(size_t)n * CAP];
    int e = 0;
    for (; e + 4 <= e1; e += 4) {
        int i0 = ap[e], i1 = ap[e + 1], i2 = ap[e + 2], i3 = ap[e + 3];
        unsigned int u0 = tbl[(size_t)i0 * 64 + f2];
        unsigned int u1 = tbl[(size_t)i1 * 64 + f2];
        unsigned int u2 = tbl[(size_t)i2 * 64 + f2];
        unsigned int u3 = tbl[(size_t)i3 * 64 + f2];
        s0 += (bfLO(u0) + bfLO(u1)) + (bfLO(u2) + bfLO(u3));
        s1 += (bfHI(u0) + bfHI(u1)) + (bfHI(u2) + bfHI(u3));
    }
    for (; e < e1; e++) {
        unsigned int u = tbl[(size_t)ap[e] * 64 + f2];
        s0 += bfLO(u); s1 += bfHI(u);
    }
    float d = dinv[n];
    float v0 = d * s0, v1 = d * s1;
    if (BIASRELU) {
        v0 = fmaxf(v0 + bias[2 * f2], 0.f);
        v1 = fmaxf(v1 + bias[2 * f2 + 1], 0.f);
    }
    if (OUT_BF16) {
        unsigned int pk = (unsigned int)f2bf(v0) | ((unsigned int)f2bf(v1) << 16);
        ((unsigned int*)outv)[(size_t)n * 64 + f2] = pk;
    } else {
        *(float2*)&((float*)outv)[(size_t)n * 128 + 2 * f2] = make_float2(v0, v1);
    }
}

// Register-tiled matmul, dual-branch via blockIdx.y, bf16-capable in/out, strided slices.
// out[n, OUT_OFF_Y*y + f] = epi(sum_k in[n, IN_OFF_Y*y + k] * W[k,f])
template <int K, int F, int TM, int IN_STRIDE, int IN_OFF_Y, int OUT_STRIDE, int OUT_OFF_Y,
          bool BIASRELU, bool SCALE, bool IN_BF16, bool OUT_BF16>
__global__ __launch_bounds__(256) void matmulX(
    const void* __restrict__ inv, const float* __restrict__ Wa, const float* __restrict__ Wb,
    const float* __restrict__ biasa, const float* __restrict__ biasb,
    const float* __restrict__ dinv, void* __restrict__ outv, int N) {
    constexpr int TN = 4;
    constexpr int CG = F / TN;
    constexpr int RG = 256 / CG;
    constexpr int BM = TM * RG;
    const int y = blockIdx.y;
    const float* W = (y == 0) ? Wa : Wb;
    const float* bias = (y == 0) ? biasa : biasb;
    __shared__ float Ws[K * F];
    __shared__ float xs[BM][K];
    int tid = threadIdx.x;
    for (int i = tid * 4; i < K * F; i += 1024)
        *(float4*)&Ws[i] = *(const float4*)&W[i];
    int node0 = blockIdx.x * BM;
    for (int i = tid * 4; i < BM * K; i += 1024) {
        int r = i / K, k = i % K;
        int n = node0 + r;
        float4 v;
        if (n < N) {
            size_t off = (size_t)n * IN_STRIDE + y * IN_OFF_Y + k;
            if (IN_BF16) {
                ushort4 u = *(const ushort4*)((const unsigned short*)inv + off);
                v.x = bf2f(u.x); v.y = bf2f(u.y); v.z = bf2f(u.z); v.w = bf2f(u.w);
            } else {
                v = *(const float4*)((const float*)inv + off);
            }
        } else v = make_float4(0.f, 0.f, 0.f, 0.f);
        *(float4*)&xs[r][k] = v;
    }
    __syncthreads();
    int cg = tid % CG, rg = tid / CG;
    int f0 = cg * TN;
    float acc[TM][TN];
#pragma unroll
    for (int m = 0; m < TM; m++)
#pragma unroll
        for (int j = 0; j < TN; j++) acc[m][j] = 0.f;
    for (int k4 = 0; k4 < K; k4 += 4) {
        float4 wv[4];
#pragma unroll
        for (int kk = 0; kk < 4; kk++) wv[kk] = *(const float4*)&Ws[(k4 + kk) * F + f0];
#pragma unroll
        for (int m = 0; m < TM; m++) {
            float4 xv = *(const float4*)&xs[rg * TM + m][k4];
#pragma unroll
            for (int kk = 0; kk < 4; kk++) {
                float xk = (&xv.x)[kk];
                acc[m][0] += xk * wv[kk].x;
                acc[m][1] += xk * wv[kk].y;
                acc[m][2] += xk * wv[kk].z;
                acc[m][3] += xk * wv[kk].w;
            }
        }
    }
#pragma unroll
    for (int m = 0; m < TM; m++) {
        int n = node0 + rg * TM + m;
        if (n < N) {
            float vv[TN];
            float d = SCALE ? dinv[n] : 1.f;
#pragma unroll
            for (int j = 0; j < TN; j++) {
                float v = acc[m][j];
                if (BIASRELU) v = fmaxf(v + bias[f0 + j], 0.f);
                if (SCALE) v *= d;
                vv[j] = v;
            }
            size_t off = (size_t)n * OUT_STRIDE + y * OUT_OFF_Y + f0;
            if (OUT_BF16) {
                ushort4 u;
                u.x = f2bf(vv[0]); u.y = f2bf(vv[1]); u.z = f2bf(vv[2]); u.w = f2bf(vv[3]);
                *(ushort4*)((unsigned short*)outv + off) = u;
            } else {
                *(float4*)((float*)outv + off) = make_float4(vv[0], vv[1], vv[2], vv[3]);
            }
        }
    }
}

// concat weights/biases for fused layer1 and fused layer3 bias
__global__ void prep_cat(const float* __restrict__ w1m, const float* __restrict__ w1l,
                         const float* __restrict__ b1m, const float* __restrict__ b1l,
                         const float* __restrict__ b3m, const float* __restrict__ b3l,
                         float* __restrict__ wcat1, float* __restrict__ bcat1,
                         float* __restrict__ bcat3) {
    int i = blockIdx.x * 256 + threadIdx.x;
    if (i < 32 * 128) {
        int k = i >> 7, f = i & 127;
        wcat1[i] = (f < 64) ? w1m[k * 64 + f] : w1l[k * 64 + f - 64];
    } else if (i < 32 * 128 + 128) {
        int f = i - 32 * 128;
        bcat1[f] = (f < 64) ? b1m[f] : b1l[f - 64];
    } else if (i < 32 * 128 + 256) {
        int f = i - 32 * 128 - 128;
        bcat3[f] = (f < 64) ? b3m[f] : b3l[f - 64];
    }
}

#define POOL_CHUNK 128
__global__ void pool128(const float* __restrict__ h, const int* __restrict__ batch,
                        float* __restrict__ sums, int n) {
    int f = threadIdx.x;  // 0..127
    int s0 = blockIdx.x * POOL_CHUNK;
    if (s0 >= n) return;
    int s1 = min(s0 + POOL_CHUNK, n);
    int cur = batch[s0];
    float acc = 0.f;
    for (int i = s0; i < s1; i++) {
        int b = batch[i];
        if (b != cur) { atomicAdd(&sums[cur * 128 + f], acc); acc = 0.f; cur = b; }
        acc += h[(size_t)i * 128 + f];
    }
    atomicAdd(&sums[cur * 128 + f], acc);
}

__global__ void finalize_pool(const float* __restrict__ sums, const int* __restrict__ bcnt,
                              float* __restrict__ out, float* __restrict__ zbuf) {
    int i = blockIdx.x * 1024 + threadIdx.x;  // 0..2047
    int b = i >> 7, f = i & 127;
    float c = fmaxf((float)bcnt[b], 1.f);
    float v = sums[i] / c;
    if (f < 64) { out[OUT_MU + b * 64 + f] = v; zbuf[b * 64 + f] = v; }
    else out[OUT_LG + b * 64 + (f - 64)] = v;
}

// zwi[b][t] = bi[t] + sum_k z[b,k]*wi[k*128+t]
__global__ void zwi_kernel(const float* __restrict__ z,
                           const float* __restrict__ nm_wi, const float* __restrict__ nm_bi,
                           const float* __restrict__ em_wi, const float* __restrict__ em_bi,
                           float* __restrict__ zwi_nm, float* __restrict__ zwi_em) {
    int b = blockIdx.x, t = threadIdx.x;  // 16 blocks x 128 threads
    float an = nm_bi[t], ae = em_bi[t];
    for (int k = 0; k < 64; k++) {
        float zv = z[b * 64 + k];
        an += zv * nm_wi[k * 128 + t];
        ae += zv * em_wi[k * 128 + t];
    }
    zwi_nm[b * 128 + t] = an;
    zwi_em[b * 128 + t] = ae;
}

#define DEC_WAVES 4
#define DEC_RPW 8
#define DEC_ROWS (DEC_WAVES * DEC_RPW)  // 32 rows/block

__global__ __launch_bounds__(256) void decoder2(
    const float* __restrict__ zwi_nm, const float* __restrict__ zwi_em,
    const float* __restrict__ nm_wi, const float* __restrict__ em_wi,
    const float* __restrict__ nm_g, const float* __restrict__ nm_be,
    const float* __restrict__ nm_wo, const float* __restrict__ nm_bo,
    const float* __restrict__ em_g, const float* __restrict__ em_be,
    const float* __restrict__ em_wo,
    const float* __restrict__ ex_w, const float* __restrict__ ex_b,
    const float* __restrict__ fu_w, const float* __restrict__ fu_b,
    const float* __restrict__ al_w, const float* __restrict__ al_b,
    const float* __restrict__ sl_w, const float* __restrict__ sl_b,
    const float* __restrict__ em_bo,
    const float* __restrict__ pos_all,
    float* __restrict__ out) {
    __shared__ float s1[DEC_WAVES][DEC_RPW][128];
    int t = threadIdx.x;
    int lane = t & 63, wave = t >> 6;
    int rowBase = blockIdx.x * DEC_ROWS;
    int b = rowBase >> 12;
    int row0 = rowBase + wave * DEC_RPW;

    int f0 = lane, f1 = lane + 64;
    float zn0 = zwi_nm[b * 128 + f0], zn1 = zwi_nm[b * 128 + f1];
    float ze0 = zwi_em[b * 128 + f0], ze1 = zwi_em[b * 128 + f1];
    float wn64_0 = nm_wi[64 * 128 + f0], wn64_1 = nm_wi[64 * 128 + f1];
    float wn65_0 = nm_wi[65 * 128 + f0], wn65_1 = nm_wi[65 * 128 + f1];
    float we64_0 = em_wi[64 * 128 + f0], we64_1 = em_wi[64 * 128 + f1];
    float we65_0 = em_wi[65 * 128 + f0], we65_1 = em_wi[65 * 128 + f1];
    float gn0 = nm_g[f0], gn1 = nm_g[f1], bn0 = nm_be[f0], bn1 = nm_be[f1];
    float ge0 = em_g[f0], ge1 = em_g[f1], be0 = em_be[f0], be1 = em_be[f1];
    float bo0 = nm_bo[f0], bo1 = nm_bo[f1];
    float exw0 = ex_w[f0], exw1 = ex_w[f1];
    float alw0 = al_w[f0], alw1 = al_w[f1];
    float slw0 = sl_w[f0], slw1 = sl_w[f1];
    float fuw0[5], fuw1[5];
#pragma unroll
    for (int j = 0; j < 5; j++) { fuw0[j] = fu_w[f0 * 5 + j]; fuw1[j] = fu_w[f1 * 5 + j]; }
    float ew0[8], ew1[8];
#pragma unroll
    for (int j = 0; j < 8; j++) { ew0[j] = em_wo[f0 * 8 + j]; ew1[j] = em_wo[f1 * 8 + j]; }
    float nhb = 0.f;
    if (lane == 0) nhb = ex_b[0];
    else if (lane < 6) nhb = fu_b[lane - 1];
    else if (lane == 6) nhb = al_b[0];
    else if (lane == 7) nhb = sl_b[0];
    float ehb = (lane < 8) ? em_bo[lane] : 0.f;

    float pxs[DEC_RPW], pys[DEC_RPW];

#pragma unroll
    for (int r = 0; r < DEC_RPW; r++) {
        int row = row0 + r, i = row & (NMAXC - 1);
        float px = pos_all[i * 2], py = pos_all[i * 2 + 1];
        pxs[r] = px; pys[r] = py;
        float a0 = zn0 + px * wn64_0 + py * wn65_0;
        float a1 = zn1 + px * wn64_1 + py * wn65_1;
        float sm = a0 + a1, sq = a0 * a0 + a1 * a1;
#pragma unroll
        for (int d = 1; d < 64; d <<= 1) { sm += __shfl_xor(sm, d); sq += __shfl_xor(sq, d); }
        float mean = sm * (1.f / 128.f);
        float var = sq * (1.f / 128.f) - mean * mean;
        float rstd = rsqrtf(var + 1e-5f);
        s1[wave][r][f0] = fmaxf((a0 - mean) * rstd * gn0 + bn0, 0.f);
        s1[wave][r][f1] = fmaxf((a1 - mean) * rstd * gn1 + bn1, 0.f);
    }

    float acc0[DEC_RPW], acc1[DEC_RPW];
#pragma unroll
    for (int r = 0; r < DEC_RPW; r++) { acc0[r] = bo0; acc1[r] = bo1; }
    for (int k4 = 0; k4 < 32; k4++) {
        float4 sv[DEC_RPW];
#pragma unroll
        for (int r = 0; r < DEC_RPW; r++)
            sv[r] = *(const float4*)&s1[wave][r][k4 * 4];
#pragma unroll
        for (int kk = 0; kk < 4; kk++) {
            int k = k4 * 4 + kk;
            float w0 = nm_wo[k * 128 + f0];
            float w1 = nm_wo[k * 128 + f1];
#pragma unroll
            for (int r = 0; r < DEC_RPW; r++) {
                float skv = (&sv[r].x)[kk];
                acc0[r] += skv * w0;
                acc1[r] += skv * w1;
            }
        }
    }

#pragma unroll
    for (int r = 0; r < DEC_RPW; r++) {
        float h0 = acc0[r], h1 = acc1[r];
        float p[8];
        p[0] = h0 * exw0 + h1 * exw1;
#pragma unroll
        for (int j = 0; j < 5; j++) p[1 + j] = h0 * fuw0[j] + h1 * fuw1[j];
        p[6] = h0 * alw0 + h1 * alw1;
        p[7] = h0 * slw0 + h1 * slw1;
#pragma unroll
        for (int d = 1; d < 64; d <<= 1) {
#pragma unroll
            for (int j = 0; j < 8; j++) p[j] += __shfl_xor(p[j], d);
        }
        int row = row0 + r;
        if (lane < 8) {
            float v = 0.f;
#pragma unroll
            for (int j = 0; j < 8; j++) if (lane == j) v = p[j];
            v += nhb;
            size_t addr = (lane == 0) ? (size_t)(OUT_NODES + row)
                        : (lane < 6) ? (size_t)OUT_FUEL + (size_t)row * 5 + (lane - 1)
                        : (lane == 6) ? (size_t)(OUT_ALT + row)
                                      : (size_t)(OUT_SLOPE + row);
            out[addr] = v;
        }
    }

#pragma unroll
    for (int r = 0; r < DEC_RPW; r++) {
        float px = pxs[r], py = pys[r];
        float a0 = ze0 + px * we64_0 + py * we65_0;
        float a1 = ze1 + px * we64_1 + py * we65_1;
        float sm = a0 + a1, sq = a0 * a0 + a1 * a1;
#pragma unroll
        for (int d = 1; d < 64; d <<= 1) { sm += __shfl_xor(sm, d); sq += __shfl_xor(sq, d); }
        float mean = sm * (1.f / 128.f);
        float var = sq * (1.f / 128.f) - mean * mean;
        float rstd = rsqrtf(var + 1e-5f);
        float se0 = fmaxf((a0 - mean) * rstd * ge0 + be0, 0.f);
        float se1 = fmaxf((a1 - mean) * rstd * ge1 + be1, 0.f);
        float p[8];
#pragma unroll
        for (int j = 0; j < 8; j++) p[j] = se0 * ew0[j] + se1 * ew1[j];
#pragma unroll
        for (int d = 1; d < 64; d <<= 1) {
#pragma unroll
            for (int j = 0; j < 8; j++) p[j] += __shfl_xor(p[j], d);
        }
        if (lane < 8) {
            float v = 0.f;
#pragma unroll
            for (int j = 0; j < 8; j++) if (lane == j) v = p[j];
            out[OUT_EDGES + (size_t)(row0 + r) * 8 + lane] = v + ehb;
        }
    }
}

extern "C" void kernel_launch(void* const* d_in, const int* in_sizes, int n_in,
                              void* d_out, int out_size, void* d_ws, size_t ws_size,
                              hipStream_t stream) {
    const float* x    = (const float*)d_in[0];
    const int* edge   = (const int*)d_in[1];
    const int* batch  = (const int*)d_in[2];
    const float* w1m = (const float*)d_in[3];  const float* b1m = (const float*)d_in[4];
    const float* w2m = (const float*)d_in[5];  const float* b2m = (const float*)d_in[6];
    const float* w3m = (const float*)d_in[7];  const float* b3m = (const float*)d_in[8];
    const float* w1l = (const float*)d_in[9];  const float* b1l = (const float*)d_in[10];
    const float* w2l = (const float*)d_in[11]; const float* b2l = (const float*)d_in[12];
    const float* w3l = (const float*)d_in[13]; const float* b3l = (const float*)d_in[14];
    const float* nm_wi = (const float*)d_in[15]; const float* nm_bi = (const float*)d_in[16];
    const float* nm_g  = (const float*)d_in[17]; const float* nm_be = (const float*)d_in[18];
    const float* nm_wo = (const float*)d_in[19]; const float* nm_bo = (const float*)d_in[20];
    const float* ex_w = (const float*)d_in[21]; const float* ex_b = (const float*)d_in[22];
    const float* fu_w = (const float*)d_in[23]; const float* fu_b = (const float*)d_in[24];
    const float* al_w = (const float*)d_in[25]; const float* al_b = (const float*)d_in[26];
    const float* sl_w = (const float*)d_in[27]; const float* sl_b = (const float*)d_in[28];
    const float* em_wi = (const float*)d_in[29]; const float* em_bi = (const float*)d_in[30];
    const float* em_g  = (const float*)d_in[31]; const float* em_be = (const float*)d_in[32];
    const float* em_wo = (const float*)d_in[33]; const float* em_bo = (const float*)d_in[34];
    const float* pos_all = (const float*)d_in[35];
    float* out = (float*)d_out;

    char* p = (char*)d_ws;
    auto alloc = [&](size_t bytes) -> void* {
        void* r = (void*)p;
        p += ((bytes + 255) / 256) * 256;
        return r;
    };
    int* cnt      = (int*)alloc((size_t)N_NODES * 4);
    float* dinv   = (float*)alloc((size_t)N_NODES * 4);
    int* bcnt     = (int*)alloc(BATCH_B * 4);
    float* sums   = (float*)alloc(BATCH_B * 128 * 4);
    float* zbuf   = (float*)alloc(BATCH_B * LATC * 4);
    float* zwi_nm = (float*)alloc(BATCH_B * 128 * 4);
    float* zwi_em = (float*)alloc(BATCH_B * 128 * 4);
    float* wcat1  = (float*)alloc(32 * 128 * 4);
    float* bcat1  = (float*)alloc(128 * 4);
    float* bcat3  = (float*)alloc(128 * 4);
    int* adj      = (int*)alloc((size_t)N_NODES * CAP * 4);          // 25.6 MB
    float* xs32   = (float*)alloc((size_t)N_NODES * 32 * 4);         // 12.8 MB
    float* agg0   = (float*)alloc((size_t)N_NODES * 32 * 4);         // 12.8 MB
    unsigned short* hA   = (unsigned short*)alloc((size_t)N_NODES * 128 * 2);  // 25.6 MB (also hD)
    unsigned short* hB   = (unsigned short*)alloc((size_t)N_NODES * 128 * 2);  // 25.6 MB
    unsigned short* h256 = (unsigned short*)alloc((size_t)N_NODES * 256 * 2);  // 51.2 MB (also final f32 [n][128])
    unsigned short* hD = hA;                 // hA dead after first agg128
    float* final128 = (float*)h256;          // h256 dead after layer-3 matmul

    const int* srcp = edge;
    const int* dstp = edge + N_EDGESC;

    hipMemsetAsync(cnt, 0, (size_t)N_NODES * 4, stream);
    hipMemsetAsync(sums, 0, (size_t)BATCH_B * 128 * 4, stream);

    fill_pass<<<(N_EDGESC + 255) / 256, 256, 0, stream>>>(srcp, dstp, cnt, adj, N_EDGESC);
    batch_count<<<1, 64, 0, stream>>>(batch, bcnt, N_NODES);
    prep_cat<<<17, 256, 0, stream>>>(w1m, w1l, b1m, b1l, b3m, b3l, wcat1, bcat1, bcat3);
    dinv_kernel<<<(N_NODES + 255) / 256, 256, 0, stream>>>(cnt, dinv, N_NODES);
    prescale_x<<<(N_NODES * 32 / 4 + 255) / 256, 256, 0, stream>>>(x, dinv, xs32, N_NODES * 32 / 4);

    // agg0 = S x  (shared by both branches)
    agg_s32<<<(N_NODES + 7) / 8, 256, 0, stream>>>(xs32, cnt, adj, dinv, agg0, N_NODES);

    // L1 (fused mu|lg): hA = dinv ⊙ relu(agg0 @ [w1m|w1l] + [b1m|b1l])   -> bf16 [n][128]
    matmulX<32, 128, 4, 32, 0, 128, 0, true, true, false, true>
        <<<dim3((N_NODES + 31) / 32, 1), 256, 0, stream>>>(
        agg0, wcat1, nullptr, bcat1, nullptr, dinv, hA, N_NODES);

    // agg #1: hB = [S mu1 | S lg1]  -> bf16 [n][128]
    agg128<false, true><<<(N_NODES + 3) / 4, 256, 0, stream>>>(
        (const unsigned int*)hA, cnt, adj, dinv, nullptr, hB, N_NODES);

    // L2 dual: h256[:, y*128:...] = relu(hB[:, y*64:...] @ w2{m,l} + b2{m,l})  -> bf16 [n][256]
    matmulX<64, 128, 4, 128, 64, 256, 128, true, false, true, true>
        <<<dim3((N_NODES + 31) / 32, 2), 256, 0, stream>>>(
        hB, w2m, w2l, b2m, b2l, nullptr, h256, N_NODES);

    // L3 dual: hD[:, y*64:...] = dinv ⊙ (h256[:, y*128:...] @ w3{m,l})  -> bf16 [n][128]
    matmulX<128, 64, 3, 256, 128, 128, 64, false, true, true, true>
        <<<dim3((N_NODES + 47) / 48, 2), 256, 0, stream>>>(
        h256, w3m, w3l, nullptr, nullptr, dinv, hD, N_NODES);

    // agg #2: final = relu(dinv*(sum) + [b3m|b3l]) = [mu3|lg3]  -> f32 [n][128]
    agg128<true, false><<<(N_NODES + 3) / 4, 256, 0, stream>>>(
        (const unsigned int*)hD, cnt, adj, dinv, bcat3, final128, N_NODES);

    pool128<<<(N_NODES + POOL_CHUNK - 1) / POOL_CHUNK, 128, 0, stream>>>(final128, batch, sums, N_NODES);
    finalize_pool<<<2, 1024, 0, stream>>>(sums, bcnt, out, zbuf);

    zwi_kernel<<<BATCH_B, 128, 0, stream>>>(zbuf, nm_wi, nm_bi, em_wi, em_bi, zwi_nm, zwi_em);

    decoder2<<<BATCH_B * NMAXC / DEC_ROWS, 256, 0, stream>>>(
        zwi_nm, zwi_em, nm_wi, em_wi, nm_g, nm_be, nm_wo, nm_bo,
        em_g, em_be, em_wo, ex_w, ex_b, fu_w, fu_b, al_w, al_b, sl_w, sl_b,
        em_bo, pos_all, out);
}

// Round 5
// 632.303 us; speedup vs baseline: 5.0922x; 1.0446x over previous
//
#include <hip/hip_runtime.h>
#include <hip/hip_bf16.h>

#define N_NODES 100000
#define N_EDGESC 1600000
#define BATCH_B 16
#define NMAXC 4096
#define LATC 64
#define CAP 64  // padded CSR bucket capacity; deg ~ Poisson(16), P(deg>64) ~ 1e-15

// output layout offsets (flat f32)
#define OUT_NODES 0
#define OUT_EDGES 65536
#define OUT_FUEL  589824
#define OUT_ALT   917504
#define OUT_SLOPE 983040
#define OUT_MU    1048576
#define OUT_LG    1049600

__device__ __forceinline__ unsigned short f2bf(float f) {
    unsigned int u = __float_as_uint(f);
    return (unsigned short)((u + 0x7FFFu + ((u >> 16) & 1u)) >> 16);  // RNE
}
__device__ __forceinline__ float bf2f(unsigned short h) {
    return __uint_as_float(((unsigned int)h) << 16);
}
__device__ __forceinline__ float bfLO(unsigned int u) { return __uint_as_float(u << 16); }
__device__ __forceinline__ float bfHI(unsigned int u) { return __uint_as_float(u & 0xFFFF0000u); }

// batch is sorted: count[b] = upper_bound(b) - lower_bound(b)
__global__ void batch_count(const int* __restrict__ batch, int* __restrict__ bcnt, int n) {
    int b = threadIdx.x;
    if (b >= BATCH_B) return;
    int lo = 0, hi = n;
    while (lo < hi) { int mid = (lo + hi) >> 1; if (batch[mid] < b) lo = mid + 1; else hi = mid; }
    int start = lo;
    lo = 0; hi = n;
    while (lo < hi) { int mid = (lo + hi) >> 1; if (batch[mid] <= b) lo = mid + 1; else hi = mid; }
    bcnt[b] = lo - start;
}

// one-pass padded-CSR build: rank atomic gives slot AND final counts (deg)
__global__ void fill_pass(const int* __restrict__ src, const int* __restrict__ dst,
                          int* __restrict__ cnt, int* __restrict__ adj, int n) {
    int i = blockIdx.x * 256 + threadIdx.x;
    if (i < n) {
        int d = dst[i];
        int r = atomicAdd(&cnt[d], 1);
        if (r < CAP) __builtin_nontemporal_store(src[i], &adj[(size_t)d * CAP + r]);
    }
}

__global__ void dinv_kernel(const int* __restrict__ cnt, float* __restrict__ dinv, int n) {
    int i = blockIdx.x * blockDim.x + threadIdx.x;
    if (i < n) dinv[i] = rsqrtf((float)(cnt[i] + 1));  // +1 = self loop
}

// xs (bf16 packed, [n][16] uints) = dinv[n] * x[n][32]
__global__ void prescale_x(const float* __restrict__ x, const float* __restrict__ dinv,
                           unsigned int* __restrict__ xs, int total2) {
    int i2 = blockIdx.x * 256 + threadIdx.x;
    if (i2 < total2) {
        float2 v = *(const float2*)&x[i2 * 2];
        float d = dinv[i2 >> 4];
        xs[i2] = (unsigned int)f2bf(v.x * d) | ((unsigned int)f2bf(v.y * d) << 16);
    }
}

// agg0 = S x : out[n,f] = dinv[n]*(xs[n,f] + sum_src xs[src,f]); bf16 table, f32 out
// 16 nodes per 256-thread block, 16 lanes (=32 feats) per node
__global__ void agg_s32(const unsigned int* __restrict__ xs, const int* __restrict__ cnt,
                        const int* __restrict__ adj, const float* __restrict__ dinv,
                        float* __restrict__ out, int N) {
    int t = threadIdx.x;
    int sub = t >> 4, f = t & 15;
    int n = blockIdx.x * 16 + sub;
    if (n >= N) return;
    unsigned int su = xs[(size_t)n * 16 + f];
    float s0 = bfLO(su), s1 = bfHI(su);
    int e1 = min(cnt[n], CAP);
    const int* ap = &adj[(size_t)n * CAP];
    int e = 0;
    for (; e + 4 <= e1; e += 4) {
        int i0 = ap[e], i1 = ap[e + 1], i2 = ap[e + 2], i3 = ap[e + 3];
        unsigned int u0 = xs[(size_t)i0 * 16 + f];
        unsigned int u1 = xs[(size_t)i1 * 16 + f];
        unsigned int u2 = xs[(size_t)i2 * 16 + f];
        unsigned int u3 = xs[(size_t)i3 * 16 + f];
        s0 += (bfLO(u0) + bfLO(u1)) + (bfLO(u2) + bfLO(u3));
        s1 += (bfHI(u0) + bfHI(u1)) + (bfHI(u2) + bfHI(u3));
    }
    for (; e < e1; e++) {
        unsigned int u = xs[(size_t)ap[e] * 16 + f];
        s0 += bfLO(u); s1 += bfHI(u);
    }
    float d = dinv[n];
    *(float2*)&out[(size_t)n * 32 + 2 * f] = make_float2(d * s0, d * s1);
}

// 128-dim bf16-table aggregation: out[n,:] = epi(dinv[n] * (tbl[n,:] + sum_src tbl[src,:]))
template <bool BIASRELU, bool OUT_BF16>
__global__ void agg128(const unsigned int* __restrict__ tbl, const int* __restrict__ cnt,
                       const int* __restrict__ adj, const float* __restrict__ dinv,
                       const float* __restrict__ bias, void* __restrict__ outv, int N) {
    int t = threadIdx.x;
    int sub = t >> 6, f2 = t & 63;
    int n = blockIdx.x * 4 + sub;
    if (n >= N) return;
    unsigned int su = tbl[(size_t)n * 64 + f2];
    float s0 = bfLO(su), s1 = bfHI(su);
    int e1 = min(cnt[n], CAP);
    const int* ap = &adj[(size_t)n * CAP];
    int e = 0;
    for (; e + 4 <= e1; e += 4) {
        int i0 = ap[e], i1 = ap[e + 1], i2 = ap[e + 2], i3 = ap[e + 3];
        unsigned int u0 = tbl[(size_t)i0 * 64 + f2];
        unsigned int u1 = tbl[(size_t)i1 * 64 + f2];
        unsigned int u2 = tbl[(size_t)i2 * 64 + f2];
        unsigned int u3 = tbl[(size_t)i3 * 64 + f2];
        s0 += (bfLO(u0) + bfLO(u1)) + (bfLO(u2) + bfLO(u3));
        s1 += (bfHI(u0) + bfHI(u1)) + (bfHI(u2) + bfHI(u3));
    }
    for (; e < e1; e++) {
        unsigned int u = tbl[(size_t)ap[e] * 64 + f2];
        s0 += bfLO(u); s1 += bfHI(u);
    }
    float d = dinv[n];
    float v0 = d * s0, v1 = d * s1;
    if (BIASRELU) {
        v0 = fmaxf(v0 + bias[2 * f2], 0.f);
        v1 = fmaxf(v1 + bias[2 * f2 + 1], 0.f);
    }
    if (OUT_BF16) {
        unsigned int pk = (unsigned int)f2bf(v0) | ((unsigned int)f2bf(v1) << 16);
        ((unsigned int*)outv)[(size_t)n * 64 + f2] = pk;
    } else {
        *(float2*)&((float*)outv)[(size_t)n * 128 + 2 * f2] = make_float2(v0, v1);
    }
}

// Register-tiled matmul, dual-branch via blockIdx.y, bf16 in/out, padded LDS (no bank conflicts).
template <int K, int F, int TM, int IN_STRIDE, int IN_OFF_Y, int OUT_STRIDE, int OUT_OFF_Y,
          bool BIASRELU, bool SCALE, bool IN_BF16, bool OUT_BF16>
__global__ __launch_bounds__(256) void matmulX(
    const void* __restrict__ inv, const float* __restrict__ Wa, const float* __restrict__ Wb,
    const float* __restrict__ biasa, const float* __restrict__ biasb,
    const float* __restrict__ dinv, void* __restrict__ outv, int N) {
    constexpr int TN = 4;
    constexpr int CG = F / TN;
    constexpr int RG = 256 / CG;
    constexpr int BM = TM * RG;
    constexpr int KP = IN_BF16 ? (K + 8) : (K + 4);  // padded row -> bank rotation
    const int y = blockIdx.y;
    const float* W = (y == 0) ? Wa : Wb;
    const float* bias = (y == 0) ? biasa : biasb;
    __shared__ float Ws[K * F];
    __shared__ alignas(16) char xsraw[(size_t)BM * KP * (IN_BF16 ? 2 : 4)];
    int tid = threadIdx.x;
    for (int i = tid * 4; i < K * F; i += 1024)
        *(float4*)&Ws[i] = *(const float4*)&W[i];
    int node0 = blockIdx.x * BM;
    if constexpr (IN_BF16) {
        unsigned short* xs = (unsigned short*)xsraw;
        for (int i = tid * 8; i < BM * K; i += 2048) {
            int r = i / K, k = i % K;
            int n = node0 + r;
            uint4 v = make_uint4(0u, 0u, 0u, 0u);
            if (n < N)
                v = *(const uint4*)((const unsigned short*)inv +
                                    (size_t)n * IN_STRIDE + y * IN_OFF_Y + k);
            *(uint4*)&xs[r * KP + k] = v;
        }
    } else {
        float* xs = (float*)xsraw;
        for (int i = tid * 4; i < BM * K; i += 1024) {
            int r = i / K, k = i % K;
            int n = node0 + r;
            float4 v = make_float4(0.f, 0.f, 0.f, 0.f);
            if (n < N)
                v = *(const float4*)((const float*)inv + (size_t)n * IN_STRIDE + y * IN_OFF_Y + k);
            *(float4*)&xs[r * KP + k] = v;
        }
    }
    __syncthreads();
    int cg = tid % CG, rg = tid / CG;
    int f0 = cg * TN;
    const unsigned short* xsb = (const unsigned short*)xsraw;
    const float* xsf = (const float*)xsraw;
    float acc[TM][TN];
#pragma unroll
    for (int m = 0; m < TM; m++)
#pragma unroll
        for (int j = 0; j < TN; j++) acc[m][j] = 0.f;
    for (int k4 = 0; k4 < K; k4 += 4) {
        float4 wv[4];
#pragma unroll
        for (int kk = 0; kk < 4; kk++) wv[kk] = *(const float4*)&Ws[(k4 + kk) * F + f0];
#pragma unroll
        for (int m = 0; m < TM; m++) {
            float4 xv;
            if constexpr (IN_BF16) {
                ushort4 u = *(const ushort4*)&xsb[(rg * TM + m) * KP + k4];
                xv = make_float4(bf2f(u.x), bf2f(u.y), bf2f(u.z), bf2f(u.w));
            } else {
                xv = *(const float4*)&xsf[(rg * TM + m) * KP + k4];
            }
#pragma unroll
            for (int kk = 0; kk < 4; kk++) {
                float xk = (&xv.x)[kk];
                acc[m][0] += xk * wv[kk].x;
                acc[m][1] += xk * wv[kk].y;
                acc[m][2] += xk * wv[kk].z;
                acc[m][3] += xk * wv[kk].w;
            }
        }
    }
#pragma unroll
    for (int m = 0; m < TM; m++) {
        int n = node0 + rg * TM + m;
        if (n < N) {
            float vv[TN];
            float d = SCALE ? dinv[n] : 1.f;
#pragma unroll
            for (int j = 0; j < TN; j++) {
                float v = acc[m][j];
                if (BIASRELU) v = fmaxf(v + bias[f0 + j], 0.f);
                if (SCALE) v *= d;
                vv[j] = v;
            }
            size_t off = (size_t)n * OUT_STRIDE + y * OUT_OFF_Y + f0;
            if (OUT_BF16) {
                ushort4 u;
                u.x = f2bf(vv[0]); u.y = f2bf(vv[1]); u.z = f2bf(vv[2]); u.w = f2bf(vv[3]);
                *(ushort4*)((unsigned short*)outv + off) = u;
            } else {
                *(float4*)((float*)outv + off) = make_float4(vv[0], vv[1], vv[2], vv[3]);
            }
        }
    }
}

// concat weights/biases for fused layer1 and fused layer3 bias
__global__ void prep_cat(const float* __restrict__ w1m, const float* __restrict__ w1l,
                         const float* __restrict__ b1m, const float* __restrict__ b1l,
                         const float* __restrict__ b3m, const float* __restrict__ b3l,
                         float* __restrict__ wcat1, float* __restrict__ bcat1,
                         float* __restrict__ bcat3) {
    int i = blockIdx.x * 256 + threadIdx.x;
    if (i < 32 * 128) {
        int k = i >> 7, f = i & 127;
        wcat1[i] = (f < 64) ? w1m[k * 64 + f] : w1l[k * 64 + f - 64];
    } else if (i < 32 * 128 + 128) {
        int f = i - 32 * 128;
        bcat1[f] = (f < 64) ? b1m[f] : b1l[f - 64];
    } else if (i < 32 * 128 + 256) {
        int f = i - 32 * 128 - 128;
        bcat3[f] = (f < 64) ? b3m[f] : b3l[f - 64];
    }
}

#define POOL_CHUNK 128
// h is bf16-packed [n][64] uints
__global__ void pool128(const unsigned int* __restrict__ h, const int* __restrict__ batch,
                        float* __restrict__ sums, int n) {
    int f = threadIdx.x;  // 0..63
    int s0 = blockIdx.x * POOL_CHUNK;
    if (s0 >= n) return;
    int s1 = min(s0 + POOL_CHUNK, n);
    int cur = batch[s0];
    float a0 = 0.f, a1 = 0.f;
    for (int i = s0; i < s1; i++) {
        int b = batch[i];
        if (b != cur) {
            atomicAdd(&sums[cur * 128 + 2 * f], a0);
            atomicAdd(&sums[cur * 128 + 2 * f + 1], a1);
            a0 = a1 = 0.f; cur = b;
        }
        unsigned int u = h[(size_t)i * 64 + f];
        a0 += bfLO(u); a1 += bfHI(u);
    }
    atomicAdd(&sums[cur * 128 + 2 * f], a0);
    atomicAdd(&sums[cur * 128 + 2 * f + 1], a1);
}

__global__ void finalize_pool(const float* __restrict__ sums, const int* __restrict__ bcnt,
                              float* __restrict__ out, float* __restrict__ zbuf) {
    int i = blockIdx.x * 1024 + threadIdx.x;  // 0..2047
    int b = i >> 7, f = i & 127;
    float c = fmaxf((float)bcnt[b], 1.f);
    float v = sums[i] / c;
    if (f < 64) { out[OUT_MU + b * 64 + f] = v; zbuf[b * 64 + f] = v; }
    else out[OUT_LG + b * 64 + (f - 64)] = v;
}

// zwi[b][t] = bi[t] + sum_k z[b,k]*wi[k*128+t]
__global__ void zwi_kernel(const float* __restrict__ z,
                           const float* __restrict__ nm_wi, const float* __restrict__ nm_bi,
                           const float* __restrict__ em_wi, const float* __restrict__ em_bi,
                           float* __restrict__ zwi_nm, float* __restrict__ zwi_em) {
    int b = blockIdx.x, t = threadIdx.x;  // 16 blocks x 128 threads
    float an = nm_bi[t], ae = em_bi[t];
    for (int k = 0; k < 64; k++) {
        float zv = z[b * 64 + k];
        an += zv * nm_wi[k * 128 + t];
        ae += zv * em_wi[k * 128 + t];
    }
    zwi_nm[b * 128 + t] = an;
    zwi_em[b * 128 + t] = ae;
}

#define DEC_WAVES 4
#define DEC_RPW 8
#define DEC_ROWS (DEC_WAVES * DEC_RPW)  // 32 rows/block

__global__ __launch_bounds__(256) void decoder2(
    const float* __restrict__ zwi_nm, const float* __restrict__ zwi_em,
    const float* __restrict__ nm_wi, const float* __restrict__ em_wi,
    const float* __restrict__ nm_g, const float* __restrict__ nm_be,
    const float* __restrict__ nm_wo, const float* __restrict__ nm_bo,
    const float* __restrict__ em_g, const float* __restrict__ em_be,
    const float* __restrict__ em_wo,
    const float* __restrict__ ex_w, const float* __restrict__ ex_b,
    const float* __restrict__ fu_w, const float* __restrict__ fu_b,
    const float* __restrict__ al_w, const float* __restrict__ al_b,
    const float* __restrict__ sl_w, const float* __restrict__ sl_b,
    const float* __restrict__ em_bo,
    const float* __restrict__ pos_all,
    float* __restrict__ out) {
    __shared__ float s1[DEC_WAVES][DEC_RPW][128];
    int t = threadIdx.x;
    int lane = t & 63, wave = t >> 6;
    int rowBase = blockIdx.x * DEC_ROWS;
    int b = rowBase >> 12;
    int row0 = rowBase + wave * DEC_RPW;

    int f0 = lane, f1 = lane + 64;
    float zn0 = zwi_nm[b * 128 + f0], zn1 = zwi_nm[b * 128 + f1];
    float ze0 = zwi_em[b * 128 + f0], ze1 = zwi_em[b * 128 + f1];
    float wn64_0 = nm_wi[64 * 128 + f0], wn64_1 = nm_wi[64 * 128 + f1];
    float wn65_0 = nm_wi[65 * 128 + f0], wn65_1 = nm_wi[65 * 128 + f1];
    float we64_0 = em_wi[64 * 128 + f0], we64_1 = em_wi[64 * 128 + f1];
    float we65_0 = em_wi[65 * 128 + f0], we65_1 = em_wi[65 * 128 + f1];
    float gn0 = nm_g[f0], gn1 = nm_g[f1], bn0 = nm_be[f0], bn1 = nm_be[f1];
    float ge0 = em_g[f0], ge1 = em_g[f1], be0 = em_be[f0], be1 = em_be[f1];
    float bo0 = nm_bo[f0], bo1 = nm_bo[f1];
    float exw0 = ex_w[f0], exw1 = ex_w[f1];
    float alw0 = al_w[f0], alw1 = al_w[f1];
    float slw0 = sl_w[f0], slw1 = sl_w[f1];
    float fuw0[5], fuw1[5];
#pragma unroll
    for (int j = 0; j < 5; j++) { fuw0[j] = fu_w[f0 * 5 + j]; fuw1[j] = fu_w[f1 * 5 + j]; }
    float ew0[8], ew1[8];
#pragma unroll
    for (int j = 0; j < 8; j++) { ew0[j] = em_wo[f0 * 8 + j]; ew1[j] = em_wo[f1 * 8 + j]; }
    float nhb = 0.f;
    if (lane == 0) nhb = ex_b[0];
    else if (lane < 6) nhb = fu_b[lane - 1];
    else if (lane == 6) nhb = al_b[0];
    else if (lane == 7) nhb = sl_b[0];
    float ehb = (lane < 8) ? em_bo[lane] : 0.f;

    float pxs[DEC_RPW], pys[DEC_RPW];

#pragma unroll
    for (int r = 0; r < DEC_RPW; r++) {
        int row = row0 + r, i = row & (NMAXC - 1);
        float px = pos_all[i * 2], py = pos_all[i * 2 + 1];
        pxs[r] = px; pys[r] = py;
        float a0 = zn0 + px * wn64_0 + py * wn65_0;
        float a1 = zn1 + px * wn64_1 + py * wn65_1;
        float sm = a0 + a1, sq = a0 * a0 + a1 * a1;
#pragma unroll
        for (int d = 1; d < 64; d <<= 1) { sm += __shfl_xor(sm, d); sq += __shfl_xor(sq, d); }
        float mean = sm * (1.f / 128.f);
        float var = sq * (1.f / 128.f) - mean * mean;
        float rstd = rsqrtf(var + 1e-5f);
        s1[wave][r][f0] = fmaxf((a0 - mean) * rstd * gn0 + bn0, 0.f);
        s1[wave][r][f1] = fmaxf((a1 - mean) * rstd * gn1 + bn1, 0.f);
    }

    float acc0[DEC_RPW], acc1[DEC_RPW];
#pragma unroll
    for (int r = 0; r < DEC_RPW; r++) { acc0[r] = bo0; acc1[r] = bo1; }
    for (int k4 = 0; k4 < 32; k4++) {
        float4 sv[DEC_RPW];
#pragma unroll
        for (int r = 0; r < DEC_RPW; r++)
            sv[r] = *(const float4*)&s1[wave][r][k4 * 4];
#pragma unroll
        for (int kk = 0; kk < 4; kk++) {
            int k = k4 * 4 + kk;
            float w0 = nm_wo[k * 128 + f0];
            float w1 = nm_wo[k * 128 + f1];
#pragma unroll
            for (int r = 0; r < DEC_RPW; r++) {
                float skv = (&sv[r].x)[kk];
                acc0[r] += skv * w0;
                acc1[r] += skv * w1;
            }
        }
    }

#pragma unroll
    for (int r = 0; r < DEC_RPW; r++) {
        float h0 = acc0[r], h1 = acc1[r];
        float p[8];
        p[0] = h0 * exw0 + h1 * exw1;
#pragma unroll
        for (int j = 0; j < 5; j++) p[1 + j] = h0 * fuw0[j] + h1 * fuw1[j];
        p[6] = h0 * alw0 + h1 * alw1;
        p[7] = h0 * slw0 + h1 * slw1;
#pragma unroll
        for (int d = 1; d < 64; d <<= 1) {
#pragma unroll
            for (int j = 0; j < 8; j++) p[j] += __shfl_xor(p[j], d);
        }
        int row = row0 + r;
        if (lane < 8) {
            float v = 0.f;
#pragma unroll
            for (int j = 0; j < 8; j++) if (lane == j) v = p[j];
            v += nhb;
            size_t addr = (lane == 0) ? (size_t)(OUT_NODES + row)
                        : (lane < 6) ? (size_t)OUT_FUEL + (size_t)row * 5 + (lane - 1)
                        : (lane == 6) ? (size_t)(OUT_ALT + row)
                                      : (size_t)(OUT_SLOPE + row);
            out[addr] = v;
        }
    }

#pragma unroll
    for (int r = 0; r < DEC_RPW; r++) {
        float px = pxs[r], py = pys[r];
        float a0 = ze0 + px * we64_0 + py * we65_0;
        float a1 = ze1 + px * we64_1 + py * we65_1;
        float sm = a0 + a1, sq = a0 * a0 + a1 * a1;
#pragma unroll
        for (int d = 1; d < 64; d <<= 1) { sm += __shfl_xor(sm, d); sq += __shfl_xor(sq, d); }
        float mean = sm * (1.f / 128.f);
        float var = sq * (1.f / 128.f) - mean * mean;
        float rstd = rsqrtf(var + 1e-5f);
        float se0 = fmaxf((a0 - mean) * rstd * ge0 + be0, 0.f);
        float se1 = fmaxf((a1 - mean) * rstd * ge1 + be1, 0.f);
        float p[8];
#pragma unroll
        for (int j = 0; j < 8; j++) p[j] = se0 * ew0[j] + se1 * ew1[j];
#pragma unroll
        for (int d = 1; d < 64; d <<= 1) {
#pragma unroll
            for (int j = 0; j < 8; j++) p[j] += __shfl_xor(p[j], d);
        }
        if (lane < 8) {
            float v = 0.f;
#pragma unroll
            for (int j = 0; j < 8; j++) if (lane == j) v = p[j];
            out[OUT_EDGES + (size_t)(row0 + r) * 8 + lane] = v + ehb;
        }
    }
}

extern "C" void kernel_launch(void* const* d_in, const int* in_sizes, int n_in,
                              void* d_out, int out_size, void* d_ws, size_t ws_size,
                              hipStream_t stream) {
    const float* x    = (const float*)d_in[0];
    const int* edge   = (const int*)d_in[1];
    const int* batch  = (const int*)d_in[2];
    const float* w1m = (const float*)d_in[3];  const float* b1m = (const float*)d_in[4];
    const float* w2m = (const float*)d_in[5];  const float* b2m = (const float*)d_in[6];
    const float* w3m = (const float*)d_in[7];  const float* b3m = (const float*)d_in[8];
    const float* w1l = (const float*)d_in[9];  const float* b1l = (const float*)d_in[10];
    const float* w2l = (const float*)d_in[11]; const float* b2l = (const float*)d_in[12];
    const float* w3l = (const float*)d_in[13]; const float* b3l = (const float*)d_in[14];
    const float* nm_wi = (const float*)d_in[15]; const float* nm_bi = (const float*)d_in[16];
    const float* nm_g  = (const float*)d_in[17]; const float* nm_be = (const float*)d_in[18];
    const float* nm_wo = (const float*)d_in[19]; const float* nm_bo = (const float*)d_in[20];
    const float* ex_w = (const float*)d_in[21]; const float* ex_b = (const float*)d_in[22];
    const float* fu_w = (const float*)d_in[23]; const float* fu_b = (const float*)d_in[24];
    const float* al_w = (const float*)d_in[25]; const float* al_b = (const float*)d_in[26];
    const float* sl_w = (const float*)d_in[27]; const float* sl_b = (const float*)d_in[28];
    const float* em_wi = (const float*)d_in[29]; const float* em_bi = (const float*)d_in[30];
    const float* em_g  = (const float*)d_in[31]; const float* em_be = (const float*)d_in[32];
    const float* em_wo = (const float*)d_in[33]; const float* em_bo = (const float*)d_in[34];
    const float* pos_all = (const float*)d_in[35];
    float* out = (float*)d_out;

    char* p = (char*)d_ws;
    auto alloc = [&](size_t bytes) -> void* {
        void* r = (void*)p;
        p += ((bytes + 255) / 256) * 256;
        return r;
    };
    int* cnt      = (int*)alloc((size_t)N_NODES * 4);
    float* dinv   = (float*)alloc((size_t)N_NODES * 4);
    int* bcnt     = (int*)alloc(BATCH_B * 4);
    float* sums   = (float*)alloc(BATCH_B * 128 * 4);
    float* zbuf   = (float*)alloc(BATCH_B * LATC * 4);
    float* zwi_nm = (float*)alloc(BATCH_B * 128 * 4);
    float* zwi_em = (float*)alloc(BATCH_B * 128 * 4);
    float* wcat1  = (float*)alloc(32 * 128 * 4);
    float* bcat1  = (float*)alloc(128 * 4);
    float* bcat3  = (float*)alloc(128 * 4);
    int* adj      = (int*)alloc((size_t)N_NODES * CAP * 4);                    // 25.6 MB
    unsigned int* xs32 = (unsigned int*)alloc((size_t)N_NODES * 16 * 4);       // 6.4 MB bf16-packed
    float* agg0   = (float*)alloc((size_t)N_NODES * 32 * 4);                   // 12.8 MB
    unsigned short* hA   = (unsigned short*)alloc((size_t)N_NODES * 128 * 2);  // 25.6 MB (also hD)
    unsigned short* hB   = (unsigned short*)alloc((size_t)N_NODES * 128 * 2);  // 25.6 MB
    unsigned short* h256 = (unsigned short*)alloc((size_t)N_NODES * 256 * 2);  // 51.2 MB (also final bf16)
    unsigned short* hD = hA;                       // hA dead after first agg128
    unsigned int* final128 = (unsigned int*)h256;  // h256 dead after layer-3 matmul

    const int* srcp = edge;
    const int* dstp = edge + N_EDGESC;

    hipMemsetAsync(cnt, 0, (size_t)N_NODES * 4, stream);
    hipMemsetAsync(sums, 0, (size_t)BATCH_B * 128 * 4, stream);

    fill_pass<<<(N_EDGESC + 255) / 256, 256, 0, stream>>>(srcp, dstp, cnt, adj, N_EDGESC);
    batch_count<<<1, 64, 0, stream>>>(batch, bcnt, N_NODES);
    prep_cat<<<17, 256, 0, stream>>>(w1m, w1l, b1m, b1l, b3m, b3l, wcat1, bcat1, bcat3);
    dinv_kernel<<<(N_NODES + 255) / 256, 256, 0, stream>>>(cnt, dinv, N_NODES);
    prescale_x<<<(N_NODES * 16 + 255) / 256, 256, 0, stream>>>(x, dinv, xs32, N_NODES * 16);

    // agg0 = S x  (shared by both branches)
    agg_s32<<<(N_NODES + 15) / 16, 256, 0, stream>>>(xs32, cnt, adj, dinv, agg0, N_NODES);

    // L1 (fused mu|lg): hA = dinv ⊙ relu(agg0 @ [w1m|w1l] + [b1m|b1l])   -> bf16 [n][128]
    matmulX<32, 128, 4, 32, 0, 128, 0, true, true, false, true>
        <<<dim3((N_NODES + 31) / 32, 1), 256, 0, stream>>>(
        agg0, wcat1, nullptr, bcat1, nullptr, dinv, hA, N_NODES);

    // agg #1: hB = [S mu1 | S lg1]  -> bf16 [n][128]
    agg128<false, true><<<(N_NODES + 3) / 4, 256, 0, stream>>>(
        (const unsigned int*)hA, cnt, adj, dinv, nullptr, hB, N_NODES);

    // L2 dual: h256[:, y*128:...] = relu(hB[:, y*64:...] @ w2{m,l} + b2{m,l})  -> bf16 [n][256]
    matmulX<64, 128, 4, 128, 64, 256, 128, true, false, true, true>
        <<<dim3((N_NODES + 31) / 32, 2), 256, 0, stream>>>(
        hB, w2m, w2l, b2m, b2l, nullptr, h256, N_NODES);

    // L3 dual: hD[:, y*64:...] = dinv ⊙ (h256[:, y*128:...] @ w3{m,l})  -> bf16 [n][128]
    matmulX<128, 64, 3, 256, 128, 128, 64, false, true, true, true>
        <<<dim3((N_NODES + 47) / 48, 2), 256, 0, stream>>>(
        h256, w3m, w3l, nullptr, nullptr, dinv, hD, N_NODES);

    // agg #2: final = relu(dinv*(sum) + [b3m|b3l]) = [mu3|lg3]  -> bf16 [n][128]
    agg128<true, true><<<(N_NODES + 3) / 4, 256, 0, stream>>>(
        (const unsigned int*)hD, cnt, adj, dinv, bcat3, final128, N_NODES);

    pool128<<<(N_NODES + POOL_CHUNK - 1) / POOL_CHUNK, 64, 0, stream>>>(final128, batch, sums, N_NODES);
    finalize_pool<<<2, 1024, 0, stream>>>(sums, bcnt, out, zbuf);

    zwi_kernel<<<BATCH_B, 128, 0, stream>>>(zbuf, nm_wi, nm_bi, em_wi, em_bi, zwi_nm, zwi_em);

    decoder2<<<BATCH_B * NMAXC / DEC_ROWS, 256, 0, stream>>>(
        zwi_nm, zwi_em, nm_wi, em_wi, nm_g, nm_be, nm_wo, nm_bo,
        em_g, em_be, em_wo, ex_w, ex_b, fu_w, fu_b, al_w, al_b, sl_w, sl_b,
        em_bo, pos_all, out);
}

// Round 6
// 585.456 us; speedup vs baseline: 5.4996x; 1.0800x over previous
//
#include <hip/hip_runtime.h>
#include <hip/hip_bf16.h>

#define N_NODES 100000
#define N_EDGESC 1600000
#define BATCH_B 16
#define NMAXC 4096
#define LATC 64
#define CAP 64      // padded CSR bucket capacity; deg ~ Binom, P(deg>64) ~ 1e-15
#define NBINS 391   // ceil(100000/256): 256 nodes per bin
#define BINCAP 1024 // edges per (xcd,bin); mean 512, std ~23 -> 22 sigma slack

// output layout offsets (flat f32)
#define OUT_NODES 0
#define OUT_EDGES 65536
#define OUT_FUEL  589824
#define OUT_ALT   917504
#define OUT_SLOPE 983040
#define OUT_MU    1048576
#define OUT_LG    1049600

__device__ __forceinline__ unsigned short f2bf(float f) {
    unsigned int u = __float_as_uint(f);
    return (unsigned short)((u + 0x7FFFu + ((u >> 16) & 1u)) >> 16);  // RNE
}
__device__ __forceinline__ float bf2f(unsigned short h) {
    return __uint_as_float(((unsigned int)h) << 16);
}
__device__ __forceinline__ float bfLO(unsigned int u) { return __uint_as_float(u << 16); }
__device__ __forceinline__ float bfHI(unsigned int u) { return __uint_as_float(u & 0xFFFF0000u); }

// batch is sorted: count[b] = upper_bound(b) - lower_bound(b)
__global__ void batch_count(const int* __restrict__ batch, int* __restrict__ bcnt, int n) {
    int b = threadIdx.x;
    if (b >= BATCH_B) return;
    int lo = 0, hi = n;
    while (lo < hi) { int mid = (lo + hi) >> 1; if (batch[mid] < b) lo = mid + 1; else hi = mid; }
    int start = lo;
    lo = 0; hi = n;
    while (lo < hi) { int mid = (lo + hi) >> 1; if (batch[mid] <= b) lo = mid + 1; else hi = mid; }
    bcnt[b] = lo - start;
}

// ---- CSR build, pass 1: XCD-local binning ----
// blockIdx%8 ~ XCD (round-robin dispatch heuristic; perf-only). All appends to a
// given bin come from one XCD -> its L2 merges the line writes (no fabric ping-pong).
__global__ void bin_pass(const int* __restrict__ src, const int* __restrict__ dst,
                         int* __restrict__ cursors, unsigned int* __restrict__ bins, int n) {
    int i = blockIdx.x * 256 + threadIdx.x;
    int xcd = blockIdx.x & 7;
    if (i < n) {
        int d = dst[i];
        int s = src[i];
        int b = d >> 8;
        int r = atomicAdd(&cursors[(xcd * NBINS + b) * 16], 1);  // 64B-padded cursor
        if (r < BINCAP)
            bins[((size_t)(xcd * NBINS + b)) * BINCAP + r] = ((unsigned int)s << 8) | (d & 255);
    }
}

// ---- CSR build, pass 2: one block per bin; LDS-atomic ranks; dense block-owned writes ----
__global__ void csr_from_bins(const int* __restrict__ cursors, const unsigned int* __restrict__ bins,
                              int* __restrict__ adj, int* __restrict__ cnt,
                              float* __restrict__ dinv, int N) {
    __shared__ int lc[256];
    int b = blockIdx.x;
    int t = threadIdx.x;
    lc[t] = 0;
    __syncthreads();
    int node0 = b * 256;
    for (int x = 0; x < 8; x++) {
        int m = min(cursors[(x * NBINS + b) * 16], BINCAP);
        const unsigned int* bp = &bins[((size_t)(x * NBINS + b)) * BINCAP];
        for (int i = t; i < m; i += 256) {
            unsigned int pk = bp[i];
            int d = pk & 255;
            int s = (int)(pk >> 8);
            int r = atomicAdd(&lc[d], 1);
            if (r < CAP) adj[(size_t)(node0 + d) * CAP + r] = s;
        }
    }
    __syncthreads();
    int n = node0 + t;
    if (n < N) {
        int c = lc[t];
        cnt[n] = c;
        dinv[n] = rsqrtf((float)(c + 1));  // +1 = self loop
    }
}

// xs (bf16 packed, [n][16] uints) = dinv[n] * x[n][32]
__global__ void prescale_x(const float* __restrict__ x, const float* __restrict__ dinv,
                           unsigned int* __restrict__ xs, int total2) {
    int i2 = blockIdx.x * 256 + threadIdx.x;
    if (i2 < total2) {
        float2 v = *(const float2*)&x[i2 * 2];
        float d = dinv[i2 >> 4];
        xs[i2] = (unsigned int)f2bf(v.x * d) | ((unsigned int)f2bf(v.y * d) << 16);
    }
}

// agg0 = S x : out[n,f] = dinv[n]*(xs[n,f] + sum_src xs[src,f]); bf16 table, f32 out
__global__ void agg_s32(const unsigned int* __restrict__ xs, const int* __restrict__ cnt,
                        const int* __restrict__ adj, const float* __restrict__ dinv,
                        float* __restrict__ out, int N) {
    int t = threadIdx.x;
    int sub = t >> 4, f = t & 15;
    int n = blockIdx.x * 16 + sub;
    if (n >= N) return;
    unsigned int su = xs[(size_t)n * 16 + f];
    float s0 = bfLO(su), s1 = bfHI(su);
    int e1 = min(cnt[n], CAP);
    const int* ap = &adj[(size_t)n * CAP];
    int e = 0;
    for (; e + 4 <= e1; e += 4) {
        int i0 = ap[e], i1 = ap[e + 1], i2 = ap[e + 2], i3 = ap[e + 3];
        unsigned int u0 = xs[(size_t)i0 * 16 + f];
        unsigned int u1 = xs[(size_t)i1 * 16 + f];
        unsigned int u2 = xs[(size_t)i2 * 16 + f];
        unsigned int u3 = xs[(size_t)i3 * 16 + f];
        s0 += (bfLO(u0) + bfLO(u1)) + (bfLO(u2) + bfLO(u3));
        s1 += (bfHI(u0) + bfHI(u1)) + (bfHI(u2) + bfHI(u3));
    }
    for (; e < e1; e++) {
        unsigned int u = xs[(size_t)ap[e] * 16 + f];
        s0 += bfLO(u); s1 += bfHI(u);
    }
    float d = dinv[n];
    *(float2*)&out[(size_t)n * 32 + 2 * f] = make_float2(d * s0, d * s1);
}

// 128-dim bf16-table aggregation: out[n,:] = epi(dinv[n] * (tbl[n,:] + sum_src tbl[src,:]))
template <bool BIASRELU, bool OUT_BF16>
__global__ void agg128(const unsigned int* __restrict__ tbl, const int* __restrict__ cnt,
                       const int* __restrict__ adj, const float* __restrict__ dinv,
                       const float* __restrict__ bias, void* __restrict__ outv, int N) {
    int t = threadIdx.x;
    int sub = t >> 6, f2 = t & 63;
    int n = blockIdx.x * 4 + sub;
    if (n >= N) return;
    unsigned int su = tbl[(size_t)n * 64 + f2];
    float s0 = bfLO(su), s1 = bfHI(su);
    int e1 = min(cnt[n], CAP);
    const int* ap = &adj[(size_t)n * CAP];
    int e = 0;
    for (; e + 4 <= e1; e += 4) {
        int i0 = ap[e], i1 = ap[e + 1], i2 = ap[e + 2], i3 = ap[e + 3];
        unsigned int u0 = tbl[(size_t)i0 * 64 + f2];
        unsigned int u1 = tbl[(size_t)i1 * 64 + f2];
        unsigned int u2 = tbl[(size_t)i2 * 64 + f2];
        unsigned int u3 = tbl[(size_t)i3 * 64 + f2];
        s0 += (bfLO(u0) + bfLO(u1)) + (bfLO(u2) + bfLO(u3));
        s1 += (bfHI(u0) + bfHI(u1)) + (bfHI(u2) + bfHI(u3));
    }
    for (; e < e1; e++) {
        unsigned int u = tbl[(size_t)ap[e] * 64 + f2];
        s0 += bfLO(u); s1 += bfHI(u);
    }
    float d = dinv[n];
    float v0 = d * s0, v1 = d * s1;
    if (BIASRELU) {
        v0 = fmaxf(v0 + bias[2 * f2], 0.f);
        v1 = fmaxf(v1 + bias[2 * f2 + 1], 0.f);
    }
    if (OUT_BF16) {
        unsigned int pk = (unsigned int)f2bf(v0) | ((unsigned int)f2bf(v1) << 16);
        ((unsigned int*)outv)[(size_t)n * 64 + f2] = pk;
    } else {
        *(float2*)&((float*)outv)[(size_t)n * 128 + 2 * f2] = make_float2(v0, v1);
    }
}

// Register-tiled matmul, dual-branch via blockIdx.y, bf16 in/out, padded LDS (no bank conflicts).
template <int K, int F, int TM, int IN_STRIDE, int IN_OFF_Y, int OUT_STRIDE, int OUT_OFF_Y,
          bool BIASRELU, bool SCALE, bool IN_BF16, bool OUT_BF16>
__global__ __launch_bounds__(256) void matmulX(
    const void* __restrict__ inv, const float* __restrict__ Wa, const float* __restrict__ Wb,
    const float* __restrict__ biasa, const float* __restrict__ biasb,
    const float* __restrict__ dinv, void* __restrict__ outv, int N) {
    constexpr int TN = 4;
    constexpr int CG = F / TN;
    constexpr int RG = 256 / CG;
    constexpr int BM = TM * RG;
    constexpr int KP = IN_BF16 ? (K + 8) : (K + 4);  // padded row -> bank rotation
    const int y = blockIdx.y;
    const float* W = (y == 0) ? Wa : Wb;
    const float* bias = (y == 0) ? biasa : biasb;
    __shared__ float Ws[K * F];
    __shared__ alignas(16) char xsraw[(size_t)BM * KP * (IN_BF16 ? 2 : 4)];
    int tid = threadIdx.x;
    for (int i = tid * 4; i < K * F; i += 1024)
        *(float4*)&Ws[i] = *(const float4*)&W[i];
    int node0 = blockIdx.x * BM;
    if constexpr (IN_BF16) {
        unsigned short* xs = (unsigned short*)xsraw;
        for (int i = tid * 8; i < BM * K; i += 2048) {
            int r = i / K, k = i % K;
            int n = node0 + r;
            uint4 v = make_uint4(0u, 0u, 0u, 0u);
            if (n < N)
                v = *(const uint4*)((const unsigned short*)inv +
                                    (size_t)n * IN_STRIDE + y * IN_OFF_Y + k);
            *(uint4*)&xs[r * KP + k] = v;
        }
    } else {
        float* xs = (float*)xsraw;
        for (int i = tid * 4; i < BM * K; i += 1024) {
            int r = i / K, k = i % K;
            int n = node0 + r;
            float4 v = make_float4(0.f, 0.f, 0.f, 0.f);
            if (n < N)
                v = *(const float4*)((const float*)inv + (size_t)n * IN_STRIDE + y * IN_OFF_Y + k);
            *(float4*)&xs[r * KP + k] = v;
        }
    }
    __syncthreads();
    int cg = tid % CG, rg = tid / CG;
    int f0 = cg * TN;
    const unsigned short* xsb = (const unsigned short*)xsraw;
    const float* xsf = (const float*)xsraw;
    float acc[TM][TN];
#pragma unroll
    for (int m = 0; m < TM; m++)
#pragma unroll
        for (int j = 0; j < TN; j++) acc[m][j] = 0.f;
    for (int k4 = 0; k4 < K; k4 += 4) {
        float4 wv[4];
#pragma unroll
        for (int kk = 0; kk < 4; kk++) wv[kk] = *(const float4*)&Ws[(k4 + kk) * F + f0];
#pragma unroll
        for (int m = 0; m < TM; m++) {
            float4 xv;
            if constexpr (IN_BF16) {
                ushort4 u = *(const ushort4*)&xsb[(rg * TM + m) * KP + k4];
                xv = make_float4(bf2f(u.x), bf2f(u.y), bf2f(u.z), bf2f(u.w));
            } else {
                xv = *(const float4*)&xsf[(rg * TM + m) * KP + k4];
            }
#pragma unroll
            for (int kk = 0; kk < 4; kk++) {
                float xk = (&xv.x)[kk];
                acc[m][0] += xk * wv[kk].x;
                acc[m][1] += xk * wv[kk].y;
                acc[m][2] += xk * wv[kk].z;
                acc[m][3] += xk * wv[kk].w;
            }
        }
    }
#pragma unroll
    for (int m = 0; m < TM; m++) {
        int n = node0 + rg * TM + m;
        if (n < N) {
            float vv[TN];
            float d = SCALE ? dinv[n] : 1.f;
#pragma unroll
            for (int j = 0; j < TN; j++) {
                float v = acc[m][j];
                if (BIASRELU) v = fmaxf(v + bias[f0 + j], 0.f);
                if (SCALE) v *= d;
                vv[j] = v;
            }
            size_t off = (size_t)n * OUT_STRIDE + y * OUT_OFF_Y + f0;
            if (OUT_BF16) {
                ushort4 u;
                u.x = f2bf(vv[0]); u.y = f2bf(vv[1]); u.z = f2bf(vv[2]); u.w = f2bf(vv[3]);
                *(ushort4*)((unsigned short*)outv + off) = u;
            } else {
                *(float4*)((float*)outv + off) = make_float4(vv[0], vv[1], vv[2], vv[3]);
            }
        }
    }
}

// concat weights/biases for fused layer1 and fused layer3 bias
__global__ void prep_cat(const float* __restrict__ w1m, const float* __restrict__ w1l,
                         const float* __restrict__ b1m, const float* __restrict__ b1l,
                         const float* __restrict__ b3m, const float* __restrict__ b3l,
                         float* __restrict__ wcat1, float* __restrict__ bcat1,
                         float* __restrict__ bcat3) {
    int i = blockIdx.x * 256 + threadIdx.x;
    if (i < 32 * 128) {
        int k = i >> 7, f = i & 127;
        wcat1[i] = (f < 64) ? w1m[k * 64 + f] : w1l[k * 64 + f - 64];
    } else if (i < 32 * 128 + 128) {
        int f = i - 32 * 128;
        bcat1[f] = (f < 64) ? b1m[f] : b1l[f - 64];
    } else if (i < 32 * 128 + 256) {
        int f = i - 32 * 128 - 128;
        bcat3[f] = (f < 64) ? b3m[f] : b3l[f - 64];
    }
}

#define POOL_CHUNK 128
// h is bf16-packed [n][64] uints
__global__ void pool128(const unsigned int* __restrict__ h, const int* __restrict__ batch,
                        float* __restrict__ sums, int n) {
    int f = threadIdx.x;  // 0..63
    int s0 = blockIdx.x * POOL_CHUNK;
    if (s0 >= n) return;
    int s1 = min(s0 + POOL_CHUNK, n);
    int cur = batch[s0];
    float a0 = 0.f, a1 = 0.f;
    for (int i = s0; i < s1; i++) {
        int b = batch[i];
        if (b != cur) {
            atomicAdd(&sums[cur * 128 + 2 * f], a0);
            atomicAdd(&sums[cur * 128 + 2 * f + 1], a1);
            a0 = a1 = 0.f; cur = b;
        }
        unsigned int u = h[(size_t)i * 64 + f];
        a0 += bfLO(u); a1 += bfHI(u);
    }
    atomicAdd(&sums[cur * 128 + 2 * f], a0);
    atomicAdd(&sums[cur * 128 + 2 * f + 1], a1);
}

__global__ void finalize_pool(const float* __restrict__ sums, const int* __restrict__ bcnt,
                              float* __restrict__ out, float* __restrict__ zbuf) {
    int i = blockIdx.x * 1024 + threadIdx.x;  // 0..2047
    int b = i >> 7, f = i & 127;
    float c = fmaxf((float)bcnt[b], 1.f);
    float v = sums[i] / c;
    if (f < 64) { out[OUT_MU + b * 64 + f] = v; zbuf[b * 64 + f] = v; }
    else out[OUT_LG + b * 64 + (f - 64)] = v;
}

// zwi[b][t] = bi[t] + sum_k z[b,k]*wi[k*128+t]
__global__ void zwi_kernel(const float* __restrict__ z,
                           const float* __restrict__ nm_wi, const float* __restrict__ nm_bi,
                           const float* __restrict__ em_wi, const float* __restrict__ em_bi,
                           float* __restrict__ zwi_nm, float* __restrict__ zwi_em) {
    int b = blockIdx.x, t = threadIdx.x;  // 16 blocks x 128 threads
    float an = nm_bi[t], ae = em_bi[t];
    for (int k = 0; k < 64; k++) {
        float zv = z[b * 64 + k];
        an += zv * nm_wi[k * 128 + t];
        ae += zv * em_wi[k * 128 + t];
    }
    zwi_nm[b * 128 + t] = an;
    zwi_em[b * 128 + t] = ae;
}

#define DEC_WAVES 4
#define DEC_RPW 8
#define DEC_ROWS (DEC_WAVES * DEC_RPW)  // 32 rows/block

__global__ __launch_bounds__(256) void decoder2(
    const float* __restrict__ zwi_nm, const float* __restrict__ zwi_em,
    const float* __restrict__ nm_wi, const float* __restrict__ em_wi,
    const float* __restrict__ nm_g, const float* __restrict__ nm_be,
    const float* __restrict__ nm_wo, const float* __restrict__ nm_bo,
    const float* __restrict__ em_g, const float* __restrict__ em_be,
    const float* __restrict__ em_wo,
    const float* __restrict__ ex_w, const float* __restrict__ ex_b,
    const float* __restrict__ fu_w, const float* __restrict__ fu_b,
    const float* __restrict__ al_w, const float* __restrict__ al_b,
    const float* __restrict__ sl_w, const float* __restrict__ sl_b,
    const float* __restrict__ em_bo,
    const float* __restrict__ pos_all,
    float* __restrict__ out) {
    __shared__ float s1[DEC_WAVES][DEC_RPW][128];
    int t = threadIdx.x;
    int lane = t & 63, wave = t >> 6;
    int rowBase = blockIdx.x * DEC_ROWS;
    int b = rowBase >> 12;
    int row0 = rowBase + wave * DEC_RPW;

    int f0 = lane, f1 = lane + 64;
    float zn0 = zwi_nm[b * 128 + f0], zn1 = zwi_nm[b * 128 + f1];
    float ze0 = zwi_em[b * 128 + f0], ze1 = zwi_em[b * 128 + f1];
    float wn64_0 = nm_wi[64 * 128 + f0], wn64_1 = nm_wi[64 * 128 + f1];
    float wn65_0 = nm_wi[65 * 128 + f0], wn65_1 = nm_wi[65 * 128 + f1];
    float we64_0 = em_wi[64 * 128 + f0], we64_1 = em_wi[64 * 128 + f1];
    float we65_0 = em_wi[65 * 128 + f0], we65_1 = em_wi[65 * 128 + f1];
    float gn0 = nm_g[f0], gn1 = nm_g[f1], bn0 = nm_be[f0], bn1 = nm_be[f1];
    float ge0 = em_g[f0], ge1 = em_g[f1], be0 = em_be[f0], be1 = em_be[f1];
    float bo0 = nm_bo[f0], bo1 = nm_bo[f1];
    float exw0 = ex_w[f0], exw1 = ex_w[f1];
    float alw0 = al_w[f0], alw1 = al_w[f1];
    float slw0 = sl_w[f0], slw1 = sl_w[f1];
    float fuw0[5], fuw1[5];
#pragma unroll
    for (int j = 0; j < 5; j++) { fuw0[j] = fu_w[f0 * 5 + j]; fuw1[j] = fu_w[f1 * 5 + j]; }
    float ew0[8], ew1[8];
#pragma unroll
    for (int j = 0; j < 8; j++) { ew0[j] = em_wo[f0 * 8 + j]; ew1[j] = em_wo[f1 * 8 + j]; }
    float nhb = 0.f;
    if (lane == 0) nhb = ex_b[0];
    else if (lane < 6) nhb = fu_b[lane - 1];
    else if (lane == 6) nhb = al_b[0];
    else if (lane == 7) nhb = sl_b[0];
    float ehb = (lane < 8) ? em_bo[lane] : 0.f;

    float pxs[DEC_RPW], pys[DEC_RPW];

#pragma unroll
    for (int r = 0; r < DEC_RPW; r++) {
        int row = row0 + r, i = row & (NMAXC - 1);
        float px = pos_all[i * 2], py = pos_all[i * 2 + 1];
        pxs[r] = px; pys[r] = py;
        float a0 = zn0 + px * wn64_0 + py * wn65_0;
        float a1 = zn1 + px * wn64_1 + py * wn65_1;
        float sm = a0 + a1, sq = a0 * a0 + a1 * a1;
#pragma unroll
        for (int d = 1; d < 64; d <<= 1) { sm += __shfl_xor(sm, d); sq += __shfl_xor(sq, d); }
        float mean = sm * (1.f / 128.f);
        float var = sq * (1.f / 128.f) - mean * mean;
        float rstd = rsqrtf(var + 1e-5f);
        s1[wave][r][f0] = fmaxf((a0 - mean) * rstd * gn0 + bn0, 0.f);
        s1[wave][r][f1] = fmaxf((a1 - mean) * rstd * gn1 + bn1, 0.f);
    }

    float acc0[DEC_RPW], acc1[DEC_RPW];
#pragma unroll
    for (int r = 0; r < DEC_RPW; r++) { acc0[r] = bo0; acc1[r] = bo1; }
    for (int k4 = 0; k4 < 32; k4++) {
        float4 sv[DEC_RPW];
#pragma unroll
        for (int r = 0; r < DEC_RPW; r++)
            sv[r] = *(const float4*)&s1[wave][r][k4 * 4];
#pragma unroll
        for (int kk = 0; kk < 4; kk++) {
            int k = k4 * 4 + kk;
            float w0 = nm_wo[k * 128 + f0];
            float w1 = nm_wo[k * 128 + f1];
#pragma unroll
            for (int r = 0; r < DEC_RPW; r++) {
                float skv = (&sv[r].x)[kk];
                acc0[r] += skv * w0;
                acc1[r] += skv * w1;
            }
        }
    }

#pragma unroll
    for (int r = 0; r < DEC_RPW; r++) {
        float h0 = acc0[r], h1 = acc1[r];
        float p[8];
        p[0] = h0 * exw0 + h1 * exw1;
#pragma unroll
        for (int j = 0; j < 5; j++) p[1 + j] = h0 * fuw0[j] + h1 * fuw1[j];
        p[6] = h0 * alw0 + h1 * alw1;
        p[7] = h0 * slw0 + h1 * slw1;
#pragma unroll
        for (int d = 1; d < 64; d <<= 1) {
#pragma unroll
            for (int j = 0; j < 8; j++) p[j] += __shfl_xor(p[j], d);
        }
        int row = row0 + r;
        if (lane < 8) {
            float v = 0.f;
#pragma unroll
            for (int j = 0; j < 8; j++) if (lane == j) v = p[j];
            v += nhb;
            size_t addr = (lane == 0) ? (size_t)(OUT_NODES + row)
                        : (lane < 6) ? (size_t)OUT_FUEL + (size_t)row * 5 + (lane - 1)
                        : (lane == 6) ? (size_t)(OUT_ALT + row)
                                      : (size_t)(OUT_SLOPE + row);
            out[addr] = v;
        }
    }

#pragma unroll
    for (int r = 0; r < DEC_RPW; r++) {
        float px = pxs[r], py = pys[r];
        float a0 = ze0 + px * we64_0 + py * we65_0;
        float a1 = ze1 + px * we64_1 + py * we65_1;
        float sm = a0 + a1, sq = a0 * a0 + a1 * a1;
#pragma unroll
        for (int d = 1; d < 64; d <<= 1) { sm += __shfl_xor(sm, d); sq += __shfl_xor(sq, d); }
        float mean = sm * (1.f / 128.f);
        float var = sq * (1.f / 128.f) - mean * mean;
        float rstd = rsqrtf(var + 1e-5f);
        float se0 = fmaxf((a0 - mean) * rstd * ge0 + be0, 0.f);
        float se1 = fmaxf((a1 - mean) * rstd * ge1 + be1, 0.f);
        float p[8];
#pragma unroll
        for (int j = 0; j < 8; j++) p[j] = se0 * ew0[j] + se1 * ew1[j];
#pragma unroll
        for (int d = 1; d < 64; d <<= 1) {
#pragma unroll
            for (int j = 0; j < 8; j++) p[j] += __shfl_xor(p[j], d);
        }
        if (lane < 8) {
            float v = 0.f;
#pragma unroll
            for (int j = 0; j < 8; j++) if (lane == j) v = p[j];
            out[OUT_EDGES + (size_t)(row0 + r) * 8 + lane] = v + ehb;
        }
    }
}

extern "C" void kernel_launch(void* const* d_in, const int* in_sizes, int n_in,
                              void* d_out, int out_size, void* d_ws, size_t ws_size,
                              hipStream_t stream) {
    const float* x    = (const float*)d_in[0];
    const int* edge   = (const int*)d_in[1];
    const int* batch  = (const int*)d_in[2];
    const float* w1m = (const float*)d_in[3];  const float* b1m = (const float*)d_in[4];
    const float* w2m = (const float*)d_in[5];  const float* b2m = (const float*)d_in[6];
    const float* w3m = (const float*)d_in[7];  const float* b3m = (const float*)d_in[8];
    const float* w1l = (const float*)d_in[9];  const float* b1l = (const float*)d_in[10];
    const float* w2l = (const float*)d_in[11]; const float* b2l = (const float*)d_in[12];
    const float* w3l = (const float*)d_in[13]; const float* b3l = (const float*)d_in[14];
    const float* nm_wi = (const float*)d_in[15]; const float* nm_bi = (const float*)d_in[16];
    const float* nm_g  = (const float*)d_in[17]; const float* nm_be = (const float*)d_in[18];
    const float* nm_wo = (const float*)d_in[19]; const float* nm_bo = (const float*)d_in[20];
    const float* ex_w = (const float*)d_in[21]; const float* ex_b = (const float*)d_in[22];
    const float* fu_w = (const float*)d_in[23]; const float* fu_b = (const float*)d_in[24];
    const float* al_w = (const float*)d_in[25]; const float* al_b = (const float*)d_in[26];
    const float* sl_w = (const float*)d_in[27]; const float* sl_b = (const float*)d_in[28];
    const float* em_wi = (const float*)d_in[29]; const float* em_bi = (const float*)d_in[30];
    const float* em_g  = (const float*)d_in[31]; const float* em_be = (const float*)d_in[32];
    const float* em_wo = (const float*)d_in[33]; const float* em_bo = (const float*)d_in[34];
    const float* pos_all = (const float*)d_in[35];
    float* out = (float*)d_out;

    char* p = (char*)d_ws;
    auto alloc = [&](size_t bytes) -> void* {
        void* r = (void*)p;
        p += ((bytes + 255) / 256) * 256;
        return r;
    };
    int* cnt      = (int*)alloc((size_t)N_NODES * 4);
    float* dinv   = (float*)alloc((size_t)N_NODES * 4);
    int* bcnt     = (int*)alloc(BATCH_B * 4);
    float* sums   = (float*)alloc(BATCH_B * 128 * 4);
    float* zbuf   = (float*)alloc(BATCH_B * LATC * 4);
    float* zwi_nm = (float*)alloc(BATCH_B * 128 * 4);
    float* zwi_em = (float*)alloc(BATCH_B * 128 * 4);
    float* wcat1  = (float*)alloc(32 * 128 * 4);
    float* bcat1  = (float*)alloc(128 * 4);
    float* bcat3  = (float*)alloc(128 * 4);
    int* cursors  = (int*)alloc((size_t)8 * NBINS * 16 * 4);                   // 200 KB (64B-padded)
    unsigned int* bins = (unsigned int*)alloc((size_t)8 * NBINS * BINCAP * 4); // 12.8 MB
    int* adj      = (int*)alloc((size_t)N_NODES * CAP * 4);                    // 25.6 MB
    unsigned int* xs32 = (unsigned int*)alloc((size_t)N_NODES * 16 * 4);       // 6.4 MB bf16-packed
    float* agg0   = (float*)alloc((size_t)N_NODES * 32 * 4);                   // 12.8 MB
    unsigned short* hA   = (unsigned short*)alloc((size_t)N_NODES * 128 * 2);  // 25.6 MB (also hD)
    unsigned short* hB   = (unsigned short*)alloc((size_t)N_NODES * 128 * 2);  // 25.6 MB
    unsigned short* h256 = (unsigned short*)alloc((size_t)N_NODES * 256 * 2);  // 51.2 MB (also final bf16)
    unsigned short* hD = hA;                       // hA dead after first agg128
    unsigned int* final128 = (unsigned int*)h256;  // h256 dead after layer-3 matmul

    const int* srcp = edge;
    const int* dstp = edge + N_EDGESC;

    hipMemsetAsync(cursors, 0, (size_t)8 * NBINS * 16 * 4, stream);
    hipMemsetAsync(sums, 0, (size_t)BATCH_B * 128 * 4, stream);

    // ---- CSR build: XCD-local binning, then per-bin dense fill ----
    bin_pass<<<(N_EDGESC + 255) / 256, 256, 0, stream>>>(srcp, dstp, cursors, bins, N_EDGESC);
    csr_from_bins<<<NBINS, 256, 0, stream>>>(cursors, bins, adj, cnt, dinv, N_NODES);

    batch_count<<<1, 64, 0, stream>>>(batch, bcnt, N_NODES);
    prep_cat<<<17, 256, 0, stream>>>(w1m, w1l, b1m, b1l, b3m, b3l, wcat1, bcat1, bcat3);
    prescale_x<<<(N_NODES * 16 + 255) / 256, 256, 0, stream>>>(x, dinv, xs32, N_NODES * 16);

    // agg0 = S x  (shared by both branches)
    agg_s32<<<(N_NODES + 15) / 16, 256, 0, stream>>>(xs32, cnt, adj, dinv, agg0, N_NODES);

    // L1 (fused mu|lg): hA = dinv ⊙ relu(agg0 @ [w1m|w1l] + [b1m|b1l])   -> bf16 [n][128]
    matmulX<32, 128, 4, 32, 0, 128, 0, true, true, false, true>
        <<<dim3((N_NODES + 31) / 32, 1), 256, 0, stream>>>(
        agg0, wcat1, nullptr, bcat1, nullptr, dinv, hA, N_NODES);

    // agg #1: hB = [S mu1 | S lg1]  -> bf16 [n][128]
    agg128<false, true><<<(N_NODES + 3) / 4, 256, 0, stream>>>(
        (const unsigned int*)hA, cnt, adj, dinv, nullptr, hB, N_NODES);

    // L2 dual: h256[:, y*128:...] = relu(hB[:, y*64:...] @ w2{m,l} + b2{m,l})  -> bf16 [n][256]
    matmulX<64, 128, 4, 128, 64, 256, 128, true, false, true, true>
        <<<dim3((N_NODES + 31) / 32, 2), 256, 0, stream>>>(
        hB, w2m, w2l, b2m, b2l, nullptr, h256, N_NODES);

    // L3 dual: hD[:, y*64:...] = dinv ⊙ (h256[:, y*128:...] @ w3{m,l})  -> bf16 [n][128]
    matmulX<128, 64, 3, 256, 128, 128, 64, false, true, true, true>
        <<<dim3((N_NODES + 47) / 48, 2), 256, 0, stream>>>(
        h256, w3m, w3l, nullptr, nullptr, dinv, hD, N_NODES);

    // agg #2: final = relu(dinv*(sum) + [b3m|b3l]) = [mu3|lg3]  -> bf16 [n][128]
    agg128<true, true><<<(N_NODES + 3) / 4, 256, 0, stream>>>(
        (const unsigned int*)hD, cnt, adj, dinv, bcat3, final128, N_NODES);

    pool128<<<(N_NODES + POOL_CHUNK - 1) / POOL_CHUNK, 64, 0, stream>>>(final128, batch, sums, N_NODES);
    finalize_pool<<<2, 1024, 0, stream>>>(sums, bcnt, out, zbuf);

    zwi_kernel<<<BATCH_B, 128, 0, stream>>>(zbuf, nm_wi, nm_bi, em_wi, em_bi, zwi_nm, zwi_em);

    decoder2<<<BATCH_B * NMAXC / DEC_ROWS, 256, 0, stream>>>(
        zwi_nm, zwi_em, nm_wi, em_wi, nm_g, nm_be, nm_wo, nm_bo,
        em_g, em_be, em_wo, ex_w, ex_b, fu_w, fu_b, al_w, al_b, sl_w, sl_b,
        em_bo, pos_all, out);
}

// Round 7
// 526.168 us; speedup vs baseline: 6.1193x; 1.1127x over previous
//
#include <hip/hip_runtime.h>
#include <hip/hip_bf16.h>

#define N_NODES 100000
#define N_EDGESC 1600000
#define BATCH_B 16
#define NMAXC 4096
#define LATC 64
#define CAP 64      // padded CSR bucket capacity; deg ~ Binom, P(deg>64) ~ 1e-15
#define NBINS 391   // ceil(100000/256): 256 nodes per bin
#define BINCAP 1024 // edges per (xcd,bin); mean 512, std ~23 -> 22 sigma slack

// output layout offsets (flat f32)
#define OUT_NODES 0
#define OUT_EDGES 65536
#define OUT_FUEL  589824
#define OUT_ALT   917504
#define OUT_SLOPE 983040
#define OUT_MU    1048576
#define OUT_LG    1049600

__device__ __forceinline__ unsigned short f2bf(float f) {
    unsigned int u = __float_as_uint(f);
    return (unsigned short)((u + 0x7FFFu + ((u >> 16) & 1u)) >> 16);  // RNE
}
__device__ __forceinline__ float bf2f(unsigned short h) {
    return __uint_as_float(((unsigned int)h) << 16);
}
__device__ __forceinline__ float bfLO(unsigned int u) { return __uint_as_float(u << 16); }
__device__ __forceinline__ float bfHI(unsigned int u) { return __uint_as_float(u & 0xFFFF0000u); }

// batch is sorted: count[b] = upper_bound(b) - lower_bound(b)
__global__ void batch_count(const int* __restrict__ batch, int* __restrict__ bcnt, int n) {
    int b = threadIdx.x;
    if (b >= BATCH_B) return;
    int lo = 0, hi = n;
    while (lo < hi) { int mid = (lo + hi) >> 1; if (batch[mid] < b) lo = mid + 1; else hi = mid; }
    int start = lo;
    lo = 0; hi = n;
    while (lo < hi) { int mid = (lo + hi) >> 1; if (batch[mid] <= b) lo = mid + 1; else hi = mid; }
    bcnt[b] = lo - start;
}

// ---- CSR build, pass 1: XCD-local binning ----
__global__ void bin_pass(const int* __restrict__ src, const int* __restrict__ dst,
                         int* __restrict__ cursors, unsigned int* __restrict__ bins, int n) {
    int i = blockIdx.x * 256 + threadIdx.x;
    int xcd = blockIdx.x & 7;
    if (i < n) {
        int d = dst[i];
        int s = src[i];
        int b = d >> 8;
        int r = atomicAdd(&cursors[(xcd * NBINS + b) * 16], 1);  // 64B-padded cursor
        if (r < BINCAP)
            bins[((size_t)(xcd * NBINS + b)) * BINCAP + r] = ((unsigned int)s << 8) | (d & 255);
    }
}

// ---- CSR build, pass 2: one block per bin; LDS-atomic ranks; dense block-owned writes ----
__global__ void csr_from_bins(const int* __restrict__ cursors, const unsigned int* __restrict__ bins,
                              int* __restrict__ adj, int* __restrict__ cnt,
                              float* __restrict__ dinv, int N) {
    __shared__ int lc[256];
    int b = blockIdx.x;
    int t = threadIdx.x;
    lc[t] = 0;
    __syncthreads();
    int node0 = b * 256;
    for (int x = 0; x < 8; x++) {
        int m = min(cursors[(x * NBINS + b) * 16], BINCAP);
        const unsigned int* bp = &bins[((size_t)(x * NBINS + b)) * BINCAP];
        for (int i = t; i < m; i += 256) {
            unsigned int pk = bp[i];
            int d = pk & 255;
            int s = (int)(pk >> 8);
            int r = atomicAdd(&lc[d], 1);
            if (r < CAP) adj[(size_t)(node0 + d) * CAP + r] = s;
        }
    }
    __syncthreads();
    int n = node0 + t;
    if (n < N) {
        int c = lc[t];
        cnt[n] = c;
        dinv[n] = rsqrtf((float)(c + 1));  // +1 = self loop
    }
}

// xs (bf16 packed, [n][16] uints) = dinv[n] * x[n][32]
__global__ void prescale_x(const float* __restrict__ x, const float* __restrict__ dinv,
                           unsigned int* __restrict__ xs, int total2) {
    int i2 = blockIdx.x * 256 + threadIdx.x;
    if (i2 < total2) {
        float2 v = *(const float2*)&x[i2 * 2];
        float d = dinv[i2 >> 4];
        xs[i2] = (unsigned int)f2bf(v.x * d) | ((unsigned int)f2bf(v.y * d) << 16);
    }
}

// agg0 = S x : out[n,f] = dinv[n]*(xs[n,f] + sum_src xs[src,f]); bf16 table, f32 out
__global__ void agg_s32(const unsigned int* __restrict__ xs, const int* __restrict__ cnt,
                        const int* __restrict__ adj, const float* __restrict__ dinv,
                        float* __restrict__ out, int N) {
    int t = threadIdx.x;
    int sub = t >> 4, f = t & 15;
    int n = blockIdx.x * 16 + sub;
    if (n >= N) return;
    unsigned int su = xs[(size_t)n * 16 + f];
    float s0 = bfLO(su), s1 = bfHI(su);
    int e1 = min(cnt[n], CAP);
    const int* ap = &adj[(size_t)n * CAP];
    int e = 0;
    for (; e + 4 <= e1; e += 4) {
        int i0 = ap[e], i1 = ap[e + 1], i2 = ap[e + 2], i3 = ap[e + 3];
        unsigned int u0 = xs[(size_t)i0 * 16 + f];
        unsigned int u1 = xs[(size_t)i1 * 16 + f];
        unsigned int u2 = xs[(size_t)i2 * 16 + f];
        unsigned int u3 = xs[(size_t)i3 * 16 + f];
        s0 += (bfLO(u0) + bfLO(u1)) + (bfLO(u2) + bfLO(u3));
        s1 += (bfHI(u0) + bfHI(u1)) + (bfHI(u2) + bfHI(u3));
    }
    for (; e < e1; e++) {
        unsigned int u = xs[(size_t)ap[e] * 16 + f];
        s0 += bfLO(u); s1 += bfHI(u);
    }
    float d = dinv[n];
    *(float2*)&out[(size_t)n * 32 + 2 * f] = make_float2(d * s0, d * s1);
}

// 128-dim bf16-table aggregation: out[n,:] = epi(dinv[n] * (tbl[n,:] + sum_src tbl[src,:]))
template <bool BIASRELU, bool OUT_BF16>
__global__ void agg128(const unsigned int* __restrict__ tbl, const int* __restrict__ cnt,
                       const int* __restrict__ adj, const float* __restrict__ dinv,
                       const float* __restrict__ bias, void* __restrict__ outv, int N) {
    int t = threadIdx.x;
    int sub = t >> 6, f2 = t & 63;
    int n = blockIdx.x * 4 + sub;
    if (n >= N) return;
    unsigned int su = tbl[(size_t)n * 64 + f2];
    float s0 = bfLO(su), s1 = bfHI(su);
    int e1 = min(cnt[n], CAP);
    const int* ap = &adj[(size_t)n * CAP];
    int e = 0;
    for (; e + 4 <= e1; e += 4) {
        int i0 = ap[e], i1 = ap[e + 1], i2 = ap[e + 2], i3 = ap[e + 3];
        unsigned int u0 = tbl[(size_t)i0 * 64 + f2];
        unsigned int u1 = tbl[(size_t)i1 * 64 + f2];
        unsigned int u2 = tbl[(size_t)i2 * 64 + f2];
        unsigned int u3 = tbl[(size_t)i3 * 64 + f2];
        s0 += (bfLO(u0) + bfLO(u1)) + (bfLO(u2) + bfLO(u3));
        s1 += (bfHI(u0) + bfHI(u1)) + (bfHI(u2) + bfHI(u3));
    }
    for (; e < e1; e++) {
        unsigned int u = tbl[(size_t)ap[e] * 64 + f2];
        s0 += bfLO(u); s1 += bfHI(u);
    }
    float d = dinv[n];
    float v0 = d * s0, v1 = d * s1;
    if (BIASRELU) {
        v0 = fmaxf(v0 + bias[2 * f2], 0.f);
        v1 = fmaxf(v1 + bias[2 * f2 + 1], 0.f);
    }
    if (OUT_BF16) {
        unsigned int pk = (unsigned int)f2bf(v0) | ((unsigned int)f2bf(v1) << 16);
        ((unsigned int*)outv)[(size_t)n * 64 + f2] = pk;
    } else {
        *(float2*)&((float*)outv)[(size_t)n * 128 + 2 * f2] = make_float2(v0, v1);
    }
}

// Register-tiled matmul, dual-branch via blockIdx.y, bf16 in/out, padded LDS.
template <int K, int F, int TM, int IN_STRIDE, int IN_OFF_Y, int OUT_STRIDE, int OUT_OFF_Y,
          bool BIASRELU, bool SCALE, bool IN_BF16, bool OUT_BF16>
__global__ __launch_bounds__(256) void matmulX(
    const void* __restrict__ inv, const float* __restrict__ Wa, const float* __restrict__ Wb,
    const float* __restrict__ biasa, const float* __restrict__ biasb,
    const float* __restrict__ dinv, void* __restrict__ outv, int N) {
    constexpr int TN = 4;
    constexpr int CG = F / TN;
    constexpr int RG = 256 / CG;
    constexpr int BM = TM * RG;
    constexpr int KP = IN_BF16 ? (K + 8) : (K + 4);
    const int y = blockIdx.y;
    const float* W = (y == 0) ? Wa : Wb;
    const float* bias = (y == 0) ? biasa : biasb;
    __shared__ float Ws[K * F];
    __shared__ alignas(16) char xsraw[(size_t)BM * KP * (IN_BF16 ? 2 : 4)];
    int tid = threadIdx.x;
    for (int i = tid * 4; i < K * F; i += 1024)
        *(float4*)&Ws[i] = *(const float4*)&W[i];
    int node0 = blockIdx.x * BM;
    if constexpr (IN_BF16) {
        unsigned short* xs = (unsigned short*)xsraw;
        for (int i = tid * 8; i < BM * K; i += 2048) {
            int r = i / K, k = i % K;
            int n = node0 + r;
            uint4 v = make_uint4(0u, 0u, 0u, 0u);
            if (n < N)
                v = *(const uint4*)((const unsigned short*)inv +
                                    (size_t)n * IN_STRIDE + y * IN_OFF_Y + k);
            *(uint4*)&xs[r * KP + k] = v;
        }
    } else {
        float* xs = (float*)xsraw;
        for (int i = tid * 4; i < BM * K; i += 1024) {
            int r = i / K, k = i % K;
            int n = node0 + r;
            float4 v = make_float4(0.f, 0.f, 0.f, 0.f);
            if (n < N)
                v = *(const float4*)((const float*)inv + (size_t)n * IN_STRIDE + y * IN_OFF_Y + k);
            *(float4*)&xs[r * KP + k] = v;
        }
    }
    __syncthreads();
    int cg = tid % CG, rg = tid / CG;
    int f0 = cg * TN;
    const unsigned short* xsb = (const unsigned short*)xsraw;
    const float* xsf = (const float*)xsraw;
    float acc[TM][TN];
#pragma unroll
    for (int m = 0; m < TM; m++)
#pragma unroll
        for (int j = 0; j < TN; j++) acc[m][j] = 0.f;
    for (int k4 = 0; k4 < K; k4 += 4) {
        float4 wv[4];
#pragma unroll
        for (int kk = 0; kk < 4; kk++) wv[kk] = *(const float4*)&Ws[(k4 + kk) * F + f0];
#pragma unroll
        for (int m = 0; m < TM; m++) {
            float4 xv;
            if constexpr (IN_BF16) {
                ushort4 u = *(const ushort4*)&xsb[(rg * TM + m) * KP + k4];
                xv = make_float4(bf2f(u.x), bf2f(u.y), bf2f(u.z), bf2f(u.w));
            } else {
                xv = *(const float4*)&xsf[(rg * TM + m) * KP + k4];
            }
#pragma unroll
            for (int kk = 0; kk < 4; kk++) {
                float xk = (&xv.x)[kk];
                acc[m][0] += xk * wv[kk].x;
                acc[m][1] += xk * wv[kk].y;
                acc[m][2] += xk * wv[kk].z;
                acc[m][3] += xk * wv[kk].w;
            }
        }
    }
#pragma unroll
    for (int m = 0; m < TM; m++) {
        int n = node0 + rg * TM + m;
        if (n < N) {
            float vv[TN];
            float d = SCALE ? dinv[n] : 1.f;
#pragma unroll
            for (int j = 0; j < TN; j++) {
                float v = acc[m][j];
                if (BIASRELU) v = fmaxf(v + bias[f0 + j], 0.f);
                if (SCALE) v *= d;
                vv[j] = v;
            }
            size_t off = (size_t)n * OUT_STRIDE + y * OUT_OFF_Y + f0;
            if (OUT_BF16) {
                ushort4 u;
                u.x = f2bf(vv[0]); u.y = f2bf(vv[1]); u.z = f2bf(vv[2]); u.w = f2bf(vv[3]);
                *(ushort4*)((unsigned short*)outv + off) = u;
            } else {
                *(float4*)((float*)outv + off) = make_float4(vv[0], vv[1], vv[2], vv[3]);
            }
        }
    }
}

// concat weights/biases for fused layer1 and fused layer3 bias
__global__ void prep_cat(const float* __restrict__ w1m, const float* __restrict__ w1l,
                         const float* __restrict__ b1m, const float* __restrict__ b1l,
                         const float* __restrict__ b3m, const float* __restrict__ b3l,
                         float* __restrict__ wcat1, float* __restrict__ bcat1,
                         float* __restrict__ bcat3) {
    int i = blockIdx.x * 256 + threadIdx.x;
    if (i < 32 * 128) {
        int k = i >> 7, f = i & 127;
        wcat1[i] = (f < 64) ? w1m[k * 64 + f] : w1l[k * 64 + f - 64];
    } else if (i < 32 * 128 + 128) {
        int f = i - 32 * 128;
        bcat1[f] = (f < 64) ? b1m[f] : b1l[f - 64];
    } else if (i < 32 * 128 + 256) {
        int f = i - 32 * 128 - 128;
        bcat3[f] = (f < 64) ? b3m[f] : b3l[f - 64];
    }
}

// decoder head-composition precompute:
// wtn[j][k] = sum_m nm_wo[k][m]*headW[m][j];  bcn[j] = sum_m nm_bo[m]*headW[m][j] + headb[j]
// wte[j][k] = em_wo[k][j]  (transpose for LDS-friendly reads)
__global__ void prep_dec(const float* __restrict__ nm_wo, const float* __restrict__ nm_bo,
                         const float* __restrict__ ex_w, const float* __restrict__ ex_b,
                         const float* __restrict__ fu_w, const float* __restrict__ fu_b,
                         const float* __restrict__ al_w, const float* __restrict__ al_b,
                         const float* __restrict__ sl_w, const float* __restrict__ sl_b,
                         const float* __restrict__ em_wo,
                         float* __restrict__ wtn, float* __restrict__ bcn,
                         float* __restrict__ wte) {
    int idx = blockIdx.x * 256 + threadIdx.x;
    if (idx < 1024) {
        int j = idx >> 7, k = idx & 127;
        float s = 0.f;
        for (int m = 0; m < 128; m++) {
            float w = (j == 0) ? ex_w[m] : (j <= 5) ? fu_w[m * 5 + (j - 1)]
                     : (j == 6) ? al_w[m] : sl_w[m];
            s += nm_wo[k * 128 + m] * w;
        }
        wtn[j * 128 + k] = s;
    } else if (idx < 2048) {
        int i2 = idx - 1024;
        int j = i2 >> 7, k = i2 & 127;
        wte[j * 128 + k] = em_wo[k * 8 + j];
    } else if (idx < 2056) {
        int j = idx - 2048;
        float s = (j == 0) ? ex_b[0] : (j <= 5) ? fu_b[j - 1] : (j == 6) ? al_b[0] : sl_b[0];
        for (int m = 0; m < 128; m++) {
            float w = (j == 0) ? ex_w[m] : (j <= 5) ? fu_w[m * 5 + (j - 1)]
                     : (j == 6) ? al_w[m] : sl_w[m];
            s += nm_bo[m] * w;
        }
        bcn[j] = s;
    }
}

#define POOL_CHUNK 128
// h is bf16-packed [n][64] uints
__global__ void pool128(const unsigned int* __restrict__ h, const int* __restrict__ batch,
                        float* __restrict__ sums, int n) {
    int f = threadIdx.x;  // 0..63
    int s0 = blockIdx.x * POOL_CHUNK;
    if (s0 >= n) return;
    int s1 = min(s0 + POOL_CHUNK, n);
    int cur = batch[s0];
    float a0 = 0.f, a1 = 0.f;
    for (int i = s0; i < s1; i++) {
        int b = batch[i];
        if (b != cur) {
            atomicAdd(&sums[cur * 128 + 2 * f], a0);
            atomicAdd(&sums[cur * 128 + 2 * f + 1], a1);
            a0 = a1 = 0.f; cur = b;
        }
        unsigned int u = h[(size_t)i * 64 + f];
        a0 += bfLO(u); a1 += bfHI(u);
    }
    atomicAdd(&sums[cur * 128 + 2 * f], a0);
    atomicAdd(&sums[cur * 128 + 2 * f + 1], a1);
}

__global__ void finalize_pool(const float* __restrict__ sums, const int* __restrict__ bcnt,
                              float* __restrict__ out, float* __restrict__ zbuf) {
    int i = blockIdx.x * 1024 + threadIdx.x;  // 0..2047
    int b = i >> 7, f = i & 127;
    float c = fmaxf((float)bcnt[b], 1.f);
    float v = sums[i] / c;
    if (f < 64) { out[OUT_MU + b * 64 + f] = v; zbuf[b * 64 + f] = v; }
    else out[OUT_LG + b * 64 + (f - 64)] = v;
}

// zwi[b][t] = bi[t] + sum_k z[b,k]*wi[k*128+t]
__global__ void zwi_kernel(const float* __restrict__ z,
                           const float* __restrict__ nm_wi, const float* __restrict__ nm_bi,
                           const float* __restrict__ em_wi, const float* __restrict__ em_bi,
                           float* __restrict__ zwi_nm, float* __restrict__ zwi_em) {
    int b = blockIdx.x, t = threadIdx.x;  // 16 blocks x 128 threads
    float an = nm_bi[t], ae = em_bi[t];
    for (int k = 0; k < 64; k++) {
        float zv = z[b * 64 + k];
        an += zv * nm_wi[k * 128 + t];
        ae += zv * em_wi[k * 128 + t];
    }
    zwi_nm[b * 128 + t] = an;
    zwi_em[b * 128 + t] = ae;
}

#define D3_ROWS 32

// decoder3: layer1+LN -> LDS; heads/edges as 128-len LDS dots (heads pre-composed
// through nm_wo since no nonlinearity separates them). One (row,j) pair per thread.
__global__ __launch_bounds__(256) void decoder3(
    const float* __restrict__ zwi_nm, const float* __restrict__ zwi_em,
    const float* __restrict__ nm_wi, const float* __restrict__ em_wi,
    const float* __restrict__ nm_g, const float* __restrict__ nm_be,
    const float* __restrict__ em_g, const float* __restrict__ em_be,
    const float* __restrict__ wtn, const float* __restrict__ bcn,
    const float* __restrict__ wte, const float* __restrict__ em_bo,
    const float* __restrict__ pos_all,
    float* __restrict__ out) {
    __shared__ float sn[D3_ROWS][132];   // +4 pad: 4-bank rotation per row
    __shared__ float se[D3_ROWS][132];
    __shared__ float Wn[8][132];
    __shared__ float We[8][132];
    int t = threadIdx.x;
    int lane = t & 63, wave = t >> 6;
    int rowBase = blockIdx.x * D3_ROWS;
    int b = rowBase >> 12;               // 32 | 4096 -> same batch for whole block
    int row0 = rowBase + wave * 8;

    for (int i = t; i < 1024; i += 256) {
        Wn[i >> 7][i & 127] = wtn[i];
        We[i >> 7][i & 127] = wte[i];
    }

    int f0 = lane, f1 = lane + 64;
    float zn0 = zwi_nm[b * 128 + f0], zn1 = zwi_nm[b * 128 + f1];
    float ze0 = zwi_em[b * 128 + f0], ze1 = zwi_em[b * 128 + f1];
    float wn64_0 = nm_wi[64 * 128 + f0], wn64_1 = nm_wi[64 * 128 + f1];
    float wn65_0 = nm_wi[65 * 128 + f0], wn65_1 = nm_wi[65 * 128 + f1];
    float we64_0 = em_wi[64 * 128 + f0], we64_1 = em_wi[64 * 128 + f1];
    float we65_0 = em_wi[65 * 128 + f0], we65_1 = em_wi[65 * 128 + f1];
    float gn0 = nm_g[f0], gn1 = nm_g[f1], bn0 = nm_be[f0], bn1 = nm_be[f1];
    float ge0 = em_g[f0], ge1 = em_g[f1], be0 = em_be[f0], be1 = em_be[f1];

#pragma unroll
    for (int r = 0; r < 8; r++) {
        int row = row0 + r, i = row & (NMAXC - 1);
        float px = pos_all[i * 2], py = pos_all[i * 2 + 1];
        float a0 = zn0 + px * wn64_0 + py * wn65_0;
        float a1 = zn1 + px * wn64_1 + py * wn65_1;
        float e0 = ze0 + px * we64_0 + py * we65_0;
        float e1 = ze1 + px * we64_1 + py * we65_1;
        float sm = a0 + a1, sq = a0 * a0 + a1 * a1;
        float sme = e0 + e1, sqe = e0 * e0 + e1 * e1;
#pragma unroll
        for (int d = 1; d < 64; d <<= 1) {
            sm += __shfl_xor(sm, d); sq += __shfl_xor(sq, d);
            sme += __shfl_xor(sme, d); sqe += __shfl_xor(sqe, d);
        }
        float mean = sm * (1.f / 128.f);
        float var = sq * (1.f / 128.f) - mean * mean;
        float rstd = rsqrtf(var + 1e-5f);
        int rl = wave * 8 + r;
        sn[rl][f0] = fmaxf((a0 - mean) * rstd * gn0 + bn0, 0.f);
        sn[rl][f1] = fmaxf((a1 - mean) * rstd * gn1 + bn1, 0.f);
        float meane = sme * (1.f / 128.f);
        float vare = sqe * (1.f / 128.f) - meane * meane;
        float rstde = rsqrtf(vare + 1e-5f);
        se[rl][f0] = fmaxf((e0 - meane) * rstde * ge0 + be0, 0.f);
        se[rl][f1] = fmaxf((e1 - meane) * rstde * ge1 + be1, 0.f);
    }
    __syncthreads();

    // dots: thread = (row rl = t>>3, output j = t&7); node + edge
    int rl = t >> 3, j = t & 7;
    float accn = 0.f, acce = 0.f;
#pragma unroll 8
    for (int k4 = 0; k4 < 128; k4 += 4) {
        float4 sv = *(const float4*)&sn[rl][k4];
        float4 wv = *(const float4*)&Wn[j][k4];
        float4 sev = *(const float4*)&se[rl][k4];
        float4 wev = *(const float4*)&We[j][k4];
        accn += sv.x * wv.x + sv.y * wv.y + sv.z * wv.z + sv.w * wv.w;
        acce += sev.x * wev.x + sev.y * wev.y + sev.z * wev.z + sev.w * wev.w;
    }
    int row = rowBase + rl;
    accn += bcn[j];
    if (j == 0)       out[OUT_NODES + row] = accn;
    else if (j <= 5)  out[OUT_FUEL + (size_t)row * 5 + (j - 1)] = accn;
    else if (j == 6)  out[OUT_ALT + row] = accn;
    else              out[OUT_SLOPE + row] = accn;
    out[OUT_EDGES + (size_t)row * 8 + j] = acce + em_bo[j];
}

extern "C" void kernel_launch(void* const* d_in, const int* in_sizes, int n_in,
                              void* d_out, int out_size, void* d_ws, size_t ws_size,
                              hipStream_t stream) {
    const float* x    = (const float*)d_in[0];
    const int* edge   = (const int*)d_in[1];
    const int* batch  = (const int*)d_in[2];
    const float* w1m = (const float*)d_in[3];  const float* b1m = (const float*)d_in[4];
    const float* w2m = (const float*)d_in[5];  const float* b2m = (const float*)d_in[6];
    const float* w3m = (const float*)d_in[7];  const float* b3m = (const float*)d_in[8];
    const float* w1l = (const float*)d_in[9];  const float* b1l = (const float*)d_in[10];
    const float* w2l = (const float*)d_in[11]; const float* b2l = (const float*)d_in[12];
    const float* w3l = (const float*)d_in[13]; const float* b3l = (const float*)d_in[14];
    const float* nm_wi = (const float*)d_in[15]; const float* nm_bi = (const float*)d_in[16];
    const float* nm_g  = (const float*)d_in[17]; const float* nm_be = (const float*)d_in[18];
    const float* nm_wo = (const float*)d_in[19]; const float* nm_bo = (const float*)d_in[20];
    const float* ex_w = (const float*)d_in[21]; const float* ex_b = (const float*)d_in[22];
    const float* fu_w = (const float*)d_in[23]; const float* fu_b = (const float*)d_in[24];
    const float* al_w = (const float*)d_in[25]; const float* al_b = (const float*)d_in[26];
    const float* sl_w = (const float*)d_in[27]; const float* sl_b = (const float*)d_in[28];
    const float* em_wi = (const float*)d_in[29]; const float* em_bi = (const float*)d_in[30];
    const float* em_g  = (const float*)d_in[31]; const float* em_be = (const float*)d_in[32];
    const float* em_wo = (const float*)d_in[33]; const float* em_bo = (const float*)d_in[34];
    const float* pos_all = (const float*)d_in[35];
    float* out = (float*)d_out;

    char* p = (char*)d_ws;
    auto alloc = [&](size_t bytes) -> void* {
        void* r = (void*)p;
        p += ((bytes + 255) / 256) * 256;
        return r;
    };
    int* cnt      = (int*)alloc((size_t)N_NODES * 4);
    float* dinv   = (float*)alloc((size_t)N_NODES * 4);
    int* bcnt     = (int*)alloc(BATCH_B * 4);
    float* sums   = (float*)alloc(BATCH_B * 128 * 4);
    float* zbuf   = (float*)alloc(BATCH_B * LATC * 4);
    float* zwi_nm = (float*)alloc(BATCH_B * 128 * 4);
    float* zwi_em = (float*)alloc(BATCH_B * 128 * 4);
    float* wcat1  = (float*)alloc(32 * 128 * 4);
    float* bcat1  = (float*)alloc(128 * 4);
    float* bcat3  = (float*)alloc(128 * 4);
    float* wtn    = (float*)alloc(8 * 128 * 4);
    float* bcn    = (float*)alloc(8 * 4);
    float* wte    = (float*)alloc(8 * 128 * 4);
    int* cursors  = (int*)alloc((size_t)8 * NBINS * 16 * 4);
    unsigned int* bins = (unsigned int*)alloc((size_t)8 * NBINS * BINCAP * 4);
    int* adj      = (int*)alloc((size_t)N_NODES * CAP * 4);
    unsigned int* xs32 = (unsigned int*)alloc((size_t)N_NODES * 16 * 4);
    float* agg0   = (float*)alloc((size_t)N_NODES * 32 * 4);
    unsigned short* hA   = (unsigned short*)alloc((size_t)N_NODES * 128 * 2);
    unsigned short* hB   = (unsigned short*)alloc((size_t)N_NODES * 128 * 2);
    unsigned short* h256 = (unsigned short*)alloc((size_t)N_NODES * 256 * 2);
    unsigned short* hD = hA;                       // hA dead after first agg128
    unsigned int* final128 = (unsigned int*)h256;  // h256 dead after layer-3 matmul

    const int* srcp = edge;
    const int* dstp = edge + N_EDGESC;

    hipMemsetAsync(cursors, 0, (size_t)8 * NBINS * 16 * 4, stream);
    hipMemsetAsync(sums, 0, (size_t)BATCH_B * 128 * 4, stream);

    // ---- CSR build: XCD-local binning, then per-bin dense fill ----
    bin_pass<<<(N_EDGESC + 255) / 256, 256, 0, stream>>>(srcp, dstp, cursors, bins, N_EDGESC);
    csr_from_bins<<<NBINS, 256, 0, stream>>>(cursors, bins, adj, cnt, dinv, N_NODES);

    batch_count<<<1, 64, 0, stream>>>(batch, bcnt, N_NODES);
    prep_cat<<<17, 256, 0, stream>>>(w1m, w1l, b1m, b1l, b3m, b3l, wcat1, bcat1, bcat3);
    prep_dec<<<9, 256, 0, stream>>>(nm_wo, nm_bo, ex_w, ex_b, fu_w, fu_b, al_w, al_b,
                                    sl_w, sl_b, em_wo, wtn, bcn, wte);
    prescale_x<<<(N_NODES * 16 + 255) / 256, 256, 0, stream>>>(x, dinv, xs32, N_NODES * 16);

    // agg0 = S x  (shared by both branches)
    agg_s32<<<(N_NODES + 15) / 16, 256, 0, stream>>>(xs32, cnt, adj, dinv, agg0, N_NODES);

    // L1 (fused mu|lg): hA = dinv ⊙ relu(agg0 @ [w1m|w1l] + [b1m|b1l])   -> bf16 [n][128]
    matmulX<32, 128, 4, 32, 0, 128, 0, true, true, false, true>
        <<<dim3((N_NODES + 31) / 32, 1), 256, 0, stream>>>(
        agg0, wcat1, nullptr, bcat1, nullptr, dinv, hA, N_NODES);

    // agg #1: hB = [S mu1 | S lg1]  -> bf16 [n][128]
    agg128<false, true><<<(N_NODES + 3) / 4, 256, 0, stream>>>(
        (const unsigned int*)hA, cnt, adj, dinv, nullptr, hB, N_NODES);

    // L2 dual: h256[:, y*128:...] = relu(hB[:, y*64:...] @ w2{m,l} + b2{m,l})  -> bf16 [n][256]
    matmulX<64, 128, 4, 128, 64, 256, 128, true, false, true, true>
        <<<dim3((N_NODES + 31) / 32, 2), 256, 0, stream>>>(
        hB, w2m, w2l, b2m, b2l, nullptr, h256, N_NODES);

    // L3 dual: hD[:, y*64:...] = dinv ⊙ (h256[:, y*128:...] @ w3{m,l})  -> bf16 [n][128]
    matmulX<128, 64, 3, 256, 128, 128, 64, false, true, true, true>
        <<<dim3((N_NODES + 47) / 48, 2), 256, 0, stream>>>(
        h256, w3m, w3l, nullptr, nullptr, dinv, hD, N_NODES);

    // agg #2: final = relu(dinv*(sum) + [b3m|b3l]) = [mu3|lg3]  -> bf16 [n][128]
    agg128<true, true><<<(N_NODES + 3) / 4, 256, 0, stream>>>(
        (const unsigned int*)hD, cnt, adj, dinv, bcat3, final128, N_NODES);

    pool128<<<(N_NODES + POOL_CHUNK - 1) / POOL_CHUNK, 64, 0, stream>>>(final128, batch, sums, N_NODES);
    finalize_pool<<<2, 1024, 0, stream>>>(sums, bcnt, out, zbuf);

    zwi_kernel<<<BATCH_B, 128, 0, stream>>>(zbuf, nm_wi, nm_bi, em_wi, em_bi, zwi_nm, zwi_em);

    decoder3<<<BATCH_B * NMAXC / D3_ROWS, 256, 0, stream>>>(
        zwi_nm, zwi_em, nm_wi, em_wi, nm_g, nm_be, em_g, em_be,
        wtn, bcn, wte, em_bo, pos_all, out);
}

// Round 8
// 458.305 us; speedup vs baseline: 7.0254x; 1.1481x over previous
//
#include <hip/hip_runtime.h>
#include <hip/hip_bf16.h>

#define N_NODES 100000
#define N_EDGESC 1600000
#define BATCH_B 16
#define NMAXC 4096
#define LATC 64
#define CAP 64      // padded CSR bucket capacity; deg ~ Binom, P(deg>64) ~ 1e-15
#define NBINS 391   // ceil(100000/256): 256 nodes per bin
#define BINCAP 1024 // edges per (xcd,bin); mean 512, std ~21 -> 24 sigma slack
#define HWREG_XCC_ID (20 | (0 << 6) | (31 << 11))  // s_getreg: id=20, offset 0, size 32

// output layout offsets (flat f32)
#define OUT_NODES 0
#define OUT_EDGES 65536
#define OUT_FUEL  589824
#define OUT_ALT   917504
#define OUT_SLOPE 983040
#define OUT_MU    1048576
#define OUT_LG    1049600

typedef float f32x2 __attribute__((ext_vector_type(2)));

__device__ __forceinline__ unsigned short f2bf(float f) {
    unsigned int u = __float_as_uint(f);
    return (unsigned short)((u + 0x7FFFu + ((u >> 16) & 1u)) >> 16);  // RNE
}
__device__ __forceinline__ float bf2f(unsigned short h) {
    return __uint_as_float(((unsigned int)h) << 16);
}
// accumulate 4 fp8(e4m3) packed in u into a0..a3 (HW cvt, OCP on gfx950)
__device__ __forceinline__ void f8acc(unsigned int u, float& a0, float& a1, float& a2, float& a3) {
    f32x2 lo = __builtin_amdgcn_cvt_pk_f32_fp8(u, false);
    f32x2 hi = __builtin_amdgcn_cvt_pk_f32_fp8(u, true);
    a0 += lo[0]; a1 += lo[1]; a2 += hi[0]; a3 += hi[1];
}

// batch is sorted: count[b] = upper_bound(b) - lower_bound(b)
__global__ void batch_count(const int* __restrict__ batch, int* __restrict__ bcnt, int n) {
    int b = threadIdx.x;
    if (b >= BATCH_B) return;
    int lo = 0, hi = n;
    while (lo < hi) { int mid = (lo + hi) >> 1; if (batch[mid] < b) lo = mid + 1; else hi = mid; }
    int start = lo;
    lo = 0; hi = n;
    while (lo < hi) { int mid = (lo + hi) >> 1; if (batch[mid] <= b) lo = mid + 1; else hi = mid; }
    bcnt[b] = lo - start;
}

// ---- CSR build, pass 1: XCD-local binning (exact XCD id via HW_REG_XCC_ID) ----
__global__ void bin_pass(const int* __restrict__ src, const int* __restrict__ dst,
                         int* __restrict__ cursors, unsigned int* __restrict__ bins,
                         int* __restrict__ spillCnt, int* __restrict__ spill, int n) {
    int i = blockIdx.x * 256 + threadIdx.x;
    unsigned int xcd = __builtin_amdgcn_s_getreg(HWREG_XCC_ID) & 7u;
    if (i < n) {
        int d = dst[i];
        int s = src[i];
        int b = d >> 8;
        int r = atomicAdd(&cursors[(xcd * NBINS + b) * 16], 1);  // 64B-padded cursor
        if (r < BINCAP)
            bins[((size_t)(xcd * NBINS + b)) * BINCAP + r] = ((unsigned int)s << 8) | (d & 255);
        else {  // overflow insurance (normally never): correctness does not depend on xcd read
            int w = atomicAdd(spillCnt, 1);
            spill[2 * w] = s; spill[2 * w + 1] = d;
        }
    }
}

// ---- CSR build, pass 2: one block per bin; LDS-atomic ranks; dense block-owned writes ----
__global__ void csr_from_bins(const int* __restrict__ cursors, const unsigned int* __restrict__ bins,
                              const int* __restrict__ spillCnt, const int* __restrict__ spill,
                              int* __restrict__ adj, int* __restrict__ cnt,
                              float* __restrict__ dinv, int N) {
    __shared__ int lc[256];
    int b = blockIdx.x;
    int t = threadIdx.x;
    lc[t] = 0;
    __syncthreads();
    int node0 = b * 256;
    for (int x = 0; x < 8; x++) {
        int m = min(cursors[(x * NBINS + b) * 16], BINCAP);
        const unsigned int* bp = &bins[((size_t)(x * NBINS + b)) * BINCAP];
        for (int i = t; i < m; i += 256) {
            unsigned int pk = bp[i];
            int d = pk & 255;
            int s = (int)(pk >> 8);
            int r = atomicAdd(&lc[d], 1);
            if (r < CAP) adj[(size_t)(node0 + d) * CAP + r] = s;
        }
    }
    int sc = min(*spillCnt, N_EDGESC);
    for (int i = t; i < sc; i += 256) {
        int s = spill[2 * i], d = spill[2 * i + 1];
        if ((d >> 8) == b) {
            int r = atomicAdd(&lc[d & 255], 1);
            if (r < CAP) adj[(size_t)d * CAP + r] = s;
        }
    }
    __syncthreads();
    int n = node0 + t;
    if (n < N) {
        int c = lc[t];
        cnt[n] = c;
        dinv[n] = rsqrtf((float)(c + 1));  // +1 = self loop
    }
}

// xs8 (fp8 packed, [n][8] uints) = 64 * dinv[n] * x[n][32]
__global__ void prescale_x(const float* __restrict__ x, const float* __restrict__ dinv,
                           unsigned int* __restrict__ xs8, int total4) {
    int i4 = blockIdx.x * 256 + threadIdx.x;
    if (i4 < total4) {
        float4 v = *(const float4*)&x[i4 * 4];
        float ds = dinv[i4 >> 3] * 64.f;
        unsigned int r = 0;
        r = __builtin_amdgcn_cvt_pk_fp8_f32(v.x * ds, v.y * ds, r, false);
        r = __builtin_amdgcn_cvt_pk_fp8_f32(v.z * ds, v.w * ds, r, true);
        xs8[i4] = r;
    }
}

// agg0 = S x : fp8 table [n][8] uints; 32 nodes per 256-thread block, 8 lanes/node
__global__ void agg_s32(const unsigned int* __restrict__ xs8, const int* __restrict__ cnt,
                        const int* __restrict__ adj, const float* __restrict__ dinv,
                        float* __restrict__ out, int N) {
    int t = threadIdx.x;
    int sub = t >> 3, f = t & 7;
    int n = blockIdx.x * 32 + sub;
    if (n >= N) return;
    float s0 = 0.f, s1 = 0.f, s2 = 0.f, s3 = 0.f;
    f8acc(xs8[(size_t)n * 8 + f], s0, s1, s2, s3);
    int e1 = min(cnt[n], CAP);
    const int* ap = &adj[(size_t)n * CAP];
    int e = 0;
    for (; e + 4 <= e1; e += 4) {
        int i0 = ap[e], i1 = ap[e + 1], i2 = ap[e + 2], i3 = ap[e + 3];
        unsigned int u0 = xs8[(size_t)i0 * 8 + f];
        unsigned int u1 = xs8[(size_t)i1 * 8 + f];
        unsigned int u2 = xs8[(size_t)i2 * 8 + f];
        unsigned int u3 = xs8[(size_t)i3 * 8 + f];
        f8acc(u0, s0, s1, s2, s3); f8acc(u1, s0, s1, s2, s3);
        f8acc(u2, s0, s1, s2, s3); f8acc(u3, s0, s1, s2, s3);
    }
    for (; e < e1; e++) f8acc(xs8[(size_t)ap[e] * 8 + f], s0, s1, s2, s3);
    float d = dinv[n] * (1.f / 64.f);
    *(float4*)&out[(size_t)n * 32 + f * 4] = make_float4(s0 * d, s1 * d, s2 * d, s3 * d);
}

// 128-dim fp8-table aggregation (table pre-scaled x32):
// out_bf16[n,:] = epi(dinv[n]/32 * (tbl[n,:] + sum_src tbl[src,:])); 8 nodes/block, 32 lanes/node
template <bool BIASRELU>
__global__ void agg128(const unsigned int* __restrict__ tbl, const int* __restrict__ cnt,
                       const int* __restrict__ adj, const float* __restrict__ dinv,
                       const float* __restrict__ bias, unsigned short* __restrict__ outb, int N) {
    int t = threadIdx.x;
    int sub = t >> 5, f = t & 31;
    int n = blockIdx.x * 8 + sub;
    if (n >= N) return;
    float s0 = 0.f, s1 = 0.f, s2 = 0.f, s3 = 0.f;
    f8acc(tbl[(size_t)n * 32 + f], s0, s1, s2, s3);
    int e1 = min(cnt[n], CAP);
    const int* ap = &adj[(size_t)n * CAP];
    int e = 0;
    for (; e + 4 <= e1; e += 4) {
        int i0 = ap[e], i1 = ap[e + 1], i2 = ap[e + 2], i3 = ap[e + 3];
        unsigned int u0 = tbl[(size_t)i0 * 32 + f];
        unsigned int u1 = tbl[(size_t)i1 * 32 + f];
        unsigned int u2 = tbl[(size_t)i2 * 32 + f];
        unsigned int u3 = tbl[(size_t)i3 * 32 + f];
        f8acc(u0, s0, s1, s2, s3); f8acc(u1, s0, s1, s2, s3);
        f8acc(u2, s0, s1, s2, s3); f8acc(u3, s0, s1, s2, s3);
    }
    for (; e < e1; e++) f8acc(tbl[(size_t)ap[e] * 32 + f], s0, s1, s2, s3);
    float d = dinv[n] * (1.f / 32.f);
    float v0 = s0 * d, v1 = s1 * d, v2 = s2 * d, v3 = s3 * d;
    if (BIASRELU) {
        float4 bv = *(const float4*)&bias[4 * f];
        v0 = fmaxf(v0 + bv.x, 0.f); v1 = fmaxf(v1 + bv.y, 0.f);
        v2 = fmaxf(v2 + bv.z, 0.f); v3 = fmaxf(v3 + bv.w, 0.f);
    }
    ushort4 u;
    u.x = f2bf(v0); u.y = f2bf(v1); u.z = f2bf(v2); u.w = f2bf(v3);
    *(ushort4*)&outb[(size_t)n * 128 + 4 * f] = u;
}

// Register-tiled matmul, dual-branch via blockIdx.y, padded LDS.
// OUTMODE: 0 = f32, 1 = bf16, 2 = fp8 e4m3 scaled x32
template <int K, int F, int TM, int IN_STRIDE, int IN_OFF_Y, int OUT_STRIDE, int OUT_OFF_Y,
          bool BIASRELU, bool SCALE, bool IN_BF16, int OUTMODE>
__global__ __launch_bounds__(256) void matmulX(
    const void* __restrict__ inv, const float* __restrict__ Wa, const float* __restrict__ Wb,
    const float* __restrict__ biasa, const float* __restrict__ biasb,
    const float* __restrict__ dinv, void* __restrict__ outv, int N) {
    constexpr int TN = 4;
    constexpr int CG = F / TN;
    constexpr int RG = 256 / CG;
    constexpr int BM = TM * RG;
    constexpr int KP = IN_BF16 ? (K + 8) : (K + 4);
    const int y = blockIdx.y;
    const float* W = (y == 0) ? Wa : Wb;
    const float* bias = (y == 0) ? biasa : biasb;
    __shared__ float Ws[K * F];
    __shared__ alignas(16) char xsraw[(size_t)BM * KP * (IN_BF16 ? 2 : 4)];
    int tid = threadIdx.x;
    for (int i = tid * 4; i < K * F; i += 1024)
        *(float4*)&Ws[i] = *(const float4*)&W[i];
    int node0 = blockIdx.x * BM;
    if constexpr (IN_BF16) {
        unsigned short* xs = (unsigned short*)xsraw;
        for (int i = tid * 8; i < BM * K; i += 2048) {
            int r = i / K, k = i % K;
            int n = node0 + r;
            uint4 v = make_uint4(0u, 0u, 0u, 0u);
            if (n < N)
                v = *(const uint4*)((const unsigned short*)inv +
                                    (size_t)n * IN_STRIDE + y * IN_OFF_Y + k);
            *(uint4*)&xs[r * KP + k] = v;
        }
    } else {
        float* xs = (float*)xsraw;
        for (int i = tid * 4; i < BM * K; i += 1024) {
            int r = i / K, k = i % K;
            int n = node0 + r;
            float4 v = make_float4(0.f, 0.f, 0.f, 0.f);
            if (n < N)
                v = *(const float4*)((const float*)inv + (size_t)n * IN_STRIDE + y * IN_OFF_Y + k);
            *(float4*)&xs[r * KP + k] = v;
        }
    }
    __syncthreads();
    int cg = tid % CG, rg = tid / CG;
    int f0 = cg * TN;
    const unsigned short* xsb = (const unsigned short*)xsraw;
    const float* xsf = (const float*)xsraw;
    float acc[TM][TN];
#pragma unroll
    for (int m = 0; m < TM; m++)
#pragma unroll
        for (int j = 0; j < TN; j++) acc[m][j] = 0.f;
    for (int k4 = 0; k4 < K; k4 += 4) {
        float4 wv[4];
#pragma unroll
        for (int kk = 0; kk < 4; kk++) wv[kk] = *(const float4*)&Ws[(k4 + kk) * F + f0];
#pragma unroll
        for (int m = 0; m < TM; m++) {
            float4 xv;
            if constexpr (IN_BF16) {
                ushort4 u = *(const ushort4*)&xsb[(rg * TM + m) * KP + k4];
                xv = make_float4(bf2f(u.x), bf2f(u.y), bf2f(u.z), bf2f(u.w));
            } else {
                xv = *(const float4*)&xsf[(rg * TM + m) * KP + k4];
            }
#pragma unroll
            for (int kk = 0; kk < 4; kk++) {
                float xk = (&xv.x)[kk];
                acc[m][0] += xk * wv[kk].x;
                acc[m][1] += xk * wv[kk].y;
                acc[m][2] += xk * wv[kk].z;
                acc[m][3] += xk * wv[kk].w;
            }
        }
    }
#pragma unroll
    for (int m = 0; m < TM; m++) {
        int n = node0 + rg * TM + m;
        if (n < N) {
            float vv[TN];
            float d = SCALE ? dinv[n] : 1.f;
#pragma unroll
            for (int j = 0; j < TN; j++) {
                float v = acc[m][j];
                if (BIASRELU) v = fmaxf(v + bias[f0 + j], 0.f);
                if (SCALE) v *= d;
                vv[j] = v;
            }
            size_t off = (size_t)n * OUT_STRIDE + y * OUT_OFF_Y + f0;
            if constexpr (OUTMODE == 2) {
                unsigned int r = 0;
                r = __builtin_amdgcn_cvt_pk_fp8_f32(vv[0] * 32.f, vv[1] * 32.f, r, false);
                r = __builtin_amdgcn_cvt_pk_fp8_f32(vv[2] * 32.f, vv[3] * 32.f, r, true);
                ((unsigned int*)outv)[off >> 2] = r;
            } else if constexpr (OUTMODE == 1) {
                ushort4 u;
                u.x = f2bf(vv[0]); u.y = f2bf(vv[1]); u.z = f2bf(vv[2]); u.w = f2bf(vv[3]);
                *(ushort4*)((unsigned short*)outv + off) = u;
            } else {
                *(float4*)((float*)outv + off) = make_float4(vv[0], vv[1], vv[2], vv[3]);
            }
        }
    }
}

// concat weights/biases for fused layer1 and fused layer3 bias
__global__ void prep_cat(const float* __restrict__ w1m, const float* __restrict__ w1l,
                         const float* __restrict__ b1m, const float* __restrict__ b1l,
                         const float* __restrict__ b3m, const float* __restrict__ b3l,
                         float* __restrict__ wcat1, float* __restrict__ bcat1,
                         float* __restrict__ bcat3) {
    int i = blockIdx.x * 256 + threadIdx.x;
    if (i < 32 * 128) {
        int k = i >> 7, f = i & 127;
        wcat1[i] = (f < 64) ? w1m[k * 64 + f] : w1l[k * 64 + f - 64];
    } else if (i < 32 * 128 + 128) {
        int f = i - 32 * 128;
        bcat1[f] = (f < 64) ? b1m[f] : b1l[f - 64];
    } else if (i < 32 * 128 + 256) {
        int f = i - 32 * 128 - 128;
        bcat3[f] = (f < 64) ? b3m[f] : b3l[f - 64];
    }
}

// decoder head-composition precompute (heads are linear in h2 -> fold through nm_wo)
__global__ void prep_dec(const float* __restrict__ nm_wo, const float* __restrict__ nm_bo,
                         const float* __restrict__ ex_w, const float* __restrict__ ex_b,
                         const float* __restrict__ fu_w, const float* __restrict__ fu_b,
                         const float* __restrict__ al_w, const float* __restrict__ al_b,
                         const float* __restrict__ sl_w, const float* __restrict__ sl_b,
                         const float* __restrict__ em_wo,
                         float* __restrict__ wtn, float* __restrict__ bcn,
                         float* __restrict__ wte) {
    int idx = blockIdx.x * 256 + threadIdx.x;
    if (idx < 1024) {
        int j = idx >> 7, k = idx & 127;
        float s = 0.f;
        for (int m = 0; m < 128; m++) {
            float w = (j == 0) ? ex_w[m] : (j <= 5) ? fu_w[m * 5 + (j - 1)]
                     : (j == 6) ? al_w[m] : sl_w[m];
            s += nm_wo[k * 128 + m] * w;
        }
        wtn[j * 128 + k] = s;
    } else if (idx < 2048) {
        int i2 = idx - 1024;
        int j = i2 >> 7, k = i2 & 127;
        wte[j * 128 + k] = em_wo[k * 8 + j];
    } else if (idx < 2056) {
        int j = idx - 2048;
        float s = (j == 0) ? ex_b[0] : (j <= 5) ? fu_b[j - 1] : (j == 6) ? al_b[0] : sl_b[0];
        for (int m = 0; m < 128; m++) {
            float w = (j == 0) ? ex_w[m] : (j <= 5) ? fu_w[m * 5 + (j - 1)]
                     : (j == 6) ? al_w[m] : sl_w[m];
            s += nm_bo[m] * w;
        }
        bcn[j] = s;
    }
}

#define POOL_CHUNK 128
// h is bf16-packed [n][64] uints
__global__ void pool128(const unsigned int* __restrict__ h, const int* __restrict__ batch,
                        float* __restrict__ sums, int n) {
    int f = threadIdx.x;  // 0..63
    int s0 = blockIdx.x * POOL_CHUNK;
    if (s0 >= n) return;
    int s1 = min(s0 + POOL_CHUNK, n);
    int cur = batch[s0];
    float a0 = 0.f, a1 = 0.f;
    for (int i = s0; i < s1; i++) {
        int b = batch[i];
        if (b != cur) {
            atomicAdd(&sums[cur * 128 + 2 * f], a0);
            atomicAdd(&sums[cur * 128 + 2 * f + 1], a1);
            a0 = a1 = 0.f; cur = b;
        }
        unsigned int u = h[(size_t)i * 64 + f];
        a0 += __uint_as_float(u << 16);
        a1 += __uint_as_float(u & 0xFFFF0000u);
    }
    atomicAdd(&sums[cur * 128 + 2 * f], a0);
    atomicAdd(&sums[cur * 128 + 2 * f + 1], a1);
}

__global__ void finalize_pool(const float* __restrict__ sums, const int* __restrict__ bcnt,
                              float* __restrict__ out, float* __restrict__ zbuf) {
    int i = blockIdx.x * 1024 + threadIdx.x;  // 0..2047
    int b = i >> 7, f = i & 127;
    float c = fmaxf((float)bcnt[b], 1.f);
    float v = sums[i] / c;
    if (f < 64) { out[OUT_MU + b * 64 + f] = v; zbuf[b * 64 + f] = v; }
    else out[OUT_LG + b * 64 + (f - 64)] = v;
}

// zwi[b][t] = bi[t] + sum_k z[b,k]*wi[k*128+t]
__global__ void zwi_kernel(const float* __restrict__ z,
                           const float* __restrict__ nm_wi, const float* __restrict__ nm_bi,
                           const float* __restrict__ em_wi, const float* __restrict__ em_bi,
                           float* __restrict__ zwi_nm, float* __restrict__ zwi_em) {
    int b = blockIdx.x, t = threadIdx.x;  // 16 blocks x 128 threads
    float an = nm_bi[t], ae = em_bi[t];
    for (int k = 0; k < 64; k++) {
        float zv = z[b * 64 + k];
        an += zv * nm_wi[k * 128 + t];
        ae += zv * em_wi[k * 128 + t];
    }
    zwi_nm[b * 128 + t] = an;
    zwi_em[b * 128 + t] = ae;
}

#define D3_ROWS 32

// decoder3: layer1+LN -> LDS; heads/edges as 128-len LDS dots (heads pre-composed)
__global__ __launch_bounds__(256) void decoder3(
    const float* __restrict__ zwi_nm, const float* __restrict__ zwi_em,
    const float* __restrict__ nm_wi, const float* __restrict__ em_wi,
    const float* __restrict__ nm_g, const float* __restrict__ nm_be,
    const float* __restrict__ em_g, const float* __restrict__ em_be,
    const float* __restrict__ wtn, const float* __restrict__ bcn,
    const float* __restrict__ wte, const float* __restrict__ em_bo,
    const float* __restrict__ pos_all,
    float* __restrict__ out) {
    __shared__ float sn[D3_ROWS][132];   // +4 pad: 4-bank rotation per row
    __shared__ float se[D3_ROWS][132];
    __shared__ float Wn[8][132];
    __shared__ float We[8][132];
    int t = threadIdx.x;
    int lane = t & 63, wave = t >> 6;
    int rowBase = blockIdx.x * D3_ROWS;
    int b = rowBase >> 12;
    int row0 = rowBase + wave * 8;

    for (int i = t; i < 1024; i += 256) {
        Wn[i >> 7][i & 127] = wtn[i];
        We[i >> 7][i & 127] = wte[i];
    }

    int f0 = lane, f1 = lane + 64;
    float zn0 = zwi_nm[b * 128 + f0], zn1 = zwi_nm[b * 128 + f1];
    float ze0 = zwi_em[b * 128 + f0], ze1 = zwi_em[b * 128 + f1];
    float wn64_0 = nm_wi[64 * 128 + f0], wn64_1 = nm_wi[64 * 128 + f1];
    float wn65_0 = nm_wi[65 * 128 + f0], wn65_1 = nm_wi[65 * 128 + f1];
    float we64_0 = em_wi[64 * 128 + f0], we64_1 = em_wi[64 * 128 + f1];
    float we65_0 = em_wi[65 * 128 + f0], we65_1 = em_wi[65 * 128 + f1];
    float gn0 = nm_g[f0], gn1 = nm_g[f1], bn0 = nm_be[f0], bn1 = nm_be[f1];
    float ge0 = em_g[f0], ge1 = em_g[f1], be0 = em_be[f0], be1 = em_be[f1];

#pragma unroll
    for (int r = 0; r < 8; r++) {
        int row = row0 + r, i = row & (NMAXC - 1);
        float px = pos_all[i * 2], py = pos_all[i * 2 + 1];
        float a0 = zn0 + px * wn64_0 + py * wn65_0;
        float a1 = zn1 + px * wn64_1 + py * wn65_1;
        float e0 = ze0 + px * we64_0 + py * we65_0;
        float e1 = ze1 + px * we64_1 + py * we65_1;
        float sm = a0 + a1, sq = a0 * a0 + a1 * a1;
        float sme = e0 + e1, sqe = e0 * e0 + e1 * e1;
#pragma unroll
        for (int d = 1; d < 64; d <<= 1) {
            sm += __shfl_xor(sm, d); sq += __shfl_xor(sq, d);
            sme += __shfl_xor(sme, d); sqe += __shfl_xor(sqe, d);
        }
        float mean = sm * (1.f / 128.f);
        float var = sq * (1.f / 128.f) - mean * mean;
        float rstd = rsqrtf(var + 1e-5f);
        int rl = wave * 8 + r;
        sn[rl][f0] = fmaxf((a0 - mean) * rstd * gn0 + bn0, 0.f);
        sn[rl][f1] = fmaxf((a1 - mean) * rstd * gn1 + bn1, 0.f);
        float meane = sme * (1.f / 128.f);
        float vare = sqe * (1.f / 128.f) - meane * meane;
        float rstde = rsqrtf(vare + 1e-5f);
        se[rl][f0] = fmaxf((e0 - meane) * rstde * ge0 + be0, 0.f);
        se[rl][f1] = fmaxf((e1 - meane) * rstde * ge1 + be1, 0.f);
    }
    __syncthreads();

    int rl = t >> 3, j = t & 7;
    float accn = 0.f, acce = 0.f;
#pragma unroll 8
    for (int k4 = 0; k4 < 128; k4 += 4) {
        float4 sv = *(const float4*)&sn[rl][k4];
        float4 wv = *(const float4*)&Wn[j][k4];
        float4 sev = *(const float4*)&se[rl][k4];
        float4 wev = *(const float4*)&We[j][k4];
        accn += sv.x * wv.x + sv.y * wv.y + sv.z * wv.z + sv.w * wv.w;
        acce += sev.x * wev.x + sev.y * wev.y + sev.z * wev.z + sev.w * wev.w;
    }
    int row = rowBase + rl;
    accn += bcn[j];
    if (j == 0)       out[OUT_NODES + row] = accn;
    else if (j <= 5)  out[OUT_FUEL + (size_t)row * 5 + (j - 1)] = accn;
    else if (j == 6)  out[OUT_ALT + row] = accn;
    else              out[OUT_SLOPE + row] = accn;
    out[OUT_EDGES + (size_t)row * 8 + j] = acce + em_bo[j];
}

extern "C" void kernel_launch(void* const* d_in, const int* in_sizes, int n_in,
                              void* d_out, int out_size, void* d_ws, size_t ws_size,
                              hipStream_t stream) {
    const float* x    = (const float*)d_in[0];
    const int* edge   = (const int*)d_in[1];
    const int* batch  = (const int*)d_in[2];
    const float* w1m = (const float*)d_in[3];  const float* b1m = (const float*)d_in[4];
    const float* w2m = (const float*)d_in[5];  const float* b2m = (const float*)d_in[6];
    const float* w3m = (const float*)d_in[7];  const float* b3m = (const float*)d_in[8];
    const float* w1l = (const float*)d_in[9];  const float* b1l = (const float*)d_in[10];
    const float* w2l = (const float*)d_in[11]; const float* b2l = (const float*)d_in[12];
    const float* w3l = (const float*)d_in[13]; const float* b3l = (const float*)d_in[14];
    const float* nm_wi = (const float*)d_in[15]; const float* nm_bi = (const float*)d_in[16];
    const float* nm_g  = (const float*)d_in[17]; const float* nm_be = (const float*)d_in[18];
    const float* nm_wo = (const float*)d_in[19]; const float* nm_bo = (const float*)d_in[20];
    const float* ex_w = (const float*)d_in[21]; const float* ex_b = (const float*)d_in[22];
    const float* fu_w = (const float*)d_in[23]; const float* fu_b = (const float*)d_in[24];
    const float* al_w = (const float*)d_in[25]; const float* al_b = (const float*)d_in[26];
    const float* sl_w = (const float*)d_in[27]; const float* sl_b = (const float*)d_in[28];
    const float* em_wi = (const float*)d_in[29]; const float* em_bi = (const float*)d_in[30];
    const float* em_g  = (const float*)d_in[31]; const float* em_be = (const float*)d_in[32];
    const float* em_wo = (const float*)d_in[33]; const float* em_bo = (const float*)d_in[34];
    const float* pos_all = (const float*)d_in[35];
    float* out = (float*)d_out;

    char* p = (char*)d_ws;
    auto alloc = [&](size_t bytes) -> void* {
        void* r = (void*)p;
        p += ((bytes + 255) / 256) * 256;
        return r;
    };
    int* cnt      = (int*)alloc((size_t)N_NODES * 4);
    float* dinv   = (float*)alloc((size_t)N_NODES * 4);
    int* bcnt     = (int*)alloc(BATCH_B * 4);
    float* sums   = (float*)alloc(BATCH_B * 128 * 4);
    float* zbuf   = (float*)alloc(BATCH_B * LATC * 4);
    float* zwi_nm = (float*)alloc(BATCH_B * 128 * 4);
    float* zwi_em = (float*)alloc(BATCH_B * 128 * 4);
    float* wcat1  = (float*)alloc(32 * 128 * 4);
    float* bcat1  = (float*)alloc(128 * 4);
    float* bcat3  = (float*)alloc(128 * 4);
    float* wtn    = (float*)alloc(8 * 128 * 4);
    float* bcn    = (float*)alloc(8 * 4);
    float* wte    = (float*)alloc(8 * 128 * 4);
    int* cursors  = (int*)alloc((size_t)8 * NBINS * 16 * 4);
    int* spillCnt = (int*)alloc(256);
    int* spill    = (int*)alloc((size_t)N_EDGESC * 8);                         // 12.8 MB
    unsigned int* bins = (unsigned int*)alloc((size_t)8 * NBINS * BINCAP * 4); // 12.8 MB
    int* adj      = (int*)alloc((size_t)N_NODES * CAP * 4);                    // 25.6 MB
    unsigned int* xs8 = (unsigned int*)alloc((size_t)N_NODES * 8 * 4);         // 3.2 MB fp8
    float* agg0   = (float*)alloc((size_t)N_NODES * 32 * 4);                   // 12.8 MB
    unsigned int* hA8 = (unsigned int*)alloc((size_t)N_NODES * 32 * 4);        // 12.8 MB fp8 (also hD8)
    unsigned short* hB   = (unsigned short*)alloc((size_t)N_NODES * 128 * 2);  // 25.6 MB bf16
    unsigned short* h256 = (unsigned short*)alloc((size_t)N_NODES * 256 * 2);  // 51.2 MB bf16 (also final)
    unsigned int* hD8 = hA8;                       // hA8 dead after agg #1
    unsigned short* final128 = h256;               // h256 dead after layer-3 matmul

    const int* srcp = edge;
    const int* dstp = edge + N_EDGESC;

    hipMemsetAsync(cursors, 0, (size_t)8 * NBINS * 16 * 4, stream);
    hipMemsetAsync(spillCnt, 0, 4, stream);
    hipMemsetAsync(sums, 0, (size_t)BATCH_B * 128 * 4, stream);

    // ---- CSR build: XCD-local binning (hw XCC id), then per-bin dense fill ----
    bin_pass<<<(N_EDGESC + 255) / 256, 256, 0, stream>>>(srcp, dstp, cursors, bins,
                                                         spillCnt, spill, N_EDGESC);
    csr_from_bins<<<NBINS, 256, 0, stream>>>(cursors, bins, spillCnt, spill, adj, cnt, dinv, N_NODES);

    batch_count<<<1, 64, 0, stream>>>(batch, bcnt, N_NODES);
    prep_cat<<<17, 256, 0, stream>>>(w1m, w1l, b1m, b1l, b3m, b3l, wcat1, bcat1, bcat3);
    prep_dec<<<9, 256, 0, stream>>>(nm_wo, nm_bo, ex_w, ex_b, fu_w, fu_b, al_w, al_b,
                                    sl_w, sl_b, em_wo, wtn, bcn, wte);
    prescale_x<<<(N_NODES * 8 + 255) / 256, 256, 0, stream>>>(x, dinv, xs8, N_NODES * 8);

    // agg0 = S x  (shared by both branches), fp8 table
    agg_s32<<<(N_NODES + 31) / 32, 256, 0, stream>>>(xs8, cnt, adj, dinv, agg0, N_NODES);

    // L1 (fused mu|lg): hA8 = fp8x32( dinv ⊙ relu(agg0 @ [w1m|w1l] + [b1m|b1l]) )
    matmulX<32, 128, 4, 32, 0, 128, 0, true, true, false, 2>
        <<<dim3((N_NODES + 31) / 32, 1), 256, 0, stream>>>(
        agg0, wcat1, nullptr, bcat1, nullptr, dinv, hA8, N_NODES);

    // agg #1: hB = [S mu1 | S lg1]  -> bf16 [n][128]
    agg128<false><<<(N_NODES + 7) / 8, 256, 0, stream>>>(
        hA8, cnt, adj, dinv, nullptr, hB, N_NODES);

    // L2 dual: h256[:, y*128:...] = relu(hB[:, y*64:...] @ w2{m,l} + b2{m,l})  -> bf16 [n][256]
    matmulX<64, 128, 4, 128, 64, 256, 128, true, false, true, 1>
        <<<dim3((N_NODES + 31) / 32, 2), 256, 0, stream>>>(
        hB, w2m, w2l, b2m, b2l, nullptr, h256, N_NODES);

    // L3 dual: hD8[:, y*64:...] = fp8x32( dinv ⊙ (h256[:, y*128:...] @ w3{m,l}) )
    matmulX<128, 64, 3, 256, 128, 128, 64, false, true, true, 2>
        <<<dim3((N_NODES + 47) / 48, 2), 256, 0, stream>>>(
        h256, w3m, w3l, nullptr, nullptr, dinv, hD8, N_NODES);

    // agg #2: final = relu(dinv*(sum) + [b3m|b3l]) = [mu3|lg3]  -> bf16 [n][128]
    agg128<true><<<(N_NODES + 7) / 8, 256, 0, stream>>>(
        hD8, cnt, adj, dinv, bcat3, final128, N_NODES);

    pool128<<<(N_NODES + POOL_CHUNK - 1) / POOL_CHUNK, 64, 0, stream>>>(
        (const unsigned int*)final128, batch, sums, N_NODES);
    finalize_pool<<<2, 1024, 0, stream>>>(sums, bcnt, out, zbuf);

    zwi_kernel<<<BATCH_B, 128, 0, stream>>>(zbuf, nm_wi, nm_bi, em_wi, em_bi, zwi_nm, zwi_em);

    decoder3<<<BATCH_B * NMAXC / D3_ROWS, 256, 0, stream>>>(
        zwi_nm, zwi_em, nm_wi, em_wi, nm_g, nm_be, em_g, em_be,
        wtn, bcn, wte, em_bo, pos_all, out);
}

// Round 9
// 405.450 us; speedup vs baseline: 7.9413x; 1.1304x over previous
//
#include <hip/hip_runtime.h>
#include <hip/hip_bf16.h>

#define N_NODES 100000
#define N_EDGESC 1600000
#define BATCH_B 16
#define NMAXC 4096
#define LATC 64
#define CAP 64      // padded CSR bucket capacity; deg ~ Binom, P(deg>64) ~ 1e-15
#define NBINS 391   // ceil(100000/256): 256 nodes per bin
#define NSB 256     // sort blocks
#define EPB ((N_EDGESC + NSB - 1) / NSB)  // 6250 edges per sort block

// output layout offsets (flat f32)
#define OUT_NODES 0
#define OUT_EDGES 65536
#define OUT_FUEL  589824
#define OUT_ALT   917504
#define OUT_SLOPE 983040
#define OUT_MU    1048576
#define OUT_LG    1049600

typedef float f32x2 __attribute__((ext_vector_type(2)));

__device__ __forceinline__ unsigned short f2bf(float f) {
    unsigned int u = __float_as_uint(f);
    return (unsigned short)((u + 0x7FFFu + ((u >> 16) & 1u)) >> 16);  // RNE
}
__device__ __forceinline__ float bf2f(unsigned short h) {
    return __uint_as_float(((unsigned int)h) << 16);
}
// accumulate 4 fp8(e4m3) packed in u into a0..a3 (HW cvt, OCP on gfx950)
__device__ __forceinline__ void f8acc(unsigned int u, float& a0, float& a1, float& a2, float& a3) {
    f32x2 lo = __builtin_amdgcn_cvt_pk_f32_fp8(u, false);
    f32x2 hi = __builtin_amdgcn_cvt_pk_f32_fp8(u, true);
    a0 += lo[0]; a1 += lo[1]; a2 += hi[0]; a3 += hi[1];
}

// batch is sorted: count[b] = upper_bound(b) - lower_bound(b)
__global__ void batch_count(const int* __restrict__ batch, int* __restrict__ bcnt, int n) {
    int b = threadIdx.x;
    if (b >= BATCH_B) return;
    int lo = 0, hi = n;
    while (lo < hi) { int mid = (lo + hi) >> 1; if (batch[mid] < b) lo = mid + 1; else hi = mid; }
    int start = lo;
    lo = 0; hi = n;
    while (lo < hi) { int mid = (lo + hi) >> 1; if (batch[mid] <= b) lo = mid + 1; else hi = mid; }
    bcnt[b] = lo - start;
}

// ---- CSR build via atomic-free counting sort by dst>>8 ----
// Pass A: per-block LDS histogram -> hist[j][b] (bin-major)
__global__ __launch_bounds__(1024) void histA(const int* __restrict__ dst, int* __restrict__ hist) {
    __shared__ int h[NBINS];
    int b = blockIdx.x, t = threadIdx.x;
    for (int i = t; i < NBINS; i += 1024) h[i] = 0;
    __syncthreads();
    int e0 = b * EPB, e1 = min(e0 + EPB, N_EDGESC);
    for (int i = e0 + t; i < e1; i += 1024)
        atomicAdd(&h[dst[i] >> 8], 1);
    __syncthreads();
    for (int i = t; i < NBINS; i += 1024) hist[i * NSB + b] = h[i];
}

// Pass B: per-bin exclusive scan over blocks; emits per-bin total
__global__ void scanB(int* __restrict__ hist, int* __restrict__ total) {
    __shared__ int sh[NSB];
    int j = blockIdx.x, t = threadIdx.x;  // 256 threads
    int v = hist[j * NSB + t];
    sh[t] = v; __syncthreads();
    for (int off = 1; off < NSB; off <<= 1) {
        int u = (t >= off) ? sh[t - off] : 0; __syncthreads();
        sh[t] += u; __syncthreads();
    }
    hist[j * NSB + t] = sh[t] - v;  // exclusive offset of block b within bin j
    if (t == NSB - 1) total[j] = sh[t];
}

// Pass C: scan bin totals -> base[j], base[NBINS] = total edges
__global__ void scanC(const int* __restrict__ total, int* __restrict__ base) {
    __shared__ int sh[512];
    int t = threadIdx.x;
    int v = (t < NBINS) ? total[t] : 0;
    sh[t] = v; __syncthreads();
    for (int off = 1; off < 512; off <<= 1) {
        int u = (t >= off) ? sh[t - off] : 0; __syncthreads();
        sh[t] += u; __syncthreads();
    }
    if (t < NBINS) base[t] = sh[t] - v;
    if (t == NBINS - 1) base[NBINS] = sh[t];
}

// Pass D: scatter to exact positions (LDS ranks only; zero global atomics)
__global__ __launch_bounds__(1024) void scatterD(const int* __restrict__ src, const int* __restrict__ dst,
                                                 const int* __restrict__ hist, const int* __restrict__ base,
                                                 unsigned int* __restrict__ sorted) {
    __shared__ int w0[NBINS];
    __shared__ int lc[NBINS];
    int b = blockIdx.x, t = threadIdx.x;
    for (int i = t; i < NBINS; i += 1024) {
        w0[i] = base[i] + hist[i * NSB + b];
        lc[i] = 0;
    }
    __syncthreads();
    int e0 = b * EPB, e1 = min(e0 + EPB, N_EDGESC);
    for (int i = e0 + t; i < e1; i += 1024) {
        int d = dst[i], s = src[i];
        int j = d >> 8;
        int r = atomicAdd(&lc[j], 1);
        sorted[w0[j] + r] = ((unsigned int)s << 8) | (d & 255);
    }
}

// Pass E: per-bin CSR fill from contiguous segment; LDS ranks; cnt + dinv
__global__ void csr_sorted(const unsigned int* __restrict__ sorted, const int* __restrict__ base,
                           int* __restrict__ adj, int* __restrict__ cnt,
                           float* __restrict__ dinv, int N) {
    __shared__ int lc[256];
    int j = blockIdx.x, t = threadIdx.x;
    lc[t] = 0; __syncthreads();
    int e0 = base[j], e1 = base[j + 1];
    int node0 = j * 256;
    for (int i = e0 + t; i < e1; i += 256) {
        unsigned int pk = sorted[i];
        int d = pk & 255;
        int r = atomicAdd(&lc[d], 1);
        if (r < CAP) adj[(size_t)(node0 + d) * CAP + r] = (int)(pk >> 8);
    }
    __syncthreads();
    int n = node0 + t;
    if (n < N) {
        int c = lc[t];
        cnt[n] = c;
        dinv[n] = rsqrtf((float)(c + 1));  // +1 = self loop
    }
}

// xs8 (fp8 packed, [n][8] uints) = 64 * dinv[n] * x[n][32]
__global__ void prescale_x(const float* __restrict__ x, const float* __restrict__ dinv,
                           unsigned int* __restrict__ xs8, int total4) {
    int i4 = blockIdx.x * 256 + threadIdx.x;
    if (i4 < total4) {
        float4 v = *(const float4*)&x[i4 * 4];
        float ds = dinv[i4 >> 3] * 64.f;
        unsigned int r = 0;
        r = __builtin_amdgcn_cvt_pk_fp8_f32(v.x * ds, v.y * ds, r, false);
        r = __builtin_amdgcn_cvt_pk_fp8_f32(v.z * ds, v.w * ds, r, true);
        xs8[i4] = r;
    }
}

// agg0 = S x : fp8 table [n][8] uints; 32 nodes per 256-thread block, 8 lanes/node
__global__ void agg_s32(const unsigned int* __restrict__ xs8, const int* __restrict__ cnt,
                        const int* __restrict__ adj, const float* __restrict__ dinv,
                        float* __restrict__ out, int N) {
    int t = threadIdx.x;
    int sub = t >> 3, f = t & 7;
    int n = blockIdx.x * 32 + sub;
    if (n >= N) return;
    float s0 = 0.f, s1 = 0.f, s2 = 0.f, s3 = 0.f;
    f8acc(xs8[(size_t)n * 8 + f], s0, s1, s2, s3);
    int e1 = min(cnt[n], CAP);
    const int* ap = &adj[(size_t)n * CAP];
    int e = 0;
    for (; e + 4 <= e1; e += 4) {
        int i0 = ap[e], i1 = ap[e + 1], i2 = ap[e + 2], i3 = ap[e + 3];
        unsigned int u0 = xs8[(size_t)i0 * 8 + f];
        unsigned int u1 = xs8[(size_t)i1 * 8 + f];
        unsigned int u2 = xs8[(size_t)i2 * 8 + f];
        unsigned int u3 = xs8[(size_t)i3 * 8 + f];
        f8acc(u0, s0, s1, s2, s3); f8acc(u1, s0, s1, s2, s3);
        f8acc(u2, s0, s1, s2, s3); f8acc(u3, s0, s1, s2, s3);
    }
    for (; e < e1; e++) f8acc(xs8[(size_t)ap[e] * 8 + f], s0, s1, s2, s3);
    float d = dinv[n] * (1.f / 64.f);
    *(float4*)&out[(size_t)n * 32 + f * 4] = make_float4(s0 * d, s1 * d, s2 * d, s3 * d);
}

// 128-dim fp8-table aggregation (table pre-scaled x32); 8 nodes/block, 32 lanes/node
// OUT8: write fp8 x32 [n][32] uints; else bf16 [n][128]
template <bool BIASRELU, bool OUT8>
__global__ void agg128(const unsigned int* __restrict__ tbl, const int* __restrict__ cnt,
                       const int* __restrict__ adj, const float* __restrict__ dinv,
                       const float* __restrict__ bias, void* __restrict__ outv, int N) {
    int t = threadIdx.x;
    int sub = t >> 5, f = t & 31;
    int n = blockIdx.x * 8 + sub;
    if (n >= N) return;
    float s0 = 0.f, s1 = 0.f, s2 = 0.f, s3 = 0.f;
    f8acc(tbl[(size_t)n * 32 + f], s0, s1, s2, s3);
    int e1 = min(cnt[n], CAP);
    const int* ap = &adj[(size_t)n * CAP];
    int e = 0;
    for (; e + 4 <= e1; e += 4) {
        int i0 = ap[e], i1 = ap[e + 1], i2 = ap[e + 2], i3 = ap[e + 3];
        unsigned int u0 = tbl[(size_t)i0 * 32 + f];
        unsigned int u1 = tbl[(size_t)i1 * 32 + f];
        unsigned int u2 = tbl[(size_t)i2 * 32 + f];
        unsigned int u3 = tbl[(size_t)i3 * 32 + f];
        f8acc(u0, s0, s1, s2, s3); f8acc(u1, s0, s1, s2, s3);
        f8acc(u2, s0, s1, s2, s3); f8acc(u3, s0, s1, s2, s3);
    }
    for (; e < e1; e++) f8acc(tbl[(size_t)ap[e] * 32 + f], s0, s1, s2, s3);
    float d = dinv[n] * (1.f / 32.f);
    float v0 = s0 * d, v1 = s1 * d, v2 = s2 * d, v3 = s3 * d;
    if (BIASRELU) {
        float4 bv = *(const float4*)&bias[4 * f];
        v0 = fmaxf(v0 + bv.x, 0.f); v1 = fmaxf(v1 + bv.y, 0.f);
        v2 = fmaxf(v2 + bv.z, 0.f); v3 = fmaxf(v3 + bv.w, 0.f);
    }
    if (OUT8) {
        unsigned int r = 0;
        r = __builtin_amdgcn_cvt_pk_fp8_f32(v0 * 32.f, v1 * 32.f, r, false);
        r = __builtin_amdgcn_cvt_pk_fp8_f32(v2 * 32.f, v3 * 32.f, r, true);
        ((unsigned int*)outv)[(size_t)n * 32 + f] = r;
    } else {
        ushort4 u;
        u.x = f2bf(v0); u.y = f2bf(v1); u.z = f2bf(v2); u.w = f2bf(v3);
        *(ushort4*)&((unsigned short*)outv)[(size_t)n * 128 + 4 * f] = u;
    }
}

// Register-tiled matmul, dual-branch via blockIdx.y, padded LDS.
// INMODE: 0 = f32, 1 = bf16, 2 = fp8 e4m3 x32 (decoded to bf16 in LDS; epilogue /32)
// OUTMODE: 0 = f32, 1 = bf16, 2 = fp8 e4m3 x32
// IN_STRIDE/IN_OFF_Y and OUT_STRIDE/OUT_OFF_Y in ELEMENTS of the respective dtype.
template <int K, int F, int TM, int IN_STRIDE, int IN_OFF_Y, int OUT_STRIDE, int OUT_OFF_Y,
          bool BIASRELU, bool SCALE, int INMODE, int OUTMODE>
__global__ __launch_bounds__(256) void matmulX(
    const void* __restrict__ inv, const float* __restrict__ Wa, const float* __restrict__ Wb,
    const float* __restrict__ biasa, const float* __restrict__ biasb,
    const float* __restrict__ dinv, void* __restrict__ outv, int N) {
    constexpr int TN = 4;
    constexpr int CG = F / TN;
    constexpr int RG = 256 / CG;
    constexpr int BM = TM * RG;
    constexpr int KP = (INMODE != 0) ? (K + 8) : (K + 4);
    const int y = blockIdx.y;
    const float* W = (y == 0) ? Wa : Wb;
    const float* bias = (y == 0) ? biasa : biasb;
    __shared__ float Ws[K * F];
    __shared__ alignas(16) char xsraw[(size_t)BM * KP * ((INMODE != 0) ? 2 : 4)];
    int tid = threadIdx.x;
    for (int i = tid * 4; i < K * F; i += 1024)
        *(float4*)&Ws[i] = *(const float4*)&W[i];
    int node0 = blockIdx.x * BM;
    if constexpr (INMODE == 1) {
        unsigned short* xs = (unsigned short*)xsraw;
        for (int i = tid * 8; i < BM * K; i += 2048) {
            int r = i / K, k = i % K;
            int n = node0 + r;
            uint4 v = make_uint4(0u, 0u, 0u, 0u);
            if (n < N)
                v = *(const uint4*)((const unsigned short*)inv +
                                    (size_t)n * IN_STRIDE + y * IN_OFF_Y + k);
            *(uint4*)&xs[r * KP + k] = v;
        }
    } else if constexpr (INMODE == 2) {
        unsigned short* xs = (unsigned short*)xsraw;
        const unsigned int* in8 = (const unsigned int*)inv;
        for (int i = tid * 4; i < BM * K; i += 1024) {
            int r = i / K, k = i % K;
            int n = node0 + r;
            unsigned int u = 0;
            if (n < N) u = in8[((size_t)n * IN_STRIDE + y * IN_OFF_Y + k) >> 2];
            f32x2 lo = __builtin_amdgcn_cvt_pk_f32_fp8(u, false);
            f32x2 hi = __builtin_amdgcn_cvt_pk_f32_fp8(u, true);
            ushort4 q;
            q.x = f2bf(lo[0]); q.y = f2bf(lo[1]); q.z = f2bf(hi[0]); q.w = f2bf(hi[1]);
            *(ushort4*)&xs[r * KP + k] = q;
        }
    } else {
        float* xs = (float*)xsraw;
        for (int i = tid * 4; i < BM * K; i += 1024) {
            int r = i / K, k = i % K;
            int n = node0 + r;
            float4 v = make_float4(0.f, 0.f, 0.f, 0.f);
            if (n < N)
                v = *(const float4*)((const float*)inv + (size_t)n * IN_STRIDE + y * IN_OFF_Y + k);
            *(float4*)&xs[r * KP + k] = v;
        }
    }
    __syncthreads();
    int cg = tid % CG, rg = tid / CG;
    int f0 = cg * TN;
    const unsigned short* xsb = (const unsigned short*)xsraw;
    const float* xsf = (const float*)xsraw;
    float acc[TM][TN];
#pragma unroll
    for (int m = 0; m < TM; m++)
#pragma unroll
        for (int j = 0; j < TN; j++) acc[m][j] = 0.f;
    for (int k4 = 0; k4 < K; k4 += 4) {
        float4 wv[4];
#pragma unroll
        for (int kk = 0; kk < 4; kk++) wv[kk] = *(const float4*)&Ws[(k4 + kk) * F + f0];
#pragma unroll
        for (int m = 0; m < TM; m++) {
            float4 xv;
            if constexpr (INMODE != 0) {
                ushort4 u = *(const ushort4*)&xsb[(rg * TM + m) * KP + k4];
                xv = make_float4(bf2f(u.x), bf2f(u.y), bf2f(u.z), bf2f(u.w));
            } else {
                xv = *(const float4*)&xsf[(rg * TM + m) * KP + k4];
            }
#pragma unroll
            for (int kk = 0; kk < 4; kk++) {
                float xk = (&xv.x)[kk];
                acc[m][0] += xk * wv[kk].x;
                acc[m][1] += xk * wv[kk].y;
                acc[m][2] += xk * wv[kk].z;
                acc[m][3] += xk * wv[kk].w;
            }
        }
    }
    constexpr float ISC = (INMODE == 2) ? (1.f / 32.f) : 1.f;
#pragma unroll
    for (int m = 0; m < TM; m++) {
        int n = node0 + rg * TM + m;
        if (n < N) {
            float vv[TN];
            float d = SCALE ? dinv[n] : 1.f;
#pragma unroll
            for (int j = 0; j < TN; j++) {
                float v = acc[m][j] * ISC;
                if (BIASRELU) v = fmaxf(v + bias[f0 + j], 0.f);
                if (SCALE) v *= d;
                vv[j] = v;
            }
            size_t off = (size_t)n * OUT_STRIDE + y * OUT_OFF_Y + f0;
            if constexpr (OUTMODE == 2) {
                unsigned int r = 0;
                r = __builtin_amdgcn_cvt_pk_fp8_f32(vv[0] * 32.f, vv[1] * 32.f, r, false);
                r = __builtin_amdgcn_cvt_pk_fp8_f32(vv[2] * 32.f, vv[3] * 32.f, r, true);
                ((unsigned int*)outv)[off >> 2] = r;
            } else if constexpr (OUTMODE == 1) {
                ushort4 u;
                u.x = f2bf(vv[0]); u.y = f2bf(vv[1]); u.z = f2bf(vv[2]); u.w = f2bf(vv[3]);
                *(ushort4*)((unsigned short*)outv + off) = u;
            } else {
                *(float4*)((float*)outv + off) = make_float4(vv[0], vv[1], vv[2], vv[3]);
            }
        }
    }
}

// concat weights/biases for fused layer1 and fused layer3 bias
__global__ void prep_cat(const float* __restrict__ w1m, const float* __restrict__ w1l,
                         const float* __restrict__ b1m, const float* __restrict__ b1l,
                         const float* __restrict__ b3m, const float* __restrict__ b3l,
                         float* __restrict__ wcat1, float* __restrict__ bcat1,
                         float* __restrict__ bcat3) {
    int i = blockIdx.x * 256 + threadIdx.x;
    if (i < 32 * 128) {
        int k = i >> 7, f = i & 127;
        wcat1[i] = (f < 64) ? w1m[k * 64 + f] : w1l[k * 64 + f - 64];
    } else if (i < 32 * 128 + 128) {
        int f = i - 32 * 128;
        bcat1[f] = (f < 64) ? b1m[f] : b1l[f - 64];
    } else if (i < 32 * 128 + 256) {
        int f = i - 32 * 128 - 128;
        bcat3[f] = (f < 64) ? b3m[f] : b3l[f - 64];
    }
}

// decoder head-composition precompute (heads are linear in h2 -> fold through nm_wo)
__global__ void prep_dec(const float* __restrict__ nm_wo, const float* __restrict__ nm_bo,
                         const float* __restrict__ ex_w, const float* __restrict__ ex_b,
                         const float* __restrict__ fu_w, const float* __restrict__ fu_b,
                         const float* __restrict__ al_w, const float* __restrict__ al_b,
                         const float* __restrict__ sl_w, const float* __restrict__ sl_b,
                         const float* __restrict__ em_wo,
                         float* __restrict__ wtn, float* __restrict__ bcn,
                         float* __restrict__ wte) {
    int idx = blockIdx.x * 256 + threadIdx.x;
    if (idx < 1024) {
        int j = idx >> 7, k = idx & 127;
        float s = 0.f;
        for (int m = 0; m < 128; m++) {
            float w = (j == 0) ? ex_w[m] : (j <= 5) ? fu_w[m * 5 + (j - 1)]
                     : (j == 6) ? al_w[m] : sl_w[m];
            s += nm_wo[k * 128 + m] * w;
        }
        wtn[j * 128 + k] = s;
    } else if (idx < 2048) {
        int i2 = idx - 1024;
        int j = i2 >> 7, k = i2 & 127;
        wte[j * 128 + k] = em_wo[k * 8 + j];
    } else if (idx < 2056) {
        int j = idx - 2048;
        float s = (j == 0) ? ex_b[0] : (j <= 5) ? fu_b[j - 1] : (j == 6) ? al_b[0] : sl_b[0];
        for (int m = 0; m < 128; m++) {
            float w = (j == 0) ? ex_w[m] : (j <= 5) ? fu_w[m * 5 + (j - 1)]
                     : (j == 6) ? al_w[m] : sl_w[m];
            s += nm_bo[m] * w;
        }
        bcn[j] = s;
    }
}

#define POOL_CHUNK 128
// h is bf16-packed [n][64] uints
__global__ void pool128(const unsigned int* __restrict__ h, const int* __restrict__ batch,
                        float* __restrict__ sums, int n) {
    int f = threadIdx.x;  // 0..63
    int s0 = blockIdx.x * POOL_CHUNK;
    if (s0 >= n) return;
    int s1 = min(s0 + POOL_CHUNK, n);
    int cur = batch[s0];
    float a0 = 0.f, a1 = 0.f;
    for (int i = s0; i < s1; i++) {
        int b = batch[i];
        if (b != cur) {
            atomicAdd(&sums[cur * 128 + 2 * f], a0);
            atomicAdd(&sums[cur * 128 + 2 * f + 1], a1);
            a0 = a1 = 0.f; cur = b;
        }
        unsigned int u = h[(size_t)i * 64 + f];
        a0 += __uint_as_float(u << 16);
        a1 += __uint_as_float(u & 0xFFFF0000u);
    }
    atomicAdd(&sums[cur * 128 + 2 * f], a0);
    atomicAdd(&sums[cur * 128 + 2 * f + 1], a1);
}

__global__ void finalize_pool(const float* __restrict__ sums, const int* __restrict__ bcnt,
                              float* __restrict__ out, float* __restrict__ zbuf) {
    int i = blockIdx.x * 1024 + threadIdx.x;  // 0..2047
    int b = i >> 7, f = i & 127;
    float c = fmaxf((float)bcnt[b], 1.f);
    float v = sums[i] / c;
    if (f < 64) { out[OUT_MU + b * 64 + f] = v; zbuf[b * 64 + f] = v; }
    else out[OUT_LG + b * 64 + (f - 64)] = v;
}

// zwi[b][t] = bi[t] + sum_k z[b,k]*wi[k*128+t]
__global__ void zwi_kernel(const float* __restrict__ z,
                           const float* __restrict__ nm_wi, const float* __restrict__ nm_bi,
                           const float* __restrict__ em_wi, const float* __restrict__ em_bi,
                           float* __restrict__ zwi_nm, float* __restrict__ zwi_em) {
    int b = blockIdx.x, t = threadIdx.x;  // 16 blocks x 128 threads
    float an = nm_bi[t], ae = em_bi[t];
    for (int k = 0; k < 64; k++) {
        float zv = z[b * 64 + k];
        an += zv * nm_wi[k * 128 + t];
        ae += zv * em_wi[k * 128 + t];
    }
    zwi_nm[b * 128 + t] = an;
    zwi_em[b * 128 + t] = ae;
}

#define D3_ROWS 32

// decoder3: layer1+LN -> LDS; heads/edges as 128-len LDS dots (heads pre-composed)
__global__ __launch_bounds__(256) void decoder3(
    const float* __restrict__ zwi_nm, const float* __restrict__ zwi_em,
    const float* __restrict__ nm_wi, const float* __restrict__ em_wi,
    const float* __restrict__ nm_g, const float* __restrict__ nm_be,
    const float* __restrict__ em_g, const float* __restrict__ em_be,
    const float* __restrict__ wtn, const float* __restrict__ bcn,
    const float* __restrict__ wte, const float* __restrict__ em_bo,
    const float* __restrict__ pos_all,
    float* __restrict__ out) {
    __shared__ float sn[D3_ROWS][132];   // +4 pad: 4-bank rotation per row
    __shared__ float se[D3_ROWS][132];
    __shared__ float Wn[8][132];
    __shared__ float We[8][132];
    int t = threadIdx.x;
    int lane = t & 63, wave = t >> 6;
    int rowBase = blockIdx.x * D3_ROWS;
    int b = rowBase >> 12;
    int row0 = rowBase + wave * 8;

    for (int i = t; i < 1024; i += 256) {
        Wn[i >> 7][i & 127] = wtn[i];
        We[i >> 7][i & 127] = wte[i];
    }

    int f0 = lane, f1 = lane + 64;
    float zn0 = zwi_nm[b * 128 + f0], zn1 = zwi_nm[b * 128 + f1];
    float ze0 = zwi_em[b * 128 + f0], ze1 = zwi_em[b * 128 + f1];
    float wn64_0 = nm_wi[64 * 128 + f0], wn64_1 = nm_wi[64 * 128 + f1];
    float wn65_0 = nm_wi[65 * 128 + f0], wn65_1 = nm_wi[65 * 128 + f1];
    float we64_0 = em_wi[64 * 128 + f0], we64_1 = em_wi[64 * 128 + f1];
    float we65_0 = em_wi[65 * 128 + f0], we65_1 = em_wi[65 * 128 + f1];
    float gn0 = nm_g[f0], gn1 = nm_g[f1], bn0 = nm_be[f0], bn1 = nm_be[f1];
    float ge0 = em_g[f0], ge1 = em_g[f1], be0 = em_be[f0], be1 = em_be[f1];

#pragma unroll
    for (int r = 0; r < 8; r++) {
        int row = row0 + r, i = row & (NMAXC - 1);
        float px = pos_all[i * 2], py = pos_all[i * 2 + 1];
        float a0 = zn0 + px * wn64_0 + py * wn65_0;
        float a1 = zn1 + px * wn64_1 + py * wn65_1;
        float e0 = ze0 + px * we64_0 + py * we65_0;
        float e1 = ze1 + px * we64_1 + py * we65_1;
        float sm = a0 + a1, sq = a0 * a0 + a1 * a1;
        float sme = e0 + e1, sqe = e0 * e0 + e1 * e1;
#pragma unroll
        for (int d = 1; d < 64; d <<= 1) {
            sm += __shfl_xor(sm, d); sq += __shfl_xor(sq, d);
            sme += __shfl_xor(sme, d); sqe += __shfl_xor(sqe, d);
        }
        float mean = sm * (1.f / 128.f);
        float var = sq * (1.f / 128.f) - mean * mean;
        float rstd = rsqrtf(var + 1e-5f);
        int rl = wave * 8 + r;
        sn[rl][f0] = fmaxf((a0 - mean) * rstd * gn0 + bn0, 0.f);
        sn[rl][f1] = fmaxf((a1 - mean) * rstd * gn1 + bn1, 0.f);
        float meane = sme * (1.f / 128.f);
        float vare = sqe * (1.f / 128.f) - meane * meane;
        float rstde = rsqrtf(vare + 1e-5f);
        se[rl][f0] = fmaxf((e0 - meane) * rstde * ge0 + be0, 0.f);
        se[rl][f1] = fmaxf((e1 - meane) * rstde * ge1 + be1, 0.f);
    }
    __syncthreads();

    int rl = t >> 3, j = t & 7;
    float accn = 0.f, acce = 0.f;
#pragma unroll 8
    for (int k4 = 0; k4 < 128; k4 += 4) {
        float4 sv = *(const float4*)&sn[rl][k4];
        float4 wv = *(const float4*)&Wn[j][k4];
        float4 sev = *(const float4*)&se[rl][k4];
        float4 wev = *(const float4*)&We[j][k4];
        accn += sv.x * wv.x + sv.y * wv.y + sv.z * wv.z + sv.w * wv.w;
        acce += sev.x * wev.x + sev.y * wev.y + sev.z * wev.z + sev.w * wev.w;
    }
    int row = rowBase + rl;
    accn += bcn[j];
    if (j == 0)       out[OUT_NODES + row] = accn;
    else if (j <= 5)  out[OUT_FUEL + (size_t)row * 5 + (j - 1)] = accn;
    else if (j == 6)  out[OUT_ALT + row] = accn;
    else              out[OUT_SLOPE + row] = accn;
    out[OUT_EDGES + (size_t)row * 8 + j] = acce + em_bo[j];
}

extern "C" void kernel_launch(void* const* d_in, const int* in_sizes, int n_in,
                              void* d_out, int out_size, void* d_ws, size_t ws_size,
                              hipStream_t stream) {
    const float* x    = (const float*)d_in[0];
    const int* edge   = (const int*)d_in[1];
    const int* batch  = (const int*)d_in[2];
    const float* w1m = (const float*)d_in[3];  const float* b1m = (const float*)d_in[4];
    const float* w2m = (const float*)d_in[5];  const float* b2m = (const float*)d_in[6];
    const float* w3m = (const float*)d_in[7];  const float* b3m = (const float*)d_in[8];
    const float* w1l = (const float*)d_in[9];  const float* b1l = (const float*)d_in[10];
    const float* w2l = (const float*)d_in[11]; const float* b2l = (const float*)d_in[12];
    const float* w3l = (const float*)d_in[13]; const float* b3l = (const float*)d_in[14];
    const float* nm_wi = (const float*)d_in[15]; const float* nm_bi = (const float*)d_in[16];
    const float* nm_g  = (const float*)d_in[17]; const float* nm_be = (const float*)d_in[18];
    const float* nm_wo = (const float*)d_in[19]; const float* nm_bo = (const float*)d_in[20];
    const float* ex_w = (const float*)d_in[21]; const float* ex_b = (const float*)d_in[22];
    const float* fu_w = (const float*)d_in[23]; const float* fu_b = (const float*)d_in[24];
    const float* al_w = (const float*)d_in[25]; const float* al_b = (const float*)d_in[26];
    const float* sl_w = (const float*)d_in[27]; const float* sl_b = (const float*)d_in[28];
    const float* em_wi = (const float*)d_in[29]; const float* em_bi = (const float*)d_in[30];
    const float* em_g  = (const float*)d_in[31]; const float* em_be = (const float*)d_in[32];
    const float* em_wo = (const float*)d_in[33]; const float* em_bo = (const float*)d_in[34];
    const float* pos_all = (const float*)d_in[35];
    float* out = (float*)d_out;

    char* p = (char*)d_ws;
    auto alloc = [&](size_t bytes) -> void* {
        void* r = (void*)p;
        p += ((bytes + 255) / 256) * 256;
        return r;
    };
    int* cnt      = (int*)alloc((size_t)N_NODES * 4);
    float* dinv   = (float*)alloc((size_t)N_NODES * 4);
    int* bcnt     = (int*)alloc(BATCH_B * 4);
    float* sums   = (float*)alloc(BATCH_B * 128 * 4);
    float* zbuf   = (float*)alloc(BATCH_B * LATC * 4);
    float* zwi_nm = (float*)alloc(BATCH_B * 128 * 4);
    float* zwi_em = (float*)alloc(BATCH_B * 128 * 4);
    float* wcat1  = (float*)alloc(32 * 128 * 4);
    float* bcat1  = (float*)alloc(128 * 4);
    float* bcat3  = (float*)alloc(128 * 4);
    float* wtn    = (float*)alloc(8 * 128 * 4);
    float* bcn    = (float*)alloc(8 * 4);
    float* wte    = (float*)alloc(8 * 128 * 4);
    int* hist     = (int*)alloc((size_t)NBINS * NSB * 4);                      // 400 KB
    int* total    = (int*)alloc((size_t)NBINS * 4);
    int* base     = (int*)alloc((size_t)(NBINS + 1) * 4);
    unsigned int* sorted = (unsigned int*)alloc((size_t)N_EDGESC * 4);         // 6.4 MB
    int* adj      = (int*)alloc((size_t)N_NODES * CAP * 4);                    // 25.6 MB
    unsigned int* xs8 = (unsigned int*)alloc((size_t)N_NODES * 8 * 4);         // 3.2 MB fp8
    float* agg0   = (float*)alloc((size_t)N_NODES * 32 * 4);                   // 12.8 MB
    unsigned int* hA8 = (unsigned int*)alloc((size_t)N_NODES * 32 * 4);        // 12.8 MB fp8 (also hD8)
    unsigned int* hB8 = (unsigned int*)alloc((size_t)N_NODES * 32 * 4);        // 12.8 MB fp8
    unsigned int* h256_8 = (unsigned int*)alloc((size_t)N_NODES * 64 * 4);     // 25.6 MB fp8 [n][256]
    unsigned short* final128 = (unsigned short*)alloc((size_t)N_NODES * 128 * 2);  // 25.6 MB bf16
    unsigned int* hD8 = hA8;                       // hA8 dead after agg #1

    const int* srcp = edge;
    const int* dstp = edge + N_EDGESC;

    hipMemsetAsync(sums, 0, (size_t)BATCH_B * 128 * 4, stream);

    // ---- CSR build: atomic-free counting sort by dst bin ----
    histA<<<NSB, 1024, 0, stream>>>(dstp, hist);
    scanB<<<NBINS, NSB, 0, stream>>>(hist, total);
    scanC<<<1, 512, 0, stream>>>(total, base);
    scatterD<<<NSB, 1024, 0, stream>>>(srcp, dstp, hist, base, sorted);
    csr_sorted<<<NBINS, 256, 0, stream>>>(sorted, base, adj, cnt, dinv, N_NODES);

    batch_count<<<1, 64, 0, stream>>>(batch, bcnt, N_NODES);
    prep_cat<<<17, 256, 0, stream>>>(w1m, w1l, b1m, b1l, b3m, b3l, wcat1, bcat1, bcat3);
    prep_dec<<<9, 256, 0, stream>>>(nm_wo, nm_bo, ex_w, ex_b, fu_w, fu_b, al_w, al_b,
                                    sl_w, sl_b, em_wo, wtn, bcn, wte);
    prescale_x<<<(N_NODES * 8 + 255) / 256, 256, 0, stream>>>(x, dinv, xs8, N_NODES * 8);

    // agg0 = S x  (shared by both branches), fp8 table
    agg_s32<<<(N_NODES + 31) / 32, 256, 0, stream>>>(xs8, cnt, adj, dinv, agg0, N_NODES);

    // L1 (fused mu|lg): hA8 = fp8x32( dinv ⊙ relu(agg0 @ [w1m|w1l] + [b1m|b1l]) )
    matmulX<32, 128, 4, 32, 0, 128, 0, true, true, 0, 2>
        <<<dim3((N_NODES + 31) / 32, 1), 256, 0, stream>>>(
        agg0, wcat1, nullptr, bcat1, nullptr, dinv, hA8, N_NODES);

    // agg #1: hB8 = fp8x32( [S mu1 | S lg1] )
    agg128<false, true><<<(N_NODES + 7) / 8, 256, 0, stream>>>(
        hA8, cnt, adj, dinv, nullptr, hB8, N_NODES);

    // L2 dual (fp8 in/out): h256_8[:, y*128:...] = fp8x32( relu(hB8[:, y*64:...] @ w2{m,l} + b2{m,l}) )
    matmulX<64, 128, 4, 128, 64, 256, 128, true, false, 2, 2>
        <<<dim3((N_NODES + 31) / 32, 2), 256, 0, stream>>>(
        hB8, w2m, w2l, b2m, b2l, nullptr, h256_8, N_NODES);

    // L3 dual (fp8 in/out): hD8[:, y*64:...] = fp8x32( dinv ⊙ (h256_8[:, y*128:...] @ w3{m,l}) )
    matmulX<128, 64, 3, 256, 128, 128, 64, false, true, 2, 2>
        <<<dim3((N_NODES + 47) / 48, 2), 256, 0, stream>>>(
        h256_8, w3m, w3l, nullptr, nullptr, dinv, hD8, N_NODES);

    // agg #2: final = relu(dinv*(sum) + [b3m|b3l]) = [mu3|lg3]  -> bf16 [n][128]
    agg128<true, false><<<(N_NODES + 7) / 8, 256, 0, stream>>>(
        hD8, cnt, adj, dinv, bcat3, final128, N_NODES);

    pool128<<<(N_NODES + POOL_CHUNK - 1) / POOL_CHUNK, 64, 0, stream>>>(
        (const unsigned int*)final128, batch, sums, N_NODES);
    finalize_pool<<<2, 1024, 0, stream>>>(sums, bcnt, out, zbuf);

    zwi_kernel<<<BATCH_B, 128, 0, stream>>>(zbuf, nm_wi, nm_bi, em_wi, em_bi, zwi_nm, zwi_em);

    decoder3<<<BATCH_B * NMAXC / D3_ROWS, 256, 0, stream>>>(
        zwi_nm, zwi_em, nm_wi, em_wi, nm_g, nm_be, em_g, em_be,
        wtn, bcn, wte, em_bo, pos_all, out);
}

// Round 10
// 311.759 us; speedup vs baseline: 10.3278x; 1.3005x over previous
//
#include <hip/hip_runtime.h>
#include <hip/hip_bf16.h>

#define N_NODES 100000
#define N_EDGESC 1600000
#define BATCH_B 16
#define NMAXC 4096
#define LATC 64
#define CAP 64      // padded CSR bucket capacity; deg ~ Binom, P(deg>64) ~ 1e-15
#define NBINS 391   // ceil(100000/256): 256 nodes per bin
#define NSB 256     // sort blocks
#define EPB ((N_EDGESC + NSB - 1) / NSB)  // 6250 edges per sort block

// output layout offsets (flat f32)
#define OUT_NODES 0
#define OUT_EDGES 65536
#define OUT_FUEL  589824
#define OUT_ALT   917504
#define OUT_SLOPE 983040
#define OUT_MU    1048576
#define OUT_LG    1049600

typedef float f32x2 __attribute__((ext_vector_type(2)));
typedef float f32x4 __attribute__((ext_vector_type(4)));
typedef short bf16x8 __attribute__((ext_vector_type(8)));
union U4B { uint4 u; bf16x8 b; };

__device__ __forceinline__ unsigned short f2bf(float f) {
    unsigned int u = __float_as_uint(f);
    return (unsigned short)((u + 0x7FFFu + ((u >> 16) & 1u)) >> 16);  // RNE
}
__device__ __forceinline__ float bf2f(unsigned short h) {
    return __uint_as_float(((unsigned int)h) << 16);
}
// accumulate 4 fp8(e4m3) packed in u into a0..a3 (HW cvt, OCP on gfx950)
__device__ __forceinline__ void f8acc(unsigned int u, float& a0, float& a1, float& a2, float& a3) {
    f32x2 lo = __builtin_amdgcn_cvt_pk_f32_fp8(u, false);
    f32x2 hi = __builtin_amdgcn_cvt_pk_f32_fp8(u, true);
    a0 += lo[0]; a1 += lo[1]; a2 += hi[0]; a3 += hi[1];
}

// batch is sorted: count[b] = upper_bound(b) - lower_bound(b)
__global__ void batch_count(const int* __restrict__ batch, int* __restrict__ bcnt, int n) {
    int b = threadIdx.x;
    if (b >= BATCH_B) return;
    int lo = 0, hi = n;
    while (lo < hi) { int mid = (lo + hi) >> 1; if (batch[mid] < b) lo = mid + 1; else hi = mid; }
    int start = lo;
    lo = 0; hi = n;
    while (lo < hi) { int mid = (lo + hi) >> 1; if (batch[mid] <= b) lo = mid + 1; else hi = mid; }
    bcnt[b] = lo - start;
}

// ---- CSR build via atomic-free counting sort by dst>>8 ----
__global__ __launch_bounds__(1024) void histA(const int* __restrict__ dst, int* __restrict__ hist) {
    __shared__ int h[NBINS];
    int b = blockIdx.x, t = threadIdx.x;
    for (int i = t; i < NBINS; i += 1024) h[i] = 0;
    __syncthreads();
    int e0 = b * EPB, e1 = min(e0 + EPB, N_EDGESC);
    for (int i = e0 + t; i < e1; i += 1024)
        atomicAdd(&h[dst[i] >> 8], 1);
    __syncthreads();
    for (int i = t; i < NBINS; i += 1024) hist[i * NSB + b] = h[i];
}

__global__ void scanB(int* __restrict__ hist, int* __restrict__ total) {
    __shared__ int sh[NSB];
    int j = blockIdx.x, t = threadIdx.x;  // 256 threads
    int v = hist[j * NSB + t];
    sh[t] = v; __syncthreads();
    for (int off = 1; off < NSB; off <<= 1) {
        int u = (t >= off) ? sh[t - off] : 0; __syncthreads();
        sh[t] += u; __syncthreads();
    }
    hist[j * NSB + t] = sh[t] - v;
    if (t == NSB - 1) total[j] = sh[t];
}

__global__ void scanC(const int* __restrict__ total, int* __restrict__ base) {
    __shared__ int sh[512];
    int t = threadIdx.x;
    int v = (t < NBINS) ? total[t] : 0;
    sh[t] = v; __syncthreads();
    for (int off = 1; off < 512; off <<= 1) {
        int u = (t >= off) ? sh[t - off] : 0; __syncthreads();
        sh[t] += u; __syncthreads();
    }
    if (t < NBINS) base[t] = sh[t] - v;
    if (t == NBINS - 1) base[NBINS] = sh[t];
}

__global__ __launch_bounds__(1024) void scatterD(const int* __restrict__ src, const int* __restrict__ dst,
                                                 const int* __restrict__ hist, const int* __restrict__ base,
                                                 unsigned int* __restrict__ sorted) {
    __shared__ int w0[NBINS];
    __shared__ int lc[NBINS];
    int b = blockIdx.x, t = threadIdx.x;
    for (int i = t; i < NBINS; i += 1024) {
        w0[i] = base[i] + hist[i * NSB + b];
        lc[i] = 0;
    }
    __syncthreads();
    int e0 = b * EPB, e1 = min(e0 + EPB, N_EDGESC);
    for (int i = e0 + t; i < e1; i += 1024) {
        int d = dst[i], s = src[i];
        int j = d >> 8;
        int r = atomicAdd(&lc[j], 1);
        sorted[w0[j] + r] = ((unsigned int)s << 8) | (d & 255);
    }
}

__global__ void csr_sorted(const unsigned int* __restrict__ sorted, const int* __restrict__ base,
                           int* __restrict__ adj, int* __restrict__ cnt,
                           float* __restrict__ dinv, int N) {
    __shared__ int lc[256];
    int j = blockIdx.x, t = threadIdx.x;
    lc[t] = 0; __syncthreads();
    int e0 = base[j], e1 = base[j + 1];
    int node0 = j * 256;
    for (int i = e0 + t; i < e1; i += 256) {
        unsigned int pk = sorted[i];
        int d = pk & 255;
        int r = atomicAdd(&lc[d], 1);
        if (r < CAP) adj[(size_t)(node0 + d) * CAP + r] = (int)(pk >> 8);
    }
    __syncthreads();
    int n = node0 + t;
    if (n < N) {
        int c = lc[t];
        cnt[n] = c;
        dinv[n] = rsqrtf((float)(c + 1));  // +1 = self loop
    }
}

// xs8 (fp8 packed, [n][8] uints) = 64 * dinv[n] * x[n][32]
__global__ void prescale_x(const float* __restrict__ x, const float* __restrict__ dinv,
                           unsigned int* __restrict__ xs8, int total4) {
    int i4 = blockIdx.x * 256 + threadIdx.x;
    if (i4 < total4) {
        float4 v = *(const float4*)&x[i4 * 4];
        float ds = dinv[i4 >> 3] * 64.f;
        unsigned int r = 0;
        r = __builtin_amdgcn_cvt_pk_fp8_f32(v.x * ds, v.y * ds, r, false);
        r = __builtin_amdgcn_cvt_pk_fp8_f32(v.z * ds, v.w * ds, r, true);
        xs8[i4] = r;
    }
}

// agg0 = S x : fp8 table [n][8] uints; 32 nodes per 256-thread block, 8 lanes/node
__global__ void agg_s32(const unsigned int* __restrict__ xs8, const int* __restrict__ cnt,
                        const int* __restrict__ adj, const float* __restrict__ dinv,
                        float* __restrict__ out, int N) {
    int t = threadIdx.x;
    int sub = t >> 3, f = t & 7;
    int n = blockIdx.x * 32 + sub;
    if (n >= N) return;
    float s0 = 0.f, s1 = 0.f, s2 = 0.f, s3 = 0.f;
    f8acc(xs8[(size_t)n * 8 + f], s0, s1, s2, s3);
    int e1 = min(cnt[n], CAP);
    const int* ap = &adj[(size_t)n * CAP];
    int e = 0;
    for (; e + 4 <= e1; e += 4) {
        int i0 = ap[e], i1 = ap[e + 1], i2 = ap[e + 2], i3 = ap[e + 3];
        unsigned int u0 = xs8[(size_t)i0 * 8 + f];
        unsigned int u1 = xs8[(size_t)i1 * 8 + f];
        unsigned int u2 = xs8[(size_t)i2 * 8 + f];
        unsigned int u3 = xs8[(size_t)i3 * 8 + f];
        f8acc(u0, s0, s1, s2, s3); f8acc(u1, s0, s1, s2, s3);
        f8acc(u2, s0, s1, s2, s3); f8acc(u3, s0, s1, s2, s3);
    }
    for (; e < e1; e++) f8acc(xs8[(size_t)ap[e] * 8 + f], s0, s1, s2, s3);
    float d = dinv[n] * (1.f / 64.f);
    *(float4*)&out[(size_t)n * 32 + f * 4] = make_float4(s0 * d, s1 * d, s2 * d, s3 * d);
}

// 128-dim fp8-table aggregation (table pre-scaled x32); 8 nodes/block, 32 lanes/node
template <bool BIASRELU, bool OUT8>
__global__ void agg128(const unsigned int* __restrict__ tbl, const int* __restrict__ cnt,
                       const int* __restrict__ adj, const float* __restrict__ dinv,
                       const float* __restrict__ bias, void* __restrict__ outv, int N) {
    int t = threadIdx.x;
    int sub = t >> 5, f = t & 31;
    int n = blockIdx.x * 8 + sub;
    if (n >= N) return;
    float s0 = 0.f, s1 = 0.f, s2 = 0.f, s3 = 0.f;
    f8acc(tbl[(size_t)n * 32 + f], s0, s1, s2, s3);
    int e1 = min(cnt[n], CAP);
    const int* ap = &adj[(size_t)n * CAP];
    int e = 0;
    for (; e + 4 <= e1; e += 4) {
        int i0 = ap[e], i1 = ap[e + 1], i2 = ap[e + 2], i3 = ap[e + 3];
        unsigned int u0 = tbl[(size_t)i0 * 32 + f];
        unsigned int u1 = tbl[(size_t)i1 * 32 + f];
        unsigned int u2 = tbl[(size_t)i2 * 32 + f];
        unsigned int u3 = tbl[(size_t)i3 * 32 + f];
        f8acc(u0, s0, s1, s2, s3); f8acc(u1, s0, s1, s2, s3);
        f8acc(u2, s0, s1, s2, s3); f8acc(u3, s0, s1, s2, s3);
    }
    for (; e < e1; e++) f8acc(tbl[(size_t)ap[e] * 32 + f], s0, s1, s2, s3);
    float d = dinv[n] * (1.f / 32.f);
    float v0 = s0 * d, v1 = s1 * d, v2 = s2 * d, v3 = s3 * d;
    if (BIASRELU) {
        float4 bv = *(const float4*)&bias[4 * f];
        v0 = fmaxf(v0 + bv.x, 0.f); v1 = fmaxf(v1 + bv.y, 0.f);
        v2 = fmaxf(v2 + bv.z, 0.f); v3 = fmaxf(v3 + bv.w, 0.f);
    }
    if (OUT8) {
        unsigned int r = 0;
        r = __builtin_amdgcn_cvt_pk_fp8_f32(v0 * 32.f, v1 * 32.f, r, false);
        r = __builtin_amdgcn_cvt_pk_fp8_f32(v2 * 32.f, v3 * 32.f, r, true);
        ((unsigned int*)outv)[(size_t)n * 32 + f] = r;
    } else {
        ushort4 u;
        u.x = f2bf(v0); u.y = f2bf(v1); u.z = f2bf(v2); u.w = f2bf(v3);
        *(ushort4*)&((unsigned short*)outv)[(size_t)n * 128 + 4 * f] = u;
    }
}

// ---- weight fragment prep: wfrag[y][s][c][lane][0..3] = bf16x2-packed B-fragment ----
// B layout for mfma_f32_16x16x32_bf16: lane holds B[k=(s*32)+(lane>>4)*8+j][col=c*16+(lane&15)], j=0..7
template <int K, int F>
__global__ void wprep(const float* __restrict__ Wa, const float* __restrict__ Wb,
                      unsigned int* __restrict__ wfrag) {
    constexpr int S = K / 32, C = F / 16;
    int lane = threadIdx.x;       // 64
    int bc = blockIdx.x;          // (y*S + s)*C + c
    int c = bc % C;
    int s = (bc / C) % S;
    int y = bc / (C * S);
    const float* W = (y == 0) ? Wa : Wb;
    int col = c * 16 + (lane & 15);
    int k0 = s * 32 + (lane >> 4) * 8;
    unsigned int q[4];
#pragma unroll
    for (int jj = 0; jj < 4; jj++) {
        float lo = W[(size_t)(k0 + 2 * jj) * F + col];
        float hi = W[(size_t)(k0 + 2 * jj + 1) * F + col];
        q[jj] = (unsigned int)f2bf(lo) | ((unsigned int)f2bf(hi) << 16);
    }
    *(uint4*)&wfrag[((size_t)bc * 64 + lane) * 4] = make_uint4(q[0], q[1], q[2], q[3]);
}

// ---- MFMA conv: out[n, y-slice] = epi( A[n, y-slice] @ W_y ), 64 rows/block, 4 waves x 16 rows
// INMODE: 0 = f32, 1 = bf16, 2 = fp8 e4m3 x32. OUTMODE: 1 = bf16, 2 = fp8 e4m3 x32.
// IN_STRIDE/OFF and OUT_STRIDE/OFF in elements of the respective dtype.
template <int K, int F, int IN_STRIDE, int IN_OFF_Y, int OUT_STRIDE, int OUT_OFF_Y,
          bool BIASRELU, bool SCALE, int INMODE, int OUTMODE>
__global__ __launch_bounds__(256) void mfma_conv(
    const void* __restrict__ inv, const unsigned int* __restrict__ wfrag,
    const float* __restrict__ biasa, const float* __restrict__ biasb,
    const float* __restrict__ dinv, void* __restrict__ outv, int N) {
    constexpr int S = K / 32, C = F / 16;
    constexpr int FP = F + 4;  // LDS row pad (bf16 elems) -> bank spread
    __shared__ unsigned short buf[4][16][FP];
    int t = threadIdx.x, lane = t & 63, wave = t >> 6;
    int y = blockIdx.y;
    int n0 = blockIdx.x * 64 + wave * 16;
    const float* bias = (y == 0) ? biasa : biasb;
    const unsigned int* wf = wfrag + (size_t)y * S * C * 64 * 4;

    f32x4 acc[C];
#pragma unroll
    for (int c = 0; c < C; c++) acc[c] = (f32x4)(0.f);

    int arow = n0 + (lane & 15);
    bool aok = arow < N;
#pragma unroll
    for (int s = 0; s < S; s++) {
        U4B af; af.u = make_uint4(0u, 0u, 0u, 0u);
        if (aok) {
            if constexpr (INMODE == 2) {
                uint2 u = *(const uint2*)((const unsigned char*)inv +
                            (size_t)arow * IN_STRIDE + y * IN_OFF_Y + s * 32 + (lane >> 4) * 8);
                f32x2 p0 = __builtin_amdgcn_cvt_pk_f32_fp8(u.x, false);
                f32x2 p1 = __builtin_amdgcn_cvt_pk_f32_fp8(u.x, true);
                f32x2 p2 = __builtin_amdgcn_cvt_pk_f32_fp8(u.y, false);
                f32x2 p3 = __builtin_amdgcn_cvt_pk_f32_fp8(u.y, true);
                af.u.x = (unsigned int)f2bf(p0[0]) | ((unsigned int)f2bf(p0[1]) << 16);
                af.u.y = (unsigned int)f2bf(p1[0]) | ((unsigned int)f2bf(p1[1]) << 16);
                af.u.z = (unsigned int)f2bf(p2[0]) | ((unsigned int)f2bf(p2[1]) << 16);
                af.u.w = (unsigned int)f2bf(p3[0]) | ((unsigned int)f2bf(p3[1]) << 16);
            } else if constexpr (INMODE == 1) {
                af.u = *(const uint4*)((const unsigned short*)inv +
                            (size_t)arow * IN_STRIDE + y * IN_OFF_Y + s * 32 + (lane >> 4) * 8);
            } else {
                const float* ap = (const float*)inv + (size_t)arow * IN_STRIDE + y * IN_OFF_Y
                                  + s * 32 + (lane >> 4) * 8;
                float4 v0 = *(const float4*)ap;
                float4 v1 = *(const float4*)(ap + 4);
                af.u.x = (unsigned int)f2bf(v0.x) | ((unsigned int)f2bf(v0.y) << 16);
                af.u.y = (unsigned int)f2bf(v0.z) | ((unsigned int)f2bf(v0.w) << 16);
                af.u.z = (unsigned int)f2bf(v1.x) | ((unsigned int)f2bf(v1.y) << 16);
                af.u.w = (unsigned int)f2bf(v1.z) | ((unsigned int)f2bf(v1.w) << 16);
            }
        }
#pragma unroll
        for (int c = 0; c < C; c++) {
            U4B wb;
            wb.u = *(const uint4*)&wf[((size_t)(s * C + c) * 64 + lane) * 4];
            acc[c] = __builtin_amdgcn_mfma_f32_16x16x32_bf16(af.b, wb.b, acc[c], 0, 0, 0);
        }
    }

    // epilogue: D[row=(lane>>4)*4+r][col=c*16+(lane&15)]; apply scale/bias/relu; bf16 -> LDS
    constexpr float ISC = (INMODE == 2) ? (1.f / 32.f) : 1.f;
#pragma unroll
    for (int c = 0; c < C; c++) {
        int col = c * 16 + (lane & 15);
        float bv = BIASRELU ? bias[col] : 0.f;
#pragma unroll
        for (int r = 0; r < 4; r++) {
            int row = (lane >> 4) * 4 + r;
            int n = n0 + row;
            float v = acc[c][r] * ISC;
            if (BIASRELU) v = fmaxf(v + bv, 0.f);
            if (SCALE) v *= dinv[min(n, N - 1)];
            buf[wave][row][col] = f2bf(v);
        }
    }
    __syncthreads();

    // pack & store: 8 consecutive f per chunk
    constexpr int CPR = F / 8;            // chunks per row
    for (int i = t; i < 64 * CPR; i += 256) {
        int row = i / CPR;
        int f0 = (i % CPR) * 8;
        int n = blockIdx.x * 64 + row;
        if (n >= N) continue;
        const unsigned short* bp = &buf[row >> 4][row & 15][f0];
        uint2 a = *(const uint2*)bp;
        uint2 b = *(const uint2*)(bp + 4);
        size_t off = (size_t)n * OUT_STRIDE + y * OUT_OFF_Y + f0;
        if constexpr (OUTMODE == 2) {
            float e0 = __uint_as_float(a.x << 16), e1 = __uint_as_float(a.x & 0xFFFF0000u);
            float e2 = __uint_as_float(a.y << 16), e3 = __uint_as_float(a.y & 0xFFFF0000u);
            float e4 = __uint_as_float(b.x << 16), e5 = __uint_as_float(b.x & 0xFFFF0000u);
            float e6 = __uint_as_float(b.y << 16), e7 = __uint_as_float(b.y & 0xFFFF0000u);
            unsigned int r0 = 0, r1 = 0;
            r0 = __builtin_amdgcn_cvt_pk_fp8_f32(e0 * 32.f, e1 * 32.f, r0, false);
            r0 = __builtin_amdgcn_cvt_pk_fp8_f32(e2 * 32.f, e3 * 32.f, r0, true);
            r1 = __builtin_amdgcn_cvt_pk_fp8_f32(e4 * 32.f, e5 * 32.f, r1, false);
            r1 = __builtin_amdgcn_cvt_pk_fp8_f32(e6 * 32.f, e7 * 32.f, r1, true);
            *(uint2*)((unsigned char*)outv + off) = make_uint2(r0, r1);
        } else {
            *(uint4*)((unsigned short*)outv + off) = make_uint4(a.x, a.y, b.x, b.y);
        }
    }
}

// concat weights/biases for fused layer1 and fused layer3 bias
__global__ void prep_cat(const float* __restrict__ w1m, const float* __restrict__ w1l,
                         const float* __restrict__ b1m, const float* __restrict__ b1l,
                         const float* __restrict__ b3m, const float* __restrict__ b3l,
                         float* __restrict__ wcat1, float* __restrict__ bcat1,
                         float* __restrict__ bcat3) {
    int i = blockIdx.x * 256 + threadIdx.x;
    if (i < 32 * 128) {
        int k = i >> 7, f = i & 127;
        wcat1[i] = (f < 64) ? w1m[k * 64 + f] : w1l[k * 64 + f - 64];
    } else if (i < 32 * 128 + 128) {
        int f = i - 32 * 128;
        bcat1[f] = (f < 64) ? b1m[f] : b1l[f - 64];
    } else if (i < 32 * 128 + 256) {
        int f = i - 32 * 128 - 128;
        bcat3[f] = (f < 64) ? b3m[f] : b3l[f - 64];
    }
}

// decoder head-composition precompute (heads are linear in h2 -> fold through nm_wo)
__global__ void prep_dec(const float* __restrict__ nm_wo, const float* __restrict__ nm_bo,
                         const float* __restrict__ ex_w, const float* __restrict__ ex_b,
                         const float* __restrict__ fu_w, const float* __restrict__ fu_b,
                         const float* __restrict__ al_w, const float* __restrict__ al_b,
                         const float* __restrict__ sl_w, const float* __restrict__ sl_b,
                         const float* __restrict__ em_wo,
                         float* __restrict__ wtn, float* __restrict__ bcn,
                         float* __restrict__ wte) {
    int idx = blockIdx.x * 256 + threadIdx.x;
    if (idx < 1024) {
        int j = idx >> 7, k = idx & 127;
        float s = 0.f;
        for (int m = 0; m < 128; m++) {
            float w = (j == 0) ? ex_w[m] : (j <= 5) ? fu_w[m * 5 + (j - 1)]
                     : (j == 6) ? al_w[m] : sl_w[m];
            s += nm_wo[k * 128 + m] * w;
        }
        wtn[j * 128 + k] = s;
    } else if (idx < 2048) {
        int i2 = idx - 1024;
        int j = i2 >> 7, k = i2 & 127;
        wte[j * 128 + k] = em_wo[k * 8 + j];
    } else if (idx < 2056) {
        int j = idx - 2048;
        float s = (j == 0) ? ex_b[0] : (j <= 5) ? fu_b[j - 1] : (j == 6) ? al_b[0] : sl_b[0];
        for (int m = 0; m < 128; m++) {
            float w = (j == 0) ? ex_w[m] : (j <= 5) ? fu_w[m * 5 + (j - 1)]
                     : (j == 6) ? al_w[m] : sl_w[m];
            s += nm_bo[m] * w;
        }
        bcn[j] = s;
    }
}

#define POOL_CHUNK 128
// h is bf16-packed [n][64] uints
__global__ void pool128(const unsigned int* __restrict__ h, const int* __restrict__ batch,
                        float* __restrict__ sums, int n) {
    int f = threadIdx.x;  // 0..63
    int s0 = blockIdx.x * POOL_CHUNK;
    if (s0 >= n) return;
    int s1 = min(s0 + POOL_CHUNK, n);
    int cur = batch[s0];
    float a0 = 0.f, a1 = 0.f;
    for (int i = s0; i < s1; i++) {
        int b = batch[i];
        if (b != cur) {
            atomicAdd(&sums[cur * 128 + 2 * f], a0);
            atomicAdd(&sums[cur * 128 + 2 * f + 1], a1);
            a0 = a1 = 0.f; cur = b;
        }
        unsigned int u = h[(size_t)i * 64 + f];
        a0 += __uint_as_float(u << 16);
        a1 += __uint_as_float(u & 0xFFFF0000u);
    }
    atomicAdd(&sums[cur * 128 + 2 * f], a0);
    atomicAdd(&sums[cur * 128 + 2 * f + 1], a1);
}

__global__ void finalize_pool(const float* __restrict__ sums, const int* __restrict__ bcnt,
                              float* __restrict__ out, float* __restrict__ zbuf) {
    int i = blockIdx.x * 1024 + threadIdx.x;  // 0..2047
    int b = i >> 7, f = i & 127;
    float c = fmaxf((float)bcnt[b], 1.f);
    float v = sums[i] / c;
    if (f < 64) { out[OUT_MU + b * 64 + f] = v; zbuf[b * 64 + f] = v; }
    else out[OUT_LG + b * 64 + (f - 64)] = v;
}

// zwi[b][t] = bi[t] + sum_k z[b,k]*wi[k*128+t]
__global__ void zwi_kernel(const float* __restrict__ z,
                           const float* __restrict__ nm_wi, const float* __restrict__ nm_bi,
                           const float* __restrict__ em_wi, const float* __restrict__ em_bi,
                           float* __restrict__ zwi_nm, float* __restrict__ zwi_em) {
    int b = blockIdx.x, t = threadIdx.x;  // 16 blocks x 128 threads
    float an = nm_bi[t], ae = em_bi[t];
    for (int k = 0; k < 64; k++) {
        float zv = z[b * 64 + k];
        an += zv * nm_wi[k * 128 + t];
        ae += zv * em_wi[k * 128 + t];
    }
    zwi_nm[b * 128 + t] = an;
    zwi_em[b * 128 + t] = ae;
}

#define D3_ROWS 32

// decoder3: layer1+LN -> LDS; heads/edges as 128-len LDS dots (heads pre-composed)
__global__ __launch_bounds__(256) void decoder3(
    const float* __restrict__ zwi_nm, const float* __restrict__ zwi_em,
    const float* __restrict__ nm_wi, const float* __restrict__ em_wi,
    const float* __restrict__ nm_g, const float* __restrict__ nm_be,
    const float* __restrict__ em_g, const float* __restrict__ em_be,
    const float* __restrict__ wtn, const float* __restrict__ bcn,
    const float* __restrict__ wte, const float* __restrict__ em_bo,
    const float* __restrict__ pos_all,
    float* __restrict__ out) {
    __shared__ float sn[D3_ROWS][132];   // +4 pad: 4-bank rotation per row
    __shared__ float se[D3_ROWS][132];
    __shared__ float Wn[8][132];
    __shared__ float We[8][132];
    int t = threadIdx.x;
    int lane = t & 63, wave = t >> 6;
    int rowBase = blockIdx.x * D3_ROWS;
    int b = rowBase >> 12;
    int row0 = rowBase + wave * 8;

    for (int i = t; i < 1024; i += 256) {
        Wn[i >> 7][i & 127] = wtn[i];
        We[i >> 7][i & 127] = wte[i];
    }

    int f0 = lane, f1 = lane + 64;
    float zn0 = zwi_nm[b * 128 + f0], zn1 = zwi_nm[b * 128 + f1];
    float ze0 = zwi_em[b * 128 + f0], ze1 = zwi_em[b * 128 + f1];
    float wn64_0 = nm_wi[64 * 128 + f0], wn64_1 = nm_wi[64 * 128 + f1];
    float wn65_0 = nm_wi[65 * 128 + f0], wn65_1 = nm_wi[65 * 128 + f1];
    float we64_0 = em_wi[64 * 128 + f0], we64_1 = em_wi[64 * 128 + f1];
    float we65_0 = em_wi[65 * 128 + f0], we65_1 = em_wi[65 * 128 + f1];
    float gn0 = nm_g[f0], gn1 = nm_g[f1], bn0 = nm_be[f0], bn1 = nm_be[f1];
    float ge0 = em_g[f0], ge1 = em_g[f1], be0 = em_be[f0], be1 = em_be[f1];

#pragma unroll
    for (int r = 0; r < 8; r++) {
        int row = row0 + r, i = row & (NMAXC - 1);
        float px = pos_all[i * 2], py = pos_all[i * 2 + 1];
        float a0 = zn0 + px * wn64_0 + py * wn65_0;
        float a1 = zn1 + px * wn64_1 + py * wn65_1;
        float e0 = ze0 + px * we64_0 + py * we65_0;
        float e1 = ze1 + px * we64_1 + py * we65_1;
        float sm = a0 + a1, sq = a0 * a0 + a1 * a1;
        float sme = e0 + e1, sqe = e0 * e0 + e1 * e1;
#pragma unroll
        for (int d = 1; d < 64; d <<= 1) {
            sm += __shfl_xor(sm, d); sq += __shfl_xor(sq, d);
            sme += __shfl_xor(sme, d); sqe += __shfl_xor(sqe, d);
        }
        float mean = sm * (1.f / 128.f);
        float var = sq * (1.f / 128.f) - mean * mean;
        float rstd = rsqrtf(var + 1e-5f);
        int rl = wave * 8 + r;
        sn[rl][f0] = fmaxf((a0 - mean) * rstd * gn0 + bn0, 0.f);
        sn[rl][f1] = fmaxf((a1 - mean) * rstd * gn1 + bn1, 0.f);
        float meane = sme * (1.f / 128.f);
        float vare = sqe * (1.f / 128.f) - meane * meane;
        float rstde = rsqrtf(vare + 1e-5f);
        se[rl][f0] = fmaxf((e0 - meane) * rstde * ge0 + be0, 0.f);
        se[rl][f1] = fmaxf((e1 - meane) * rstde * ge1 + be1, 0.f);
    }
    __syncthreads();

    int rl = t >> 3, j = t & 7;
    float accn = 0.f, acce = 0.f;
#pragma unroll 8
    for (int k4 = 0; k4 < 128; k4 += 4) {
        float4 sv = *(const float4*)&sn[rl][k4];
        float4 wv = *(const float4*)&Wn[j][k4];
        float4 sev = *(const float4*)&se[rl][k4];
        float4 wev = *(const float4*)&We[j][k4];
        accn += sv.x * wv.x + sv.y * wv.y + sv.z * wv.z + sv.w * wv.w;
        acce += sev.x * wev.x + sev.y * wev.y + sev.z * wev.z + sev.w * wev.w;
    }
    int row = rowBase + rl;
    accn += bcn[j];
    if (j == 0)       out[OUT_NODES + row] = accn;
    else if (j <= 5)  out[OUT_FUEL + (size_t)row * 5 + (j - 1)] = accn;
    else if (j == 6)  out[OUT_ALT + row] = accn;
    else              out[OUT_SLOPE + row] = accn;
    out[OUT_EDGES + (size_t)row * 8 + j] = acce + em_bo[j];
}

extern "C" void kernel_launch(void* const* d_in, const int* in_sizes, int n_in,
                              void* d_out, int out_size, void* d_ws, size_t ws_size,
                              hipStream_t stream) {
    const float* x    = (const float*)d_in[0];
    const int* edge   = (const int*)d_in[1];
    const int* batch  = (const int*)d_in[2];
    const float* w1m = (const float*)d_in[3];  const float* b1m = (const float*)d_in[4];
    const float* w2m = (const float*)d_in[5];  const float* b2m = (const float*)d_in[6];
    const float* w3m = (const float*)d_in[7];  const float* b3m = (const float*)d_in[8];
    const float* w1l = (const float*)d_in[9];  const float* b1l = (const float*)d_in[10];
    const float* w2l = (const float*)d_in[11]; const float* b2l = (const float*)d_in[12];
    const float* w3l = (const float*)d_in[13]; const float* b3l = (const float*)d_in[14];
    const float* nm_wi = (const float*)d_in[15]; const float* nm_bi = (const float*)d_in[16];
    const float* nm_g  = (const float*)d_in[17]; const float* nm_be = (const float*)d_in[18];
    const float* nm_wo = (const float*)d_in[19]; const float* nm_bo = (const float*)d_in[20];
    const float* ex_w = (const float*)d_in[21]; const float* ex_b = (const float*)d_in[22];
    const float* fu_w = (const float*)d_in[23]; const float* fu_b = (const float*)d_in[24];
    const float* al_w = (const float*)d_in[25]; const float* al_b = (const float*)d_in[26];
    const float* sl_w = (const float*)d_in[27]; const float* sl_b = (const float*)d_in[28];
    const float* em_wi = (const float*)d_in[29]; const float* em_bi = (const float*)d_in[30];
    const float* em_g  = (const float*)d_in[31]; const float* em_be = (const float*)d_in[32];
    const float* em_wo = (const float*)d_in[33]; const float* em_bo = (const float*)d_in[34];
    const float* pos_all = (const float*)d_in[35];
    float* out = (float*)d_out;

    char* p = (char*)d_ws;
    auto alloc = [&](size_t bytes) -> void* {
        void* r = (void*)p;
        p += ((bytes + 255) / 256) * 256;
        return r;
    };
    int* cnt      = (int*)alloc((size_t)N_NODES * 4);
    float* dinv   = (float*)alloc((size_t)N_NODES * 4);
    int* bcnt     = (int*)alloc(BATCH_B * 4);
    float* sums   = (float*)alloc(BATCH_B * 128 * 4);
    float* zbuf   = (float*)alloc(BATCH_B * LATC * 4);
    float* zwi_nm = (float*)alloc(BATCH_B * 128 * 4);
    float* zwi_em = (float*)alloc(BATCH_B * 128 * 4);
    float* wcat1  = (float*)alloc(32 * 128 * 4);
    float* bcat1  = (float*)alloc(128 * 4);
    float* bcat3  = (float*)alloc(128 * 4);
    float* wtn    = (float*)alloc(8 * 128 * 4);
    float* bcn    = (float*)alloc(8 * 4);
    float* wte    = (float*)alloc(8 * 128 * 4);
    unsigned int* wf1 = (unsigned int*)alloc((size_t)1 * 1 * 8 * 64 * 4 * 4);   // 8 KB
    unsigned int* wf2 = (unsigned int*)alloc((size_t)2 * 2 * 8 * 64 * 4 * 4);   // 64 KB
    unsigned int* wf3 = (unsigned int*)alloc((size_t)2 * 4 * 4 * 64 * 4 * 4);   // 32 KB
    int* hist     = (int*)alloc((size_t)NBINS * NSB * 4);                      // 400 KB
    int* total    = (int*)alloc((size_t)NBINS * 4);
    int* base     = (int*)alloc((size_t)(NBINS + 1) * 4);
    unsigned int* sorted = (unsigned int*)alloc((size_t)N_EDGESC * 4);         // 6.4 MB
    int* adj      = (int*)alloc((size_t)N_NODES * CAP * 4);                    // 25.6 MB
    unsigned int* xs8 = (unsigned int*)alloc((size_t)N_NODES * 8 * 4);         // 3.2 MB fp8
    float* agg0   = (float*)alloc((size_t)N_NODES * 32 * 4);                   // 12.8 MB
    unsigned int* hA8 = (unsigned int*)alloc((size_t)N_NODES * 32 * 4);        // 12.8 MB fp8 (also hD8)
    unsigned int* hB8 = (unsigned int*)alloc((size_t)N_NODES * 32 * 4);        // 12.8 MB fp8
    unsigned short* h256 = (unsigned short*)alloc((size_t)N_NODES * 256 * 2);  // 51.2 MB bf16
    unsigned short* final128 = (unsigned short*)alloc((size_t)N_NODES * 128 * 2);  // 25.6 MB bf16
    unsigned int* hD8 = hA8;  // hA8 dead after agg #1

    const int* srcp = edge;
    const int* dstp = edge + N_EDGESC;

    hipMemsetAsync(sums, 0, (size_t)BATCH_B * 128 * 4, stream);

    // ---- CSR build: atomic-free counting sort by dst bin ----
    histA<<<NSB, 1024, 0, stream>>>(dstp, hist);
    scanB<<<NBINS, NSB, 0, stream>>>(hist, total);
    scanC<<<1, 512, 0, stream>>>(total, base);
    scatterD<<<NSB, 1024, 0, stream>>>(srcp, dstp, hist, base, sorted);
    csr_sorted<<<NBINS, 256, 0, stream>>>(sorted, base, adj, cnt, dinv, N_NODES);

    batch_count<<<1, 64, 0, stream>>>(batch, bcnt, N_NODES);
    prep_cat<<<17, 256, 0, stream>>>(w1m, w1l, b1m, b1l, b3m, b3l, wcat1, bcat1, bcat3);
    prep_dec<<<9, 256, 0, stream>>>(nm_wo, nm_bo, ex_w, ex_b, fu_w, fu_b, al_w, al_b,
                                    sl_w, sl_b, em_wo, wtn, bcn, wte);
    wprep<32, 128><<<1 * 1 * 8, 64, 0, stream>>>(wcat1, wcat1, wf1);
    wprep<64, 128><<<2 * 2 * 8, 64, 0, stream>>>(w2m, w2l, wf2);
    wprep<128, 64><<<2 * 4 * 4, 64, 0, stream>>>(w3m, w3l, wf3);
    prescale_x<<<(N_NODES * 8 + 255) / 256, 256, 0, stream>>>(x, dinv, xs8, N_NODES * 8);

    // agg0 = S x  (shared by both branches), fp8 table
    agg_s32<<<(N_NODES + 31) / 32, 256, 0, stream>>>(xs8, cnt, adj, dinv, agg0, N_NODES);

    const int GB = (N_NODES + 63) / 64;  // 1563 row blocks

    // L1 (fused mu|lg): hA8 = fp8x32( dinv ⊙ relu(agg0 @ [w1m|w1l] + [b1m|b1l]) )  [MFMA]
    mfma_conv<32, 128, 32, 0, 128, 0, true, true, 0, 2>
        <<<dim3(GB, 1), 256, 0, stream>>>(agg0, wf1, bcat1, bcat1, dinv, hA8, N_NODES);

    // agg #1: hB8 = fp8x32( [S mu1 | S lg1] )
    agg128<false, true><<<(N_NODES + 7) / 8, 256, 0, stream>>>(
        hA8, cnt, adj, dinv, nullptr, hB8, N_NODES);

    // L2 dual: h256 = bf16( relu(hB8[:, y*64:] @ w2{m,l} + b2{m,l}) )  [MFMA]
    mfma_conv<64, 128, 128, 64, 256, 128, true, false, 2, 1>
        <<<dim3(GB, 2), 256, 0, stream>>>(hB8, wf2, b2m, b2l, dinv, h256, N_NODES);

    // L3 dual: hD8 = fp8x32( dinv ⊙ (h256[:, y*128:] @ w3{m,l}) )  [MFMA]
    mfma_conv<128, 64, 256, 128, 128, 64, false, true, 1, 2>
        <<<dim3(GB, 2), 256, 0, stream>>>(h256, wf3, nullptr, nullptr, dinv, hD8, N_NODES);

    // agg #2: final = relu(dinv*(sum) + [b3m|b3l]) = [mu3|lg3]  -> bf16 [n][128]
    agg128<true, false><<<(N_NODES + 7) / 8, 256, 0, stream>>>(
        hD8, cnt, adj, dinv, bcat3, final128, N_NODES);

    pool128<<<(N_NODES + POOL_CHUNK - 1) / POOL_CHUNK, 64, 0, stream>>>(
        (const unsigned int*)final128, batch, sums, N_NODES);
    finalize_pool<<<2, 1024, 0, stream>>>(sums, bcnt, out, zbuf);

    zwi_kernel<<<BATCH_B, 128, 0, stream>>>(zbuf, nm_wi, nm_bi, em_wi, em_bi, zwi_nm, zwi_em);

    decoder3<<<BATCH_B * NMAXC / D3_ROWS, 256, 0, stream>>>(
        zwi_nm, zwi_em, nm_wi, em_wi, nm_g, nm_be, em_g, em_be,
        wtn, bcn, wte, em_bo, pos_all, out);
}

// Round 11
// 297.179 us; speedup vs baseline: 10.8345x; 1.0491x over previous
//
#include <hip/hip_runtime.h>
#include <hip/hip_bf16.h>

#define N_NODES 100000
#define N_EDGESC 1600000
#define BATCH_B 16
#define NMAXC 4096
#define LATC 64
#define NBINS 391   // ceil(100000/256): 256 nodes per bin
#define NSB 256     // sort blocks
#define EPB ((N_EDGESC + NSB - 1) / NSB)  // 6250 edges per sort block
#define BIN_PAD 768 // worst-case per-bin alignment padding (256 nodes x 3)

// output layout offsets (flat f32)
#define OUT_NODES 0
#define OUT_EDGES 65536
#define OUT_FUEL  589824
#define OUT_ALT   917504
#define OUT_SLOPE 983040
#define OUT_MU    1048576
#define OUT_LG    1049600

typedef float f32x2 __attribute__((ext_vector_type(2)));
typedef float f32x4 __attribute__((ext_vector_type(4)));
typedef short bf16x8 __attribute__((ext_vector_type(8)));
union U4B { uint4 u; bf16x8 b; };

__device__ __forceinline__ unsigned short f2bf(float f) {
    unsigned int u = __float_as_uint(f);
    return (unsigned short)((u + 0x7FFFu + ((u >> 16) & 1u)) >> 16);  // RNE
}
__device__ __forceinline__ float bf2f(unsigned short h) {
    return __uint_as_float(((unsigned int)h) << 16);
}
// accumulate 4 fp8(e4m3) packed in u into a0..a3 (HW cvt, OCP on gfx950)
__device__ __forceinline__ void f8acc(unsigned int u, float& a0, float& a1, float& a2, float& a3) {
    f32x2 lo = __builtin_amdgcn_cvt_pk_f32_fp8(u, false);
    f32x2 hi = __builtin_amdgcn_cvt_pk_f32_fp8(u, true);
    a0 += lo[0]; a1 += lo[1]; a2 += hi[0]; a3 += hi[1];
}

// batch is sorted: count[b] = upper_bound(b) - lower_bound(b)
__global__ void batch_count(const int* __restrict__ batch, int* __restrict__ bcnt, int n) {
    int b = threadIdx.x;
    if (b >= BATCH_B) return;
    int lo = 0, hi = n;
    while (lo < hi) { int mid = (lo + hi) >> 1; if (batch[mid] < b) lo = mid + 1; else hi = mid; }
    int start = lo;
    lo = 0; hi = n;
    while (lo < hi) { int mid = (lo + hi) >> 1; if (batch[mid] <= b) lo = mid + 1; else hi = mid; }
    bcnt[b] = lo - start;
}

// ---- CSR build via atomic-free counting sort by dst>>8 ----
__global__ __launch_bounds__(1024) void histA(const int* __restrict__ dst, int* __restrict__ hist) {
    __shared__ int h[NBINS];
    int b = blockIdx.x, t = threadIdx.x;
    for (int i = t; i < NBINS; i += 1024) h[i] = 0;
    __syncthreads();
    int e0 = b * EPB, e1 = min(e0 + EPB, N_EDGESC);
    for (int i = e0 + t; i < e1; i += 1024)
        atomicAdd(&h[dst[i] >> 8], 1);
    __syncthreads();
    for (int i = t; i < NBINS; i += 1024) hist[i * NSB + b] = h[i];
}

__global__ void scanB(int* __restrict__ hist, int* __restrict__ total) {
    __shared__ int sh[NSB];
    int j = blockIdx.x, t = threadIdx.x;  // 256 threads
    int v = hist[j * NSB + t];
    sh[t] = v; __syncthreads();
    for (int off = 1; off < NSB; off <<= 1) {
        int u = (t >= off) ? sh[t - off] : 0; __syncthreads();
        sh[t] += u; __syncthreads();
    }
    hist[j * NSB + t] = sh[t] - v;
    if (t == NSB - 1) total[j] = sh[t];
}

__global__ void scanC(const int* __restrict__ total, int* __restrict__ base) {
    __shared__ int sh[512];
    int t = threadIdx.x;
    int v = (t < NBINS) ? total[t] : 0;
    sh[t] = v; __syncthreads();
    for (int off = 1; off < 512; off <<= 1) {
        int u = (t >= off) ? sh[t - off] : 0; __syncthreads();
        sh[t] += u; __syncthreads();
    }
    if (t < NBINS) base[t] = sh[t] - v;
    if (t == NBINS - 1) base[NBINS] = sh[t];
}

__global__ __launch_bounds__(1024) void scatterD(const int* __restrict__ src, const int* __restrict__ dst,
                                                 const int* __restrict__ hist, const int* __restrict__ base,
                                                 unsigned int* __restrict__ sorted) {
    __shared__ int w0[NBINS];
    __shared__ int lc[NBINS];
    int b = blockIdx.x, t = threadIdx.x;
    for (int i = t; i < NBINS; i += 1024) {
        w0[i] = base[i] + hist[i * NSB + b];
        lc[i] = 0;
    }
    __syncthreads();
    int e0 = b * EPB, e1 = min(e0 + EPB, N_EDGESC);
    for (int i = e0 + t; i < e1; i += 1024) {
        int d = dst[i], s = src[i];
        int j = d >> 8;
        int r = atomicAdd(&lc[j], 1);
        sorted[w0[j] + r] = ((unsigned int)s << 8) | (d & 255);
    }
}

// compact CSR with 16B-aligned per-node lists: adj + offs + cnt + dinv
__global__ void csr_compact(const unsigned int* __restrict__ sorted, const int* __restrict__ base,
                            int* __restrict__ adj, int* __restrict__ offs,
                            int* __restrict__ cnt, float* __restrict__ dinv, int N) {
    __shared__ int lc[256];
    __shared__ int cur[256];
    __shared__ int so4[256];
    int j = blockIdx.x, t = threadIdx.x;
    lc[t] = 0; cur[t] = 0;
    __syncthreads();
    int e0 = base[j], e1 = base[j + 1];
    for (int i = e0 + t; i < e1; i += 256)
        atomicAdd(&lc[sorted[i] & 255], 1);
    __syncthreads();
    int c4 = (lc[t] + 3) & ~3;   // align each list to 4 entries (16B)
    so4[t] = c4;
    __syncthreads();
    for (int off = 1; off < 256; off <<= 1) {
        int u = (t >= off) ? so4[t - off] : 0; __syncthreads();
        so4[t] += u; __syncthreads();
    }
    int mybase = base[j] + j * BIN_PAD + so4[t] - c4;  // exclusive, aligned
    __syncthreads();
    so4[t] = mybase;
    __syncthreads();
    for (int i = e0 + t; i < e1; i += 256) {
        unsigned int pk = sorted[i];
        int d = pk & 255;
        int r = atomicAdd(&cur[d], 1);
        adj[so4[d] + r] = (int)(pk >> 8);
    }
    int n = j * 256 + t;
    if (n < N) {
        cnt[n] = lc[t];
        offs[n] = so4[t];
        dinv[n] = rsqrtf((float)(lc[t] + 1));  // +1 = self loop
    }
}

// xs8 (fp8 packed, [n][8] uints) = 64 * dinv[n] * x[n][32]
__global__ void prescale_x(const float* __restrict__ x, const float* __restrict__ dinv,
                           unsigned int* __restrict__ xs8, int total4) {
    int i4 = blockIdx.x * 256 + threadIdx.x;
    if (i4 < total4) {
        float4 v = *(const float4*)&x[i4 * 4];
        float ds = dinv[i4 >> 3] * 64.f;
        unsigned int r = 0;
        r = __builtin_amdgcn_cvt_pk_fp8_f32(v.x * ds, v.y * ds, r, false);
        r = __builtin_amdgcn_cvt_pk_fp8_f32(v.z * ds, v.w * ds, r, true);
        xs8[i4] = r;
    }
}

// agg0 = S x : fp8 table [n][8] uints; 32 nodes per 256-thread block, 8 lanes/node
__global__ void agg_s32(const unsigned int* __restrict__ xs8, const int* __restrict__ cnt,
                        const int* __restrict__ offs, const int* __restrict__ adj,
                        const float* __restrict__ dinv, float* __restrict__ out, int N) {
    int t = threadIdx.x;
    int sub = t >> 3, f = t & 7;
    int n = blockIdx.x * 32 + sub;
    if (n >= N) return;
    float s0 = 0.f, s1 = 0.f, s2 = 0.f, s3 = 0.f;
    f8acc(xs8[(size_t)n * 8 + f], s0, s1, s2, s3);
    int e = offs[n];
    int e1 = e + cnt[n];
    for (; e + 8 <= e1; e += 8) {
        int4 ia = *(const int4*)&adj[e];
        int4 ib = *(const int4*)&adj[e + 4];
        unsigned int u0 = xs8[(size_t)ia.x * 8 + f];
        unsigned int u1 = xs8[(size_t)ia.y * 8 + f];
        unsigned int u2 = xs8[(size_t)ia.z * 8 + f];
        unsigned int u3 = xs8[(size_t)ia.w * 8 + f];
        unsigned int u4 = xs8[(size_t)ib.x * 8 + f];
        unsigned int u5 = xs8[(size_t)ib.y * 8 + f];
        unsigned int u6 = xs8[(size_t)ib.z * 8 + f];
        unsigned int u7 = xs8[(size_t)ib.w * 8 + f];
        f8acc(u0, s0, s1, s2, s3); f8acc(u1, s0, s1, s2, s3);
        f8acc(u2, s0, s1, s2, s3); f8acc(u3, s0, s1, s2, s3);
        f8acc(u4, s0, s1, s2, s3); f8acc(u5, s0, s1, s2, s3);
        f8acc(u6, s0, s1, s2, s3); f8acc(u7, s0, s1, s2, s3);
    }
    if (e + 4 <= e1) {
        int4 ia = *(const int4*)&adj[e];
        unsigned int u0 = xs8[(size_t)ia.x * 8 + f];
        unsigned int u1 = xs8[(size_t)ia.y * 8 + f];
        unsigned int u2 = xs8[(size_t)ia.z * 8 + f];
        unsigned int u3 = xs8[(size_t)ia.w * 8 + f];
        f8acc(u0, s0, s1, s2, s3); f8acc(u1, s0, s1, s2, s3);
        f8acc(u2, s0, s1, s2, s3); f8acc(u3, s0, s1, s2, s3);
        e += 4;
    }
    for (; e < e1; e++) f8acc(xs8[(size_t)adj[e] * 8 + f], s0, s1, s2, s3);
    float d = dinv[n] * (1.f / 64.f);
    *(float4*)&out[(size_t)n * 32 + f * 4] = make_float4(s0 * d, s1 * d, s2 * d, s3 * d);
}

// 128-dim fp8-table aggregation (table pre-scaled x32); 8 nodes/block, 32 lanes/node
template <bool BIASRELU, bool OUT8>
__global__ void agg128(const unsigned int* __restrict__ tbl, const int* __restrict__ cnt,
                       const int* __restrict__ offs, const int* __restrict__ adj,
                       const float* __restrict__ dinv, const float* __restrict__ bias,
                       void* __restrict__ outv, int N) {
    int t = threadIdx.x;
    int sub = t >> 5, f = t & 31;
    int n = blockIdx.x * 8 + sub;
    if (n >= N) return;
    float s0 = 0.f, s1 = 0.f, s2 = 0.f, s3 = 0.f;
    f8acc(tbl[(size_t)n * 32 + f], s0, s1, s2, s3);
    int e = offs[n];
    int e1 = e + cnt[n];
    for (; e + 8 <= e1; e += 8) {
        int4 ia = *(const int4*)&adj[e];
        int4 ib = *(const int4*)&adj[e + 4];
        unsigned int u0 = tbl[(size_t)ia.x * 32 + f];
        unsigned int u1 = tbl[(size_t)ia.y * 32 + f];
        unsigned int u2 = tbl[(size_t)ia.z * 32 + f];
        unsigned int u3 = tbl[(size_t)ia.w * 32 + f];
        unsigned int u4 = tbl[(size_t)ib.x * 32 + f];
        unsigned int u5 = tbl[(size_t)ib.y * 32 + f];
        unsigned int u6 = tbl[(size_t)ib.z * 32 + f];
        unsigned int u7 = tbl[(size_t)ib.w * 32 + f];
        f8acc(u0, s0, s1, s2, s3); f8acc(u1, s0, s1, s2, s3);
        f8acc(u2, s0, s1, s2, s3); f8acc(u3, s0, s1, s2, s3);
        f8acc(u4, s0, s1, s2, s3); f8acc(u5, s0, s1, s2, s3);
        f8acc(u6, s0, s1, s2, s3); f8acc(u7, s0, s1, s2, s3);
    }
    if (e + 4 <= e1) {
        int4 ia = *(const int4*)&adj[e];
        unsigned int u0 = tbl[(size_t)ia.x * 32 + f];
        unsigned int u1 = tbl[(size_t)ia.y * 32 + f];
        unsigned int u2 = tbl[(size_t)ia.z * 32 + f];
        unsigned int u3 = tbl[(size_t)ia.w * 32 + f];
        f8acc(u0, s0, s1, s2, s3); f8acc(u1, s0, s1, s2, s3);
        f8acc(u2, s0, s1, s2, s3); f8acc(u3, s0, s1, s2, s3);
        e += 4;
    }
    for (; e < e1; e++) f8acc(tbl[(size_t)adj[e] * 32 + f], s0, s1, s2, s3);
    float d = dinv[n] * (1.f / 32.f);
    float v0 = s0 * d, v1 = s1 * d, v2 = s2 * d, v3 = s3 * d;
    if (BIASRELU) {
        float4 bv = *(const float4*)&bias[4 * f];
        v0 = fmaxf(v0 + bv.x, 0.f); v1 = fmaxf(v1 + bv.y, 0.f);
        v2 = fmaxf(v2 + bv.z, 0.f); v3 = fmaxf(v3 + bv.w, 0.f);
    }
    if (OUT8) {
        unsigned int r = 0;
        r = __builtin_amdgcn_cvt_pk_fp8_f32(v0 * 32.f, v1 * 32.f, r, false);
        r = __builtin_amdgcn_cvt_pk_fp8_f32(v2 * 32.f, v3 * 32.f, r, true);
        ((unsigned int*)outv)[(size_t)n * 32 + f] = r;
    } else {
        ushort4 u;
        u.x = f2bf(v0); u.y = f2bf(v1); u.z = f2bf(v2); u.w = f2bf(v3);
        *(ushort4*)&((unsigned short*)outv)[(size_t)n * 128 + 4 * f] = u;
    }
}

// ---- weight fragment prep: wfrag[y][s][c][lane][0..3] = bf16x2-packed B-fragment ----
template <int K, int F>
__global__ void wprep(const float* __restrict__ Wa, const float* __restrict__ Wb,
                      unsigned int* __restrict__ wfrag) {
    constexpr int S = K / 32, C = F / 16;
    int lane = threadIdx.x;       // 64
    int bc = blockIdx.x;          // (y*S + s)*C + c
    int c = bc % C;
    int s = (bc / C) % S;
    int y = bc / (C * S);
    const float* W = (y == 0) ? Wa : Wb;
    int col = c * 16 + (lane & 15);
    int k0 = s * 32 + (lane >> 4) * 8;
    unsigned int q[4];
#pragma unroll
    for (int jj = 0; jj < 4; jj++) {
        float lo = W[(size_t)(k0 + 2 * jj) * F + col];
        float hi = W[(size_t)(k0 + 2 * jj + 1) * F + col];
        q[jj] = (unsigned int)f2bf(lo) | ((unsigned int)f2bf(hi) << 16);
    }
    *(uint4*)&wfrag[((size_t)bc * 64 + lane) * 4] = make_uint4(q[0], q[1], q[2], q[3]);
}

// ---- MFMA conv: out[n, y-slice] = epi( A[n, y-slice] @ W_y ), 64 rows/block, 4 waves x 16 rows
template <int K, int F, int IN_STRIDE, int IN_OFF_Y, int OUT_STRIDE, int OUT_OFF_Y,
          bool BIASRELU, bool SCALE, int INMODE, int OUTMODE>
__global__ __launch_bounds__(256) void mfma_conv(
    const void* __restrict__ inv, const unsigned int* __restrict__ wfrag,
    const float* __restrict__ biasa, const float* __restrict__ biasb,
    const float* __restrict__ dinv, void* __restrict__ outv, int N) {
    constexpr int S = K / 32, C = F / 16;
    constexpr int FP = F + 4;
    __shared__ unsigned short buf[4][16][FP];
    int t = threadIdx.x, lane = t & 63, wave = t >> 6;
    int y = blockIdx.y;
    int n0 = blockIdx.x * 64 + wave * 16;
    const float* bias = (y == 0) ? biasa : biasb;
    const unsigned int* wf = wfrag + (size_t)y * S * C * 64 * 4;

    f32x4 acc[C];
#pragma unroll
    for (int c = 0; c < C; c++) acc[c] = (f32x4)(0.f);

    int arow = n0 + (lane & 15);
    bool aok = arow < N;
#pragma unroll
    for (int s = 0; s < S; s++) {
        U4B af; af.u = make_uint4(0u, 0u, 0u, 0u);
        if (aok) {
            if constexpr (INMODE == 2) {
                uint2 u = *(const uint2*)((const unsigned char*)inv +
                            (size_t)arow * IN_STRIDE + y * IN_OFF_Y + s * 32 + (lane >> 4) * 8);
                f32x2 p0 = __builtin_amdgcn_cvt_pk_f32_fp8(u.x, false);
                f32x2 p1 = __builtin_amdgcn_cvt_pk_f32_fp8(u.x, true);
                f32x2 p2 = __builtin_amdgcn_cvt_pk_f32_fp8(u.y, false);
                f32x2 p3 = __builtin_amdgcn_cvt_pk_f32_fp8(u.y, true);
                af.u.x = (unsigned int)f2bf(p0[0]) | ((unsigned int)f2bf(p0[1]) << 16);
                af.u.y = (unsigned int)f2bf(p1[0]) | ((unsigned int)f2bf(p1[1]) << 16);
                af.u.z = (unsigned int)f2bf(p2[0]) | ((unsigned int)f2bf(p2[1]) << 16);
                af.u.w = (unsigned int)f2bf(p3[0]) | ((unsigned int)f2bf(p3[1]) << 16);
            } else if constexpr (INMODE == 1) {
                af.u = *(const uint4*)((const unsigned short*)inv +
                            (size_t)arow * IN_STRIDE + y * IN_OFF_Y + s * 32 + (lane >> 4) * 8);
            } else {
                const float* ap = (const float*)inv + (size_t)arow * IN_STRIDE + y * IN_OFF_Y
                                  + s * 32 + (lane >> 4) * 8;
                float4 v0 = *(const float4*)ap;
                float4 v1 = *(const float4*)(ap + 4);
                af.u.x = (unsigned int)f2bf(v0.x) | ((unsigned int)f2bf(v0.y) << 16);
                af.u.y = (unsigned int)f2bf(v0.z) | ((unsigned int)f2bf(v0.w) << 16);
                af.u.z = (unsigned int)f2bf(v1.x) | ((unsigned int)f2bf(v1.y) << 16);
                af.u.w = (unsigned int)f2bf(v1.z) | ((unsigned int)f2bf(v1.w) << 16);
            }
        }
#pragma unroll
        for (int c = 0; c < C; c++) {
            U4B wb;
            wb.u = *(const uint4*)&wf[((size_t)(s * C + c) * 64 + lane) * 4];
            acc[c] = __builtin_amdgcn_mfma_f32_16x16x32_bf16(af.b, wb.b, acc[c], 0, 0, 0);
        }
    }

    constexpr float ISC = (INMODE == 2) ? (1.f / 32.f) : 1.f;
#pragma unroll
    for (int c = 0; c < C; c++) {
        int col = c * 16 + (lane & 15);
        float bv = BIASRELU ? bias[col] : 0.f;
#pragma unroll
        for (int r = 0; r < 4; r++) {
            int row = (lane >> 4) * 4 + r;
            int n = n0 + row;
            float v = acc[c][r] * ISC;
            if (BIASRELU) v = fmaxf(v + bv, 0.f);
            if (SCALE) v *= dinv[min(n, N - 1)];
            buf[wave][row][col] = f2bf(v);
        }
    }
    __syncthreads();

    constexpr int CPR = F / 8;
    for (int i = t; i < 64 * CPR; i += 256) {
        int row = i / CPR;
        int f0 = (i % CPR) * 8;
        int n = blockIdx.x * 64 + row;
        if (n >= N) continue;
        const unsigned short* bp = &buf[row >> 4][row & 15][f0];
        uint2 a = *(const uint2*)bp;
        uint2 b = *(const uint2*)(bp + 4);
        size_t off = (size_t)n * OUT_STRIDE + y * OUT_OFF_Y + f0;
        if constexpr (OUTMODE == 2) {
            float e0 = __uint_as_float(a.x << 16), e1 = __uint_as_float(a.x & 0xFFFF0000u);
            float e2 = __uint_as_float(a.y << 16), e3 = __uint_as_float(a.y & 0xFFFF0000u);
            float e4 = __uint_as_float(b.x << 16), e5 = __uint_as_float(b.x & 0xFFFF0000u);
            float e6 = __uint_as_float(b.y << 16), e7 = __uint_as_float(b.y & 0xFFFF0000u);
            unsigned int r0 = 0, r1 = 0;
            r0 = __builtin_amdgcn_cvt_pk_fp8_f32(e0 * 32.f, e1 * 32.f, r0, false);
            r0 = __builtin_amdgcn_cvt_pk_fp8_f32(e2 * 32.f, e3 * 32.f, r0, true);
            r1 = __builtin_amdgcn_cvt_pk_fp8_f32(e4 * 32.f, e5 * 32.f, r1, false);
            r1 = __builtin_amdgcn_cvt_pk_fp8_f32(e6 * 32.f, e7 * 32.f, r1, true);
            *(uint2*)((unsigned char*)outv + off) = make_uint2(r0, r1);
        } else {
            *(uint4*)((unsigned short*)outv + off) = make_uint4(a.x, a.y, b.x, b.y);
        }
    }
}

// concat weights/biases for fused layer1 and fused layer3 bias
__global__ void prep_cat(const float* __restrict__ w1m, const float* __restrict__ w1l,
                         const float* __restrict__ b1m, const float* __restrict__ b1l,
                         const float* __restrict__ b3m, const float* __restrict__ b3l,
                         float* __restrict__ wcat1, float* __restrict__ bcat1,
                         float* __restrict__ bcat3) {
    int i = blockIdx.x * 256 + threadIdx.x;
    if (i < 32 * 128) {
        int k = i >> 7, f = i & 127;
        wcat1[i] = (f < 64) ? w1m[k * 64 + f] : w1l[k * 64 + f - 64];
    } else if (i < 32 * 128 + 128) {
        int f = i - 32 * 128;
        bcat1[f] = (f < 64) ? b1m[f] : b1l[f - 64];
    } else if (i < 32 * 128 + 256) {
        int f = i - 32 * 128 - 128;
        bcat3[f] = (f < 64) ? b3m[f] : b3l[f - 64];
    }
}

// decoder head-composition precompute (heads are linear in h2 -> fold through nm_wo)
__global__ void prep_dec(const float* __restrict__ nm_wo, const float* __restrict__ nm_bo,
                         const float* __restrict__ ex_w, const float* __restrict__ ex_b,
                         const float* __restrict__ fu_w, const float* __restrict__ fu_b,
                         const float* __restrict__ al_w, const float* __restrict__ al_b,
                         const float* __restrict__ sl_w, const float* __restrict__ sl_b,
                         const float* __restrict__ em_wo,
                         float* __restrict__ wtn, float* __restrict__ bcn,
                         float* __restrict__ wte) {
    int idx = blockIdx.x * 256 + threadIdx.x;
    if (idx < 1024) {
        int j = idx >> 7, k = idx & 127;
        float s = 0.f;
        for (int m = 0; m < 128; m++) {
            float w = (j == 0) ? ex_w[m] : (j <= 5) ? fu_w[m * 5 + (j - 1)]
                     : (j == 6) ? al_w[m] : sl_w[m];
            s += nm_wo[k * 128 + m] * w;
        }
        wtn[j * 128 + k] = s;
    } else if (idx < 2048) {
        int i2 = idx - 1024;
        int j = i2 >> 7, k = i2 & 127;
        wte[j * 128 + k] = em_wo[k * 8 + j];
    } else if (idx < 2056) {
        int j = idx - 2048;
        float s = (j == 0) ? ex_b[0] : (j <= 5) ? fu_b[j - 1] : (j == 6) ? al_b[0] : sl_b[0];
        for (int m = 0; m < 128; m++) {
            float w = (j == 0) ? ex_w[m] : (j <= 5) ? fu_w[m * 5 + (j - 1)]
                     : (j == 6) ? al_w[m] : sl_w[m];
            s += nm_bo[m] * w;
        }
        bcn[j] = s;
    }
}

#define POOL_CHUNK 128
// h is bf16-packed [n][64] uints
__global__ void pool128(const unsigned int* __restrict__ h, const int* __restrict__ batch,
                        float* __restrict__ sums, int n) {
    int f = threadIdx.x;  // 0..63
    int s0 = blockIdx.x * POOL_CHUNK;
    if (s0 >= n) return;
    int s1 = min(s0 + POOL_CHUNK, n);
    int cur = batch[s0];
    float a0 = 0.f, a1 = 0.f;
    for (int i = s0; i < s1; i++) {
        int b = batch[i];
        if (b != cur) {
            atomicAdd(&sums[cur * 128 + 2 * f], a0);
            atomicAdd(&sums[cur * 128 + 2 * f + 1], a1);
            a0 = a1 = 0.f; cur = b;
        }
        unsigned int u = h[(size_t)i * 64 + f];
        a0 += __uint_as_float(u << 16);
        a1 += __uint_as_float(u & 0xFFFF0000u);
    }
    atomicAdd(&sums[cur * 128 + 2 * f], a0);
    atomicAdd(&sums[cur * 128 + 2 * f + 1], a1);
}

__global__ void finalize_pool(const float* __restrict__ sums, const int* __restrict__ bcnt,
                              float* __restrict__ out, float* __restrict__ zbuf) {
    int i = blockIdx.x * 1024 + threadIdx.x;  // 0..2047
    int b = i >> 7, f = i & 127;
    float c = fmaxf((float)bcnt[b], 1.f);
    float v = sums[i] / c;
    if (f < 64) { out[OUT_MU + b * 64 + f] = v; zbuf[b * 64 + f] = v; }
    else out[OUT_LG + b * 64 + (f - 64)] = v;
}

// zwi[b][t] = bi[t] + sum_k z[b,k]*wi[k*128+t]
__global__ void zwi_kernel(const float* __restrict__ z,
                           const float* __restrict__ nm_wi, const float* __restrict__ nm_bi,
                           const float* __restrict__ em_wi, const float* __restrict__ em_bi,
                           float* __restrict__ zwi_nm, float* __restrict__ zwi_em) {
    int b = blockIdx.x, t = threadIdx.x;  // 16 blocks x 128 threads
    float an = nm_bi[t], ae = em_bi[t];
    for (int k = 0; k < 64; k++) {
        float zv = z[b * 64 + k];
        an += zv * nm_wi[k * 128 + t];
        ae += zv * em_wi[k * 128 + t];
    }
    zwi_nm[b * 128 + t] = an;
    zwi_em[b * 128 + t] = ae;
}

#define D3_ROWS 32

// decoder3: layer1+LN -> LDS; heads/edges as 128-len LDS dots (heads pre-composed)
__global__ __launch_bounds__(256) void decoder3(
    const float* __restrict__ zwi_nm, const float* __restrict__ zwi_em,
    const float* __restrict__ nm_wi, const float* __restrict__ em_wi,
    const float* __restrict__ nm_g, const float* __restrict__ nm_be,
    const float* __restrict__ em_g, const float* __restrict__ em_be,
    const float* __restrict__ wtn, const float* __restrict__ bcn,
    const float* __restrict__ wte, const float* __restrict__ em_bo,
    const float* __restrict__ pos_all,
    float* __restrict__ out) {
    __shared__ float sn[D3_ROWS][132];
    __shared__ float se[D3_ROWS][132];
    __shared__ float Wn[8][132];
    __shared__ float We[8][132];
    int t = threadIdx.x;
    int lane = t & 63, wave = t >> 6;
    int rowBase = blockIdx.x * D3_ROWS;
    int b = rowBase >> 12;
    int row0 = rowBase + wave * 8;

    for (int i = t; i < 1024; i += 256) {
        Wn[i >> 7][i & 127] = wtn[i];
        We[i >> 7][i & 127] = wte[i];
    }

    int f0 = lane, f1 = lane + 64;
    float zn0 = zwi_nm[b * 128 + f0], zn1 = zwi_nm[b * 128 + f1];
    float ze0 = zwi_em[b * 128 + f0], ze1 = zwi_em[b * 128 + f1];
    float wn64_0 = nm_wi[64 * 128 + f0], wn64_1 = nm_wi[64 * 128 + f1];
    float wn65_0 = nm_wi[65 * 128 + f0], wn65_1 = nm_wi[65 * 128 + f1];
    float we64_0 = em_wi[64 * 128 + f0], we64_1 = em_wi[64 * 128 + f1];
    float we65_0 = em_wi[65 * 128 + f0], we65_1 = em_wi[65 * 128 + f1];
    float gn0 = nm_g[f0], gn1 = nm_g[f1], bn0 = nm_be[f0], bn1 = nm_be[f1];
    float ge0 = em_g[f0], ge1 = em_g[f1], be0 = em_be[f0], be1 = em_be[f1];

#pragma unroll
    for (int r = 0; r < 8; r++) {
        int row = row0 + r, i = row & (NMAXC - 1);
        float px = pos_all[i * 2], py = pos_all[i * 2 + 1];
        float a0 = zn0 + px * wn64_0 + py * wn65_0;
        float a1 = zn1 + px * wn64_1 + py * wn65_1;
        float e0 = ze0 + px * we64_0 + py * we65_0;
        float e1 = ze1 + px * we64_1 + py * we65_1;
        float sm = a0 + a1, sq = a0 * a0 + a1 * a1;
        float sme = e0 + e1, sqe = e0 * e0 + e1 * e1;
#pragma unroll
        for (int d = 1; d < 64; d <<= 1) {
            sm += __shfl_xor(sm, d); sq += __shfl_xor(sq, d);
            sme += __shfl_xor(sme, d); sqe += __shfl_xor(sqe, d);
        }
        float mean = sm * (1.f / 128.f);
        float var = sq * (1.f / 128.f) - mean * mean;
        float rstd = rsqrtf(var + 1e-5f);
        int rl = wave * 8 + r;
        sn[rl][f0] = fmaxf((a0 - mean) * rstd * gn0 + bn0, 0.f);
        sn[rl][f1] = fmaxf((a1 - mean) * rstd * gn1 + bn1, 0.f);
        float meane = sme * (1.f / 128.f);
        float vare = sqe * (1.f / 128.f) - meane * meane;
        float rstde = rsqrtf(vare + 1e-5f);
        se[rl][f0] = fmaxf((e0 - meane) * rstde * ge0 + be0, 0.f);
        se[rl][f1] = fmaxf((e1 - meane) * rstde * ge1 + be1, 0.f);
    }
    __syncthreads();

    int rl = t >> 3, j = t & 7;
    float accn = 0.f, acce = 0.f;
#pragma unroll 8
    for (int k4 = 0; k4 < 128; k4 += 4) {
        float4 sv = *(const float4*)&sn[rl][k4];
        float4 wv = *(const float4*)&Wn[j][k4];
        float4 sev = *(const float4*)&se[rl][k4];
        float4 wev = *(const float4*)&We[j][k4];
        accn += sv.x * wv.x + sv.y * wv.y + sv.z * wv.z + sv.w * wv.w;
        acce += sev.x * wev.x + sev.y * wev.y + sev.z * wev.z + sev.w * wev.w;
    }
    int row = rowBase + rl;
    accn += bcn[j];
    if (j == 0)       out[OUT_NODES + row] = accn;
    else if (j <= 5)  out[OUT_FUEL + (size_t)row * 5 + (j - 1)] = accn;
    else if (j == 6)  out[OUT_ALT + row] = accn;
    else              out[OUT_SLOPE + row] = accn;
    out[OUT_EDGES + (size_t)row * 8 + j] = acce + em_bo[j];
}

extern "C" void kernel_launch(void* const* d_in, const int* in_sizes, int n_in,
                              void* d_out, int out_size, void* d_ws, size_t ws_size,
                              hipStream_t stream) {
    const float* x    = (const float*)d_in[0];
    const int* edge   = (const int*)d_in[1];
    const int* batch  = (const int*)d_in[2];
    const float* w1m = (const float*)d_in[3];  const float* b1m = (const float*)d_in[4];
    const float* w2m = (const float*)d_in[5];  const float* b2m = (const float*)d_in[6];
    const float* w3m = (const float*)d_in[7];  const float* b3m = (const float*)d_in[8];
    const float* w1l = (const float*)d_in[9];  const float* b1l = (const float*)d_in[10];
    const float* w2l = (const float*)d_in[11]; const float* b2l = (const float*)d_in[12];
    const float* w3l = (const float*)d_in[13]; const float* b3l = (const float*)d_in[14];
    const float* nm_wi = (const float*)d_in[15]; const float* nm_bi = (const float*)d_in[16];
    const float* nm_g  = (const float*)d_in[17]; const float* nm_be = (const float*)d_in[18];
    const float* nm_wo = (const float*)d_in[19]; const float* nm_bo = (const float*)d_in[20];
    const float* ex_w = (const float*)d_in[21]; const float* ex_b = (const float*)d_in[22];
    const float* fu_w = (const float*)d_in[23]; const float* fu_b = (const float*)d_in[24];
    const float* al_w = (const float*)d_in[25]; const float* al_b = (const float*)d_in[26];
    const float* sl_w = (const float*)d_in[27]; const float* sl_b = (const float*)d_in[28];
    const float* em_wi = (const float*)d_in[29]; const float* em_bi = (const float*)d_in[30];
    const float* em_g  = (const float*)d_in[31]; const float* em_be = (const float*)d_in[32];
    const float* em_wo = (const float*)d_in[33]; const float* em_bo = (const float*)d_in[34];
    const float* pos_all = (const float*)d_in[35];
    float* out = (float*)d_out;

    char* p = (char*)d_ws;
    auto alloc = [&](size_t bytes) -> void* {
        void* r = (void*)p;
        p += ((bytes + 255) / 256) * 256;
        return r;
    };
    int* cnt      = (int*)alloc((size_t)N_NODES * 4);
    int* offs     = (int*)alloc((size_t)N_NODES * 4);
    float* dinv   = (float*)alloc((size_t)N_NODES * 4);
    int* bcnt     = (int*)alloc(BATCH_B * 4);
    float* sums   = (float*)alloc(BATCH_B * 128 * 4);
    float* zbuf   = (float*)alloc(BATCH_B * LATC * 4);
    float* zwi_nm = (float*)alloc(BATCH_B * 128 * 4);
    float* zwi_em = (float*)alloc(BATCH_B * 128 * 4);
    float* wcat1  = (float*)alloc(32 * 128 * 4);
    float* bcat1  = (float*)alloc(128 * 4);
    float* bcat3  = (float*)alloc(128 * 4);
    float* wtn    = (float*)alloc(8 * 128 * 4);
    float* bcn    = (float*)alloc(8 * 4);
    float* wte    = (float*)alloc(8 * 128 * 4);
    unsigned int* wf1 = (unsigned int*)alloc((size_t)1 * 1 * 8 * 64 * 4 * 4);   // 8 KB
    unsigned int* wf2 = (unsigned int*)alloc((size_t)2 * 2 * 8 * 64 * 4 * 4);   // 64 KB
    unsigned int* wf3 = (unsigned int*)alloc((size_t)2 * 4 * 4 * 64 * 4 * 4);   // 32 KB
    int* hist     = (int*)alloc((size_t)NBINS * NSB * 4);                      // 400 KB
    int* total    = (int*)alloc((size_t)NBINS * 4);
    int* base     = (int*)alloc((size_t)(NBINS + 1) * 4);
    unsigned int* sorted = (unsigned int*)alloc((size_t)N_EDGESC * 4);         // 6.4 MB
    int* adj      = (int*)alloc((size_t)(N_EDGESC + NBINS * BIN_PAD + 256) * 4); // 7.7 MB compact
    unsigned int* xs8 = (unsigned int*)alloc((size_t)N_NODES * 8 * 4);         // 3.2 MB fp8
    float* agg0   = (float*)alloc((size_t)N_NODES * 32 * 4);                   // 12.8 MB
    unsigned int* hA8 = (unsigned int*)alloc((size_t)N_NODES * 32 * 4);        // 12.8 MB fp8 (also hD8)
    unsigned int* hB8 = (unsigned int*)alloc((size_t)N_NODES * 32 * 4);        // 12.8 MB fp8
    unsigned short* h256 = (unsigned short*)alloc((size_t)N_NODES * 256 * 2);  // 51.2 MB bf16
    unsigned short* final128 = (unsigned short*)alloc((size_t)N_NODES * 128 * 2);  // 25.6 MB bf16
    unsigned int* hD8 = hA8;  // hA8 dead after agg #1

    const int* srcp = edge;
    const int* dstp = edge + N_EDGESC;

    hipMemsetAsync(sums, 0, (size_t)BATCH_B * 128 * 4, stream);

    // ---- CSR build: atomic-free counting sort by dst bin -> compact aligned CSR ----
    histA<<<NSB, 1024, 0, stream>>>(dstp, hist);
    scanB<<<NBINS, NSB, 0, stream>>>(hist, total);
    scanC<<<1, 512, 0, stream>>>(total, base);
    scatterD<<<NSB, 1024, 0, stream>>>(srcp, dstp, hist, base, sorted);
    csr_compact<<<NBINS, 256, 0, stream>>>(sorted, base, adj, offs, cnt, dinv, N_NODES);

    batch_count<<<1, 64, 0, stream>>>(batch, bcnt, N_NODES);
    prep_cat<<<17, 256, 0, stream>>>(w1m, w1l, b1m, b1l, b3m, b3l, wcat1, bcat1, bcat3);
    prep_dec<<<9, 256, 0, stream>>>(nm_wo, nm_bo, ex_w, ex_b, fu_w, fu_b, al_w, al_b,
                                    sl_w, sl_b, em_wo, wtn, bcn, wte);
    wprep<32, 128><<<1 * 1 * 8, 64, 0, stream>>>(wcat1, wcat1, wf1);
    wprep<64, 128><<<2 * 2 * 8, 64, 0, stream>>>(w2m, w2l, wf2);
    wprep<128, 64><<<2 * 4 * 4, 64, 0, stream>>>(w3m, w3l, wf3);
    prescale_x<<<(N_NODES * 8 + 255) / 256, 256, 0, stream>>>(x, dinv, xs8, N_NODES * 8);

    // agg0 = S x  (shared by both branches), fp8 table
    agg_s32<<<(N_NODES + 31) / 32, 256, 0, stream>>>(xs8, cnt, offs, adj, dinv, agg0, N_NODES);

    const int GB = (N_NODES + 63) / 64;  // 1563 row blocks

    // L1 (fused mu|lg): hA8 = fp8x32( dinv ⊙ relu(agg0 @ [w1m|w1l] + [b1m|b1l]) )  [MFMA]
    mfma_conv<32, 128, 32, 0, 128, 0, true, true, 0, 2>
        <<<dim3(GB, 1), 256, 0, stream>>>(agg0, wf1, bcat1, bcat1, dinv, hA8, N_NODES);

    // agg #1: hB8 = fp8x32( [S mu1 | S lg1] )
    agg128<false, true><<<(N_NODES + 7) / 8, 256, 0, stream>>>(
        hA8, cnt, offs, adj, dinv, nullptr, hB8, N_NODES);

    // L2 dual: h256 = bf16( relu(hB8[:, y*64:] @ w2{m,l} + b2{m,l}) )  [MFMA]
    mfma_conv<64, 128, 128, 64, 256, 128, true, false, 2, 1>
        <<<dim3(GB, 2), 256, 0, stream>>>(hB8, wf2, b2m, b2l, dinv, h256, N_NODES);

    // L3 dual: hD8 = fp8x32( dinv ⊙ (h256[:, y*128:] @ w3{m,l}) )  [MFMA]
    mfma_conv<128, 64, 256, 128, 128, 64, false, true, 1, 2>
        <<<dim3(GB, 2), 256, 0, stream>>>(h256, wf3, nullptr, nullptr, dinv, hD8, N_NODES);

    // agg #2: final = relu(dinv*(sum) + [b3m|b3l]) = [mu3|lg3]  -> bf16 [n][128]
    agg128<true, false><<<(N_NODES + 7) / 8, 256, 0, stream>>>(
        hD8, cnt, offs, adj, dinv, bcat3, final128, N_NODES);

    pool128<<<(N_NODES + POOL_CHUNK - 1) / POOL_CHUNK, 64, 0, stream>>>(
        (const unsigned int*)final128, batch, sums, N_NODES);
    finalize_pool<<<2, 1024, 0, stream>>>(sums, bcnt, out, zbuf);

    zwi_kernel<<<BATCH_B, 128, 0, stream>>>(zbuf, nm_wi, nm_bi, em_wi, em_bi, zwi_nm, zwi_em);

    decoder3<<<BATCH_B * NMAXC / D3_ROWS, 256, 0, stream>>>(
        zwi_nm, zwi_em, nm_wi, em_wi, nm_g, nm_be, em_g, em_be,
        wtn, bcn, wte, em_bo, pos_all, out);
}

// Round 12
// 265.926 us; speedup vs baseline: 12.1078x; 1.1175x over previous
//
#include <hip/hip_runtime.h>
#include <hip/hip_bf16.h>

#define N_NODES 100000
#define N_EDGESC 1600000
#define BATCH_B 16
#define NMAXC 4096
#define LATC 64
#define NBINS 391   // ceil(100000/256): 256 nodes per bin
#define NSB 256     // sort blocks
#define EPB ((N_EDGESC + NSB - 1) / NSB)  // 6250 edges per sort block
#define BIN_PAD 768 // worst-case per-bin alignment padding (256 nodes x 3)

// output layout offsets (flat f32)
#define OUT_NODES 0
#define OUT_EDGES 65536
#define OUT_FUEL  589824
#define OUT_ALT   917504
#define OUT_SLOPE 983040
#define OUT_MU    1048576
#define OUT_LG    1049600

typedef float f32x2 __attribute__((ext_vector_type(2)));
typedef float f32x4 __attribute__((ext_vector_type(4)));
typedef short bf16x8 __attribute__((ext_vector_type(8)));
union U4B { uint4 u; bf16x8 b; };

__device__ __forceinline__ unsigned short f2bf(float f) {
    unsigned int u = __float_as_uint(f);
    return (unsigned short)((u + 0x7FFFu + ((u >> 16) & 1u)) >> 16);  // RNE
}
__device__ __forceinline__ float bf2f(unsigned short h) {
    return __uint_as_float(((unsigned int)h) << 16);
}
__device__ __forceinline__ void f8acc(unsigned int u, float& a0, float& a1, float& a2, float& a3) {
    f32x2 lo = __builtin_amdgcn_cvt_pk_f32_fp8(u, false);
    f32x2 hi = __builtin_amdgcn_cvt_pk_f32_fp8(u, true);
    a0 += lo[0]; a1 += lo[1]; a2 += hi[0]; a3 += hi[1];
}
// decode 4 fp8 -> bf16x2 pair packed in 2 uints
__device__ __forceinline__ void f8_to_bf2(unsigned int u, unsigned int& q0, unsigned int& q1) {
    f32x2 lo = __builtin_amdgcn_cvt_pk_f32_fp8(u, false);
    f32x2 hi = __builtin_amdgcn_cvt_pk_f32_fp8(u, true);
    q0 = (unsigned int)f2bf(lo[0]) | ((unsigned int)f2bf(lo[1]) << 16);
    q1 = (unsigned int)f2bf(hi[0]) | ((unsigned int)f2bf(hi[1]) << 16);
}

// ---- CSR build via atomic-free counting sort by dst>>8 ----
__global__ __launch_bounds__(1024) void histA(const int* __restrict__ dst, int* __restrict__ hist) {
    __shared__ int h[NBINS];
    int b = blockIdx.x, t = threadIdx.x;
    for (int i = t; i < NBINS; i += 1024) h[i] = 0;
    __syncthreads();
    int e0 = b * EPB, e1 = min(e0 + EPB, N_EDGESC);
    for (int i = e0 + t; i < e1; i += 1024)
        atomicAdd(&h[dst[i] >> 8], 1);
    __syncthreads();
    for (int i = t; i < NBINS; i += 1024) hist[i * NSB + b] = h[i];
}

__global__ void scanB(int* __restrict__ hist, int* __restrict__ total) {
    __shared__ int sh[NSB];
    int j = blockIdx.x, t = threadIdx.x;  // 256 threads
    int v = hist[j * NSB + t];
    sh[t] = v; __syncthreads();
    for (int off = 1; off < NSB; off <<= 1) {
        int u = (t >= off) ? sh[t - off] : 0; __syncthreads();
        sh[t] += u; __syncthreads();
    }
    hist[j * NSB + t] = sh[t] - v;
    if (t == NSB - 1) total[j] = sh[t];
}

__global__ void scanC(const int* __restrict__ total, int* __restrict__ base) {
    __shared__ int sh[512];
    int t = threadIdx.x;
    int v = (t < NBINS) ? total[t] : 0;
    sh[t] = v; __syncthreads();
    for (int off = 1; off < 512; off <<= 1) {
        int u = (t >= off) ? sh[t - off] : 0; __syncthreads();
        sh[t] += u; __syncthreads();
    }
    if (t < NBINS) base[t] = sh[t] - v;
    if (t == NBINS - 1) base[NBINS] = sh[t];
}

__global__ __launch_bounds__(1024) void scatterD(const int* __restrict__ src, const int* __restrict__ dst,
                                                 const int* __restrict__ hist, const int* __restrict__ base,
                                                 unsigned int* __restrict__ sorted) {
    __shared__ int w0[NBINS];
    __shared__ int lc[NBINS];
    int b = blockIdx.x, t = threadIdx.x;
    for (int i = t; i < NBINS; i += 1024) {
        w0[i] = base[i] + hist[i * NSB + b];
        lc[i] = 0;
    }
    __syncthreads();
    int e0 = b * EPB, e1 = min(e0 + EPB, N_EDGESC);
    for (int i = e0 + t; i < e1; i += 1024) {
        int d = dst[i], s = src[i];
        int j = d >> 8;
        int r = atomicAdd(&lc[j], 1);
        sorted[w0[j] + r] = ((unsigned int)s << 8) | (d & 255);
    }
}

// compact CSR with 16B-aligned per-node lists + fused fp8 prescale of x
__global__ void csr_compact(const unsigned int* __restrict__ sorted, const int* __restrict__ base,
                            const float* __restrict__ x,
                            int* __restrict__ adj, int* __restrict__ offs,
                            int* __restrict__ cnt, float* __restrict__ dinv,
                            unsigned int* __restrict__ xs8, int N) {
    __shared__ int lc[256];
    __shared__ int cur[256];
    __shared__ int so4[256];
    int j = blockIdx.x, t = threadIdx.x;
    lc[t] = 0; cur[t] = 0;
    __syncthreads();
    int e0 = base[j], e1 = base[j + 1];
    for (int i = e0 + t; i < e1; i += 256)
        atomicAdd(&lc[sorted[i] & 255], 1);
    __syncthreads();
    int c4 = (lc[t] + 3) & ~3;   // align each list to 4 entries (16B)
    so4[t] = c4;
    __syncthreads();
    for (int off = 1; off < 256; off <<= 1) {
        int u = (t >= off) ? so4[t - off] : 0; __syncthreads();
        so4[t] += u; __syncthreads();
    }
    int mybase = base[j] + j * BIN_PAD + so4[t] - c4;  // exclusive, aligned
    __syncthreads();
    so4[t] = mybase;
    __syncthreads();
    for (int i = e0 + t; i < e1; i += 256) {
        unsigned int pk = sorted[i];
        int d = pk & 255;
        int r = atomicAdd(&cur[d], 1);
        adj[so4[d] + r] = (int)(pk >> 8);
    }
    int n = j * 256 + t;
    if (n < N) {
        int c = lc[t];
        cnt[n] = c;
        offs[n] = so4[t];
        float dv = rsqrtf((float)(c + 1));  // +1 = self loop
        dinv[n] = dv;
        // fused prescale: xs8[n] = fp8(64 * dinv * x[n][0..31])
        float ds = dv * 64.f;
        const float* xr = &x[(size_t)n * 32];
        unsigned int q[8];
#pragma unroll
        for (int jj = 0; jj < 8; jj++) {
            float4 v = *(const float4*)&xr[jj * 4];
            unsigned int r8 = 0;
            r8 = __builtin_amdgcn_cvt_pk_fp8_f32(v.x * ds, v.y * ds, r8, false);
            r8 = __builtin_amdgcn_cvt_pk_fp8_f32(v.z * ds, v.w * ds, r8, true);
            q[jj] = r8;
        }
        *(uint4*)&xs8[(size_t)n * 8] = make_uint4(q[0], q[1], q[2], q[3]);
        *(uint4*)&xs8[(size_t)n * 8 + 4] = make_uint4(q[4], q[5], q[6], q[7]);
    }
}

// agg0 = S x : fp8 table [n][8] uints; 32 nodes per 256-thread block, 8 lanes/node
__global__ void agg_s32(const unsigned int* __restrict__ xs8, const int* __restrict__ cnt,
                        const int* __restrict__ offs, const int* __restrict__ adj,
                        const float* __restrict__ dinv, float* __restrict__ out, int N) {
    int t = threadIdx.x;
    int sub = t >> 3, f = t & 7;
    int n = blockIdx.x * 32 + sub;
    if (n >= N) return;
    float s0 = 0.f, s1 = 0.f, s2 = 0.f, s3 = 0.f;
    f8acc(xs8[(size_t)n * 8 + f], s0, s1, s2, s3);
    int e = offs[n];
    int e1 = e + cnt[n];
    for (; e + 8 <= e1; e += 8) {
        int4 ia = *(const int4*)&adj[e];
        int4 ib = *(const int4*)&adj[e + 4];
        unsigned int u0 = xs8[(size_t)ia.x * 8 + f];
        unsigned int u1 = xs8[(size_t)ia.y * 8 + f];
        unsigned int u2 = xs8[(size_t)ia.z * 8 + f];
        unsigned int u3 = xs8[(size_t)ia.w * 8 + f];
        unsigned int u4 = xs8[(size_t)ib.x * 8 + f];
        unsigned int u5 = xs8[(size_t)ib.y * 8 + f];
        unsigned int u6 = xs8[(size_t)ib.z * 8 + f];
        unsigned int u7 = xs8[(size_t)ib.w * 8 + f];
        f8acc(u0, s0, s1, s2, s3); f8acc(u1, s0, s1, s2, s3);
        f8acc(u2, s0, s1, s2, s3); f8acc(u3, s0, s1, s2, s3);
        f8acc(u4, s0, s1, s2, s3); f8acc(u5, s0, s1, s2, s3);
        f8acc(u6, s0, s1, s2, s3); f8acc(u7, s0, s1, s2, s3);
    }
    if (e + 4 <= e1) {
        int4 ia = *(const int4*)&adj[e];
        unsigned int u0 = xs8[(size_t)ia.x * 8 + f];
        unsigned int u1 = xs8[(size_t)ia.y * 8 + f];
        unsigned int u2 = xs8[(size_t)ia.z * 8 + f];
        unsigned int u3 = xs8[(size_t)ia.w * 8 + f];
        f8acc(u0, s0, s1, s2, s3); f8acc(u1, s0, s1, s2, s3);
        f8acc(u2, s0, s1, s2, s3); f8acc(u3, s0, s1, s2, s3);
        e += 4;
    }
    for (; e < e1; e++) f8acc(xs8[(size_t)adj[e] * 8 + f], s0, s1, s2, s3);
    float d = dinv[n] * (1.f / 64.f);
    *(float4*)&out[(size_t)n * 32 + f * 4] = make_float4(s0 * d, s1 * d, s2 * d, s3 * d);
}

// 128-dim fp8-table aggregation (table pre-scaled x32); 8 nodes/block, 32 lanes/node
template <bool BIASRELU, bool OUT8>
__global__ void agg128(const unsigned int* __restrict__ tbl, const int* __restrict__ cnt,
                       const int* __restrict__ offs, const int* __restrict__ adj,
                       const float* __restrict__ dinv, const float* __restrict__ bias,
                       void* __restrict__ outv, int N) {
    int t = threadIdx.x;
    int sub = t >> 5, f = t & 31;
    int n = blockIdx.x * 8 + sub;
    if (n >= N) return;
    float s0 = 0.f, s1 = 0.f, s2 = 0.f, s3 = 0.f;
    f8acc(tbl[(size_t)n * 32 + f], s0, s1, s2, s3);
    int e = offs[n];
    int e1 = e + cnt[n];
    for (; e + 8 <= e1; e += 8) {
        int4 ia = *(const int4*)&adj[e];
        int4 ib = *(const int4*)&adj[e + 4];
        unsigned int u0 = tbl[(size_t)ia.x * 32 + f];
        unsigned int u1 = tbl[(size_t)ia.y * 32 + f];
        unsigned int u2 = tbl[(size_t)ia.z * 32 + f];
        unsigned int u3 = tbl[(size_t)ia.w * 32 + f];
        unsigned int u4 = tbl[(size_t)ib.x * 32 + f];
        unsigned int u5 = tbl[(size_t)ib.y * 32 + f];
        unsigned int u6 = tbl[(size_t)ib.z * 32 + f];
        unsigned int u7 = tbl[(size_t)ib.w * 32 + f];
        f8acc(u0, s0, s1, s2, s3); f8acc(u1, s0, s1, s2, s3);
        f8acc(u2, s0, s1, s2, s3); f8acc(u3, s0, s1, s2, s3);
        f8acc(u4, s0, s1, s2, s3); f8acc(u5, s0, s1, s2, s3);
        f8acc(u6, s0, s1, s2, s3); f8acc(u7, s0, s1, s2, s3);
    }
    if (e + 4 <= e1) {
        int4 ia = *(const int4*)&adj[e];
        unsigned int u0 = tbl[(size_t)ia.x * 32 + f];
        unsigned int u1 = tbl[(size_t)ia.y * 32 + f];
        unsigned int u2 = tbl[(size_t)ia.z * 32 + f];
        unsigned int u3 = tbl[(size_t)ia.w * 32 + f];
        f8acc(u0, s0, s1, s2, s3); f8acc(u1, s0, s1, s2, s3);
        f8acc(u2, s0, s1, s2, s3); f8acc(u3, s0, s1, s2, s3);
        e += 4;
    }
    for (; e < e1; e++) f8acc(tbl[(size_t)adj[e] * 32 + f], s0, s1, s2, s3);
    float d = dinv[n] * (1.f / 32.f);
    float v0 = s0 * d, v1 = s1 * d, v2 = s2 * d, v3 = s3 * d;
    if (BIASRELU) {
        float4 bv = *(const float4*)&bias[4 * f];
        v0 = fmaxf(v0 + bv.x, 0.f); v1 = fmaxf(v1 + bv.y, 0.f);
        v2 = fmaxf(v2 + bv.z, 0.f); v3 = fmaxf(v3 + bv.w, 0.f);
    }
    if (OUT8) {
        unsigned int r = 0;
        r = __builtin_amdgcn_cvt_pk_fp8_f32(v0 * 32.f, v1 * 32.f, r, false);
        r = __builtin_amdgcn_cvt_pk_fp8_f32(v2 * 32.f, v3 * 32.f, r, true);
        ((unsigned int*)outv)[(size_t)n * 32 + f] = r;
    } else {
        ushort4 u;
        u.x = f2bf(v0); u.y = f2bf(v1); u.z = f2bf(v2); u.w = f2bf(v3);
        *(ushort4*)&((unsigned short*)outv)[(size_t)n * 128 + 4 * f] = u;
    }
}

// device helper: pack one B-fragment quad from f32 weight matrix
__device__ __forceinline__ void wfrag_write(const float* W, int F, int col, int k0,
                                            unsigned int* dst) {
    unsigned int q[4];
#pragma unroll
    for (int jj = 0; jj < 4; jj++) {
        float lo = W[(size_t)(k0 + 2 * jj) * F + col];
        float hi = W[(size_t)(k0 + 2 * jj + 1) * F + col];
        q[jj] = (unsigned int)f2bf(lo) | ((unsigned int)f2bf(hi) << 16);
    }
    *(uint4*)dst = make_uint4(q[0], q[1], q[2], q[3]);
}

// ---- mega-prep: batch_count + bias concats + head composition + weight fragments ----
// blocks: 0 = biases+batch_count; 1..9 = prep_dec; 10..17 = wf1; 18..49 = wf2; 50..81 = wf3
__global__ void mega_prep(const int* __restrict__ batch,
                          const float* __restrict__ w1m, const float* __restrict__ w1l,
                          const float* __restrict__ b1m, const float* __restrict__ b1l,
                          const float* __restrict__ b3m, const float* __restrict__ b3l,
                          const float* __restrict__ w2m, const float* __restrict__ w2l,
                          const float* __restrict__ w3m, const float* __restrict__ w3l,
                          const float* __restrict__ nm_wo, const float* __restrict__ nm_bo,
                          const float* __restrict__ ex_w, const float* __restrict__ ex_b,
                          const float* __restrict__ fu_w, const float* __restrict__ fu_b,
                          const float* __restrict__ al_w, const float* __restrict__ al_b,
                          const float* __restrict__ sl_w, const float* __restrict__ sl_b,
                          const float* __restrict__ em_wo,
                          int* __restrict__ bcnt, float* __restrict__ bcat1,
                          float* __restrict__ bcat3, float* __restrict__ wtn,
                          float* __restrict__ bcn, float* __restrict__ wte,
                          unsigned int* __restrict__ wf1, unsigned int* __restrict__ wf2,
                          unsigned int* __restrict__ wf3) {
    int blk = blockIdx.x, t = threadIdx.x;
    if (blk == 0) {
        if (t < 128) bcat1[t] = (t < 64) ? b1m[t] : b1l[t - 64];
        else { int f = t - 128; bcat3[f] = (f < 64) ? b3m[f] : b3l[f - 64]; }
        if (t < BATCH_B) {
            int b = t;
            int lo = 0, hi = N_NODES;
            while (lo < hi) { int mid = (lo + hi) >> 1; if (batch[mid] < b) lo = mid + 1; else hi = mid; }
            int start = lo;
            lo = 0; hi = N_NODES;
            while (lo < hi) { int mid = (lo + hi) >> 1; if (batch[mid] <= b) lo = mid + 1; else hi = mid; }
            bcnt[b] = lo - start;
        }
    } else if (blk <= 9) {
        int idx = (blk - 1) * 256 + t;
        if (idx < 1024) {
            int j = idx >> 7, k = idx & 127;
            float s = 0.f;
            for (int m = 0; m < 128; m++) {
                float w = (j == 0) ? ex_w[m] : (j <= 5) ? fu_w[m * 5 + (j - 1)]
                         : (j == 6) ? al_w[m] : sl_w[m];
                s += nm_wo[k * 128 + m] * w;
            }
            wtn[j * 128 + k] = s;
        } else if (idx < 2048) {
            int i2 = idx - 1024;
            int j = i2 >> 7, k = i2 & 127;
            wte[j * 128 + k] = em_wo[k * 8 + j];
        } else if (idx < 2056) {
            int j = idx - 2048;
            float s = (j == 0) ? ex_b[0] : (j <= 5) ? fu_b[j - 1] : (j == 6) ? al_b[0] : sl_b[0];
            for (int m = 0; m < 128; m++) {
                float w = (j == 0) ? ex_w[m] : (j <= 5) ? fu_w[m * 5 + (j - 1)]
                         : (j == 6) ? al_w[m] : sl_w[m];
                s += nm_bo[m] * w;
            }
            bcn[j] = s;
        }
    } else if (blk <= 17) {     // wf1: K=32 (S=1), F=128 concat [w1m|w1l]
        if (t < 64) {
            int c = blk - 10;                 // 0..7
            int col = c * 16 + (t & 15);
            int k0 = (t >> 4) * 8;
            unsigned int q[4];
#pragma unroll
            for (int jj = 0; jj < 4; jj++) {
                int ka = k0 + 2 * jj, kb = ka + 1;
                float lo = (col < 64) ? w1m[ka * 64 + col] : w1l[ka * 64 + col - 64];
                float hi = (col < 64) ? w1m[kb * 64 + col] : w1l[kb * 64 + col - 64];
                q[jj] = (unsigned int)f2bf(lo) | ((unsigned int)f2bf(hi) << 16);
            }
            *(uint4*)&wf1[((size_t)c * 64 + t) * 4] = make_uint4(q[0], q[1], q[2], q[3]);
        }
    } else if (blk <= 49) {     // wf2: K=64 (S=2), F=128 (C=8), y in {0,1}
        if (t < 64) {
            int bc = blk - 18;                // (y*2+s)*8+c
            int c = bc % 8, s = (bc / 8) % 2, y = bc / 16;
            const float* W = y ? w2l : w2m;
            wfrag_write(W, 128, c * 16 + (t & 15), s * 32 + (t >> 4) * 8,
                        &wf2[((size_t)bc * 64 + t) * 4]);
        }
    } else {                    // wf3: K=128 (S=4), F=64 (C=4), y in {0,1}
        if (t < 64) {
            int bc = blk - 50;                // (y*4+s)*4+c
            int c = bc % 4, s = (bc / 4) % 4, y = bc / 16;
            const float* W = y ? w3l : w3m;
            wfrag_write(W, 64, c * 16 + (t & 15), s * 32 + (t >> 4) * 8,
                        &wf3[((size_t)bc * 64 + t) * 4]);
        }
    }
}

// ---- MFMA conv (L1 only): out[n] = fp8x32( dinv*relu(A@W + bias) ); f32 input
__global__ __launch_bounds__(256) void mfma_conv1(
    const float* __restrict__ inv, const unsigned int* __restrict__ wfrag,
    const float* __restrict__ bias, const float* __restrict__ dinv,
    unsigned int* __restrict__ outv, int N) {
    constexpr int C = 8;       // F=128
    constexpr int FP = 132;
    __shared__ unsigned short buf[4][16][FP];
    int t = threadIdx.x, lane = t & 63, wave = t >> 6;
    int n0 = blockIdx.x * 64 + wave * 16;

    f32x4 acc[C];
#pragma unroll
    for (int c = 0; c < C; c++) acc[c] = (f32x4)(0.f);

    int arow = n0 + (lane & 15);
    bool aok = arow < N;
    U4B af; af.u = make_uint4(0u, 0u, 0u, 0u);
    if (aok) {
        const float* ap = inv + (size_t)arow * 32 + (lane >> 4) * 8;
        float4 v0 = *(const float4*)ap;
        float4 v1 = *(const float4*)(ap + 4);
        af.u.x = (unsigned int)f2bf(v0.x) | ((unsigned int)f2bf(v0.y) << 16);
        af.u.y = (unsigned int)f2bf(v0.z) | ((unsigned int)f2bf(v0.w) << 16);
        af.u.z = (unsigned int)f2bf(v1.x) | ((unsigned int)f2bf(v1.y) << 16);
        af.u.w = (unsigned int)f2bf(v1.z) | ((unsigned int)f2bf(v1.w) << 16);
    }
#pragma unroll
    for (int c = 0; c < C; c++) {
        U4B wb;
        wb.u = *(const uint4*)&wfrag[((size_t)c * 64 + lane) * 4];
        acc[c] = __builtin_amdgcn_mfma_f32_16x16x32_bf16(af.b, wb.b, acc[c], 0, 0, 0);
    }

#pragma unroll
    for (int c = 0; c < C; c++) {
        int col = c * 16 + (lane & 15);
        float bv = bias[col];
#pragma unroll
        for (int r = 0; r < 4; r++) {
            int row = (lane >> 4) * 4 + r;
            int n = n0 + row;
            float v = fmaxf(acc[c][r] + bv, 0.f) * dinv[min(n, N - 1)];
            buf[wave][row][col] = f2bf(v);
        }
    }
    __syncthreads();

    for (int i = t; i < 64 * 16; i += 256) {   // CPR = 128/8 = 16
        int row = i / 16;
        int f0 = (i % 16) * 8;
        int n = blockIdx.x * 64 + row;
        if (n >= N) continue;
        const unsigned short* bp = &buf[row >> 4][row & 15][f0];
        uint2 a = *(const uint2*)bp;
        uint2 b = *(const uint2*)(bp + 4);
        float e0 = __uint_as_float(a.x << 16), e1 = __uint_as_float(a.x & 0xFFFF0000u);
        float e2 = __uint_as_float(a.y << 16), e3 = __uint_as_float(a.y & 0xFFFF0000u);
        float e4 = __uint_as_float(b.x << 16), e5 = __uint_as_float(b.x & 0xFFFF0000u);
        float e6 = __uint_as_float(b.y << 16), e7 = __uint_as_float(b.y & 0xFFFF0000u);
        unsigned int r0 = 0, r1 = 0;
        r0 = __builtin_amdgcn_cvt_pk_fp8_f32(e0 * 32.f, e1 * 32.f, r0, false);
        r0 = __builtin_amdgcn_cvt_pk_fp8_f32(e2 * 32.f, e3 * 32.f, r0, true);
        r1 = __builtin_amdgcn_cvt_pk_fp8_f32(e4 * 32.f, e5 * 32.f, r1, false);
        r1 = __builtin_amdgcn_cvt_pk_fp8_f32(e6 * 32.f, e7 * 32.f, r1, true);
        *(uint2*)((unsigned char*)outv + (size_t)n * 128 + f0) = make_uint2(r0, r1);
    }
}

// ---- fused L2+L3 conv: hB8 -> (L2, LDS) -> (L3) -> hD8. Per branch y; 64 rows/block.
__global__ __launch_bounds__(256) void conv23(
    const unsigned int* __restrict__ hB8, const unsigned int* __restrict__ wf2,
    const unsigned int* __restrict__ wf3, const float* __restrict__ b2m,
    const float* __restrict__ b2l, const float* __restrict__ dinv,
    unsigned int* __restrict__ hD8, int N) {
    __shared__ unsigned short hbuf[4][16][136];   // L2 out tile (wave-local)
    __shared__ unsigned short obuf[4][16][72];    // L3 out tile
    int t = threadIdx.x, lane = t & 63, wave = t >> 6;
    int y = blockIdx.y;
    int n0 = blockIdx.x * 64 + wave * 16;
    const float* bias = y ? b2l : b2m;
    const unsigned int* w2 = wf2 + (size_t)y * 2 * 8 * 64 * 4;
    const unsigned int* w3 = wf3 + (size_t)y * 4 * 4 * 64 * 4;

    // L2: K=64 (S=2), F=128 (C=8); input fp8 x32
    f32x4 acc2[8];
#pragma unroll
    for (int c = 0; c < 8; c++) acc2[c] = (f32x4)(0.f);
    int arow = n0 + (lane & 15);
    bool aok = arow < N;
#pragma unroll
    for (int s = 0; s < 2; s++) {
        U4B af; af.u = make_uint4(0u, 0u, 0u, 0u);
        if (aok) {
            uint2 u = *(const uint2*)((const unsigned char*)hB8 +
                        (size_t)arow * 128 + y * 64 + s * 32 + (lane >> 4) * 8);
            f8_to_bf2(u.x, af.u.x, af.u.y);
            f8_to_bf2(u.y, af.u.z, af.u.w);
        }
#pragma unroll
        for (int c = 0; c < 8; c++) {
            U4B wb;
            wb.u = *(const uint4*)&w2[((size_t)(s * 8 + c) * 64 + lane) * 4];
            acc2[c] = __builtin_amdgcn_mfma_f32_16x16x32_bf16(af.b, wb.b, acc2[c], 0, 0, 0);
        }
    }
    // L2 epilogue -> wave-local LDS (bf16), same rounding as old h256 path
#pragma unroll
    for (int c = 0; c < 8; c++) {
        int col = c * 16 + (lane & 15);
        float bv = bias[col];
#pragma unroll
        for (int r = 0; r < 4; r++) {
            int row = (lane >> 4) * 4 + r;
            float v = fmaxf(acc2[c][r] * (1.f / 32.f) + bv, 0.f);
            hbuf[wave][row][col] = f2bf(v);
        }
    }
    // wave-local LDS write->read: same-wave DS ops are in-order; no block barrier needed

    // L3: K=128 (S=4), F=64 (C=4); A from LDS bf16
    f32x4 acc3[4];
#pragma unroll
    for (int c = 0; c < 4; c++) acc3[c] = (f32x4)(0.f);
#pragma unroll
    for (int s = 0; s < 4; s++) {
        U4B af;
        af.u = *(const uint4*)&hbuf[wave][lane & 15][s * 32 + (lane >> 4) * 8];
#pragma unroll
        for (int c = 0; c < 4; c++) {
            U4B wb;
            wb.u = *(const uint4*)&w3[((size_t)(s * 4 + c) * 64 + lane) * 4];
            acc3[c] = __builtin_amdgcn_mfma_f32_16x16x32_bf16(af.b, wb.b, acc3[c], 0, 0, 0);
        }
    }
#pragma unroll
    for (int c = 0; c < 4; c++) {
        int col = c * 16 + (lane & 15);
#pragma unroll
        for (int r = 0; r < 4; r++) {
            int row = (lane >> 4) * 4 + r;
            int n = n0 + row;
            float v = acc3[c][r] * dinv[min(n, N - 1)];
            obuf[wave][row][col] = f2bf(v);
        }
    }
    __syncthreads();
    for (int i = t; i < 64 * 8; i += 256) {   // F=64 -> 8 chunks/row
        int row = i / 8;
        int f0 = (i % 8) * 8;
        int n = blockIdx.x * 64 + row;
        if (n >= N) continue;
        const unsigned short* bp = &obuf[row >> 4][row & 15][f0];
        uint2 a = *(const uint2*)bp;
        uint2 b = *(const uint2*)(bp + 4);
        float e0 = __uint_as_float(a.x << 16), e1 = __uint_as_float(a.x & 0xFFFF0000u);
        float e2 = __uint_as_float(a.y << 16), e3 = __uint_as_float(a.y & 0xFFFF0000u);
        float e4 = __uint_as_float(b.x << 16), e5 = __uint_as_float(b.x & 0xFFFF0000u);
        float e6 = __uint_as_float(b.y << 16), e7 = __uint_as_float(b.y & 0xFFFF0000u);
        unsigned int r0 = 0, r1 = 0;
        r0 = __builtin_amdgcn_cvt_pk_fp8_f32(e0 * 32.f, e1 * 32.f, r0, false);
        r0 = __builtin_amdgcn_cvt_pk_fp8_f32(e2 * 32.f, e3 * 32.f, r0, true);
        r1 = __builtin_amdgcn_cvt_pk_fp8_f32(e4 * 32.f, e5 * 32.f, r1, false);
        r1 = __builtin_amdgcn_cvt_pk_fp8_f32(e6 * 32.f, e7 * 32.f, r1, true);
        *(uint2*)((unsigned char*)hD8 + (size_t)n * 128 + y * 64 + f0) = make_uint2(r0, r1);
    }
}

#define POOL_CHUNK 128
// h is bf16-packed [n][64] uints
__global__ void pool128(const unsigned int* __restrict__ h, const int* __restrict__ batch,
                        float* __restrict__ sums, int n) {
    int f = threadIdx.x;  // 0..63
    int s0 = blockIdx.x * POOL_CHUNK;
    if (s0 >= n) return;
    int s1 = min(s0 + POOL_CHUNK, n);
    int cur = batch[s0];
    float a0 = 0.f, a1 = 0.f;
    for (int i = s0; i < s1; i++) {
        int b = batch[i];
        if (b != cur) {
            atomicAdd(&sums[cur * 128 + 2 * f], a0);
            atomicAdd(&sums[cur * 128 + 2 * f + 1], a1);
            a0 = a1 = 0.f; cur = b;
        }
        unsigned int u = h[(size_t)i * 64 + f];
        a0 += __uint_as_float(u << 16);
        a1 += __uint_as_float(u & 0xFFFF0000u);
    }
    atomicAdd(&sums[cur * 128 + 2 * f], a0);
    atomicAdd(&sums[cur * 128 + 2 * f + 1], a1);
}

// finalize pool + zwi fused: 16 blocks x 128 threads
__global__ void finalize_zwi(const float* __restrict__ sums, const int* __restrict__ bcnt,
                             const float* __restrict__ nm_wi, const float* __restrict__ nm_bi,
                             const float* __restrict__ em_wi, const float* __restrict__ em_bi,
                             float* __restrict__ out, float* __restrict__ zwi_nm,
                             float* __restrict__ zwi_em) {
    __shared__ float zs[64];
    int b = blockIdx.x, t = threadIdx.x;
    float c = fmaxf((float)bcnt[b], 1.f);
    float v = sums[b * 128 + t] / c;
    if (t < 64) { out[OUT_MU + b * 64 + t] = v; zs[t] = v; }
    else out[OUT_LG + b * 64 + (t - 64)] = v;
    __syncthreads();
    float an = nm_bi[t], ae = em_bi[t];
    for (int k = 0; k < 64; k++) {
        float zv = zs[k];
        an += zv * nm_wi[k * 128 + t];
        ae += zv * em_wi[k * 128 + t];
    }
    zwi_nm[b * 128 + t] = an;
    zwi_em[b * 128 + t] = ae;
}

#define D3_ROWS 32

// decoder3: layer1+LN -> LDS; heads/edges as 128-len LDS dots (heads pre-composed)
__global__ __launch_bounds__(256) void decoder3(
    const float* __restrict__ zwi_nm, const float* __restrict__ zwi_em,
    const float* __restrict__ nm_wi, const float* __restrict__ em_wi,
    const float* __restrict__ nm_g, const float* __restrict__ nm_be,
    const float* __restrict__ em_g, const float* __restrict__ em_be,
    const float* __restrict__ wtn, const float* __restrict__ bcn,
    const float* __restrict__ wte, const float* __restrict__ em_bo,
    const float* __restrict__ pos_all,
    float* __restrict__ out) {
    __shared__ float sn[D3_ROWS][132];
    __shared__ float se[D3_ROWS][132];
    __shared__ float Wn[8][132];
    __shared__ float We[8][132];
    int t = threadIdx.x;
    int lane = t & 63, wave = t >> 6;
    int rowBase = blockIdx.x * D3_ROWS;
    int b = rowBase >> 12;
    int row0 = rowBase + wave * 8;

    for (int i = t; i < 1024; i += 256) {
        Wn[i >> 7][i & 127] = wtn[i];
        We[i >> 7][i & 127] = wte[i];
    }

    int f0 = lane, f1 = lane + 64;
    float zn0 = zwi_nm[b * 128 + f0], zn1 = zwi_nm[b * 128 + f1];
    float ze0 = zwi_em[b * 128 + f0], ze1 = zwi_em[b * 128 + f1];
    float wn64_0 = nm_wi[64 * 128 + f0], wn64_1 = nm_wi[64 * 128 + f1];
    float wn65_0 = nm_wi[65 * 128 + f0], wn65_1 = nm_wi[65 * 128 + f1];
    float we64_0 = em_wi[64 * 128 + f0], we64_1 = em_wi[64 * 128 + f1];
    float we65_0 = em_wi[65 * 128 + f0], we65_1 = em_wi[65 * 128 + f1];
    float gn0 = nm_g[f0], gn1 = nm_g[f1], bn0 = nm_be[f0], bn1 = nm_be[f1];
    float ge0 = em_g[f0], ge1 = em_g[f1], be0 = em_be[f0], be1 = em_be[f1];

#pragma unroll
    for (int r = 0; r < 8; r++) {
        int row = row0 + r, i = row & (NMAXC - 1);
        float px = pos_all[i * 2], py = pos_all[i * 2 + 1];
        float a0 = zn0 + px * wn64_0 + py * wn65_0;
        float a1 = zn1 + px * wn64_1 + py * wn65_1;
        float e0 = ze0 + px * we64_0 + py * we65_0;
        float e1 = ze1 + px * we64_1 + py * we65_1;
        float sm = a0 + a1, sq = a0 * a0 + a1 * a1;
        float sme = e0 + e1, sqe = e0 * e0 + e1 * e1;
#pragma unroll
        for (int d = 1; d < 64; d <<= 1) {
            sm += __shfl_xor(sm, d); sq += __shfl_xor(sq, d);
            sme += __shfl_xor(sme, d); sqe += __shfl_xor(sqe, d);
        }
        float mean = sm * (1.f / 128.f);
        float var = sq * (1.f / 128.f) - mean * mean;
        float rstd = rsqrtf(var + 1e-5f);
        int rl = wave * 8 + r;
        sn[rl][f0] = fmaxf((a0 - mean) * rstd * gn0 + bn0, 0.f);
        sn[rl][f1] = fmaxf((a1 - mean) * rstd * gn1 + bn1, 0.f);
        float meane = sme * (1.f / 128.f);
        float vare = sqe * (1.f / 128.f) - meane * meane;
        float rstde = rsqrtf(vare + 1e-5f);
        se[rl][f0] = fmaxf((e0 - meane) * rstde * ge0 + be0, 0.f);
        se[rl][f1] = fmaxf((e1 - meane) * rstde * ge1 + be1, 0.f);
    }
    __syncthreads();

    int rl = t >> 3, j = t & 7;
    float accn = 0.f, acce = 0.f;
#pragma unroll 8
    for (int k4 = 0; k4 < 128; k4 += 4) {
        float4 sv = *(const float4*)&sn[rl][k4];
        float4 wv = *(const float4*)&Wn[j][k4];
        float4 sev = *(const float4*)&se[rl][k4];
        float4 wev = *(const float4*)&We[j][k4];
        accn += sv.x * wv.x + sv.y * wv.y + sv.z * wv.z + sv.w * wv.w;
        acce += sev.x * wev.x + sev.y * wev.y + sev.z * wev.z + sev.w * wev.w;
    }
    int row = rowBase + rl;
    accn += bcn[j];
    if (j == 0)       out[OUT_NODES + row] = accn;
    else if (j <= 5)  out[OUT_FUEL + (size_t)row * 5 + (j - 1)] = accn;
    else if (j == 6)  out[OUT_ALT + row] = accn;
    else              out[OUT_SLOPE + row] = accn;
    out[OUT_EDGES + (size_t)row * 8 + j] = acce + em_bo[j];
}

extern "C" void kernel_launch(void* const* d_in, const int* in_sizes, int n_in,
                              void* d_out, int out_size, void* d_ws, size_t ws_size,
                              hipStream_t stream) {
    const float* x    = (const float*)d_in[0];
    const int* edge   = (const int*)d_in[1];
    const int* batch  = (const int*)d_in[2];
    const float* w1m = (const float*)d_in[3];  const float* b1m = (const float*)d_in[4];
    const float* w2m = (const float*)d_in[5];  const float* b2m = (const float*)d_in[6];
    const float* w3m = (const float*)d_in[7];  const float* b3m = (const float*)d_in[8];
    const float* w1l = (const float*)d_in[9];  const float* b1l = (const float*)d_in[10];
    const float* w2l = (const float*)d_in[11]; const float* b2l = (const float*)d_in[12];
    const float* w3l = (const float*)d_in[13]; const float* b3l = (const float*)d_in[14];
    const float* nm_wi = (const float*)d_in[15]; const float* nm_bi = (const float*)d_in[16];
    const float* nm_g  = (const float*)d_in[17]; const float* nm_be = (const float*)d_in[18];
    const float* nm_wo = (const float*)d_in[19]; const float* nm_bo = (const float*)d_in[20];
    const float* ex_w = (const float*)d_in[21]; const float* ex_b = (const float*)d_in[22];
    const float* fu_w = (const float*)d_in[23]; const float* fu_b = (const float*)d_in[24];
    const float* al_w = (const float*)d_in[25]; const float* al_b = (const float*)d_in[26];
    const float* sl_w = (const float*)d_in[27]; const float* sl_b = (const float*)d_in[28];
    const float* em_wi = (const float*)d_in[29]; const float* em_bi = (const float*)d_in[30];
    const float* em_g  = (const float*)d_in[31]; const float* em_be = (const float*)d_in[32];
    const float* em_wo = (const float*)d_in[33]; const float* em_bo = (const float*)d_in[34];
    const float* pos_all = (const float*)d_in[35];
    float* out = (float*)d_out;

    char* p = (char*)d_ws;
    auto alloc = [&](size_t bytes) -> void* {
        void* r = (void*)p;
        p += ((bytes + 255) / 256) * 256;
        return r;
    };
    int* cnt      = (int*)alloc((size_t)N_NODES * 4);
    int* offs     = (int*)alloc((size_t)N_NODES * 4);
    float* dinv   = (float*)alloc((size_t)N_NODES * 4);
    int* bcnt     = (int*)alloc(BATCH_B * 4);
    float* sums   = (float*)alloc(BATCH_B * 128 * 4);
    float* zwi_nm = (float*)alloc(BATCH_B * 128 * 4);
    float* zwi_em = (float*)alloc(BATCH_B * 128 * 4);
    float* bcat1  = (float*)alloc(128 * 4);
    float* bcat3  = (float*)alloc(128 * 4);
    float* wtn    = (float*)alloc(8 * 128 * 4);
    float* bcn    = (float*)alloc(8 * 4);
    float* wte    = (float*)alloc(8 * 128 * 4);
    unsigned int* wf1 = (unsigned int*)alloc((size_t)8 * 64 * 4 * 4);           // 8 KB
    unsigned int* wf2 = (unsigned int*)alloc((size_t)32 * 64 * 4 * 4);          // 32 KB
    unsigned int* wf3 = (unsigned int*)alloc((size_t)32 * 64 * 4 * 4);          // 32 KB
    int* hist     = (int*)alloc((size_t)NBINS * NSB * 4);                      // 400 KB
    int* total    = (int*)alloc((size_t)NBINS * 4);
    int* base     = (int*)alloc((size_t)(NBINS + 1) * 4);
    unsigned int* sorted = (unsigned int*)alloc((size_t)N_EDGESC * 4);         // 6.4 MB
    int* adj      = (int*)alloc((size_t)(N_EDGESC + NBINS * BIN_PAD + 256) * 4); // 7.7 MB compact
    unsigned int* xs8 = (unsigned int*)alloc((size_t)N_NODES * 8 * 4);         // 3.2 MB fp8
    float* agg0   = (float*)alloc((size_t)N_NODES * 32 * 4);                   // 12.8 MB
    unsigned int* hA8 = (unsigned int*)alloc((size_t)N_NODES * 32 * 4);        // 12.8 MB fp8 (also hD8)
    unsigned int* hB8 = (unsigned int*)alloc((size_t)N_NODES * 32 * 4);        // 12.8 MB fp8
    unsigned short* final128 = (unsigned short*)alloc((size_t)N_NODES * 128 * 2);  // 25.6 MB bf16
    unsigned int* hD8 = hA8;  // hA8 dead after agg #1

    const int* srcp = edge;
    const int* dstp = edge + N_EDGESC;

    hipMemsetAsync(sums, 0, (size_t)BATCH_B * 128 * 4, stream);

    // all small prep work in one kernel (independent of CSR chain)
    mega_prep<<<82, 256, 0, stream>>>(batch, w1m, w1l, b1m, b1l, b3m, b3l,
                                      w2m, w2l, w3m, w3l, nm_wo, nm_bo,
                                      ex_w, ex_b, fu_w, fu_b, al_w, al_b, sl_w, sl_b,
                                      em_wo, bcnt, bcat1, bcat3, wtn, bcn, wte,
                                      wf1, wf2, wf3);

    // ---- CSR build: atomic-free counting sort -> compact aligned CSR (+fused prescale) ----
    histA<<<NSB, 1024, 0, stream>>>(dstp, hist);
    scanB<<<NBINS, NSB, 0, stream>>>(hist, total);
    scanC<<<1, 512, 0, stream>>>(total, base);
    scatterD<<<NSB, 1024, 0, stream>>>(srcp, dstp, hist, base, sorted);
    csr_compact<<<NBINS, 256, 0, stream>>>(sorted, base, x, adj, offs, cnt, dinv, xs8, N_NODES);

    // agg0 = S x  (shared by both branches), fp8 table
    agg_s32<<<(N_NODES + 31) / 32, 256, 0, stream>>>(xs8, cnt, offs, adj, dinv, agg0, N_NODES);

    const int GB = (N_NODES + 63) / 64;  // 1563 row blocks

    // L1 (fused mu|lg): hA8 = fp8x32( dinv * relu(agg0 @ [w1m|w1l] + bcat1) )  [MFMA]
    mfma_conv1<<<GB, 256, 0, stream>>>(agg0, wf1, bcat1, dinv, hA8, N_NODES);

    // agg #1: hB8 = fp8x32( [S mu1 | S lg1] )
    agg128<false, true><<<(N_NODES + 7) / 8, 256, 0, stream>>>(
        hA8, cnt, offs, adj, dinv, nullptr, hB8, N_NODES);

    // fused L2+L3: hD8 = fp8x32( dinv * ( relu(hB8@w2 + b2) @ w3 ) )  [MFMA, LDS mid]
    conv23<<<dim3(GB, 2), 256, 0, stream>>>(hB8, wf2, wf3, b2m, b2l, dinv, hD8, N_NODES);

    // agg #2: final = relu(dinv*(sum) + bcat3) = [mu3|lg3]  -> bf16 [n][128]
    agg128<true, false><<<(N_NODES + 7) / 8, 256, 0, stream>>>(
        hD8, cnt, offs, adj, dinv, bcat3, final128, N_NODES);

    pool128<<<(N_NODES + POOL_CHUNK - 1) / POOL_CHUNK, 64, 0, stream>>>(
        (const unsigned int*)final128, batch, sums, N_NODES);
    finalize_zwi<<<BATCH_B, 128, 0, stream>>>(sums, bcnt, nm_wi, nm_bi, em_wi, em_bi,
                                              out, zwi_nm, zwi_em);

    decoder3<<<BATCH_B * NMAXC / D3_ROWS, 256, 0, stream>>>(
        zwi_nm, zwi_em, nm_wi, em_wi, nm_g, nm_be, em_g, em_be,
        wtn, bcn, wte, em_bo, pos_all, out);
}

// Round 13
// 259.413 us; speedup vs baseline: 12.4118x; 1.0251x over previous
//
#include <hip/hip_runtime.h>
#include <hip/hip_bf16.h>

#define N_NODES 100000
#define N_EDGESC 1600000
#define BATCH_B 16
#define NMAXC 4096
#define LATC 64
#define NBINS 391   // ceil(100000/256): 256 nodes per bin
#define NSB 256     // sort blocks
#define EPB ((N_EDGESC + NSB - 1) / NSB)  // 6250 edges per sort block
#define BIN_PAD 768 // worst-case per-bin alignment padding (256 nodes x 3)

// output layout offsets (flat f32)
#define OUT_NODES 0
#define OUT_EDGES 65536
#define OUT_FUEL  589824
#define OUT_ALT   917504
#define OUT_SLOPE 983040
#define OUT_MU    1048576
#define OUT_LG    1049600

typedef float f32x2 __attribute__((ext_vector_type(2)));
typedef float f32x4 __attribute__((ext_vector_type(4)));
typedef short bf16x8 __attribute__((ext_vector_type(8)));
union U4B { uint4 u; bf16x8 b; };

__device__ __forceinline__ unsigned short f2bf(float f) {
    unsigned int u = __float_as_uint(f);
    return (unsigned short)((u + 0x7FFFu + ((u >> 16) & 1u)) >> 16);  // RNE
}
__device__ __forceinline__ float bf2f(unsigned short h) {
    return __uint_as_float(((unsigned int)h) << 16);
}
__device__ __forceinline__ void f8acc(unsigned int u, float& a0, float& a1, float& a2, float& a3) {
    f32x2 lo = __builtin_amdgcn_cvt_pk_f32_fp8(u, false);
    f32x2 hi = __builtin_amdgcn_cvt_pk_f32_fp8(u, true);
    a0 += lo[0]; a1 += lo[1]; a2 += hi[0]; a3 += hi[1];
}
// decode 4 fp8 -> bf16x2 pair packed in 2 uints
__device__ __forceinline__ void f8_to_bf2(unsigned int u, unsigned int& q0, unsigned int& q1) {
    f32x2 lo = __builtin_amdgcn_cvt_pk_f32_fp8(u, false);
    f32x2 hi = __builtin_amdgcn_cvt_pk_f32_fp8(u, true);
    q0 = (unsigned int)f2bf(lo[0]) | ((unsigned int)f2bf(lo[1]) << 16);
    q1 = (unsigned int)f2bf(hi[0]) | ((unsigned int)f2bf(hi[1]) << 16);
}

// ---- CSR build via atomic-free counting sort by dst>>8 ----
__global__ __launch_bounds__(1024) void histA(const int* __restrict__ dst, int* __restrict__ hist) {
    __shared__ int h[NBINS];
    int b = blockIdx.x, t = threadIdx.x;
    for (int i = t; i < NBINS; i += 1024) h[i] = 0;
    __syncthreads();
    int e0 = b * EPB, e1 = min(e0 + EPB, N_EDGESC);
    for (int i = e0 + t; i < e1; i += 1024)
        atomicAdd(&h[dst[i] >> 8], 1);
    __syncthreads();
    for (int i = t; i < NBINS; i += 1024) hist[i * NSB + b] = h[i];
}

__global__ void scanB(int* __restrict__ hist, int* __restrict__ total) {
    __shared__ int sh[NSB];
    int j = blockIdx.x, t = threadIdx.x;  // 256 threads
    int v = hist[j * NSB + t];
    sh[t] = v; __syncthreads();
    for (int off = 1; off < NSB; off <<= 1) {
        int u = (t >= off) ? sh[t - off] : 0; __syncthreads();
        sh[t] += u; __syncthreads();
    }
    hist[j * NSB + t] = sh[t] - v;
    if (t == NSB - 1) total[j] = sh[t];
}

__global__ void scanC(const int* __restrict__ total, int* __restrict__ base) {
    __shared__ int sh[512];
    int t = threadIdx.x;
    int v = (t < NBINS) ? total[t] : 0;
    sh[t] = v; __syncthreads();
    for (int off = 1; off < 512; off <<= 1) {
        int u = (t >= off) ? sh[t - off] : 0; __syncthreads();
        sh[t] += u; __syncthreads();
    }
    if (t < NBINS) base[t] = sh[t] - v;
    if (t == NBINS - 1) base[NBINS] = sh[t];
}

__global__ __launch_bounds__(1024) void scatterD(const int* __restrict__ src, const int* __restrict__ dst,
                                                 const int* __restrict__ hist, const int* __restrict__ base,
                                                 unsigned int* __restrict__ sorted) {
    __shared__ int w0[NBINS];
    __shared__ int lc[NBINS];
    int b = blockIdx.x, t = threadIdx.x;
    for (int i = t; i < NBINS; i += 1024) {
        w0[i] = base[i] + hist[i * NSB + b];
        lc[i] = 0;
    }
    __syncthreads();
    int e0 = b * EPB, e1 = min(e0 + EPB, N_EDGESC);
    for (int i = e0 + t; i < e1; i += 1024) {
        int d = dst[i], s = src[i];
        int j = d >> 8;
        int r = atomicAdd(&lc[j], 1);
        sorted[w0[j] + r] = ((unsigned int)s << 8) | (d & 255);
    }
}

// compact CSR with 16B-aligned per-node lists + fused fp8 prescale of x
__global__ void csr_compact(const unsigned int* __restrict__ sorted, const int* __restrict__ base,
                            const float* __restrict__ x,
                            int* __restrict__ adj, int* __restrict__ offs,
                            int* __restrict__ cnt, float* __restrict__ dinv,
                            unsigned int* __restrict__ xs8, int N) {
    __shared__ int lc[256];
    __shared__ int cur[256];
    __shared__ int so4[256];
    int j = blockIdx.x, t = threadIdx.x;
    lc[t] = 0; cur[t] = 0;
    __syncthreads();
    int e0 = base[j], e1 = base[j + 1];
    for (int i = e0 + t; i < e1; i += 256)
        atomicAdd(&lc[sorted[i] & 255], 1);
    __syncthreads();
    int c4 = (lc[t] + 3) & ~3;   // align each list to 4 entries (16B)
    so4[t] = c4;
    __syncthreads();
    for (int off = 1; off < 256; off <<= 1) {
        int u = (t >= off) ? so4[t - off] : 0; __syncthreads();
        so4[t] += u; __syncthreads();
    }
    int mybase = base[j] + j * BIN_PAD + so4[t] - c4;  // exclusive, aligned
    __syncthreads();
    so4[t] = mybase;
    __syncthreads();
    for (int i = e0 + t; i < e1; i += 256) {
        unsigned int pk = sorted[i];
        int d = pk & 255;
        int r = atomicAdd(&cur[d], 1);
        adj[so4[d] + r] = (int)(pk >> 8);
    }
    int n = j * 256 + t;
    if (n < N) {
        int c = lc[t];
        cnt[n] = c;
        offs[n] = so4[t];
        float dv = rsqrtf((float)(c + 1));  // +1 = self loop
        dinv[n] = dv;
        // fused prescale: xs8[n] = fp8(64 * dinv * x[n][0..31])
        float ds = dv * 64.f;
        const float* xr = &x[(size_t)n * 32];
        unsigned int q[8];
#pragma unroll
        for (int jj = 0; jj < 8; jj++) {
            float4 v = *(const float4*)&xr[jj * 4];
            unsigned int r8 = 0;
            r8 = __builtin_amdgcn_cvt_pk_fp8_f32(v.x * ds, v.y * ds, r8, false);
            r8 = __builtin_amdgcn_cvt_pk_fp8_f32(v.z * ds, v.w * ds, r8, true);
            q[jj] = r8;
        }
        *(uint4*)&xs8[(size_t)n * 8] = make_uint4(q[0], q[1], q[2], q[3]);
        *(uint4*)&xs8[(size_t)n * 8 + 4] = make_uint4(q[4], q[5], q[6], q[7]);
    }
}

// agg0 = S x : fp8 table [n][8] uints; 32 nodes per 256-thread block, 8 lanes/node
// output bf16 [n][32] (same rounding point as the old f32->bf16 conversion in conv1)
__global__ void agg_s32(const unsigned int* __restrict__ xs8, const int* __restrict__ cnt,
                        const int* __restrict__ offs, const int* __restrict__ adj,
                        const float* __restrict__ dinv, unsigned short* __restrict__ outb, int N) {
    int t = threadIdx.x;
    int sub = t >> 3, f = t & 7;
    int n = blockIdx.x * 32 + sub;
    if (n >= N) return;
    float s0 = 0.f, s1 = 0.f, s2 = 0.f, s3 = 0.f;
    f8acc(xs8[(size_t)n * 8 + f], s0, s1, s2, s3);
    int e = offs[n];
    int e1 = e + cnt[n];
    for (; e + 8 <= e1; e += 8) {
        int4 ia = *(const int4*)&adj[e];
        int4 ib = *(const int4*)&adj[e + 4];
        unsigned int u0 = xs8[(size_t)ia.x * 8 + f];
        unsigned int u1 = xs8[(size_t)ia.y * 8 + f];
        unsigned int u2 = xs8[(size_t)ia.z * 8 + f];
        unsigned int u3 = xs8[(size_t)ia.w * 8 + f];
        unsigned int u4 = xs8[(size_t)ib.x * 8 + f];
        unsigned int u5 = xs8[(size_t)ib.y * 8 + f];
        unsigned int u6 = xs8[(size_t)ib.z * 8 + f];
        unsigned int u7 = xs8[(size_t)ib.w * 8 + f];
        f8acc(u0, s0, s1, s2, s3); f8acc(u1, s0, s1, s2, s3);
        f8acc(u2, s0, s1, s2, s3); f8acc(u3, s0, s1, s2, s3);
        f8acc(u4, s0, s1, s2, s3); f8acc(u5, s0, s1, s2, s3);
        f8acc(u6, s0, s1, s2, s3); f8acc(u7, s0, s1, s2, s3);
    }
    if (e + 4 <= e1) {
        int4 ia = *(const int4*)&adj[e];
        unsigned int u0 = xs8[(size_t)ia.x * 8 + f];
        unsigned int u1 = xs8[(size_t)ia.y * 8 + f];
        unsigned int u2 = xs8[(size_t)ia.z * 8 + f];
        unsigned int u3 = xs8[(size_t)ia.w * 8 + f];
        f8acc(u0, s0, s1, s2, s3); f8acc(u1, s0, s1, s2, s3);
        f8acc(u2, s0, s1, s2, s3); f8acc(u3, s0, s1, s2, s3);
        e += 4;
    }
    for (; e < e1; e++) f8acc(xs8[(size_t)adj[e] * 8 + f], s0, s1, s2, s3);
    float d = dinv[n] * (1.f / 64.f);
    ushort4 o;
    o.x = f2bf(s0 * d); o.y = f2bf(s1 * d); o.z = f2bf(s2 * d); o.w = f2bf(s3 * d);
    *(ushort4*)&outb[(size_t)n * 32 + f * 4] = o;
}

// 128-dim fp8-table aggregation (table pre-scaled x32); 8 nodes/block, 32 lanes/node
template <bool BIASRELU, bool OUT8>
__global__ void agg128(const unsigned int* __restrict__ tbl, const int* __restrict__ cnt,
                       const int* __restrict__ offs, const int* __restrict__ adj,
                       const float* __restrict__ dinv, const float* __restrict__ bias,
                       void* __restrict__ outv, int N) {
    int t = threadIdx.x;
    int sub = t >> 5, f = t & 31;
    int n = blockIdx.x * 8 + sub;
    if (n >= N) return;
    float s0 = 0.f, s1 = 0.f, s2 = 0.f, s3 = 0.f;
    f8acc(tbl[(size_t)n * 32 + f], s0, s1, s2, s3);
    int e = offs[n];
    int e1 = e + cnt[n];
    for (; e + 8 <= e1; e += 8) {
        int4 ia = *(const int4*)&adj[e];
        int4 ib = *(const int4*)&adj[e + 4];
        unsigned int u0 = tbl[(size_t)ia.x * 32 + f];
        unsigned int u1 = tbl[(size_t)ia.y * 32 + f];
        unsigned int u2 = tbl[(size_t)ia.z * 32 + f];
        unsigned int u3 = tbl[(size_t)ia.w * 32 + f];
        unsigned int u4 = tbl[(size_t)ib.x * 32 + f];
        unsigned int u5 = tbl[(size_t)ib.y * 32 + f];
        unsigned int u6 = tbl[(size_t)ib.z * 32 + f];
        unsigned int u7 = tbl[(size_t)ib.w * 32 + f];
        f8acc(u0, s0, s1, s2, s3); f8acc(u1, s0, s1, s2, s3);
        f8acc(u2, s0, s1, s2, s3); f8acc(u3, s0, s1, s2, s3);
        f8acc(u4, s0, s1, s2, s3); f8acc(u5, s0, s1, s2, s3);
        f8acc(u6, s0, s1, s2, s3); f8acc(u7, s0, s1, s2, s3);
    }
    if (e + 4 <= e1) {
        int4 ia = *(const int4*)&adj[e];
        unsigned int u0 = tbl[(size_t)ia.x * 32 + f];
        unsigned int u1 = tbl[(size_t)ia.y * 32 + f];
        unsigned int u2 = tbl[(size_t)ia.z * 32 + f];
        unsigned int u3 = tbl[(size_t)ia.w * 32 + f];
        f8acc(u0, s0, s1, s2, s3); f8acc(u1, s0, s1, s2, s3);
        f8acc(u2, s0, s1, s2, s3); f8acc(u3, s0, s1, s2, s3);
        e += 4;
    }
    for (; e < e1; e++) f8acc(tbl[(size_t)adj[e] * 32 + f], s0, s1, s2, s3);
    float d = dinv[n] * (1.f / 32.f);
    float v0 = s0 * d, v1 = s1 * d, v2 = s2 * d, v3 = s3 * d;
    if (BIASRELU) {
        float4 bv = *(const float4*)&bias[4 * f];
        v0 = fmaxf(v0 + bv.x, 0.f); v1 = fmaxf(v1 + bv.y, 0.f);
        v2 = fmaxf(v2 + bv.z, 0.f); v3 = fmaxf(v3 + bv.w, 0.f);
    }
    if (OUT8) {
        unsigned int r = 0;
        r = __builtin_amdgcn_cvt_pk_fp8_f32(v0 * 32.f, v1 * 32.f, r, false);
        r = __builtin_amdgcn_cvt_pk_fp8_f32(v2 * 32.f, v3 * 32.f, r, true);
        ((unsigned int*)outv)[(size_t)n * 32 + f] = r;
    } else {
        ushort4 u;
        u.x = f2bf(v0); u.y = f2bf(v1); u.z = f2bf(v2); u.w = f2bf(v3);
        *(ushort4*)&((unsigned short*)outv)[(size_t)n * 128 + 4 * f] = u;
    }
}

// device helper: pack one B-fragment quad from f32 weight matrix
__device__ __forceinline__ void wfrag_write(const float* W, int F, int col, int k0,
                                            unsigned int* dst) {
    unsigned int q[4];
#pragma unroll
    for (int jj = 0; jj < 4; jj++) {
        float lo = W[(size_t)(k0 + 2 * jj) * F + col];
        float hi = W[(size_t)(k0 + 2 * jj + 1) * F + col];
        q[jj] = (unsigned int)f2bf(lo) | ((unsigned int)f2bf(hi) << 16);
    }
    *(uint4*)dst = make_uint4(q[0], q[1], q[2], q[3]);
}

// ---- mega-prep: batch_count + bias concats + head composition + weight fragments ----
__global__ void mega_prep(const int* __restrict__ batch,
                          const float* __restrict__ w1m, const float* __restrict__ w1l,
                          const float* __restrict__ b1m, const float* __restrict__ b1l,
                          const float* __restrict__ b3m, const float* __restrict__ b3l,
                          const float* __restrict__ w2m, const float* __restrict__ w2l,
                          const float* __restrict__ w3m, const float* __restrict__ w3l,
                          const float* __restrict__ nm_wo, const float* __restrict__ nm_bo,
                          const float* __restrict__ ex_w, const float* __restrict__ ex_b,
                          const float* __restrict__ fu_w, const float* __restrict__ fu_b,
                          const float* __restrict__ al_w, const float* __restrict__ al_b,
                          const float* __restrict__ sl_w, const float* __restrict__ sl_b,
                          const float* __restrict__ em_wo,
                          int* __restrict__ bcnt, float* __restrict__ bcat1,
                          float* __restrict__ bcat3, float* __restrict__ wtn,
                          float* __restrict__ bcn, float* __restrict__ wte,
                          unsigned int* __restrict__ wf1, unsigned int* __restrict__ wf2,
                          unsigned int* __restrict__ wf3) {
    int blk = blockIdx.x, t = threadIdx.x;
    if (blk == 0) {
        if (t < 128) bcat1[t] = (t < 64) ? b1m[t] : b1l[t - 64];
        else { int f = t - 128; bcat3[f] = (f < 64) ? b3m[f] : b3l[f - 64]; }
        if (t < BATCH_B) {
            int b = t;
            int lo = 0, hi = N_NODES;
            while (lo < hi) { int mid = (lo + hi) >> 1; if (batch[mid] < b) lo = mid + 1; else hi = mid; }
            int start = lo;
            lo = 0; hi = N_NODES;
            while (lo < hi) { int mid = (lo + hi) >> 1; if (batch[mid] <= b) lo = mid + 1; else hi = mid; }
            bcnt[b] = lo - start;
        }
    } else if (blk <= 9) {
        int idx = (blk - 1) * 256 + t;
        if (idx < 1024) {
            int j = idx >> 7, k = idx & 127;
            float s = 0.f;
            for (int m = 0; m < 128; m++) {
                float w = (j == 0) ? ex_w[m] : (j <= 5) ? fu_w[m * 5 + (j - 1)]
                         : (j == 6) ? al_w[m] : sl_w[m];
                s += nm_wo[k * 128 + m] * w;
            }
            wtn[j * 128 + k] = s;
        } else if (idx < 2048) {
            int i2 = idx - 1024;
            int j = i2 >> 7, k = i2 & 127;
            wte[j * 128 + k] = em_wo[k * 8 + j];
        } else if (idx < 2056) {
            int j = idx - 2048;
            float s = (j == 0) ? ex_b[0] : (j <= 5) ? fu_b[j - 1] : (j == 6) ? al_b[0] : sl_b[0];
            for (int m = 0; m < 128; m++) {
                float w = (j == 0) ? ex_w[m] : (j <= 5) ? fu_w[m * 5 + (j - 1)]
                         : (j == 6) ? al_w[m] : sl_w[m];
                s += nm_bo[m] * w;
            }
            bcn[j] = s;
        }
    } else if (blk <= 17) {     // wf1: K=32 (S=1), F=128 concat [w1m|w1l]
        if (t < 64) {
            int c = blk - 10;
            int col = c * 16 + (t & 15);
            int k0 = (t >> 4) * 8;
            unsigned int q[4];
#pragma unroll
            for (int jj = 0; jj < 4; jj++) {
                int ka = k0 + 2 * jj, kb = ka + 1;
                float lo = (col < 64) ? w1m[ka * 64 + col] : w1l[ka * 64 + col - 64];
                float hi = (col < 64) ? w1m[kb * 64 + col] : w1l[kb * 64 + col - 64];
                q[jj] = (unsigned int)f2bf(lo) | ((unsigned int)f2bf(hi) << 16);
            }
            *(uint4*)&wf1[((size_t)c * 64 + t) * 4] = make_uint4(q[0], q[1], q[2], q[3]);
        }
    } else if (blk <= 49) {     // wf2: K=64 (S=2), F=128 (C=8), y in {0,1}
        if (t < 64) {
            int bc = blk - 18;
            int c = bc % 8, s = (bc / 8) % 2, y = bc / 16;
            const float* W = y ? w2l : w2m;
            wfrag_write(W, 128, c * 16 + (t & 15), s * 32 + (t >> 4) * 8,
                        &wf2[((size_t)bc * 64 + t) * 4]);
        }
    } else {                    // wf3: K=128 (S=4), F=64 (C=4), y in {0,1}
        if (t < 64) {
            int bc = blk - 50;
            int c = bc % 4, s = (bc / 4) % 4, y = bc / 16;
            const float* W = y ? w3l : w3m;
            wfrag_write(W, 64, c * 16 + (t & 15), s * 32 + (t >> 4) * 8,
                        &wf3[((size_t)bc * 64 + t) * 4]);
        }
    }
}

// ---- MFMA conv (L1): out[n] = fp8x32( dinv*relu(A@W + bias) ); bf16 input [n][32]
__global__ __launch_bounds__(256) void mfma_conv1(
    const unsigned short* __restrict__ inv, const unsigned int* __restrict__ wfrag,
    const float* __restrict__ bias, const float* __restrict__ dinv,
    unsigned int* __restrict__ outv, int N) {
    constexpr int C = 8;       // F=128
    constexpr int FP = 132;
    __shared__ unsigned short buf[4][16][FP];
    int t = threadIdx.x, lane = t & 63, wave = t >> 6;
    int n0 = blockIdx.x * 64 + wave * 16;

    f32x4 acc[C];
#pragma unroll
    for (int c = 0; c < C; c++) acc[c] = (f32x4)(0.f);

    int arow = n0 + (lane & 15);
    bool aok = arow < N;
    U4B af; af.u = make_uint4(0u, 0u, 0u, 0u);
    if (aok)
        af.u = *(const uint4*)(inv + (size_t)arow * 32 + (lane >> 4) * 8);
#pragma unroll
    for (int c = 0; c < C; c++) {
        U4B wb;
        wb.u = *(const uint4*)&wfrag[((size_t)c * 64 + lane) * 4];
        acc[c] = __builtin_amdgcn_mfma_f32_16x16x32_bf16(af.b, wb.b, acc[c], 0, 0, 0);
    }

#pragma unroll
    for (int c = 0; c < C; c++) {
        int col = c * 16 + (lane & 15);
        float bv = bias[col];
#pragma unroll
        for (int r = 0; r < 4; r++) {
            int row = (lane >> 4) * 4 + r;
            int n = n0 + row;
            float v = fmaxf(acc[c][r] + bv, 0.f) * dinv[min(n, N - 1)];
            buf[wave][row][col] = f2bf(v);
        }
    }
    __syncthreads();

    for (int i = t; i < 64 * 16; i += 256) {   // CPR = 128/8 = 16
        int row = i / 16;
        int f0 = (i % 16) * 8;
        int n = blockIdx.x * 64 + row;
        if (n >= N) continue;
        const unsigned short* bp = &buf[row >> 4][row & 15][f0];
        uint2 a = *(const uint2*)bp;
        uint2 b = *(const uint2*)(bp + 4);
        float e0 = __uint_as_float(a.x << 16), e1 = __uint_as_float(a.x & 0xFFFF0000u);
        float e2 = __uint_as_float(a.y << 16), e3 = __uint_as_float(a.y & 0xFFFF0000u);
        float e4 = __uint_as_float(b.x << 16), e5 = __uint_as_float(b.x & 0xFFFF0000u);
        float e6 = __uint_as_float(b.y << 16), e7 = __uint_as_float(b.y & 0xFFFF0000u);
        unsigned int r0 = 0, r1 = 0;
        r0 = __builtin_amdgcn_cvt_pk_fp8_f32(e0 * 32.f, e1 * 32.f, r0, false);
        r0 = __builtin_amdgcn_cvt_pk_fp8_f32(e2 * 32.f, e3 * 32.f, r0, true);
        r1 = __builtin_amdgcn_cvt_pk_fp8_f32(e4 * 32.f, e5 * 32.f, r1, false);
        r1 = __builtin_amdgcn_cvt_pk_fp8_f32(e6 * 32.f, e7 * 32.f, r1, true);
        *(uint2*)((unsigned char*)outv + (size_t)n * 128 + f0) = make_uint2(r0, r1);
    }
}

// ---- fused L2+L3 conv: hB8 -> (L2, LDS) -> (L3) -> hD8. Per branch y; 64 rows/block.
__global__ __launch_bounds__(256) void conv23(
    const unsigned int* __restrict__ hB8, const unsigned int* __restrict__ wf2,
    const unsigned int* __restrict__ wf3, const float* __restrict__ b2m,
    const float* __restrict__ b2l, const float* __restrict__ dinv,
    unsigned int* __restrict__ hD8, int N) {
    __shared__ unsigned short hbuf[4][16][136];   // L2 out tile (wave-local)
    __shared__ unsigned short obuf[4][16][72];    // L3 out tile
    int t = threadIdx.x, lane = t & 63, wave = t >> 6;
    int y = blockIdx.y;
    int n0 = blockIdx.x * 64 + wave * 16;
    const float* bias = y ? b2l : b2m;
    const unsigned int* w2 = wf2 + (size_t)y * 2 * 8 * 64 * 4;
    const unsigned int* w3 = wf3 + (size_t)y * 4 * 4 * 64 * 4;

    f32x4 acc2[8];
#pragma unroll
    for (int c = 0; c < 8; c++) acc2[c] = (f32x4)(0.f);
    int arow = n0 + (lane & 15);
    bool aok = arow < N;
#pragma unroll
    for (int s = 0; s < 2; s++) {
        U4B af; af.u = make_uint4(0u, 0u, 0u, 0u);
        if (aok) {
            uint2 u = *(const uint2*)((const unsigned char*)hB8 +
                        (size_t)arow * 128 + y * 64 + s * 32 + (lane >> 4) * 8);
            f8_to_bf2(u.x, af.u.x, af.u.y);
            f8_to_bf2(u.y, af.u.z, af.u.w);
        }
#pragma unroll
        for (int c = 0; c < 8; c++) {
            U4B wb;
            wb.u = *(const uint4*)&w2[((size_t)(s * 8 + c) * 64 + lane) * 4];
            acc2[c] = __builtin_amdgcn_mfma_f32_16x16x32_bf16(af.b, wb.b, acc2[c], 0, 0, 0);
        }
    }
#pragma unroll
    for (int c = 0; c < 8; c++) {
        int col = c * 16 + (lane & 15);
        float bv = bias[col];
#pragma unroll
        for (int r = 0; r < 4; r++) {
            int row = (lane >> 4) * 4 + r;
            float v = fmaxf(acc2[c][r] * (1.f / 32.f) + bv, 0.f);
            hbuf[wave][row][col] = f2bf(v);
        }
    }
    // wave-local LDS write->read: same-wave DS ops are in-order; no block barrier needed

    f32x4 acc3[4];
#pragma unroll
    for (int c = 0; c < 4; c++) acc3[c] = (f32x4)(0.f);
#pragma unroll
    for (int s = 0; s < 4; s++) {
        U4B af;
        af.u = *(const uint4*)&hbuf[wave][lane & 15][s * 32 + (lane >> 4) * 8];
#pragma unroll
        for (int c = 0; c < 4; c++) {
            U4B wb;
            wb.u = *(const uint4*)&w3[((size_t)(s * 4 + c) * 64 + lane) * 4];
            acc3[c] = __builtin_amdgcn_mfma_f32_16x16x32_bf16(af.b, wb.b, acc3[c], 0, 0, 0);
        }
    }
#pragma unroll
    for (int c = 0; c < 4; c++) {
        int col = c * 16 + (lane & 15);
#pragma unroll
        for (int r = 0; r < 4; r++) {
            int row = (lane >> 4) * 4 + r;
            int n = n0 + row;
            float v = acc3[c][r] * dinv[min(n, N - 1)];
            obuf[wave][row][col] = f2bf(v);
        }
    }
    __syncthreads();
    for (int i = t; i < 64 * 8; i += 256) {   // F=64 -> 8 chunks/row
        int row = i / 8;
        int f0 = (i % 8) * 8;
        int n = blockIdx.x * 64 + row;
        if (n >= N) continue;
        const unsigned short* bp = &obuf[row >> 4][row & 15][f0];
        uint2 a = *(const uint2*)bp;
        uint2 b = *(const uint2*)(bp + 4);
        float e0 = __uint_as_float(a.x << 16), e1 = __uint_as_float(a.x & 0xFFFF0000u);
        float e2 = __uint_as_float(a.y << 16), e3 = __uint_as_float(a.y & 0xFFFF0000u);
        float e4 = __uint_as_float(b.x << 16), e5 = __uint_as_float(b.x & 0xFFFF0000u);
        float e6 = __uint_as_float(b.y << 16), e7 = __uint_as_float(b.y & 0xFFFF0000u);
        unsigned int r0 = 0, r1 = 0;
        r0 = __builtin_amdgcn_cvt_pk_fp8_f32(e0 * 32.f, e1 * 32.f, r0, false);
        r0 = __builtin_amdgcn_cvt_pk_fp8_f32(e2 * 32.f, e3 * 32.f, r0, true);
        r1 = __builtin_amdgcn_cvt_pk_fp8_f32(e4 * 32.f, e5 * 32.f, r1, false);
        r1 = __builtin_amdgcn_cvt_pk_fp8_f32(e6 * 32.f, e7 * 32.f, r1, true);
        *(uint2*)((unsigned char*)hD8 + (size_t)n * 128 + y * 64 + f0) = make_uint2(r0, r1);
    }
}

// parallel pooled sum: 4 waves/block, each wave reduces 16 rows (run-detected on sorted batch)
__global__ __launch_bounds__(256) void pool128(const unsigned int* __restrict__ h,
                                               const int* __restrict__ batch,
                                               float* __restrict__ sums, int n) {
    int t = threadIdx.x, lane = t & 63, wave = t >> 6;
    int r0 = blockIdx.x * 64 + wave * 16;
    if (r0 >= n) return;
    int r1 = min(r0 + 16, n);
    int cur = batch[r0];
    float a0 = 0.f, a1 = 0.f;
    for (int i = r0; i < r1; i++) {
        int b = batch[i];
        if (b != cur) {
            atomicAdd(&sums[cur * 128 + 2 * lane], a0);
            atomicAdd(&sums[cur * 128 + 2 * lane + 1], a1);
            a0 = a1 = 0.f; cur = b;
        }
        unsigned int u = h[(size_t)i * 64 + lane];
        a0 += __uint_as_float(u << 16);
        a1 += __uint_as_float(u & 0xFFFF0000u);
    }
    atomicAdd(&sums[cur * 128 + 2 * lane], a0);
    atomicAdd(&sums[cur * 128 + 2 * lane + 1], a1);
}

// finalize pool + zwi fused: 16 blocks x 128 threads
__global__ void finalize_zwi(const float* __restrict__ sums, const int* __restrict__ bcnt,
                             const float* __restrict__ nm_wi, const float* __restrict__ nm_bi,
                             const float* __restrict__ em_wi, const float* __restrict__ em_bi,
                             float* __restrict__ out, float* __restrict__ zwi_nm,
                             float* __restrict__ zwi_em) {
    __shared__ float zs[64];
    int b = blockIdx.x, t = threadIdx.x;
    float c = fmaxf((float)bcnt[b], 1.f);
    float v = sums[b * 128 + t] / c;
    if (t < 64) { out[OUT_MU + b * 64 + t] = v; zs[t] = v; }
    else out[OUT_LG + b * 64 + (t - 64)] = v;
    __syncthreads();
    float an = nm_bi[t], ae = em_bi[t];
    for (int k = 0; k < 64; k++) {
        float zv = zs[k];
        an += zv * nm_wi[k * 128 + t];
        ae += zv * em_wi[k * 128 + t];
    }
    zwi_nm[b * 128 + t] = an;
    zwi_em[b * 128 + t] = ae;
}

#define D3_ROWS 32

// decoder3: layer1+LN -> LDS; heads/edges as 128-len LDS dots (heads pre-composed)
__global__ __launch_bounds__(256) void decoder3(
    const float* __restrict__ zwi_nm, const float* __restrict__ zwi_em,
    const float* __restrict__ nm_wi, const float* __restrict__ em_wi,
    const float* __restrict__ nm_g, const float* __restrict__ nm_be,
    const float* __restrict__ em_g, const float* __restrict__ em_be,
    const float* __restrict__ wtn, const float* __restrict__ bcn,
    const float* __restrict__ wte, const float* __restrict__ em_bo,
    const float* __restrict__ pos_all,
    float* __restrict__ out) {
    __shared__ float sn[D3_ROWS][132];
    __shared__ float se[D3_ROWS][132];
    __shared__ float Wn[8][132];
    __shared__ float We[8][132];
    int t = threadIdx.x;
    int lane = t & 63, wave = t >> 6;
    int rowBase = blockIdx.x * D3_ROWS;
    int b = rowBase >> 12;
    int row0 = rowBase + wave * 8;

    for (int i = t; i < 1024; i += 256) {
        Wn[i >> 7][i & 127] = wtn[i];
        We[i >> 7][i & 127] = wte[i];
    }

    int f0 = lane, f1 = lane + 64;
    float zn0 = zwi_nm[b * 128 + f0], zn1 = zwi_nm[b * 128 + f1];
    float ze0 = zwi_em[b * 128 + f0], ze1 = zwi_em[b * 128 + f1];
    float wn64_0 = nm_wi[64 * 128 + f0], wn64_1 = nm_wi[64 * 128 + f1];
    float wn65_0 = nm_wi[65 * 128 + f0], wn65_1 = nm_wi[65 * 128 + f1];
    float we64_0 = em_wi[64 * 128 + f0], we64_1 = em_wi[64 * 128 + f1];
    float we65_0 = em_wi[65 * 128 + f0], we65_1 = em_wi[65 * 128 + f1];
    float gn0 = nm_g[f0], gn1 = nm_g[f1], bn0 = nm_be[f0], bn1 = nm_be[f1];
    float ge0 = em_g[f0], ge1 = em_g[f1], be0 = em_be[f0], be1 = em_be[f1];

#pragma unroll
    for (int r = 0; r < 8; r++) {
        int row = row0 + r, i = row & (NMAXC - 1);
        float px = pos_all[i * 2], py = pos_all[i * 2 + 1];
        float a0 = zn0 + px * wn64_0 + py * wn65_0;
        float a1 = zn1 + px * wn64_1 + py * wn65_1;
        float e0 = ze0 + px * we64_0 + py * we65_0;
        float e1 = ze1 + px * we64_1 + py * we65_1;
        float sm = a0 + a1, sq = a0 * a0 + a1 * a1;
        float sme = e0 + e1, sqe = e0 * e0 + e1 * e1;
#pragma unroll
        for (int d = 1; d < 64; d <<= 1) {
            sm += __shfl_xor(sm, d); sq += __shfl_xor(sq, d);
            sme += __shfl_xor(sme, d); sqe += __shfl_xor(sqe, d);
        }
        float mean = sm * (1.f / 128.f);
        float var = sq * (1.f / 128.f) - mean * mean;
        float rstd = rsqrtf(var + 1e-5f);
        int rl = wave * 8 + r;
        sn[rl][f0] = fmaxf((a0 - mean) * rstd * gn0 + bn0, 0.f);
        sn[rl][f1] = fmaxf((a1 - mean) * rstd * gn1 + bn1, 0.f);
        float meane = sme * (1.f / 128.f);
        float vare = sqe * (1.f / 128.f) - meane * meane;
        float rstde = rsqrtf(vare + 1e-5f);
        se[rl][f0] = fmaxf((e0 - meane) * rstde * ge0 + be0, 0.f);
        se[rl][f1] = fmaxf((e1 - meane) * rstde * ge1 + be1, 0.f);
    }
    __syncthreads();

    int rl = t >> 3, j = t & 7;
    float accn = 0.f, acce = 0.f;
#pragma unroll 8
    for (int k4 = 0; k4 < 128; k4 += 4) {
        float4 sv = *(const float4*)&sn[rl][k4];
        float4 wv = *(const float4*)&Wn[j][k4];
        float4 sev = *(const float4*)&se[rl][k4];
        float4 wev = *(const float4*)&We[j][k4];
        accn += sv.x * wv.x + sv.y * wv.y + sv.z * wv.z + sv.w * wv.w;
        acce += sev.x * wev.x + sev.y * wev.y + sev.z * wev.z + sev.w * wev.w;
    }
    int row = rowBase + rl;
    accn += bcn[j];
    if (j == 0)       out[OUT_NODES + row] = accn;
    else if (j <= 5)  out[OUT_FUEL + (size_t)row * 5 + (j - 1)] = accn;
    else if (j == 6)  out[OUT_ALT + row] = accn;
    else              out[OUT_SLOPE + row] = accn;
    out[OUT_EDGES + (size_t)row * 8 + j] = acce + em_bo[j];
}

extern "C" void kernel_launch(void* const* d_in, const int* in_sizes, int n_in,
                              void* d_out, int out_size, void* d_ws, size_t ws_size,
                              hipStream_t stream) {
    const float* x    = (const float*)d_in[0];
    const int* edge   = (const int*)d_in[1];
    const int* batch  = (const int*)d_in[2];
    const float* w1m = (const float*)d_in[3];  const float* b1m = (const float*)d_in[4];
    const float* w2m = (const float*)d_in[5];  const float* b2m = (const float*)d_in[6];
    const float* w3m = (const float*)d_in[7];  const float* b3m = (const float*)d_in[8];
    const float* w1l = (const float*)d_in[9];  const float* b1l = (const float*)d_in[10];
    const float* w2l = (const float*)d_in[11]; const float* b2l = (const float*)d_in[12];
    const float* w3l = (const float*)d_in[13]; const float* b3l = (const float*)d_in[14];
    const float* nm_wi = (const float*)d_in[15]; const float* nm_bi = (const float*)d_in[16];
    const float* nm_g  = (const float*)d_in[17]; const float* nm_be = (const float*)d_in[18];
    const float* nm_wo = (const float*)d_in[19]; const float* nm_bo = (const float*)d_in[20];
    const float* ex_w = (const float*)d_in[21]; const float* ex_b = (const float*)d_in[22];
    const float* fu_w = (const float*)d_in[23]; const float* fu_b = (const float*)d_in[24];
    const float* al_w = (const float*)d_in[25]; const float* al_b = (const float*)d_in[26];
    const float* sl_w = (const float*)d_in[27]; const float* sl_b = (const float*)d_in[28];
    const float* em_wi = (const float*)d_in[29]; const float* em_bi = (const float*)d_in[30];
    const float* em_g  = (const float*)d_in[31]; const float* em_be = (const float*)d_in[32];
    const float* em_wo = (const float*)d_in[33]; const float* em_bo = (const float*)d_in[34];
    const float* pos_all = (const float*)d_in[35];
    float* out = (float*)d_out;

    char* p = (char*)d_ws;
    auto alloc = [&](size_t bytes) -> void* {
        void* r = (void*)p;
        p += ((bytes + 255) / 256) * 256;
        return r;
    };
    int* cnt      = (int*)alloc((size_t)N_NODES * 4);
    int* offs     = (int*)alloc((size_t)N_NODES * 4);
    float* dinv   = (float*)alloc((size_t)N_NODES * 4);
    int* bcnt     = (int*)alloc(BATCH_B * 4);
    float* sums   = (float*)alloc(BATCH_B * 128 * 4);
    float* zwi_nm = (float*)alloc(BATCH_B * 128 * 4);
    float* zwi_em = (float*)alloc(BATCH_B * 128 * 4);
    float* bcat1  = (float*)alloc(128 * 4);
    float* bcat3  = (float*)alloc(128 * 4);
    float* wtn    = (float*)alloc(8 * 128 * 4);
    float* bcn    = (float*)alloc(8 * 4);
    float* wte    = (float*)alloc(8 * 128 * 4);
    unsigned int* wf1 = (unsigned int*)alloc((size_t)8 * 64 * 4 * 4);           // 8 KB
    unsigned int* wf2 = (unsigned int*)alloc((size_t)32 * 64 * 4 * 4);          // 32 KB
    unsigned int* wf3 = (unsigned int*)alloc((size_t)32 * 64 * 4 * 4);          // 32 KB
    int* hist     = (int*)alloc((size_t)NBINS * NSB * 4);                      // 400 KB
    int* total    = (int*)alloc((size_t)NBINS * 4);
    int* base     = (int*)alloc((size_t)(NBINS + 1) * 4);
    unsigned int* sorted = (unsigned int*)alloc((size_t)N_EDGESC * 4);         // 6.4 MB
    int* adj      = (int*)alloc((size_t)(N_EDGESC + NBINS * BIN_PAD + 256) * 4); // 7.7 MB compact
    unsigned int* xs8 = (unsigned int*)alloc((size_t)N_NODES * 8 * 4);         // 3.2 MB fp8
    unsigned short* agg0b = (unsigned short*)alloc((size_t)N_NODES * 32 * 2);  // 6.4 MB bf16
    unsigned int* hA8 = (unsigned int*)alloc((size_t)N_NODES * 32 * 4);        // 12.8 MB fp8 (also hD8)
    unsigned int* hB8 = (unsigned int*)alloc((size_t)N_NODES * 32 * 4);        // 12.8 MB fp8
    unsigned short* final128 = (unsigned short*)alloc((size_t)N_NODES * 128 * 2);  // 25.6 MB bf16
    unsigned int* hD8 = hA8;  // hA8 dead after agg #1

    const int* srcp = edge;
    const int* dstp = edge + N_EDGESC;

    hipMemsetAsync(sums, 0, (size_t)BATCH_B * 128 * 4, stream);

    // all small prep work in one kernel (independent of CSR chain)
    mega_prep<<<82, 256, 0, stream>>>(batch, w1m, w1l, b1m, b1l, b3m, b3l,
                                      w2m, w2l, w3m, w3l, nm_wo, nm_bo,
                                      ex_w, ex_b, fu_w, fu_b, al_w, al_b, sl_w, sl_b,
                                      em_wo, bcnt, bcat1, bcat3, wtn, bcn, wte,
                                      wf1, wf2, wf3);

    // ---- CSR build: atomic-free counting sort -> compact aligned CSR (+fused prescale) ----
    histA<<<NSB, 1024, 0, stream>>>(dstp, hist);
    scanB<<<NBINS, NSB, 0, stream>>>(hist, total);
    scanC<<<1, 512, 0, stream>>>(total, base);
    scatterD<<<NSB, 1024, 0, stream>>>(srcp, dstp, hist, base, sorted);
    csr_compact<<<NBINS, 256, 0, stream>>>(sorted, base, x, adj, offs, cnt, dinv, xs8, N_NODES);

    // agg0 = S x  (shared by both branches), fp8 table -> bf16 out
    agg_s32<<<(N_NODES + 31) / 32, 256, 0, stream>>>(xs8, cnt, offs, adj, dinv, agg0b, N_NODES);

    const int GB = (N_NODES + 63) / 64;  // 1563 row blocks

    // L1 (fused mu|lg): hA8 = fp8x32( dinv * relu(agg0 @ [w1m|w1l] + bcat1) )  [MFMA]
    mfma_conv1<<<GB, 256, 0, stream>>>(agg0b, wf1, bcat1, dinv, hA8, N_NODES);

    // agg #1: hB8 = fp8x32( [S mu1 | S lg1] )
    agg128<false, true><<<(N_NODES + 7) / 8, 256, 0, stream>>>(
        hA8, cnt, offs, adj, dinv, nullptr, hB8, N_NODES);

    // fused L2+L3: hD8 = fp8x32( dinv * ( relu(hB8@w2 + b2) @ w3 ) )  [MFMA, LDS mid]
    conv23<<<dim3(GB, 2), 256, 0, stream>>>(hB8, wf2, wf3, b2m, b2l, dinv, hD8, N_NODES);

    // agg #2: final = relu(dinv*(sum) + bcat3) = [mu3|lg3]  -> bf16 [n][128]
    agg128<true, false><<<(N_NODES + 7) / 8, 256, 0, stream>>>(
        hD8, cnt, offs, adj, dinv, bcat3, final128, N_NODES);

    pool128<<<GB, 256, 0, stream>>>((const unsigned int*)final128, batch, sums, N_NODES);
    finalize_zwi<<<BATCH_B, 128, 0, stream>>>(sums, bcnt, nm_wi, nm_bi, em_wi, em_bi,
                                              out, zwi_nm, zwi_em);

    decoder3<<<BATCH_B * NMAXC / D3_ROWS, 256, 0, stream>>>(
        zwi_nm, zwi_em, nm_wi, em_wi, nm_g, nm_be, em_g, em_be,
        wtn, bcn, wte, em_bo, pos_all, out);
}